// Round 2
// 981.871 us; speedup vs baseline: 1.1593x; 1.1593x over previous
//
#include <hip/hip_runtime.h>
#include <hip/hip_bf16.h>

// GCNEncoder — r18: isolate r17's two changes. KEEP the mid-QR drop (math:
// un-orthed 5-product chain has kappa(G) ~ 1e8-1e10, safe for f64 CholQR by
// 5+ orders); REVERT k_cholinv64 to the r16 harness-proven version (122us,
// register-resident factorization + per-thread column back-sub). r17's
// 1-barrier factorization + blocked inverse produced NaN (suspected race in
// the same-wave/double-buffer elisions) — retry later with race-screen.
// History: r16 1138us (2x cholinv); r15 1393us.

#define NN    4096
#define NEDG  131072
#define INC   512
#define HIDC  512
#define OUTC  64
#define RK    64
#define NDOM  4
#define EPSBN 1e-5f

static inline int cdiv(int a, int b){ return (a + b - 1) / b; }

// ---------------- input dtype detection (f32 vs bf16 carriers) ----------------
__global__ __launch_bounds__(256) void k_detect(const unsigned short* __restrict__ p,
                                                int* __restrict__ flag){
  int t = threadIdx.x;
  int cnt = 0;
  for (int i = t; i < 4096; i += 256){
    unsigned short v = p[2*i];
    int e = (v >> 7) & 0xFF;
    if (e >= 100 && e <= 140) cnt++;
  }
  __shared__ int sh[256];
  sh[t] = cnt; __syncthreads();
  for (int off = 128; off > 0; off >>= 1){ if (t < off) sh[t] += sh[t+off]; __syncthreads(); }
  if (t == 0) *flag = (sh[0] >= 2048) ? 0 : 1;
}

// ---------------- elementwise utils ----------------
__global__ __launch_bounds__(256) void k_upcast(const void* __restrict__ s,
                                                const int* __restrict__ isf32,
                                                float* __restrict__ d, int n){
  int i = blockIdx.x*256 + threadIdx.x;
  if (i >= n) return;
  if (*isf32) d[i] = ((const float*)s)[i];
  else        d[i] = __bfloat162float(((const __hip_bfloat16*)s)[i]);
}
__global__ __launch_bounds__(256) void k_fill(float* d, float v, int n){
  int i = blockIdx.x*256 + threadIdx.x;
  if (i < n) d[i] = v;
}
__global__ __launch_bounds__(256) void k_filli(int* d, int v, int n){
  int i = blockIdx.x*256 + threadIdx.x;
  if (i < n) d[i] = v;
}
__global__ __launch_bounds__(256) void k_filld(double* d, double v, int n){
  int i = blockIdx.x*256 + threadIdx.x;
  if (i < n) d[i] = v;
}
__global__ __launch_bounds__(256) void k_copy(const float* __restrict__ z,
                                              float* __restrict__ o, int n){
  int i = blockIdx.x*256 + threadIdx.x;
  if (i < n) o[i] = z[i];
}
__global__ __launch_bounds__(256) void k_f32to64(const float* __restrict__ s,
                                                 double* __restrict__ d, int n){
  int i = blockIdx.x*256 + threadIdx.x;
  if (i < n) d[i] = (double)s[i];
}
__global__ __launch_bounds__(256) void k_f64to32(const double* __restrict__ s,
                                                 float* __restrict__ d, int n){
  int i = blockIdx.x*256 + threadIdx.x;
  if (i < n) d[i] = (float)s[i];
}

// ---------------- graph preprocessing ----------------
__global__ __launch_bounds__(256) void k_hist(const int* __restrict__ row, const int* __restrict__ col,
                                              const float* __restrict__ w, float* deg,
                                              int* cntR, int* cntC){
  int e = blockIdx.x*256 + threadIdx.x;
  if (e < NEDG){
    atomicAdd(&deg[col[e]], w[e]);
    atomicAdd(&cntR[row[e]], 1);
    atomicAdd(&cntC[col[e]], 1);
  }
}
__global__ __launch_bounds__(256) void k_dinv(const float* deg, float* dinv, int n){
  int i = blockIdx.x*256 + threadIdx.x;
  if (i < n){ float d = deg[i]; dinv[i] = (d > 0.f) ? 1.f/sqrtf(d) : 0.f; }
}
__global__ __launch_bounds__(256) void k_norm1(const int* __restrict__ row, const int* __restrict__ col,
                                               const float* __restrict__ w, const float* __restrict__ dinv,
                                               float* __restrict__ nrm){
  int e = blockIdx.x*256 + threadIdx.x;
  if (e < NEDG) nrm[e] = dinv[row[e]] * w[e] * dinv[col[e]];
}
__global__ __launch_bounds__(1024) void k_scan4096(const int* __restrict__ cnt,
                                                   int* __restrict__ ptr, int* __restrict__ pos){
  __shared__ int sh[1024];
  int t = threadIdx.x;
  int b = t*4;
  int a0 = cnt[b], a1 = cnt[b+1], a2 = cnt[b+2], a3 = cnt[b+3];
  sh[t] = a0 + a1 + a2 + a3;
  __syncthreads();
  for (int off = 1; off < 1024; off <<= 1){
    int v = (t >= off) ? sh[t-off] : 0;
    __syncthreads();
    sh[t] += v;
    __syncthreads();
  }
  int excl = (t == 0) ? 0 : sh[t-1];
  ptr[b]   = excl;            pos[b]   = excl;
  ptr[b+1] = excl+a0;         pos[b+1] = excl+a0;
  ptr[b+2] = excl+a0+a1;      pos[b+2] = excl+a0+a1;
  ptr[b+3] = excl+a0+a1+a2;   pos[b+3] = excl+a0+a1+a2;
  if (t == 1023) ptr[4096] = sh[1023];
}
__global__ __launch_bounds__(256) void k_scatter(const int* __restrict__ row, const int* __restrict__ col,
                                                 int* posR, int* posC, int* eidR, int* eidC){
  int e = blockIdx.x*256 + threadIdx.x;
  if (e < NEDG){
    int p = atomicAdd(&posR[row[e]], 1); eidR[p] = e;
    int q = atomicAdd(&posC[col[e]], 1); eidC[q] = e;
  }
}
__global__ __launch_bounds__(256) void k_dcnt(const int* __restrict__ y, int* dcnt){
  int i = blockIdx.x*256 + threadIdx.x;
  if (i < NN) atomicAdd(&dcnt[y[i]], 1);
}

// ---------------- threefry2x32 core (KAT-verified round 8) ----------------
__device__ __forceinline__ unsigned rotl32(unsigned x, unsigned d){ return (x << d) | (x >> (32u - d)); }
#define TF_ROUND4(R0,R1,R2,R3) \
  x0 += x1; x1 = rotl32(x1,R0); x1 ^= x0; \
  x0 += x1; x1 = rotl32(x1,R1); x1 ^= x0; \
  x0 += x1; x1 = rotl32(x1,R2); x1 ^= x0; \
  x0 += x1; x1 = rotl32(x1,R3); x1 ^= x0;

__device__ __forceinline__ void tf2x32(unsigned k0, unsigned k1, unsigned c0, unsigned c1,
                                       unsigned* o0, unsigned* o1){
  unsigned ks2 = 0x1BD11BDAu ^ k0 ^ k1;
  unsigned x0 = c0 + k0, x1 = c1 + k1;
  TF_ROUND4(13,15,26,6);   x0 += k1;  x1 += ks2 + 1u;
  TF_ROUND4(17,29,16,24);  x0 += ks2; x1 += k0 + 2u;
  TF_ROUND4(13,15,26,6);   x0 += k0;  x1 += k1 + 3u;
  TF_ROUND4(17,29,16,24);  x0 += k1;  x1 += ks2 + 4u;
  TF_ROUND4(13,15,26,6);   x0 += ks2; x1 += k0 + 5u;
  *o0 = x0; *o1 = x1;
}

// ---------------- omega (verified round 10) ----------------
__device__ double erfinv64(double x){
  double w = -log1p(-x*x);
  double p;
  if (w < 5.0){
    w -= 2.5;
    p = 2.81022636e-08;  p = p*w + 3.43273939e-07; p = p*w - 3.5233877e-06;
    p = p*w - 4.39150654e-06; p = p*w + 0.00021858087; p = p*w - 0.00125372503;
    p = p*w - 0.00417768164;  p = p*w + 0.246640727;   p = p*w + 1.50140941;
  } else {
    w = sqrt(w) - 3.0;
    p = -0.000200214257; p = p*w + 0.000100950558; p = p*w + 0.00134934322;
    p = p*w - 0.00367342844; p = p*w + 0.00573950773; p = p*w - 0.0076224613;
    p = p*w + 0.00943887047; p = p*w + 1.00167406;    p = p*w + 2.83297682;
  }
  double y = p * x;
  const double c = 1.1283791670955126;   // 2/sqrt(pi)
  #pragma unroll
  for (int it = 0; it < 3; it++){
    double err = erf(y) - x;
    y -= err / (c * exp(-y*y));
  }
  return y;
}

__device__ float bits_to_normal(unsigned b){
  float f = __uint_as_float((b >> 9) | 0x3f800000u) - 1.0f;
  const float lo = -0.99999994f;               // nextafter(-1,0) in f32
  float x = fmaxf(lo, f * 2.0f + lo);
  double r = 1.4142135623730951 * erfinv64((double)x);
  return (float)r;
}

__global__ __launch_bounds__(256) void k_omega(float* __restrict__ om){
  int i = blockIdx.x*256 + threadIdx.x;
  if (i >= 262144) return;
  unsigned o0, o1;
  tf2x32(0u, 42u, 0u, (unsigned)i, &o0, &o1);   // counter = (0, i)
  om[i] = bits_to_normal(o0 ^ o1);              // partitionable: bits1 ^ bits2
}

// ---------------- GEMM (fp32, tiled 64x64, 4x4/thread) ----------------
__global__ __launch_bounds__(256) void k_gemm_nn(int M, int Nn, int K,
      const float* __restrict__ A, int lda, const float* __restrict__ B, int ldb,
      float* __restrict__ Cc, int ldc, const float* __restrict__ rowscale,
      const float* __restrict__ kscale, const float* __restrict__ bias){
  __shared__ float As[16][65];
  __shared__ float Bs[16][65];
  int bm = blockIdx.y*64, bn = blockIdx.x*64;
  int t = threadIdx.x;
  int tr = t >> 4, tc = t & 15;
  float acc[4][4] = {};
  for (int k0 = 0; k0 < K; k0 += 16){
    #pragma unroll
    for (int q = 0; q < 4; q++){
      int idx = t*4 + q;
      int m = idx >> 4, kk = idx & 15;
      As[kk][m] = A[(size_t)(bm+m)*lda + (k0+kk)];
    }
    #pragma unroll
    for (int q = 0; q < 4; q++){
      int idx = t + q*256;
      int kk = idx >> 6, n = idx & 63;
      float ks = kscale ? kscale[k0+kk] : 1.0f;
      Bs[kk][n] = B[(size_t)(k0+kk)*ldb + (bn+n)] * ks;
    }
    __syncthreads();
    #pragma unroll
    for (int kk = 0; kk < 16; kk++){
      float a0 = As[kk][tr*4+0], a1 = As[kk][tr*4+1], a2 = As[kk][tr*4+2], a3 = As[kk][tr*4+3];
      float b0 = Bs[kk][tc*4+0], b1 = Bs[kk][tc*4+1], b2 = Bs[kk][tc*4+2], b3 = Bs[kk][tc*4+3];
      acc[0][0] += a0*b0; acc[0][1] += a0*b1; acc[0][2] += a0*b2; acc[0][3] += a0*b3;
      acc[1][0] += a1*b0; acc[1][1] += a1*b1; acc[1][2] += a1*b2; acc[1][3] += a1*b3;
      acc[2][0] += a2*b0; acc[2][1] += a2*b1; acc[2][2] += a2*b2; acc[2][3] += a2*b3;
      acc[3][0] += a3*b0; acc[3][1] += a3*b1; acc[3][2] += a3*b2; acc[3][3] += a3*b3;
    }
    __syncthreads();
  }
  #pragma unroll
  for (int i2 = 0; i2 < 4; i2++){
    int m = bm + tr*4 + i2;
    float rs = rowscale ? rowscale[m] : 1.0f;
    #pragma unroll
    for (int j2 = 0; j2 < 4; j2++){
      int n = bn + tc*4 + j2;
      float v = acc[i2][j2] * rs;
      if (bias) v += bias[n];
      Cc[(size_t)m*ldc + n] = v;
    }
  }
}

// split-K NN: C += partial (C pre-zeroed); grid (Nn/64, M/64, K/kchunk)
__global__ __launch_bounds__(256) void k_gemm_nn_sk(int M, int Nn, int K, int kchunk,
      const float* __restrict__ A, int lda, const float* __restrict__ B, int ldb,
      float* __restrict__ Cc, int ldc){
  __shared__ float As[16][65];
  __shared__ float Bs[16][65];
  int bm = blockIdx.y*64, bn = blockIdx.x*64;
  int kb = blockIdx.z*kchunk, ke = kb + kchunk;
  int t = threadIdx.x;
  int tr = t >> 4, tc = t & 15;
  float acc[4][4] = {};
  for (int k0 = kb; k0 < ke; k0 += 16){
    #pragma unroll
    for (int q = 0; q < 4; q++){
      int idx = t*4 + q;
      int m = idx >> 4, kk = idx & 15;
      As[kk][m] = A[(size_t)(bm+m)*lda + (k0+kk)];
    }
    #pragma unroll
    for (int q = 0; q < 4; q++){
      int idx = t + q*256;
      int kk = idx >> 6, n = idx & 63;
      Bs[kk][n] = B[(size_t)(k0+kk)*ldb + (bn+n)];
    }
    __syncthreads();
    #pragma unroll
    for (int kk = 0; kk < 16; kk++){
      float a0 = As[kk][tr*4+0], a1 = As[kk][tr*4+1], a2 = As[kk][tr*4+2], a3 = As[kk][tr*4+3];
      float b0 = Bs[kk][tc*4+0], b1 = Bs[kk][tc*4+1], b2 = Bs[kk][tc*4+2], b3 = Bs[kk][tc*4+3];
      acc[0][0] += a0*b0; acc[0][1] += a0*b1; acc[0][2] += a0*b2; acc[0][3] += a0*b3;
      acc[1][0] += a1*b0; acc[1][1] += a1*b1; acc[1][2] += a1*b2; acc[1][3] += a1*b3;
      acc[2][0] += a2*b0; acc[2][1] += a2*b1; acc[2][2] += a2*b2; acc[2][3] += a2*b3;
      acc[3][0] += a3*b0; acc[3][1] += a3*b1; acc[3][2] += a3*b2; acc[3][3] += a3*b3;
    }
    __syncthreads();
  }
  #pragma unroll
  for (int i2 = 0; i2 < 4; i2++){
    int m = bm + tr*4 + i2;
    #pragma unroll
    for (int j2 = 0; j2 < 4; j2++){
      int n = bn + tc*4 + j2;
      atomicAdd(&Cc[(size_t)m*ldc + n], acc[i2][j2]);
    }
  }
}

// split-K TN: C += partial (C pre-zeroed); grid (Nn/16, M/16, K/kchunk)
__global__ __launch_bounds__(256) void k_gemm_tn_sk(int M, int Nn, int K, int kchunk,
      const float* __restrict__ A, int lda, const float* __restrict__ B, int ldb,
      float* __restrict__ Cc, int ldc, const float* __restrict__ kscale){
  __shared__ float As[32][17];
  __shared__ float Bs[32][17];
  int bm = blockIdx.y*16, bn = blockIdx.x*16;
  int kb = blockIdx.z*kchunk, ke = kb + kchunk;
  int t = threadIdx.x;
  int tm = t >> 4, tn = t & 15;
  float acc = 0.f;
  for (int k0 = kb; k0 < ke; k0 += 32){
    #pragma unroll
    for (int q = 0; q < 2; q++){
      int idx = t + q*256;
      int kk = idx >> 4, m = idx & 15;
      float sv = kscale ? kscale[k0+kk] : 1.0f;
      As[kk][m] = A[(size_t)(k0+kk)*lda + (bm+m)] * sv;
      Bs[kk][m] = B[(size_t)(k0+kk)*ldb + (bn+m)];
    }
    __syncthreads();
    #pragma unroll
    for (int kk = 0; kk < 32; kk++) acc += As[kk][tm] * Bs[kk][tn];
    __syncthreads();
  }
  atomicAdd(&Cc[(size_t)(bm+tm)*ldc + (bn+tn)], acc);
}

// ---------------- f64 randomized-subspace chain ----------------
__global__ __launch_bounds__(64) void k_spmm64(const int* __restrict__ ptr, const int* __restrict__ eid,
                       const int* __restrict__ oidx, const float* __restrict__ coef,
                       const double* __restrict__ X, double* __restrict__ Y){
  int seg = blockIdx.x;
  int t = threadIdx.x;
  double acc = 0.0;
  int p0 = ptr[seg], p1 = ptr[seg+1];
  for (int p = p0; p < p1; ++p){
    int e = eid[p];
    acc += (double)coef[e] * X[(size_t)oidx[e]*RK + t];
  }
  Y[(size_t)seg*RK + t] = acc;
}
// Gram: G += Xslice^T Xslice over 64-row slices (G zeroed before)
__global__ __launch_bounds__(256) void k_gram64(const double* __restrict__ X, double* __restrict__ G){
  __shared__ double Xs[64][65];
  int b = blockIdx.x;
  int t = threadIdx.x;
  #pragma unroll
  for (int q = 0; q < 16; q++){
    int idx = t + q*256;
    Xs[idx >> 6][idx & 63] = X[(size_t)(b*64 + (idx >> 6))*RK + (idx & 63)];
  }
  __syncthreads();
  int i = t >> 2;
  int j0 = (t & 3) * 16;
  double acc[16];
  #pragma unroll
  for (int jj = 0; jj < 16; jj++) acc[jj] = 0.0;
  for (int k = 0; k < 64; k++){
    double a = Xs[k][i];
    #pragma unroll
    for (int jj = 0; jj < 16; jj++) acc[jj] += a * Xs[k][j0+jj];
  }
  #pragma unroll
  for (int jj = 0; jj < 16; jj++) atomicAdd(&G[i*RK + j0 + jj], acc[jj]);
}
// Cholesky + upper-tri inverse, f64 (r16, harness-proven): register-resident
// factorization + per-thread column back-substitution — NO shuffles, NO
// barriers in the solve; thread c keeps x in its own LDS column.
__global__ __launch_bounds__(256) void k_cholinv64(const double* __restrict__ G, double* __restrict__ Rinv){
  __shared__ double colk[64];
  __shared__ double sdinv[64];
  __shared__ double gl[64][65];
  __shared__ double Xc[64][65];
  int t = threadIdx.x;
  int wv = t >> 6, lane = t & 63;
  int j = lane;                   // owned column
  double r[16];                   // rows i = 4q + wv
  #pragma unroll
  for (int q = 0; q < 16; q++)
    r[q] = G[(size_t)(((q << 2) + wv) << 6) + j];
  for (int k = 0; k < 64; k++){
    int kq = k >> 2, kw = k & 3;
    if (wv == kw && j == k){
      double d = sqrt(fmax(r[kq], 1e-300));
      r[kq] = d;
      sdinv[k] = 1.0 / d;
    }
    __syncthreads();
    if (j == k){
      double di = sdinv[k];
      #pragma unroll
      for (int q = 0; q < 16; q++){
        int i = (q << 2) + wv;
        if (i > k){ r[q] *= di; colk[i] = r[q]; }
      }
    }
    __syncthreads();
    if (j > k){
      double cj = colk[j];
      #pragma unroll
      for (int q = 0; q < 16; q++){
        int i = (q << 2) + wv;
        if (i >= j) r[q] -= colk[i] * cj;   // i >= j > k
      }
    }
    __syncthreads();
  }
  // dump L to LDS for back-substitution
  #pragma unroll
  for (int q = 0; q < 16; q++)
    gl[(q << 2) + wv][j] = r[q];
  __syncthreads();
  // back-sub: thread c (< 64) solves R x = e_c; R[i][k] = L[k][i] = gl[k][i].
  // x lives in Xc[.][c] (own column) — no cross-thread deps, no barriers.
  if (t < 64){
    int c = t;
    Xc[c][c] = sdinv[c];
    for (int i = c - 1; i >= 0; i--){
      double s0 = 0.0, s1 = 0.0, s2 = 0.0, s3 = 0.0;
      int k = i + 1;
      for (; k + 3 <= c; k += 4){
        s0 += gl[k  ][i] * Xc[k  ][c];
        s1 += gl[k+1][i] * Xc[k+1][c];
        s2 += gl[k+2][i] * Xc[k+2][c];
        s3 += gl[k+3][i] * Xc[k+3][c];
      }
      for (; k <= c; k++) s0 += gl[k][i] * Xc[k][c];
      Xc[i][c] = -((s0 + s1) + (s2 + s3)) * sdinv[i];
    }
    for (int i = 0; i < 64; i++)
      Rinv[i*64 + c] = (i <= c) ? Xc[i][c] : 0.0;
  }
}
// dst[NNx64] = src[NNx64] * Rinv(upper); 4 rows per 256-thread block
__global__ __launch_bounds__(256) void k_applyR64(const double* __restrict__ src,
      const double* __restrict__ Rinv, double* __restrict__ dst){
  __shared__ double Rs[64][65];
  int t = threadIdx.x;
  #pragma unroll
  for (int q = 0; q < 16; q++){
    int idx = t + q*256;
    Rs[idx >> 6][idx & 63] = Rinv[idx];
  }
  __syncthreads();
  int r = blockIdx.x*4 + (t >> 6);
  int j = t & 63;
  const double* rowp = src + (size_t)r*RK;
  double s = 0.0;
  for (int k = 0; k <= j; k++) s += rowp[k] * Rs[k][j];
  dst[(size_t)r*RK + j] = s;
}
__global__ __launch_bounds__(256) void k_qsum64(const double* __restrict__ Q, double* __restrict__ qs){
  int j = blockIdx.x;  int t = threadIdx.x;
  double a = 0.0;
  for (int n = t; n < NN; n += 256) a += Q[(size_t)n*RK + j];
  __shared__ double sh[256];
  sh[t] = a; __syncthreads();
  for (int off = 128; off > 0; off >>= 1){ if (t < off) sh[t] += sh[t+off]; __syncthreads(); }
  if (t == 0) qs[j] = sh[0];
}
__global__ __launch_bounds__(256) void k_deg2f(const double* __restrict__ C, const double* __restrict__ qs,
                                               float* __restrict__ dinv2){
  int i = blockIdx.x*256 + threadIdx.x;
  if (i >= NN) return;
  double s = 0.0;
  #pragma unroll
  for (int k = 0; k < RK; k++) s += C[(size_t)i*RK + k] * qs[k];
  dinv2[i] = (s > 0.0) ? (float)(1.0/sqrt(s)) : 0.f;
}

// ---------------- SpMM over sorted edge lists (f32, branch 1) ----------------
__global__ void k_spmm(const int* __restrict__ ptr, const int* __restrict__ eid,
                       const int* __restrict__ oidx, const float* __restrict__ coef,
                       const float* __restrict__ X, int ldx,
                       float* __restrict__ Y, int ldy, int F,
                       const float* __restrict__ self_dinv, const float* __restrict__ bias){
  int seg = blockIdx.x;
  int t = threadIdx.x, bd = blockDim.x;
  int f1 = t + bd;
  bool two = (f1 < F);
  float acc0 = 0.f, acc1 = 0.f;
  if (self_dinv){
    float sd = self_dinv[seg]; float s2 = sd*sd;
    acc0 = s2 * X[(size_t)seg*ldx + t];
    if (two) acc1 = s2 * X[(size_t)seg*ldx + f1];
  }
  int p0 = ptr[seg], p1 = ptr[seg+1];
  for (int p = p0; p < p1; ++p){
    int e = eid[p];
    int o = oidx[e];
    float c = coef[e];
    const float* xr = X + (size_t)o*ldx;
    acc0 += c * xr[t];
    if (two) acc1 += c * xr[f1];
  }
  if (bias){ acc0 += bias[t]; if (two) acc1 += bias[f1]; }
  Y[(size_t)seg*ldy + t] = acc0;
  if (two) Y[(size_t)seg*ldy + f1] = acc1;
}

// ---------------- domain-specific BN ----------------
__global__ __launch_bounds__(256) void k_bnstats(const float* __restrict__ H, const int* __restrict__ y,
        const int* __restrict__ dcnt, const float* __restrict__ gamma, const float* __restrict__ beta,
        float* __restrict__ scal, float* __restrict__ shft){
  int j = blockIdx.x;
  int t = threadIdx.x;
  float s0=0,s1=0,s2=0,s3=0,q0=0,q1=0,q2=0,q3=0;
  for (int n = t; n < NN; n += 256){
    float v = H[(size_t)n*HIDC + j];
    int d = y[n];
    float v2 = v*v;
    if      (d == 0){ s0 += v; q0 += v2; }
    else if (d == 1){ s1 += v; q1 += v2; }
    else if (d == 2){ s2 += v; q2 += v2; }
    else            { s3 += v; q3 += v2; }
  }
  __shared__ float sh[256][8];
  sh[t][0]=s0; sh[t][1]=s1; sh[t][2]=s2; sh[t][3]=s3;
  sh[t][4]=q0; sh[t][5]=q1; sh[t][6]=q2; sh[t][7]=q3;
  __syncthreads();
  for (int off = 128; off > 0; off >>= 1){
    if (t < off){
      #pragma unroll
      for (int q = 0; q < 8; q++) sh[t][q] += sh[t+off][q];
    }
    __syncthreads();
  }
  if (t < NDOM){
    float cnt  = fmaxf((float)dcnt[t], 1.0f);
    float mean = sh[0][t] / cnt;
    float var  = fmaxf(sh[0][4+t] / cnt - mean*mean, 0.f);
    float inv  = 1.0f / sqrtf(var + EPSBN);
    float gmm  = gamma[t*HIDC + j];
    scal[t*HIDC + j] = gmm * inv;
    shft[t*HIDC + j] = beta[t*HIDC + j] - mean * gmm * inv;
  }
}
__global__ __launch_bounds__(256) void k_bnapply(float* __restrict__ H, const int* __restrict__ y,
        const float* __restrict__ scal, const float* __restrict__ shft){
  int idx = blockIdx.x*256 + threadIdx.x;
  if (idx >= NN*HIDC) return;
  int n = idx >> 9, j = idx & (HIDC-1);
  int d = y[n];
  float v = H[idx] * scal[d*HIDC + j] + shft[d*HIDC + j];
  H[idx] = v > 0.f ? v : 0.f;
}

// ---------------- launch ----------------
extern "C" void kernel_launch(void* const* d_in, const int* in_sizes, int n_in,
                              void* d_out, int out_size, void* d_ws, size_t ws_size,
                              hipStream_t stream){
  (void)in_sizes; (void)n_in; (void)out_size;
  const void* x_in  = d_in[0];
  const int*  ei    = (const int*)d_in[1];
  const void* w_in  = d_in[2];
  const int*  yv    = (const int*)d_in[3];
  const void* W1i   = d_in[4];
  const void* b1i   = d_in[5];
  const void* Wmui  = d_in[6];
  const void* bmui  = d_in[7];
  const void* Wlvi  = d_in[8];
  const void* blvi  = d_in[9];
  const void* gmi   = d_in[10];
  const void* bti   = d_in[11];
  const int* rowA = ei;
  const int* colA = ei + NEDG;

  // ---- workspace: doubles | floats | ints (~38 MB) ----
  double* Dp = (double*)d_ws;
  size_t od = 0;
  double* Qd0 = Dp + od; od += (size_t)NN*RK;
  double* Qd1 = Dp + od; od += (size_t)NN*RK;
  double* Cd  = Dp + od; od += (size_t)NN*RK;
  double* Gd  = Dp + od; od += RK*RK;
  double* Rid = Dp + od; od += RK*RK;
  double* qsd = Dp + od; od += RK;
  float* Fp = (float*)(Dp + od);
  size_t o = 0;
  float* xf   = Fp + o; o += (size_t)NN*INC;       // reused as h1/h2 buffer
  float* W1f  = Fp + o; o += (size_t)INC*HIDC;
  float* b1f  = Fp + o; o += HIDC;
  float* Wmuf = Fp + o; o += (size_t)HIDC*OUTC;
  float* bmuf = Fp + o; o += OUTC;
  float* Wlvf = Fp + o; o += (size_t)HIDC*OUTC;
  float* blvf = Fp + o; o += OUTC;
  float* gmf  = Fp + o; o += NDOM*HIDC;
  float* btf  = Fp + o; o += NDOM*HIDC;
  float* wf   = Fp + o; o += NEDG;
  float* xw1  = Fp + o; o += (size_t)NN*HIDC;
  float* hwA  = Fp + o; o += (size_t)NN*OUTC;
  float* hwB  = Fp + o; o += (size_t)NN*OUTC;     // contiguous after hwA
  float* Bf0  = Fp + o; o += (size_t)NN*RK;        // omega (f32)
  float* Bf1  = Fp + o; o += (size_t)NN*RK;        // Qb (f32)
  float* Cm   = Fp + o; o += (size_t)NN*RK;        // C (f32)
  float* Tm   = Fp + o; o += (size_t)RK*HIDC;
  float* Umu  = Fp + o; o += RK*RK;
  float* deg1 = Fp + o; o += NN;
  float* dinv1= Fp + o; o += NN;
  float* dinv2= Fp + o; o += NN;
  float* norm1= Fp + o; o += NEDG;
  float* scal = Fp + o; o += NDOM*HIDC;
  float* shft = Fp + o; o += NDOM*HIDC;
  float* zb   = Fp + o; o += (size_t)4*NN*OUTC;
  int* Ip = (int*)(Fp + o);
  size_t oi = 0;
  int* cntR = Ip + oi; oi += NN;
  int* ptrR = Ip + oi; oi += NN + 1;
  int* posR = Ip + oi; oi += NN;
  int* eidR = Ip + oi; oi += NEDG;
  int* cntC = Ip + oi; oi += NN;
  int* ptrC = Ip + oi; oi += NN + 1;
  int* posC = Ip + oi; oi += NN;
  int* eidC = Ip + oi; oi += NEDG;
  int* dcnt = Ip + oi; oi += NDOM;
  int* dflag= Ip + oi; oi += 1;

  size_t need = od*sizeof(double) + o*sizeof(float) + (oi+16)*sizeof(int);
  if (ws_size < need) return;

  float* hbuf = xf;  // x dead after xw1 GEMM

  const int T = 256;
  k_detect<<<1,T,0,stream>>>((const unsigned short*)x_in, dflag);
  k_upcast<<<cdiv(NN*INC,T),T,0,stream>>>(x_in, dflag, xf, NN*INC);
  k_upcast<<<cdiv(INC*HIDC,T),T,0,stream>>>(W1i, dflag, W1f, INC*HIDC);
  k_upcast<<<cdiv(HIDC,T),T,0,stream>>>(b1i, dflag, b1f, HIDC);
  k_upcast<<<cdiv(HIDC*OUTC,T),T,0,stream>>>(Wmui, dflag, Wmuf, HIDC*OUTC);
  k_upcast<<<1,T,0,stream>>>(bmui, dflag, bmuf, OUTC);
  k_upcast<<<cdiv(HIDC*OUTC,T),T,0,stream>>>(Wlvi, dflag, Wlvf, HIDC*OUTC);
  k_upcast<<<1,T,0,stream>>>(blvi, dflag, blvf, OUTC);
  k_upcast<<<cdiv(NDOM*HIDC,T),T,0,stream>>>(gmi, dflag, gmf, NDOM*HIDC);
  k_upcast<<<cdiv(NDOM*HIDC,T),T,0,stream>>>(bti, dflag, btf, NDOM*HIDC);
  k_upcast<<<cdiv(NEDG,T),T,0,stream>>>(w_in, dflag, wf, NEDG);

  k_fill <<<cdiv(NN,T),T,0,stream>>>(deg1, 1.0f, NN);   // self-loop weight 1
  k_filli<<<cdiv(NN,T),T,0,stream>>>(cntR, 0, NN);
  k_filli<<<cdiv(NN,T),T,0,stream>>>(cntC, 0, NN);
  k_filli<<<1,T,0,stream>>>(dcnt, 0, NDOM);
  k_hist <<<cdiv(NEDG,T),T,0,stream>>>(rowA, colA, wf, deg1, cntR, cntC);
  k_dinv <<<cdiv(NN,T),T,0,stream>>>(deg1, dinv1, NN);
  k_norm1<<<cdiv(NEDG,T),T,0,stream>>>(rowA, colA, wf, dinv1, norm1);
  k_scan4096<<<1,1024,0,stream>>>(cntR, ptrR, posR);
  k_scan4096<<<1,1024,0,stream>>>(cntC, ptrC, posC);
  k_scatter<<<cdiv(NEDG,T),T,0,stream>>>(rowA, colA, posR, posC, eidR, eidC);
  k_omega<<<cdiv(262144,T),T,0,stream>>>(Bf0);
  k_dcnt <<<cdiv(NN,T),T,0,stream>>>(yv, dcnt);

  // ---- branch 1 (verified) ----
  k_gemm_nn<<<dim3(HIDC/64, NN/64),256,0,stream>>>(NN,HIDC,INC, xf,INC, W1f,HIDC, xw1,HIDC, nullptr,nullptr,nullptr);
  k_spmm<<<NN,256,0,stream>>>(ptrC,eidC,rowA,norm1, xw1,HIDC, hbuf,HIDC, HIDC, dinv1, b1f);
  k_bnstats<<<HIDC,256,0,stream>>>(hbuf, yv, dcnt, gmf, btf, scal, shft);
  k_bnapply<<<cdiv(NN*HIDC,T),T,0,stream>>>(hbuf, yv, scal, shft);
  k_fill<<<cdiv(2*NN*OUTC,T),T,0,stream>>>(hwA, 0.f, 2*NN*OUTC);   // hwA|hwB contiguous
  k_gemm_nn_sk<<<dim3(1, NN/64, 4),256,0,stream>>>(NN,OUTC,HIDC,128, hbuf,HIDC, Wmuf,OUTC, hwA,OUTC);
  k_gemm_nn_sk<<<dim3(1, NN/64, 4),256,0,stream>>>(NN,OUTC,HIDC,128, hbuf,HIDC, Wlvf,OUTC, hwB,OUTC);
  k_spmm<<<NN,64,0,stream>>>(ptrC,eidC,rowA,norm1, hwA,OUTC, zb + 0*NN*OUTC,OUTC, OUTC, dinv1, bmuf);
  k_spmm<<<NN,64,0,stream>>>(ptrC,eidC,rowA,norm1, hwB,OUTC, zb + 1*NN*OUTC,OUTC, OUTC, dinv1, blvf);

  // ---- branch 2: f64 subspace, single final QR1 (mid QR dropped) ----
  auto spmmA64 = [&](const double* s, double* d){   // d = A @ s
    k_spmm64<<<NN,64,0,stream>>>(ptrR,eidR,colA,wf, s, d);
  };
  auto spmmAT64 = [&](const double* s, double* d){  // d = A^T @ s
    k_spmm64<<<NN,64,0,stream>>>(ptrC,eidC,rowA,wf, s, d);
  };
  auto orth164 = [&](double* src, double* dst){     // dst = src * R^{-1}
    k_filld<<<cdiv(RK*RK,T),T,0,stream>>>(Gd, 0.0, RK*RK);
    k_gram64<<<NN/64,256,0,stream>>>(src, Gd);
    k_cholinv64<<<1,256,0,stream>>>(Gd, Rid);
    k_applyR64<<<NN/4,256,0,stream>>>(src, Rid, dst);
  };

  k_f32to64<<<cdiv(NN*RK,T),T,0,stream>>>(Bf0, Qd0, NN*RK);
  spmmA64 (Qd0, Qd1);                      // P1 -> Qd1
  spmmAT64(Qd1, Qd0);                      // P2 -> Qd0
  spmmA64 (Qd0, Qd1);                      // P3 -> Qd1
  spmmAT64(Qd1, Qd0);                      // P4 -> Qd0
  spmmA64 (Qd0, Qd1);                      // P5 -> Qd1 (f64: kappa(G)~1e8-1e10 ok)
  orth164(Qd1, Qd0);                       // final QR1 -> Qb in Qd0
  spmmAT64(Qd0, Cd);                       // C = A^T Qb  (A2 = Qb C^T)
  k_qsum64<<<RK,256,0,stream>>>(Qd0, qsd);
  k_deg2f<<<cdiv(NN,T),T,0,stream>>>(Cd, qsd, dinv2);
  k_f64to32<<<cdiv(NN*RK,T),T,0,stream>>>(Qd0, Bf1, NN*RK);
  k_f64to32<<<cdiv(NN*RK,T),T,0,stream>>>(Cd,  Cm,  NN*RK);

  // h2 = dsbn_relu( D C (Qb^T (D xw1)) + b1 )
  k_fill<<<cdiv(RK*HIDC,T),T,0,stream>>>(Tm, 0.f, RK*HIDC);
  k_gemm_tn_sk<<<dim3(HIDC/16, RK/16, 8),256,0,stream>>>(RK,HIDC,NN,512, Bf1,RK, xw1,HIDC, Tm,HIDC, dinv2);
  k_gemm_nn<<<dim3(HIDC/64, NN/64),256,0,stream>>>(NN,HIDC,RK, Cm,RK, Tm,HIDC, hbuf,HIDC, dinv2, nullptr, b1f);
  k_bnstats<<<HIDC,256,0,stream>>>(hbuf, yv, dcnt, gmf, btf, scal, shft);
  k_bnapply<<<cdiv(NN*HIDC,T),T,0,stream>>>(hbuf, yv, scal, shft);
  // z2 = D C (Qb^T (D (h2 W))) + b
  k_fill<<<cdiv(2*NN*OUTC,T),T,0,stream>>>(hwA, 0.f, 2*NN*OUTC);
  k_gemm_nn_sk<<<dim3(1, NN/64, 4),256,0,stream>>>(NN,OUTC,HIDC,128, hbuf,HIDC, Wmuf,OUTC, hwA,OUTC);
  k_gemm_nn_sk<<<dim3(1, NN/64, 4),256,0,stream>>>(NN,OUTC,HIDC,128, hbuf,HIDC, Wlvf,OUTC, hwB,OUTC);
  k_fill<<<cdiv(RK*RK,T),T,0,stream>>>(Umu, 0.f, RK*RK);
  k_gemm_tn_sk<<<dim3(RK/16, RK/16, 16),256,0,stream>>>(RK,RK,NN,256, Bf1,RK, hwA,OUTC, Umu,RK, dinv2);
  k_gemm_nn<<<dim3(1, NN/64),256,0,stream>>>(NN,OUTC,RK, Cm,RK, Umu,RK, zb + 2*NN*OUTC,OUTC, dinv2, nullptr, bmuf);
  k_fill<<<cdiv(RK*RK,T),T,0,stream>>>(Umu, 0.f, RK*RK);
  k_gemm_tn_sk<<<dim3(RK/16, RK/16, 16),256,0,stream>>>(RK,RK,NN,256, Bf1,RK, hwB,OUTC, Umu,RK, dinv2);
  k_gemm_nn<<<dim3(1, NN/64),256,0,stream>>>(NN,OUTC,RK, Cm,RK, Umu,RK, zb + 3*NN*OUTC,OUTC, dinv2, nullptr, blvf);

  // outputs -> f32
  k_copy<<<cdiv(4*NN*OUTC,T),T,0,stream>>>(zb, (float*)d_out, 4*NN*OUTC);
}

// Round 3
// 942.784 us; speedup vs baseline: 1.2074x; 1.0415x over previous
//
#include <hip/hip_runtime.h>
#include <hip/hip_bf16.h>

// GCNEncoder — r19: r18 (982us, passing) + blocked triangular inverse in
// k_cholinv64. Factorization kept VERBATIM from r16 (harness-proven, 3
// barriers/iter). Only the back-sub is replaced: 4 independent 16x16 diag
// column-solves (one wave, no cross-thread deps) + 3 barrier-separated
// superdiagonal rounds of 16x16 block GEMMs X_IJ = -X_II (sum R_IK X_KJ).
// All stage transitions via full __syncthreads — none of r17's same-wave /
// double-buffer elisions (r17 NaN'd; factorization elisions prime suspect).
// History: r18 982us (mid-QR drop proven safe); r16 1138us; r15 1393us.

#define NN    4096
#define NEDG  131072
#define INC   512
#define HIDC  512
#define OUTC  64
#define RK    64
#define NDOM  4
#define EPSBN 1e-5f

static inline int cdiv(int a, int b){ return (a + b - 1) / b; }

// ---------------- input dtype detection (f32 vs bf16 carriers) ----------------
__global__ __launch_bounds__(256) void k_detect(const unsigned short* __restrict__ p,
                                                int* __restrict__ flag){
  int t = threadIdx.x;
  int cnt = 0;
  for (int i = t; i < 4096; i += 256){
    unsigned short v = p[2*i];
    int e = (v >> 7) & 0xFF;
    if (e >= 100 && e <= 140) cnt++;
  }
  __shared__ int sh[256];
  sh[t] = cnt; __syncthreads();
  for (int off = 128; off > 0; off >>= 1){ if (t < off) sh[t] += sh[t+off]; __syncthreads(); }
  if (t == 0) *flag = (sh[0] >= 2048) ? 0 : 1;
}

// ---------------- elementwise utils ----------------
__global__ __launch_bounds__(256) void k_upcast(const void* __restrict__ s,
                                                const int* __restrict__ isf32,
                                                float* __restrict__ d, int n){
  int i = blockIdx.x*256 + threadIdx.x;
  if (i >= n) return;
  if (*isf32) d[i] = ((const float*)s)[i];
  else        d[i] = __bfloat162float(((const __hip_bfloat16*)s)[i]);
}
__global__ __launch_bounds__(256) void k_fill(float* d, float v, int n){
  int i = blockIdx.x*256 + threadIdx.x;
  if (i < n) d[i] = v;
}
__global__ __launch_bounds__(256) void k_filli(int* d, int v, int n){
  int i = blockIdx.x*256 + threadIdx.x;
  if (i < n) d[i] = v;
}
__global__ __launch_bounds__(256) void k_filld(double* d, double v, int n){
  int i = blockIdx.x*256 + threadIdx.x;
  if (i < n) d[i] = v;
}
__global__ __launch_bounds__(256) void k_copy(const float* __restrict__ z,
                                              float* __restrict__ o, int n){
  int i = blockIdx.x*256 + threadIdx.x;
  if (i < n) o[i] = z[i];
}
__global__ __launch_bounds__(256) void k_f32to64(const float* __restrict__ s,
                                                 double* __restrict__ d, int n){
  int i = blockIdx.x*256 + threadIdx.x;
  if (i < n) d[i] = (double)s[i];
}
__global__ __launch_bounds__(256) void k_f64to32(const double* __restrict__ s,
                                                 float* __restrict__ d, int n){
  int i = blockIdx.x*256 + threadIdx.x;
  if (i < n) d[i] = (float)s[i];
}

// ---------------- graph preprocessing ----------------
__global__ __launch_bounds__(256) void k_hist(const int* __restrict__ row, const int* __restrict__ col,
                                              const float* __restrict__ w, float* deg,
                                              int* cntR, int* cntC){
  int e = blockIdx.x*256 + threadIdx.x;
  if (e < NEDG){
    atomicAdd(&deg[col[e]], w[e]);
    atomicAdd(&cntR[row[e]], 1);
    atomicAdd(&cntC[col[e]], 1);
  }
}
__global__ __launch_bounds__(256) void k_dinv(const float* deg, float* dinv, int n){
  int i = blockIdx.x*256 + threadIdx.x;
  if (i < n){ float d = deg[i]; dinv[i] = (d > 0.f) ? 1.f/sqrtf(d) : 0.f; }
}
__global__ __launch_bounds__(256) void k_norm1(const int* __restrict__ row, const int* __restrict__ col,
                                               const float* __restrict__ w, const float* __restrict__ dinv,
                                               float* __restrict__ nrm){
  int e = blockIdx.x*256 + threadIdx.x;
  if (e < NEDG) nrm[e] = dinv[row[e]] * w[e] * dinv[col[e]];
}
__global__ __launch_bounds__(1024) void k_scan4096(const int* __restrict__ cnt,
                                                   int* __restrict__ ptr, int* __restrict__ pos){
  __shared__ int sh[1024];
  int t = threadIdx.x;
  int b = t*4;
  int a0 = cnt[b], a1 = cnt[b+1], a2 = cnt[b+2], a3 = cnt[b+3];
  sh[t] = a0 + a1 + a2 + a3;
  __syncthreads();
  for (int off = 1; off < 1024; off <<= 1){
    int v = (t >= off) ? sh[t-off] : 0;
    __syncthreads();
    sh[t] += v;
    __syncthreads();
  }
  int excl = (t == 0) ? 0 : sh[t-1];
  ptr[b]   = excl;            pos[b]   = excl;
  ptr[b+1] = excl+a0;         pos[b+1] = excl+a0;
  ptr[b+2] = excl+a0+a1;      pos[b+2] = excl+a0+a1;
  ptr[b+3] = excl+a0+a1+a2;   pos[b+3] = excl+a0+a1+a2;
  if (t == 1023) ptr[4096] = sh[1023];
}
__global__ __launch_bounds__(256) void k_scatter(const int* __restrict__ row, const int* __restrict__ col,
                                                 int* posR, int* posC, int* eidR, int* eidC){
  int e = blockIdx.x*256 + threadIdx.x;
  if (e < NEDG){
    int p = atomicAdd(&posR[row[e]], 1); eidR[p] = e;
    int q = atomicAdd(&posC[col[e]], 1); eidC[q] = e;
  }
}
__global__ __launch_bounds__(256) void k_dcnt(const int* __restrict__ y, int* dcnt){
  int i = blockIdx.x*256 + threadIdx.x;
  if (i < NN) atomicAdd(&dcnt[y[i]], 1);
}

// ---------------- threefry2x32 core (KAT-verified round 8) ----------------
__device__ __forceinline__ unsigned rotl32(unsigned x, unsigned d){ return (x << d) | (x >> (32u - d)); }
#define TF_ROUND4(R0,R1,R2,R3) \
  x0 += x1; x1 = rotl32(x1,R0); x1 ^= x0; \
  x0 += x1; x1 = rotl32(x1,R1); x1 ^= x0; \
  x0 += x1; x1 = rotl32(x1,R2); x1 ^= x0; \
  x0 += x1; x1 = rotl32(x1,R3); x1 ^= x0;

__device__ __forceinline__ void tf2x32(unsigned k0, unsigned k1, unsigned c0, unsigned c1,
                                       unsigned* o0, unsigned* o1){
  unsigned ks2 = 0x1BD11BDAu ^ k0 ^ k1;
  unsigned x0 = c0 + k0, x1 = c1 + k1;
  TF_ROUND4(13,15,26,6);   x0 += k1;  x1 += ks2 + 1u;
  TF_ROUND4(17,29,16,24);  x0 += ks2; x1 += k0 + 2u;
  TF_ROUND4(13,15,26,6);   x0 += k0;  x1 += k1 + 3u;
  TF_ROUND4(17,29,16,24);  x0 += k1;  x1 += ks2 + 4u;
  TF_ROUND4(13,15,26,6);   x0 += ks2; x1 += k0 + 5u;
  *o0 = x0; *o1 = x1;
}

// ---------------- omega (verified round 10) ----------------
__device__ double erfinv64(double x){
  double w = -log1p(-x*x);
  double p;
  if (w < 5.0){
    w -= 2.5;
    p = 2.81022636e-08;  p = p*w + 3.43273939e-07; p = p*w - 3.5233877e-06;
    p = p*w - 4.39150654e-06; p = p*w + 0.00021858087; p = p*w - 0.00125372503;
    p = p*w - 0.00417768164;  p = p*w + 0.246640727;   p = p*w + 1.50140941;
  } else {
    w = sqrt(w) - 3.0;
    p = -0.000200214257; p = p*w + 0.000100950558; p = p*w + 0.00134934322;
    p = p*w - 0.00367342844; p = p*w + 0.00573950773; p = p*w - 0.0076224613;
    p = p*w + 0.00943887047; p = p*w + 1.00167406;    p = p*w + 2.83297682;
  }
  double y = p * x;
  const double c = 1.1283791670955126;   // 2/sqrt(pi)
  #pragma unroll
  for (int it = 0; it < 3; it++){
    double err = erf(y) - x;
    y -= err / (c * exp(-y*y));
  }
  return y;
}

__device__ float bits_to_normal(unsigned b){
  float f = __uint_as_float((b >> 9) | 0x3f800000u) - 1.0f;
  const float lo = -0.99999994f;               // nextafter(-1,0) in f32
  float x = fmaxf(lo, f * 2.0f + lo);
  double r = 1.4142135623730951 * erfinv64((double)x);
  return (float)r;
}

__global__ __launch_bounds__(256) void k_omega(float* __restrict__ om){
  int i = blockIdx.x*256 + threadIdx.x;
  if (i >= 262144) return;
  unsigned o0, o1;
  tf2x32(0u, 42u, 0u, (unsigned)i, &o0, &o1);   // counter = (0, i)
  om[i] = bits_to_normal(o0 ^ o1);              // partitionable: bits1 ^ bits2
}

// ---------------- GEMM (fp32, tiled 64x64, 4x4/thread) ----------------
__global__ __launch_bounds__(256) void k_gemm_nn(int M, int Nn, int K,
      const float* __restrict__ A, int lda, const float* __restrict__ B, int ldb,
      float* __restrict__ Cc, int ldc, const float* __restrict__ rowscale,
      const float* __restrict__ kscale, const float* __restrict__ bias){
  __shared__ float As[16][65];
  __shared__ float Bs[16][65];
  int bm = blockIdx.y*64, bn = blockIdx.x*64;
  int t = threadIdx.x;
  int tr = t >> 4, tc = t & 15;
  float acc[4][4] = {};
  for (int k0 = 0; k0 < K; k0 += 16){
    #pragma unroll
    for (int q = 0; q < 4; q++){
      int idx = t*4 + q;
      int m = idx >> 4, kk = idx & 15;
      As[kk][m] = A[(size_t)(bm+m)*lda + (k0+kk)];
    }
    #pragma unroll
    for (int q = 0; q < 4; q++){
      int idx = t + q*256;
      int kk = idx >> 6, n = idx & 63;
      float ks = kscale ? kscale[k0+kk] : 1.0f;
      Bs[kk][n] = B[(size_t)(k0+kk)*ldb + (bn+n)] * ks;
    }
    __syncthreads();
    #pragma unroll
    for (int kk = 0; kk < 16; kk++){
      float a0 = As[kk][tr*4+0], a1 = As[kk][tr*4+1], a2 = As[kk][tr*4+2], a3 = As[kk][tr*4+3];
      float b0 = Bs[kk][tc*4+0], b1 = Bs[kk][tc*4+1], b2 = Bs[kk][tc*4+2], b3 = Bs[kk][tc*4+3];
      acc[0][0] += a0*b0; acc[0][1] += a0*b1; acc[0][2] += a0*b2; acc[0][3] += a0*b3;
      acc[1][0] += a1*b0; acc[1][1] += a1*b1; acc[1][2] += a1*b2; acc[1][3] += a1*b3;
      acc[2][0] += a2*b0; acc[2][1] += a2*b1; acc[2][2] += a2*b2; acc[2][3] += a2*b3;
      acc[3][0] += a3*b0; acc[3][1] += a3*b1; acc[3][2] += a3*b2; acc[3][3] += a3*b3;
    }
    __syncthreads();
  }
  #pragma unroll
  for (int i2 = 0; i2 < 4; i2++){
    int m = bm + tr*4 + i2;
    float rs = rowscale ? rowscale[m] : 1.0f;
    #pragma unroll
    for (int j2 = 0; j2 < 4; j2++){
      int n = bn + tc*4 + j2;
      float v = acc[i2][j2] * rs;
      if (bias) v += bias[n];
      Cc[(size_t)m*ldc + n] = v;
    }
  }
}

// split-K NN: C += partial (C pre-zeroed); grid (Nn/64, M/64, K/kchunk)
__global__ __launch_bounds__(256) void k_gemm_nn_sk(int M, int Nn, int K, int kchunk,
      const float* __restrict__ A, int lda, const float* __restrict__ B, int ldb,
      float* __restrict__ Cc, int ldc){
  __shared__ float As[16][65];
  __shared__ float Bs[16][65];
  int bm = blockIdx.y*64, bn = blockIdx.x*64;
  int kb = blockIdx.z*kchunk, ke = kb + kchunk;
  int t = threadIdx.x;
  int tr = t >> 4, tc = t & 15;
  float acc[4][4] = {};
  for (int k0 = kb; k0 < ke; k0 += 16){
    #pragma unroll
    for (int q = 0; q < 4; q++){
      int idx = t*4 + q;
      int m = idx >> 4, kk = idx & 15;
      As[kk][m] = A[(size_t)(bm+m)*lda + (k0+kk)];
    }
    #pragma unroll
    for (int q = 0; q < 4; q++){
      int idx = t + q*256;
      int kk = idx >> 6, n = idx & 63;
      Bs[kk][n] = B[(size_t)(k0+kk)*ldb + (bn+n)];
    }
    __syncthreads();
    #pragma unroll
    for (int kk = 0; kk < 16; kk++){
      float a0 = As[kk][tr*4+0], a1 = As[kk][tr*4+1], a2 = As[kk][tr*4+2], a3 = As[kk][tr*4+3];
      float b0 = Bs[kk][tc*4+0], b1 = Bs[kk][tc*4+1], b2 = Bs[kk][tc*4+2], b3 = Bs[kk][tc*4+3];
      acc[0][0] += a0*b0; acc[0][1] += a0*b1; acc[0][2] += a0*b2; acc[0][3] += a0*b3;
      acc[1][0] += a1*b0; acc[1][1] += a1*b1; acc[1][2] += a1*b2; acc[1][3] += a1*b3;
      acc[2][0] += a2*b0; acc[2][1] += a2*b1; acc[2][2] += a2*b2; acc[2][3] += a2*b3;
      acc[3][0] += a3*b0; acc[3][1] += a3*b1; acc[3][2] += a3*b2; acc[3][3] += a3*b3;
    }
    __syncthreads();
  }
  #pragma unroll
  for (int i2 = 0; i2 < 4; i2++){
    int m = bm + tr*4 + i2;
    #pragma unroll
    for (int j2 = 0; j2 < 4; j2++){
      int n = bn + tc*4 + j2;
      atomicAdd(&Cc[(size_t)m*ldc + n], acc[i2][j2]);
    }
  }
}

// split-K TN: C += partial (C pre-zeroed); grid (Nn/16, M/16, K/kchunk)
__global__ __launch_bounds__(256) void k_gemm_tn_sk(int M, int Nn, int K, int kchunk,
      const float* __restrict__ A, int lda, const float* __restrict__ B, int ldb,
      float* __restrict__ Cc, int ldc, const float* __restrict__ kscale){
  __shared__ float As[32][17];
  __shared__ float Bs[32][17];
  int bm = blockIdx.y*16, bn = blockIdx.x*16;
  int kb = blockIdx.z*kchunk, ke = kb + kchunk;
  int t = threadIdx.x;
  int tm = t >> 4, tn = t & 15;
  float acc = 0.f;
  for (int k0 = kb; k0 < ke; k0 += 32){
    #pragma unroll
    for (int q = 0; q < 2; q++){
      int idx = t + q*256;
      int kk = idx >> 4, m = idx & 15;
      float sv = kscale ? kscale[k0+kk] : 1.0f;
      As[kk][m] = A[(size_t)(k0+kk)*lda + (bm+m)] * sv;
      Bs[kk][m] = B[(size_t)(k0+kk)*ldb + (bn+m)];
    }
    __syncthreads();
    #pragma unroll
    for (int kk = 0; kk < 32; kk++) acc += As[kk][tm] * Bs[kk][tn];
    __syncthreads();
  }
  atomicAdd(&Cc[(size_t)(bm+tm)*ldc + (bn+tn)], acc);
}

// ---------------- f64 randomized-subspace chain ----------------
__global__ __launch_bounds__(64) void k_spmm64(const int* __restrict__ ptr, const int* __restrict__ eid,
                       const int* __restrict__ oidx, const float* __restrict__ coef,
                       const double* __restrict__ X, double* __restrict__ Y){
  int seg = blockIdx.x;
  int t = threadIdx.x;
  double acc = 0.0;
  int p0 = ptr[seg], p1 = ptr[seg+1];
  for (int p = p0; p < p1; ++p){
    int e = eid[p];
    acc += (double)coef[e] * X[(size_t)oidx[e]*RK + t];
  }
  Y[(size_t)seg*RK + t] = acc;
}
// Gram: G += Xslice^T Xslice over 64-row slices (G zeroed before)
__global__ __launch_bounds__(256) void k_gram64(const double* __restrict__ X, double* __restrict__ G){
  __shared__ double Xs[64][65];
  int b = blockIdx.x;
  int t = threadIdx.x;
  #pragma unroll
  for (int q = 0; q < 16; q++){
    int idx = t + q*256;
    Xs[idx >> 6][idx & 63] = X[(size_t)(b*64 + (idx >> 6))*RK + (idx & 63)];
  }
  __syncthreads();
  int i = t >> 2;
  int j0 = (t & 3) * 16;
  double acc[16];
  #pragma unroll
  for (int jj = 0; jj < 16; jj++) acc[jj] = 0.0;
  for (int k = 0; k < 64; k++){
    double a = Xs[k][i];
    #pragma unroll
    for (int jj = 0; jj < 16; jj++) acc[jj] += a * Xs[k][j0+jj];
  }
  #pragma unroll
  for (int jj = 0; jj < 16; jj++) atomicAdd(&G[i*RK + j0 + jj], acc[jj]);
}
// Cholesky + upper-tri inverse, f64 (r19):
//  - factorization: VERBATIM r16 (harness-proven): column j owned by threads
//    {j, j+64, j+128, j+192}, 3 __syncthreads per k, L in registers.
//  - inverse (new): blocked. Dump R to LDS; 4 independent 16x16 diag
//    triangular column-solves (one wave, each thread its own column, no
//    cross-thread deps); then 3 superdiagonal rounds of barrier-separated
//    16x16 block GEMMs X_IJ = -X_II (sum_{K=I+1..J} R_IK X_KJ).
__global__ __launch_bounds__(256) void k_cholinv64(const double* __restrict__ G, double* __restrict__ Rinv){
  __shared__ double colk[64];
  __shared__ double sdinv[64];
  __shared__ double Rl[64][65];   // R row-major: Rl[i][j] = R[i][j] = L[j][i]
  __shared__ double Xl[64][65];   // X = R^{-1} (upper); lower stays 0
  __shared__ double Sl[3][16][17];
  int t = threadIdx.x;
  int wv = t >> 6, lane = t & 63;
  int j = lane;                   // owned column
  double r[16];                   // rows i = 4q + wv
  #pragma unroll
  for (int q = 0; q < 16; q++)
    r[q] = G[(size_t)(((q << 2) + wv) << 6) + j];
  // zero Xl (lower region must read as 0 in the blocked stages)
  for (int idx = t; idx < 64*65; idx += 256)
    ((double*)Xl)[idx] = 0.0;
  // ---- factorization (r16-proven, 3 barriers/iter) ----
  for (int k = 0; k < 64; k++){
    int kq = k >> 2, kw = k & 3;
    if (wv == kw && j == k){
      double d = sqrt(fmax(r[kq], 1e-300));
      r[kq] = d;
      sdinv[k] = 1.0 / d;
    }
    __syncthreads();
    if (j == k){
      double di = sdinv[k];
      #pragma unroll
      for (int q = 0; q < 16; q++){
        int i = (q << 2) + wv;
        if (i > k){ r[q] *= di; colk[i] = r[q]; }
      }
    }
    __syncthreads();
    if (j > k){
      double cj = colk[j];
      #pragma unroll
      for (int q = 0; q < 16; q++){
        int i = (q << 2) + wv;
        if (i >= j) r[q] -= colk[i] * cj;   // i >= j > k
      }
    }
    __syncthreads();
  }
  // dump R = L^T to LDS: Rl[j][i] = L[i][j] for i >= j, else 0
  #pragma unroll
  for (int q = 0; q < 16; q++){
    int i = (q << 2) + wv;
    Rl[j][i] = (i >= j) ? r[q] : 0.0;
  }
  __syncthreads();
  // ---- diag blocks: 4 independent 16x16 upper-tri inverses (one wave) ----
  if (t < 64){
    int b = t >> 4, c = t & 15;
    int g0 = b << 4;
    int gc = g0 + c;
    Xl[gc][gc] = sdinv[gc];
    for (int i = c - 1; i >= 0; i--){
      int gi = g0 + i;
      double s = 0.0;
      for (int k2 = i + 1; k2 <= c; k2++)
        s += Rl[gi][g0 + k2] * Xl[g0 + k2][gc];
      Xl[gi][gc] = -s * sdinv[gi];
    }
  }
  __syncthreads();
  // ---- off-diag blocks by superdiagonal d: X_IJ = -X_II * S,
  //      S = sum over block-cols K=I+1..J of R_IK X_KJ ----
  for (int d = 1; d < 4; d++){
    int np = 4 - d;
    int tot = np << 8;
    for (int e = t; e < tot; e += 256){
      int p = e >> 8;
      int i = (e >> 4) & 15, jj = e & 15;
      int gi = (p << 4) + i, gj = ((p + d) << 4) + jj;
      double s = 0.0;
      int a0 = (p + 1) << 4, a1 = (p + d + 1) << 4;
      for (int a = a0; a < a1; a++)
        s += Rl[gi][a] * Xl[a][gj];
      Sl[p][i][jj] = s;
    }
    __syncthreads();
    for (int e = t; e < tot; e += 256){
      int p = e >> 8;
      int i = (e >> 4) & 15, jj = e & 15;
      int gi = (p << 4) + i, gj = ((p + d) << 4) + jj;
      double s = 0.0;
      #pragma unroll
      for (int k2 = 0; k2 < 16; k2++)
        s += Xl[gi][(p << 4) + k2] * Sl[p][k2][jj];   // Xl lower = 0
      Xl[gi][gj] = -s;
    }
    __syncthreads();
  }
  // ---- store (coalesced) ----
  #pragma unroll
  for (int q = 0; q < 16; q++){
    int e2 = t + (q << 8);
    Rinv[e2] = Xl[e2 >> 6][e2 & 63];
  }
}
// dst[NNx64] = src[NNx64] * Rinv(upper); 4 rows per 256-thread block
__global__ __launch_bounds__(256) void k_applyR64(const double* __restrict__ src,
      const double* __restrict__ Rinv, double* __restrict__ dst){
  __shared__ double Rs[64][65];
  int t = threadIdx.x;
  #pragma unroll
  for (int q = 0; q < 16; q++){
    int idx = t + q*256;
    Rs[idx >> 6][idx & 63] = Rinv[idx];
  }
  __syncthreads();
  int r = blockIdx.x*4 + (t >> 6);
  int j = t & 63;
  const double* rowp = src + (size_t)r*RK;
  double s = 0.0;
  for (int k = 0; k <= j; k++) s += rowp[k] * Rs[k][j];
  dst[(size_t)r*RK + j] = s;
}
__global__ __launch_bounds__(256) void k_qsum64(const double* __restrict__ Q, double* __restrict__ qs){
  int j = blockIdx.x;  int t = threadIdx.x;
  double a = 0.0;
  for (int n = t; n < NN; n += 256) a += Q[(size_t)n*RK + j];
  __shared__ double sh[256];
  sh[t] = a; __syncthreads();
  for (int off = 128; off > 0; off >>= 1){ if (t < off) sh[t] += sh[t+off]; __syncthreads(); }
  if (t == 0) qs[j] = sh[0];
}
__global__ __launch_bounds__(256) void k_deg2f(const double* __restrict__ C, const double* __restrict__ qs,
                                               float* __restrict__ dinv2){
  int i = blockIdx.x*256 + threadIdx.x;
  if (i >= NN) return;
  double s = 0.0;
  #pragma unroll
  for (int k = 0; k < RK; k++) s += C[(size_t)i*RK + k] * qs[k];
  dinv2[i] = (s > 0.0) ? (float)(1.0/sqrt(s)) : 0.f;
}

// ---------------- SpMM over sorted edge lists (f32, branch 1) ----------------
__global__ void k_spmm(const int* __restrict__ ptr, const int* __restrict__ eid,
                       const int* __restrict__ oidx, const float* __restrict__ coef,
                       const float* __restrict__ X, int ldx,
                       float* __restrict__ Y, int ldy, int F,
                       const float* __restrict__ self_dinv, const float* __restrict__ bias){
  int seg = blockIdx.x;
  int t = threadIdx.x, bd = blockDim.x;
  int f1 = t + bd;
  bool two = (f1 < F);
  float acc0 = 0.f, acc1 = 0.f;
  if (self_dinv){
    float sd = self_dinv[seg]; float s2 = sd*sd;
    acc0 = s2 * X[(size_t)seg*ldx + t];
    if (two) acc1 = s2 * X[(size_t)seg*ldx + f1];
  }
  int p0 = ptr[seg], p1 = ptr[seg+1];
  for (int p = p0; p < p1; ++p){
    int e = eid[p];
    int o = oidx[e];
    float c = coef[e];
    const float* xr = X + (size_t)o*ldx;
    acc0 += c * xr[t];
    if (two) acc1 += c * xr[f1];
  }
  if (bias){ acc0 += bias[t]; if (two) acc1 += bias[f1]; }
  Y[(size_t)seg*ldy + t] = acc0;
  if (two) Y[(size_t)seg*ldy + f1] = acc1;
}

// ---------------- domain-specific BN ----------------
__global__ __launch_bounds__(256) void k_bnstats(const float* __restrict__ H, const int* __restrict__ y,
        const int* __restrict__ dcnt, const float* __restrict__ gamma, const float* __restrict__ beta,
        float* __restrict__ scal, float* __restrict__ shft){
  int j = blockIdx.x;
  int t = threadIdx.x;
  float s0=0,s1=0,s2=0,s3=0,q0=0,q1=0,q2=0,q3=0;
  for (int n = t; n < NN; n += 256){
    float v = H[(size_t)n*HIDC + j];
    int d = y[n];
    float v2 = v*v;
    if      (d == 0){ s0 += v; q0 += v2; }
    else if (d == 1){ s1 += v; q1 += v2; }
    else if (d == 2){ s2 += v; q2 += v2; }
    else            { s3 += v; q3 += v2; }
  }
  __shared__ float sh[256][8];
  sh[t][0]=s0; sh[t][1]=s1; sh[t][2]=s2; sh[t][3]=s3;
  sh[t][4]=q0; sh[t][5]=q1; sh[t][6]=q2; sh[t][7]=q3;
  __syncthreads();
  for (int off = 128; off > 0; off >>= 1){
    if (t < off){
      #pragma unroll
      for (int q = 0; q < 8; q++) sh[t][q] += sh[t+off][q];
    }
    __syncthreads();
  }
  if (t < NDOM){
    float cnt  = fmaxf((float)dcnt[t], 1.0f);
    float mean = sh[0][t] / cnt;
    float var  = fmaxf(sh[0][4+t] / cnt - mean*mean, 0.f);
    float inv  = 1.0f / sqrtf(var + EPSBN);
    float gmm  = gamma[t*HIDC + j];
    scal[t*HIDC + j] = gmm * inv;
    shft[t*HIDC + j] = beta[t*HIDC + j] - mean * gmm * inv;
  }
}
__global__ __launch_bounds__(256) void k_bnapply(float* __restrict__ H, const int* __restrict__ y,
        const float* __restrict__ scal, const float* __restrict__ shft){
  int idx = blockIdx.x*256 + threadIdx.x;
  if (idx >= NN*HIDC) return;
  int n = idx >> 9, j = idx & (HIDC-1);
  int d = y[n];
  float v = H[idx] * scal[d*HIDC + j] + shft[d*HIDC + j];
  H[idx] = v > 0.f ? v : 0.f;
}

// ---------------- launch ----------------
extern "C" void kernel_launch(void* const* d_in, const int* in_sizes, int n_in,
                              void* d_out, int out_size, void* d_ws, size_t ws_size,
                              hipStream_t stream){
  (void)in_sizes; (void)n_in; (void)out_size;
  const void* x_in  = d_in[0];
  const int*  ei    = (const int*)d_in[1];
  const void* w_in  = d_in[2];
  const int*  yv    = (const int*)d_in[3];
  const void* W1i   = d_in[4];
  const void* b1i   = d_in[5];
  const void* Wmui  = d_in[6];
  const void* bmui  = d_in[7];
  const void* Wlvi  = d_in[8];
  const void* blvi  = d_in[9];
  const void* gmi   = d_in[10];
  const void* bti   = d_in[11];
  const int* rowA = ei;
  const int* colA = ei + NEDG;

  // ---- workspace: doubles | floats | ints (~38 MB) ----
  double* Dp = (double*)d_ws;
  size_t od = 0;
  double* Qd0 = Dp + od; od += (size_t)NN*RK;
  double* Qd1 = Dp + od; od += (size_t)NN*RK;
  double* Cd  = Dp + od; od += (size_t)NN*RK;
  double* Gd  = Dp + od; od += RK*RK;
  double* Rid = Dp + od; od += RK*RK;
  double* qsd = Dp + od; od += RK;
  float* Fp = (float*)(Dp + od);
  size_t o = 0;
  float* xf   = Fp + o; o += (size_t)NN*INC;       // reused as h1/h2 buffer
  float* W1f  = Fp + o; o += (size_t)INC*HIDC;
  float* b1f  = Fp + o; o += HIDC;
  float* Wmuf = Fp + o; o += (size_t)HIDC*OUTC;
  float* bmuf = Fp + o; o += OUTC;
  float* Wlvf = Fp + o; o += (size_t)HIDC*OUTC;
  float* blvf = Fp + o; o += OUTC;
  float* gmf  = Fp + o; o += NDOM*HIDC;
  float* btf  = Fp + o; o += NDOM*HIDC;
  float* wf   = Fp + o; o += NEDG;
  float* xw1  = Fp + o; o += (size_t)NN*HIDC;
  float* hwA  = Fp + o; o += (size_t)NN*OUTC;
  float* hwB  = Fp + o; o += (size_t)NN*OUTC;     // contiguous after hwA
  float* Bf0  = Fp + o; o += (size_t)NN*RK;        // omega (f32)
  float* Bf1  = Fp + o; o += (size_t)NN*RK;        // Qb (f32)
  float* Cm   = Fp + o; o += (size_t)NN*RK;        // C (f32)
  float* Tm   = Fp + o; o += (size_t)RK*HIDC;
  float* Umu  = Fp + o; o += RK*RK;
  float* deg1 = Fp + o; o += NN;
  float* dinv1= Fp + o; o += NN;
  float* dinv2= Fp + o; o += NN;
  float* norm1= Fp + o; o += NEDG;
  float* scal = Fp + o; o += NDOM*HIDC;
  float* shft = Fp + o; o += NDOM*HIDC;
  float* zb   = Fp + o; o += (size_t)4*NN*OUTC;
  int* Ip = (int*)(Fp + o);
  size_t oi = 0;
  int* cntR = Ip + oi; oi += NN;
  int* ptrR = Ip + oi; oi += NN + 1;
  int* posR = Ip + oi; oi += NN;
  int* eidR = Ip + oi; oi += NEDG;
  int* cntC = Ip + oi; oi += NN;
  int* ptrC = Ip + oi; oi += NN + 1;
  int* posC = Ip + oi; oi += NN;
  int* eidC = Ip + oi; oi += NEDG;
  int* dcnt = Ip + oi; oi += NDOM;
  int* dflag= Ip + oi; oi += 1;

  size_t need = od*sizeof(double) + o*sizeof(float) + (oi+16)*sizeof(int);
  if (ws_size < need) return;

  float* hbuf = xf;  // x dead after xw1 GEMM

  const int T = 256;
  k_detect<<<1,T,0,stream>>>((const unsigned short*)x_in, dflag);
  k_upcast<<<cdiv(NN*INC,T),T,0,stream>>>(x_in, dflag, xf, NN*INC);
  k_upcast<<<cdiv(INC*HIDC,T),T,0,stream>>>(W1i, dflag, W1f, INC*HIDC);
  k_upcast<<<cdiv(HIDC,T),T,0,stream>>>(b1i, dflag, b1f, HIDC);
  k_upcast<<<cdiv(HIDC*OUTC,T),T,0,stream>>>(Wmui, dflag, Wmuf, HIDC*OUTC);
  k_upcast<<<1,T,0,stream>>>(bmui, dflag, bmuf, OUTC);
  k_upcast<<<cdiv(HIDC*OUTC,T),T,0,stream>>>(Wlvi, dflag, Wlvf, HIDC*OUTC);
  k_upcast<<<1,T,0,stream>>>(blvi, dflag, blvf, OUTC);
  k_upcast<<<cdiv(NDOM*HIDC,T),T,0,stream>>>(gmi, dflag, gmf, NDOM*HIDC);
  k_upcast<<<cdiv(NDOM*HIDC,T),T,0,stream>>>(bti, dflag, btf, NDOM*HIDC);
  k_upcast<<<cdiv(NEDG,T),T,0,stream>>>(w_in, dflag, wf, NEDG);

  k_fill <<<cdiv(NN,T),T,0,stream>>>(deg1, 1.0f, NN);   // self-loop weight 1
  k_filli<<<cdiv(NN,T),T,0,stream>>>(cntR, 0, NN);
  k_filli<<<cdiv(NN,T),T,0,stream>>>(cntC, 0, NN);
  k_filli<<<1,T,0,stream>>>(dcnt, 0, NDOM);
  k_hist <<<cdiv(NEDG,T),T,0,stream>>>(rowA, colA, wf, deg1, cntR, cntC);
  k_dinv <<<cdiv(NN,T),T,0,stream>>>(deg1, dinv1, NN);
  k_norm1<<<cdiv(NEDG,T),T,0,stream>>>(rowA, colA, wf, dinv1, norm1);
  k_scan4096<<<1,1024,0,stream>>>(cntR, ptrR, posR);
  k_scan4096<<<1,1024,0,stream>>>(cntC, ptrC, posC);
  k_scatter<<<cdiv(NEDG,T),T,0,stream>>>(rowA, colA, posR, posC, eidR, eidC);
  k_omega<<<cdiv(262144,T),T,0,stream>>>(Bf0);
  k_dcnt <<<cdiv(NN,T),T,0,stream>>>(yv, dcnt);

  // ---- branch 1 (verified) ----
  k_gemm_nn<<<dim3(HIDC/64, NN/64),256,0,stream>>>(NN,HIDC,INC, xf,INC, W1f,HIDC, xw1,HIDC, nullptr,nullptr,nullptr);
  k_spmm<<<NN,256,0,stream>>>(ptrC,eidC,rowA,norm1, xw1,HIDC, hbuf,HIDC, HIDC, dinv1, b1f);
  k_bnstats<<<HIDC,256,0,stream>>>(hbuf, yv, dcnt, gmf, btf, scal, shft);
  k_bnapply<<<cdiv(NN*HIDC,T),T,0,stream>>>(hbuf, yv, scal, shft);
  k_fill<<<cdiv(2*NN*OUTC,T),T,0,stream>>>(hwA, 0.f, 2*NN*OUTC);   // hwA|hwB contiguous
  k_gemm_nn_sk<<<dim3(1, NN/64, 4),256,0,stream>>>(NN,OUTC,HIDC,128, hbuf,HIDC, Wmuf,OUTC, hwA,OUTC);
  k_gemm_nn_sk<<<dim3(1, NN/64, 4),256,0,stream>>>(NN,OUTC,HIDC,128, hbuf,HIDC, Wlvf,OUTC, hwB,OUTC);
  k_spmm<<<NN,64,0,stream>>>(ptrC,eidC,rowA,norm1, hwA,OUTC, zb + 0*NN*OUTC,OUTC, OUTC, dinv1, bmuf);
  k_spmm<<<NN,64,0,stream>>>(ptrC,eidC,rowA,norm1, hwB,OUTC, zb + 1*NN*OUTC,OUTC, OUTC, dinv1, blvf);

  // ---- branch 2: f64 subspace, single final QR1 (mid QR dropped) ----
  auto spmmA64 = [&](const double* s, double* d){   // d = A @ s
    k_spmm64<<<NN,64,0,stream>>>(ptrR,eidR,colA,wf, s, d);
  };
  auto spmmAT64 = [&](const double* s, double* d){  // d = A^T @ s
    k_spmm64<<<NN,64,0,stream>>>(ptrC,eidC,rowA,wf, s, d);
  };
  auto orth164 = [&](double* src, double* dst){     // dst = src * R^{-1}
    k_filld<<<cdiv(RK*RK,T),T,0,stream>>>(Gd, 0.0, RK*RK);
    k_gram64<<<NN/64,256,0,stream>>>(src, Gd);
    k_cholinv64<<<1,256,0,stream>>>(Gd, Rid);
    k_applyR64<<<NN/4,256,0,stream>>>(src, Rid, dst);
  };

  k_f32to64<<<cdiv(NN*RK,T),T,0,stream>>>(Bf0, Qd0, NN*RK);
  spmmA64 (Qd0, Qd1);                      // P1 -> Qd1
  spmmAT64(Qd1, Qd0);                      // P2 -> Qd0
  spmmA64 (Qd0, Qd1);                      // P3 -> Qd1
  spmmAT64(Qd1, Qd0);                      // P4 -> Qd0
  spmmA64 (Qd0, Qd1);                      // P5 -> Qd1 (f64: kappa(G) safe for CholQR)
  orth164(Qd1, Qd0);                       // final QR1 -> Qb in Qd0
  spmmAT64(Qd0, Cd);                       // C = A^T Qb  (A2 = Qb C^T)
  k_qsum64<<<RK,256,0,stream>>>(Qd0, qsd);
  k_deg2f<<<cdiv(NN,T),T,0,stream>>>(Cd, qsd, dinv2);
  k_f64to32<<<cdiv(NN*RK,T),T,0,stream>>>(Qd0, Bf1, NN*RK);
  k_f64to32<<<cdiv(NN*RK,T),T,0,stream>>>(Cd,  Cm,  NN*RK);

  // h2 = dsbn_relu( D C (Qb^T (D xw1)) + b1 )
  k_fill<<<cdiv(RK*HIDC,T),T,0,stream>>>(Tm, 0.f, RK*HIDC);
  k_gemm_tn_sk<<<dim3(HIDC/16, RK/16, 8),256,0,stream>>>(RK,HIDC,NN,512, Bf1,RK, xw1,HIDC, Tm,HIDC, dinv2);
  k_gemm_nn<<<dim3(HIDC/64, NN/64),256,0,stream>>>(NN,HIDC,RK, Cm,RK, Tm,HIDC, hbuf,HIDC, dinv2, nullptr, b1f);
  k_bnstats<<<HIDC,256,0,stream>>>(hbuf, yv, dcnt, gmf, btf, scal, shft);
  k_bnapply<<<cdiv(NN*HIDC,T),T,0,stream>>>(hbuf, yv, scal, shft);
  // z2 = D C (Qb^T (D (h2 W))) + b
  k_fill<<<cdiv(2*NN*OUTC,T),T,0,stream>>>(hwA, 0.f, 2*NN*OUTC);
  k_gemm_nn_sk<<<dim3(1, NN/64, 4),256,0,stream>>>(NN,OUTC,HIDC,128, hbuf,HIDC, Wmuf,OUTC, hwA,OUTC);
  k_gemm_nn_sk<<<dim3(1, NN/64, 4),256,0,stream>>>(NN,OUTC,HIDC,128, hbuf,HIDC, Wlvf,OUTC, hwB,OUTC);
  k_fill<<<cdiv(RK*RK,T),T,0,stream>>>(Umu, 0.f, RK*RK);
  k_gemm_tn_sk<<<dim3(RK/16, RK/16, 16),256,0,stream>>>(RK,RK,NN,256, Bf1,RK, hwA,OUTC, Umu,RK, dinv2);
  k_gemm_nn<<<dim3(1, NN/64),256,0,stream>>>(NN,OUTC,RK, Cm,RK, Umu,RK, zb + 2*NN*OUTC,OUTC, dinv2, nullptr, bmuf);
  k_fill<<<cdiv(RK*RK,T),T,0,stream>>>(Umu, 0.f, RK*RK);
  k_gemm_tn_sk<<<dim3(RK/16, RK/16, 16),256,0,stream>>>(RK,RK,NN,256, Bf1,RK, hwB,OUTC, Umu,RK, dinv2);
  k_gemm_nn<<<dim3(1, NN/64),256,0,stream>>>(NN,OUTC,RK, Cm,RK, Umu,RK, zb + 3*NN*OUTC,OUTC, dinv2, nullptr, blvf);

  // outputs -> f32
  k_copy<<<cdiv(4*NN*OUTC,T),T,0,stream>>>(zb, (float*)d_out, 4*NN*OUTC);
}

// Round 4
// 930.169 us; speedup vs baseline: 1.2237x; 1.0136x over previous
//
#include <hip/hip_runtime.h>
#include <hip/hip_bf16.h>

// GCNEncoder — r20: (a) k_cholinv64 blocked factorization (NB=16): diag factor
// on a SINGLE thread (no cross-lane hazards at all), diag inverse = 16
// own-column solves, panel = one thread per row, trailing = disjoint elems;
// every phase barrier-separated. Off-diag inverse rounds verbatim r19.
// (b) launch fusion: 10 upcasts -> 1, 4 fills -> k_prep, omega writes f64
// (drops f32to64+Bf0), f64to32 x2 -> 1, outputs write d_out directly (drops
// k_copy). -15 launches. History: r19 943us; r18 982us; r16 1138us.

#define NN    4096
#define NEDG  131072
#define INC   512
#define HIDC  512
#define OUTC  64
#define RK    64
#define NDOM  4
#define EPSBN 1e-5f

static inline int cdiv(int a, int b){ return (a + b - 1) / b; }

// ---------------- input dtype detection (f32 vs bf16 carriers) ----------------
__global__ __launch_bounds__(256) void k_detect(const unsigned short* __restrict__ p,
                                                int* __restrict__ flag){
  int t = threadIdx.x;
  int cnt = 0;
  for (int i = t; i < 4096; i += 256){
    unsigned short v = p[2*i];
    int e = (v >> 7) & 0xFF;
    if (e >= 100 && e <= 140) cnt++;
  }
  __shared__ int sh[256];
  sh[t] = cnt; __syncthreads();
  for (int off = 128; off > 0; off >>= 1){ if (t < off) sh[t] += sh[t+off]; __syncthreads(); }
  if (t == 0) *flag = (sh[0] >= 2048) ? 0 : 1;
}

// ---------------- fused upcast of all 10 inputs ----------------
__device__ __forceinline__ float upc1(const void* s, int f, int off){
  return f ? ((const float*)s)[off]
           : __bfloat162float(((const __hip_bfloat16*)s)[off]);
}
#define SEG_X   2097152
#define SEG_W1  262144
#define SEG_W   131072
#define SEG_WMU 32768
#define SEG_GB  2048
#define SEG_B1  512
#define SEG_BO  64
// cumulative offsets
#define OFF1 (SEG_X)                     // 2097152
#define OFF2 (OFF1+SEG_W1)               // 2359296
#define OFF3 (OFF2+SEG_W)                // 2490368
#define OFF4 (OFF3+SEG_WMU)              // 2523136
#define OFF5 (OFF4+SEG_WMU)              // 2555904
#define OFF6 (OFF5+SEG_GB)               // 2557952
#define OFF7 (OFF6+SEG_GB)               // 2560000
#define OFF8 (OFF7+SEG_B1)               // 2560512
#define OFF9 (OFF8+SEG_BO)               // 2560576
#define OFFT (OFF9+SEG_BO)               // 2560640

__global__ __launch_bounds__(256) void k_upcast_all(
    const void* x, const void* W1, const void* w, const void* Wmu, const void* Wlv,
    const void* gm, const void* bt, const void* b1, const void* bmu, const void* blv,
    const int* __restrict__ isf32,
    float* dx, float* dW1, float* dw, float* dWmu, float* dWlv,
    float* dgm, float* dbt, float* db1, float* dbmu, float* dblv){
  int i = blockIdx.x*256 + threadIdx.x;
  if (i >= OFFT) return;
  int f = *isf32;
  if      (i < OFF1) dx  [i]        = upc1(x,   f, i);
  else if (i < OFF2) dW1 [i - OFF1] = upc1(W1,  f, i - OFF1);
  else if (i < OFF3) dw  [i - OFF2] = upc1(w,   f, i - OFF2);
  else if (i < OFF4) dWmu[i - OFF3] = upc1(Wmu, f, i - OFF3);
  else if (i < OFF5) dWlv[i - OFF4] = upc1(Wlv, f, i - OFF4);
  else if (i < OFF6) dgm [i - OFF5] = upc1(gm,  f, i - OFF5);
  else if (i < OFF7) dbt [i - OFF6] = upc1(bt,  f, i - OFF6);
  else if (i < OFF8) db1 [i - OFF7] = upc1(b1,  f, i - OFF7);
  else if (i < OFF9) dbmu[i - OFF8] = upc1(bmu, f, i - OFF8);
  else               dblv[i - OFF9] = upc1(blv, f, i - OFF9);
}

// ---------------- elementwise utils ----------------
__global__ __launch_bounds__(256) void k_fill(float* d, float v, int n){
  int i = blockIdx.x*256 + threadIdx.x;
  if (i < n) d[i] = v;
}
__global__ __launch_bounds__(256) void k_filld(double* d, double v, int n){
  int i = blockIdx.x*256 + threadIdx.x;
  if (i < n) d[i] = v;
}
__global__ __launch_bounds__(256) void k_prep(float* deg, int* cntR, int* cntC, int* dcnt){
  int i = blockIdx.x*256 + threadIdx.x;
  if (i < NN){ deg[i] = 1.0f; cntR[i] = 0; cntC[i] = 0; }
  if (i < NDOM) dcnt[i] = 0;
}
__global__ __launch_bounds__(256) void k_f64to32x2(const double* __restrict__ s0, float* __restrict__ d0,
                                                   const double* __restrict__ s1, float* __restrict__ d1,
                                                   int n){
  int i = blockIdx.x*256 + threadIdx.x;
  if (i < n){ d0[i] = (float)s0[i]; d1[i] = (float)s1[i]; }
}

// ---------------- graph preprocessing ----------------
__global__ __launch_bounds__(256) void k_hist(const int* __restrict__ row, const int* __restrict__ col,
                                              const float* __restrict__ w, float* deg,
                                              int* cntR, int* cntC){
  int e = blockIdx.x*256 + threadIdx.x;
  if (e < NEDG){
    atomicAdd(&deg[col[e]], w[e]);
    atomicAdd(&cntR[row[e]], 1);
    atomicAdd(&cntC[col[e]], 1);
  }
}
__global__ __launch_bounds__(256) void k_dinv(const float* deg, float* dinv, int n){
  int i = blockIdx.x*256 + threadIdx.x;
  if (i < n){ float d = deg[i]; dinv[i] = (d > 0.f) ? 1.f/sqrtf(d) : 0.f; }
}
__global__ __launch_bounds__(256) void k_norm1(const int* __restrict__ row, const int* __restrict__ col,
                                               const float* __restrict__ w, const float* __restrict__ dinv,
                                               float* __restrict__ nrm){
  int e = blockIdx.x*256 + threadIdx.x;
  if (e < NEDG) nrm[e] = dinv[row[e]] * w[e] * dinv[col[e]];
}
__global__ __launch_bounds__(1024) void k_scan4096(const int* __restrict__ cnt,
                                                   int* __restrict__ ptr, int* __restrict__ pos){
  __shared__ int sh[1024];
  int t = threadIdx.x;
  int b = t*4;
  int a0 = cnt[b], a1 = cnt[b+1], a2 = cnt[b+2], a3 = cnt[b+3];
  sh[t] = a0 + a1 + a2 + a3;
  __syncthreads();
  for (int off = 1; off < 1024; off <<= 1){
    int v = (t >= off) ? sh[t-off] : 0;
    __syncthreads();
    sh[t] += v;
    __syncthreads();
  }
  int excl = (t == 0) ? 0 : sh[t-1];
  ptr[b]   = excl;            pos[b]   = excl;
  ptr[b+1] = excl+a0;         pos[b+1] = excl+a0;
  ptr[b+2] = excl+a0+a1;      pos[b+2] = excl+a0+a1;
  ptr[b+3] = excl+a0+a1+a2;   pos[b+3] = excl+a0+a1+a2;
  if (t == 1023) ptr[4096] = sh[1023];
}
__global__ __launch_bounds__(256) void k_scatter(const int* __restrict__ row, const int* __restrict__ col,
                                                 int* posR, int* posC, int* eidR, int* eidC){
  int e = blockIdx.x*256 + threadIdx.x;
  if (e < NEDG){
    int p = atomicAdd(&posR[row[e]], 1); eidR[p] = e;
    int q = atomicAdd(&posC[col[e]], 1); eidC[q] = e;
  }
}
__global__ __launch_bounds__(256) void k_dcnt(const int* __restrict__ y, int* dcnt){
  int i = blockIdx.x*256 + threadIdx.x;
  if (i < NN) atomicAdd(&dcnt[y[i]], 1);
}

// ---------------- threefry2x32 core (KAT-verified round 8) ----------------
__device__ __forceinline__ unsigned rotl32(unsigned x, unsigned d){ return (x << d) | (x >> (32u - d)); }
#define TF_ROUND4(R0,R1,R2,R3) \
  x0 += x1; x1 = rotl32(x1,R0); x1 ^= x0; \
  x0 += x1; x1 = rotl32(x1,R1); x1 ^= x0; \
  x0 += x1; x1 = rotl32(x1,R2); x1 ^= x0; \
  x0 += x1; x1 = rotl32(x1,R3); x1 ^= x0;

__device__ __forceinline__ void tf2x32(unsigned k0, unsigned k1, unsigned c0, unsigned c1,
                                       unsigned* o0, unsigned* o1){
  unsigned ks2 = 0x1BD11BDAu ^ k0 ^ k1;
  unsigned x0 = c0 + k0, x1 = c1 + k1;
  TF_ROUND4(13,15,26,6);   x0 += k1;  x1 += ks2 + 1u;
  TF_ROUND4(17,29,16,24);  x0 += ks2; x1 += k0 + 2u;
  TF_ROUND4(13,15,26,6);   x0 += k0;  x1 += k1 + 3u;
  TF_ROUND4(17,29,16,24);  x0 += k1;  x1 += ks2 + 4u;
  TF_ROUND4(13,15,26,6);   x0 += ks2; x1 += k0 + 5u;
  *o0 = x0; *o1 = x1;
}

// ---------------- omega (verified round 10; r20: direct f64 output) ----------------
__device__ double erfinv64(double x){
  double w = -log1p(-x*x);
  double p;
  if (w < 5.0){
    w -= 2.5;
    p = 2.81022636e-08;  p = p*w + 3.43273939e-07; p = p*w - 3.5233877e-06;
    p = p*w - 4.39150654e-06; p = p*w + 0.00021858087; p = p*w - 0.00125372503;
    p = p*w - 0.00417768164;  p = p*w + 0.246640727;   p = p*w + 1.50140941;
  } else {
    w = sqrt(w) - 3.0;
    p = -0.000200214257; p = p*w + 0.000100950558; p = p*w + 0.00134934322;
    p = p*w - 0.00367342844; p = p*w + 0.00573950773; p = p*w - 0.0076224613;
    p = p*w + 0.00943887047; p = p*w + 1.00167406;    p = p*w + 2.83297682;
  }
  double y = p * x;
  const double c = 1.1283791670955126;   // 2/sqrt(pi)
  #pragma unroll
  for (int it = 0; it < 3; it++){
    double err = erf(y) - x;
    y -= err / (c * exp(-y*y));
  }
  return y;
}

__device__ float bits_to_normal(unsigned b){
  float f = __uint_as_float((b >> 9) | 0x3f800000u) - 1.0f;
  const float lo = -0.99999994f;               // nextafter(-1,0) in f32
  float x = fmaxf(lo, f * 2.0f + lo);
  double r = 1.4142135623730951 * erfinv64((double)x);
  return (float)r;
}

__global__ __launch_bounds__(256) void k_omega(double* __restrict__ om){
  int i = blockIdx.x*256 + threadIdx.x;
  if (i >= 262144) return;
  unsigned o0, o1;
  tf2x32(0u, 42u, 0u, (unsigned)i, &o0, &o1);   // counter = (0, i)
  om[i] = (double)bits_to_normal(o0 ^ o1);      // same f32 value as before, widened
}

// ---------------- GEMM (fp32, tiled 64x64, 4x4/thread) ----------------
__global__ __launch_bounds__(256) void k_gemm_nn(int M, int Nn, int K,
      const float* __restrict__ A, int lda, const float* __restrict__ B, int ldb,
      float* __restrict__ Cc, int ldc, const float* __restrict__ rowscale,
      const float* __restrict__ kscale, const float* __restrict__ bias){
  __shared__ float As[16][65];
  __shared__ float Bs[16][65];
  int bm = blockIdx.y*64, bn = blockIdx.x*64;
  int t = threadIdx.x;
  int tr = t >> 4, tc = t & 15;
  float acc[4][4] = {};
  for (int k0 = 0; k0 < K; k0 += 16){
    #pragma unroll
    for (int q = 0; q < 4; q++){
      int idx = t*4 + q;
      int m = idx >> 4, kk = idx & 15;
      As[kk][m] = A[(size_t)(bm+m)*lda + (k0+kk)];
    }
    #pragma unroll
    for (int q = 0; q < 4; q++){
      int idx = t + q*256;
      int kk = idx >> 6, n = idx & 63;
      float ks = kscale ? kscale[k0+kk] : 1.0f;
      Bs[kk][n] = B[(size_t)(k0+kk)*ldb + (bn+n)] * ks;
    }
    __syncthreads();
    #pragma unroll
    for (int kk = 0; kk < 16; kk++){
      float a0 = As[kk][tr*4+0], a1 = As[kk][tr*4+1], a2 = As[kk][tr*4+2], a3 = As[kk][tr*4+3];
      float b0 = Bs[kk][tc*4+0], b1 = Bs[kk][tc*4+1], b2 = Bs[kk][tc*4+2], b3 = Bs[kk][tc*4+3];
      acc[0][0] += a0*b0; acc[0][1] += a0*b1; acc[0][2] += a0*b2; acc[0][3] += a0*b3;
      acc[1][0] += a1*b0; acc[1][1] += a1*b1; acc[1][2] += a1*b2; acc[1][3] += a1*b3;
      acc[2][0] += a2*b0; acc[2][1] += a2*b1; acc[2][2] += a2*b2; acc[2][3] += a2*b3;
      acc[3][0] += a3*b0; acc[3][1] += a3*b1; acc[3][2] += a3*b2; acc[3][3] += a3*b3;
    }
    __syncthreads();
  }
  #pragma unroll
  for (int i2 = 0; i2 < 4; i2++){
    int m = bm + tr*4 + i2;
    float rs = rowscale ? rowscale[m] : 1.0f;
    #pragma unroll
    for (int j2 = 0; j2 < 4; j2++){
      int n = bn + tc*4 + j2;
      float v = acc[i2][j2] * rs;
      if (bias) v += bias[n];
      Cc[(size_t)m*ldc + n] = v;
    }
  }
}

// split-K NN: C += partial (C pre-zeroed); grid (Nn/64, M/64, K/kchunk)
__global__ __launch_bounds__(256) void k_gemm_nn_sk(int M, int Nn, int K, int kchunk,
      const float* __restrict__ A, int lda, const float* __restrict__ B, int ldb,
      float* __restrict__ Cc, int ldc){
  __shared__ float As[16][65];
  __shared__ float Bs[16][65];
  int bm = blockIdx.y*64, bn = blockIdx.x*64;
  int kb = blockIdx.z*kchunk, ke = kb + kchunk;
  int t = threadIdx.x;
  int tr = t >> 4, tc = t & 15;
  float acc[4][4] = {};
  for (int k0 = kb; k0 < ke; k0 += 16){
    #pragma unroll
    for (int q = 0; q < 4; q++){
      int idx = t*4 + q;
      int m = idx >> 4, kk = idx & 15;
      As[kk][m] = A[(size_t)(bm+m)*lda + (k0+kk)];
    }
    #pragma unroll
    for (int q = 0; q < 4; q++){
      int idx = t + q*256;
      int kk = idx >> 6, n = idx & 63;
      Bs[kk][n] = B[(size_t)(k0+kk)*ldb + (bn+n)];
    }
    __syncthreads();
    #pragma unroll
    for (int kk = 0; kk < 16; kk++){
      float a0 = As[kk][tr*4+0], a1 = As[kk][tr*4+1], a2 = As[kk][tr*4+2], a3 = As[kk][tr*4+3];
      float b0 = Bs[kk][tc*4+0], b1 = Bs[kk][tc*4+1], b2 = Bs[kk][tc*4+2], b3 = Bs[kk][tc*4+3];
      acc[0][0] += a0*b0; acc[0][1] += a0*b1; acc[0][2] += a0*b2; acc[0][3] += a0*b3;
      acc[1][0] += a1*b0; acc[1][1] += a1*b1; acc[1][2] += a1*b2; acc[1][3] += a1*b3;
      acc[2][0] += a2*b0; acc[2][1] += a2*b1; acc[2][2] += a2*b2; acc[2][3] += a2*b3;
      acc[3][0] += a3*b0; acc[3][1] += a3*b1; acc[3][2] += a3*b2; acc[3][3] += a3*b3;
    }
    __syncthreads();
  }
  #pragma unroll
  for (int i2 = 0; i2 < 4; i2++){
    int m = bm + tr*4 + i2;
    #pragma unroll
    for (int j2 = 0; j2 < 4; j2++){
      int n = bn + tc*4 + j2;
      atomicAdd(&Cc[(size_t)m*ldc + n], acc[i2][j2]);
    }
  }
}

// split-K TN: C += partial (C pre-zeroed); grid (Nn/16, M/16, K/kchunk)
__global__ __launch_bounds__(256) void k_gemm_tn_sk(int M, int Nn, int K, int kchunk,
      const float* __restrict__ A, int lda, const float* __restrict__ B, int ldb,
      float* __restrict__ Cc, int ldc, const float* __restrict__ kscale){
  __shared__ float As[32][17];
  __shared__ float Bs[32][17];
  int bm = blockIdx.y*16, bn = blockIdx.x*16;
  int kb = blockIdx.z*kchunk, ke = kb + kchunk;
  int t = threadIdx.x;
  int tm = t >> 4, tn = t & 15;
  float acc = 0.f;
  for (int k0 = kb; k0 < ke; k0 += 32){
    #pragma unroll
    for (int q = 0; q < 2; q++){
      int idx = t + q*256;
      int kk = idx >> 4, m = idx & 15;
      float sv = kscale ? kscale[k0+kk] : 1.0f;
      As[kk][m] = A[(size_t)(k0+kk)*lda + (bm+m)] * sv;
      Bs[kk][m] = B[(size_t)(k0+kk)*ldb + (bn+m)];
    }
    __syncthreads();
    #pragma unroll
    for (int kk = 0; kk < 32; kk++) acc += As[kk][tm] * Bs[kk][tn];
    __syncthreads();
  }
  atomicAdd(&Cc[(size_t)(bm+tm)*ldc + (bn+tn)], acc);
}

// ---------------- f64 randomized-subspace chain ----------------
__global__ __launch_bounds__(64) void k_spmm64(const int* __restrict__ ptr, const int* __restrict__ eid,
                       const int* __restrict__ oidx, const float* __restrict__ coef,
                       const double* __restrict__ X, double* __restrict__ Y){
  int seg = blockIdx.x;
  int t = threadIdx.x;
  double acc = 0.0;
  int p0 = ptr[seg], p1 = ptr[seg+1];
  for (int p = p0; p < p1; ++p){
    int e = eid[p];
    acc += (double)coef[e] * X[(size_t)oidx[e]*RK + t];
  }
  Y[(size_t)seg*RK + t] = acc;
}
// Gram: G += Xslice^T Xslice over 64-row slices (G zeroed before)
__global__ __launch_bounds__(256) void k_gram64(const double* __restrict__ X, double* __restrict__ G){
  __shared__ double Xs[64][65];
  int b = blockIdx.x;
  int t = threadIdx.x;
  #pragma unroll
  for (int q = 0; q < 16; q++){
    int idx = t + q*256;
    Xs[idx >> 6][idx & 63] = X[(size_t)(b*64 + (idx >> 6))*RK + (idx & 63)];
  }
  __syncthreads();
  int i = t >> 2;
  int j0 = (t & 3) * 16;
  double acc[16];
  #pragma unroll
  for (int jj = 0; jj < 16; jj++) acc[jj] = 0.0;
  for (int k = 0; k < 64; k++){
    double a = Xs[k][i];
    #pragma unroll
    for (int jj = 0; jj < 16; jj++) acc[jj] += a * Xs[k][j0+jj];
  }
  #pragma unroll
  for (int jj = 0; jj < 16; jj++) atomicAdd(&G[i*RK + j0 + jj], acc[jj]);
}
// Cholesky + upper-tri inverse, f64 (r20): blocked NB=16 right-looking.
//  - diag factor: SINGLE thread (own LDS reads/writes in program order — no
//    cross-lane hazards whatsoever); serial 16-step chain per block.
//  - diag inverse: 16 threads, thread c solves L u = e_c (reads L stable
//    after barrier + own Xl row only); X_pp = U^T stored into Xl.
//  - panel: one thread per row, register-staged G row (exclusive row).
//  - trailing: disjoint (i,j) elements, lower triangle.
//  All phases separated by full __syncthreads. Off-diag inverse rounds =
//  r19's proven code (Rl[gi][a] read as Gs[a][gi], strictly lower).
__global__ __launch_bounds__(256) void k_cholinv64(const double* __restrict__ G, double* __restrict__ Rinv){
  __shared__ double Gs[64][65];    // G in; L in lower triangle after factorization
  __shared__ double Xl[64][65];    // X = R^{-1} (upper); lower stays 0
  __shared__ double sdinv[64];
  __shared__ double Sl[3][16][17];
  int t = threadIdx.x;
  #pragma unroll
  for (int q = 0; q < 16; q++){
    int idx = t + (q << 8);
    Gs[idx >> 6][idx & 63] = G[idx];
  }
  for (int idx = t; idx < 64*65; idx += 256)
    ((double*)Xl)[idx] = 0.0;
  __syncthreads();
  for (int p = 0; p < 4; p++){
    int p0 = p << 4;
    // ---- diag block factor (single thread) ----
    if (t == 0){
      for (int k2 = 0; k2 < 16; k2++){
        double d2 = fmax(Gs[p0+k2][p0+k2], 1e-300);
        double s  = rsqrt(d2);
        Gs[p0+k2][p0+k2] = d2 * s;       // L[k2][k2] = sqrt(d2)
        sdinv[p0+k2] = s;                // 1/L[k2][k2]
        for (int i = k2+1; i < 16; i++) Gs[p0+i][p0+k2] *= s;
        for (int j = k2+1; j < 16; j++){
          double ljk = Gs[p0+j][p0+k2];
          for (int i = j; i < 16; i++)
            Gs[p0+i][p0+j] -= Gs[p0+i][p0+k2] * ljk;
        }
      }
    }
    __syncthreads();
    // ---- diag inverse: U = L_pp^{-1}; store X_pp = U^T: Xl[p0+c][p0+i] = U[i][c] ----
    if (t < 16){
      int c = t;
      Xl[p0+c][p0+c] = sdinv[p0+c];
      for (int i = c+1; i < 16; i++){
        double s = 0.0;
        for (int m = c; m < i; m++)
          s += Gs[p0+i][p0+m] * Xl[p0+c][p0+m];
        Xl[p0+c][p0+i] = -s * sdinv[p0+i];
      }
    }
    __syncthreads();
    if (p < 3){
      int p1 = p0 + 16;
      int nrows = 64 - p1;
      // ---- panel: L[i][p0+k] = sum_{m<=k} G[i][p0+m] * U[k][m], U[k][m]=Xl[p0+m][p0+k] ----
      if (t < nrows){
        int i = p1 + t;
        double g[16];
        #pragma unroll
        for (int m = 0; m < 16; m++) g[m] = Gs[i][p0+m];
        #pragma unroll
        for (int k = 0; k < 16; k++){
          double s = 0.0;
          #pragma unroll
          for (int m = 0; m <= k; m++)
            s += g[m] * Xl[p0+m][p0+k];
          Gs[i][p0+k] = s;
        }
      }
      __syncthreads();
      // ---- trailing update (lower triangle) ----
      int nr = nrows;
      int tot = nr * nr;
      for (int e = t; e < tot; e += 256){
        int i = p1 + e / nr, j = p1 + e % nr;
        if (i >= j){
          double s = 0.0;
          #pragma unroll
          for (int k = 0; k < 16; k++)
            s += Gs[i][p0+k] * Gs[j][p0+k];
          Gs[i][j] -= s;
        }
      }
      __syncthreads();
    }
  }
  // ---- off-diag blocks by superdiagonal d (r19-proven structure) ----
  for (int d = 1; d < 4; d++){
    int np = 4 - d;
    int tot = np << 8;
    for (int e = t; e < tot; e += 256){
      int p = e >> 8;
      int i = (e >> 4) & 15, jj = e & 15;
      int gi = (p << 4) + i, gj = ((p + d) << 4) + jj;
      double s = 0.0;
      int a0 = (p + 1) << 4, a1 = (p + d + 1) << 4;
      for (int a = a0; a < a1; a++)
        s += Gs[a][gi] * Xl[a][gj];     // R[gi][a] = L[a][gi] (strictly lower of Gs)
      Sl[p][i][jj] = s;
    }
    __syncthreads();
    for (int e = t; e < tot; e += 256){
      int p = e >> 8;
      int i = (e >> 4) & 15, jj = e & 15;
      int gi = (p << 4) + i, gj = ((p + d) << 4) + jj;
      double s = 0.0;
      #pragma unroll
      for (int k2 = 0; k2 < 16; k2++)
        s += Xl[gi][(p << 4) + k2] * Sl[p][k2][jj];   // Xl lower = 0
      Xl[gi][gj] = -s;
    }
    __syncthreads();
  }
  // ---- store (coalesced) ----
  #pragma unroll
  for (int q = 0; q < 16; q++){
    int e2 = t + (q << 8);
    Rinv[e2] = Xl[e2 >> 6][e2 & 63];
  }
}
// dst[NNx64] = src[NNx64] * Rinv(upper); 4 rows per 256-thread block
__global__ __launch_bounds__(256) void k_applyR64(const double* __restrict__ src,
      const double* __restrict__ Rinv, double* __restrict__ dst){
  __shared__ double Rs[64][65];
  int t = threadIdx.x;
  #pragma unroll
  for (int q = 0; q < 16; q++){
    int idx = t + q*256;
    Rs[idx >> 6][idx & 63] = Rinv[idx];
  }
  __syncthreads();
  int r = blockIdx.x*4 + (t >> 6);
  int j = t & 63;
  const double* rowp = src + (size_t)r*RK;
  double s = 0.0;
  for (int k = 0; k <= j; k++) s += rowp[k] * Rs[k][j];
  dst[(size_t)r*RK + j] = s;
}
__global__ __launch_bounds__(256) void k_qsum64(const double* __restrict__ Q, double* __restrict__ qs){
  int j = blockIdx.x;  int t = threadIdx.x;
  double a = 0.0;
  for (int n = t; n < NN; n += 256) a += Q[(size_t)n*RK + j];
  __shared__ double sh[256];
  sh[t] = a; __syncthreads();
  for (int off = 128; off > 0; off >>= 1){ if (t < off) sh[t] += sh[t+off]; __syncthreads(); }
  if (t == 0) qs[j] = sh[0];
}
__global__ __launch_bounds__(256) void k_deg2f(const double* __restrict__ C, const double* __restrict__ qs,
                                               float* __restrict__ dinv2){
  int i = blockIdx.x*256 + threadIdx.x;
  if (i >= NN) return;
  double s = 0.0;
  #pragma unroll
  for (int k = 0; k < RK; k++) s += C[(size_t)i*RK + k] * qs[k];
  dinv2[i] = (s > 0.0) ? (float)(1.0/sqrt(s)) : 0.f;
}

// ---------------- SpMM over sorted edge lists (f32, branch 1) ----------------
__global__ void k_spmm(const int* __restrict__ ptr, const int* __restrict__ eid,
                       const int* __restrict__ oidx, const float* __restrict__ coef,
                       const float* __restrict__ X, int ldx,
                       float* __restrict__ Y, int ldy, int F,
                       const float* __restrict__ self_dinv, const float* __restrict__ bias){
  int seg = blockIdx.x;
  int t = threadIdx.x, bd = blockDim.x;
  int f1 = t + bd;
  bool two = (f1 < F);
  float acc0 = 0.f, acc1 = 0.f;
  if (self_dinv){
    float sd = self_dinv[seg]; float s2 = sd*sd;
    acc0 = s2 * X[(size_t)seg*ldx + t];
    if (two) acc1 = s2 * X[(size_t)seg*ldx + f1];
  }
  int p0 = ptr[seg], p1 = ptr[seg+1];
  for (int p = p0; p < p1; ++p){
    int e = eid[p];
    int o = oidx[e];
    float c = coef[e];
    const float* xr = X + (size_t)o*ldx;
    acc0 += c * xr[t];
    if (two) acc1 += c * xr[f1];
  }
  if (bias){ acc0 += bias[t]; if (two) acc1 += bias[f1]; }
  Y[(size_t)seg*ldy + t] = acc0;
  if (two) Y[(size_t)seg*ldy + f1] = acc1;
}

// ---------------- domain-specific BN ----------------
__global__ __launch_bounds__(256) void k_bnstats(const float* __restrict__ H, const int* __restrict__ y,
        const int* __restrict__ dcnt, const float* __restrict__ gamma, const float* __restrict__ beta,
        float* __restrict__ scal, float* __restrict__ shft){
  int j = blockIdx.x;
  int t = threadIdx.x;
  float s0=0,s1=0,s2=0,s3=0,q0=0,q1=0,q2=0,q3=0;
  for (int n = t; n < NN; n += 256){
    float v = H[(size_t)n*HIDC + j];
    int d = y[n];
    float v2 = v*v;
    if      (d == 0){ s0 += v; q0 += v2; }
    else if (d == 1){ s1 += v; q1 += v2; }
    else if (d == 2){ s2 += v; q2 += v2; }
    else            { s3 += v; q3 += v2; }
  }
  __shared__ float sh[256][8];
  sh[t][0]=s0; sh[t][1]=s1; sh[t][2]=s2; sh[t][3]=s3;
  sh[t][4]=q0; sh[t][5]=q1; sh[t][6]=q2; sh[t][7]=q3;
  __syncthreads();
  for (int off = 128; off > 0; off >>= 1){
    if (t < off){
      #pragma unroll
      for (int q = 0; q < 8; q++) sh[t][q] += sh[t+off][q];
    }
    __syncthreads();
  }
  if (t < NDOM){
    float cnt  = fmaxf((float)dcnt[t], 1.0f);
    float mean = sh[0][t] / cnt;
    float var  = fmaxf(sh[0][4+t] / cnt - mean*mean, 0.f);
    float inv  = 1.0f / sqrtf(var + EPSBN);
    float gmm  = gamma[t*HIDC + j];
    scal[t*HIDC + j] = gmm * inv;
    shft[t*HIDC + j] = beta[t*HIDC + j] - mean * gmm * inv;
  }
}
__global__ __launch_bounds__(256) void k_bnapply(float* __restrict__ H, const int* __restrict__ y,
        const float* __restrict__ scal, const float* __restrict__ shft){
  int idx = blockIdx.x*256 + threadIdx.x;
  if (idx >= NN*HIDC) return;
  int n = idx >> 9, j = idx & (HIDC-1);
  int d = y[n];
  float v = H[idx] * scal[d*HIDC + j] + shft[d*HIDC + j];
  H[idx] = v > 0.f ? v : 0.f;
}

// ---------------- launch ----------------
extern "C" void kernel_launch(void* const* d_in, const int* in_sizes, int n_in,
                              void* d_out, int out_size, void* d_ws, size_t ws_size,
                              hipStream_t stream){
  (void)in_sizes; (void)n_in; (void)out_size;
  const void* x_in  = d_in[0];
  const int*  ei    = (const int*)d_in[1];
  const void* w_in  = d_in[2];
  const int*  yv    = (const int*)d_in[3];
  const void* W1i   = d_in[4];
  const void* b1i   = d_in[5];
  const void* Wmui  = d_in[6];
  const void* bmui  = d_in[7];
  const void* Wlvi  = d_in[8];
  const void* blvi  = d_in[9];
  const void* gmi   = d_in[10];
  const void* bti   = d_in[11];
  const int* rowA = ei;
  const int* colA = ei + NEDG;
  float* zout = (float*)d_out;

  // ---- workspace: doubles | floats | ints ----
  double* Dp = (double*)d_ws;
  size_t od = 0;
  double* Qd0 = Dp + od; od += (size_t)NN*RK;
  double* Qd1 = Dp + od; od += (size_t)NN*RK;
  double* Cd  = Dp + od; od += (size_t)NN*RK;
  double* Gd  = Dp + od; od += RK*RK;
  double* Rid = Dp + od; od += RK*RK;
  double* qsd = Dp + od; od += RK;
  float* Fp = (float*)(Dp + od);
  size_t o = 0;
  float* xf   = Fp + o; o += (size_t)NN*INC;       // reused as h1/h2 buffer
  float* W1f  = Fp + o; o += (size_t)INC*HIDC;
  float* b1f  = Fp + o; o += HIDC;
  float* Wmuf = Fp + o; o += (size_t)HIDC*OUTC;
  float* bmuf = Fp + o; o += OUTC;
  float* Wlvf = Fp + o; o += (size_t)HIDC*OUTC;
  float* blvf = Fp + o; o += OUTC;
  float* gmf  = Fp + o; o += NDOM*HIDC;
  float* btf  = Fp + o; o += NDOM*HIDC;
  float* wf   = Fp + o; o += NEDG;
  float* xw1  = Fp + o; o += (size_t)NN*HIDC;
  float* hwA  = Fp + o; o += (size_t)NN*OUTC;
  float* hwB  = Fp + o; o += (size_t)NN*OUTC;     // contiguous after hwA
  float* Bf1  = Fp + o; o += (size_t)NN*RK;        // Qb (f32)
  float* Cm   = Fp + o; o += (size_t)NN*RK;        // C (f32)
  float* Tm   = Fp + o; o += (size_t)RK*HIDC;
  float* Umu  = Fp + o; o += RK*RK;
  float* deg1 = Fp + o; o += NN;
  float* dinv1= Fp + o; o += NN;
  float* dinv2= Fp + o; o += NN;
  float* norm1= Fp + o; o += NEDG;
  float* scal = Fp + o; o += NDOM*HIDC;
  float* shft = Fp + o; o += NDOM*HIDC;
  int* Ip = (int*)(Fp + o);
  size_t oi = 0;
  int* cntR = Ip + oi; oi += NN;
  int* ptrR = Ip + oi; oi += NN + 1;
  int* posR = Ip + oi; oi += NN;
  int* eidR = Ip + oi; oi += NEDG;
  int* cntC = Ip + oi; oi += NN;
  int* ptrC = Ip + oi; oi += NN + 1;
  int* posC = Ip + oi; oi += NN;
  int* eidC = Ip + oi; oi += NEDG;
  int* dcnt = Ip + oi; oi += NDOM;
  int* dflag= Ip + oi; oi += 1;

  size_t need = od*sizeof(double) + o*sizeof(float) + (oi+16)*sizeof(int);
  if (ws_size < need) return;

  float* hbuf = xf;  // x dead after xw1 GEMM

  const int T = 256;
  k_detect<<<1,T,0,stream>>>((const unsigned short*)x_in, dflag);
  k_upcast_all<<<cdiv(OFFT,T),T,0,stream>>>(
      x_in, W1i, w_in, Wmui, Wlvi, gmi, bti, b1i, bmui, blvi, dflag,
      xf, W1f, wf, Wmuf, Wlvf, gmf, btf, b1f, bmuf, blvf);

  k_prep<<<cdiv(NN,T),T,0,stream>>>(deg1, cntR, cntC, dcnt);
  k_hist <<<cdiv(NEDG,T),T,0,stream>>>(rowA, colA, wf, deg1, cntR, cntC);
  k_dinv <<<cdiv(NN,T),T,0,stream>>>(deg1, dinv1, NN);
  k_norm1<<<cdiv(NEDG,T),T,0,stream>>>(rowA, colA, wf, dinv1, norm1);
  k_scan4096<<<1,1024,0,stream>>>(cntR, ptrR, posR);
  k_scan4096<<<1,1024,0,stream>>>(cntC, ptrC, posC);
  k_scatter<<<cdiv(NEDG,T),T,0,stream>>>(rowA, colA, posR, posC, eidR, eidC);
  k_omega<<<cdiv(NN*RK,T),T,0,stream>>>(Qd0);      // f64 seed directly
  k_dcnt <<<cdiv(NN,T),T,0,stream>>>(yv, dcnt);

  // ---- branch 1 ----
  k_gemm_nn<<<dim3(HIDC/64, NN/64),256,0,stream>>>(NN,HIDC,INC, xf,INC, W1f,HIDC, xw1,HIDC, nullptr,nullptr,nullptr);
  k_spmm<<<NN,256,0,stream>>>(ptrC,eidC,rowA,norm1, xw1,HIDC, hbuf,HIDC, HIDC, dinv1, b1f);
  k_bnstats<<<HIDC,256,0,stream>>>(hbuf, yv, dcnt, gmf, btf, scal, shft);
  k_bnapply<<<cdiv(NN*HIDC,T),T,0,stream>>>(hbuf, yv, scal, shft);
  k_fill<<<cdiv(2*NN*OUTC,T),T,0,stream>>>(hwA, 0.f, 2*NN*OUTC);   // hwA|hwB contiguous
  k_gemm_nn_sk<<<dim3(1, NN/64, 4),256,0,stream>>>(NN,OUTC,HIDC,128, hbuf,HIDC, Wmuf,OUTC, hwA,OUTC);
  k_gemm_nn_sk<<<dim3(1, NN/64, 4),256,0,stream>>>(NN,OUTC,HIDC,128, hbuf,HIDC, Wlvf,OUTC, hwB,OUTC);
  k_spmm<<<NN,64,0,stream>>>(ptrC,eidC,rowA,norm1, hwA,OUTC, zout + 0*NN*OUTC,OUTC, OUTC, dinv1, bmuf);
  k_spmm<<<NN,64,0,stream>>>(ptrC,eidC,rowA,norm1, hwB,OUTC, zout + 1*NN*OUTC,OUTC, OUTC, dinv1, blvf);

  // ---- branch 2: f64 subspace, single final QR1 ----
  auto spmmA64 = [&](const double* s, double* d){   // d = A @ s
    k_spmm64<<<NN,64,0,stream>>>(ptrR,eidR,colA,wf, s, d);
  };
  auto spmmAT64 = [&](const double* s, double* d){  // d = A^T @ s
    k_spmm64<<<NN,64,0,stream>>>(ptrC,eidC,rowA,wf, s, d);
  };

  spmmA64 (Qd0, Qd1);                      // P1 -> Qd1
  spmmAT64(Qd1, Qd0);                      // P2 -> Qd0
  spmmA64 (Qd0, Qd1);                      // P3 -> Qd1
  spmmAT64(Qd1, Qd0);                      // P4 -> Qd0
  spmmA64 (Qd0, Qd1);                      // P5 -> Qd1
  k_filld<<<cdiv(RK*RK,T),T,0,stream>>>(Gd, 0.0, RK*RK);
  k_gram64<<<NN/64,256,0,stream>>>(Qd1, Gd);
  k_cholinv64<<<1,256,0,stream>>>(Gd, Rid);
  k_applyR64<<<NN/4,256,0,stream>>>(Qd1, Rid, Qd0); // Qb -> Qd0
  spmmAT64(Qd0, Cd);                       // C = A^T Qb  (A2 = Qb C^T)
  k_qsum64<<<RK,256,0,stream>>>(Qd0, qsd);
  k_deg2f<<<cdiv(NN,T),T,0,stream>>>(Cd, qsd, dinv2);
  k_f64to32x2<<<cdiv(NN*RK,T),T,0,stream>>>(Qd0, Bf1, Cd, Cm, NN*RK);

  // h2 = dsbn_relu( D C (Qb^T (D xw1)) + b1 )
  k_fill<<<cdiv(RK*HIDC,T),T,0,stream>>>(Tm, 0.f, RK*HIDC);
  k_gemm_tn_sk<<<dim3(HIDC/16, RK/16, 8),256,0,stream>>>(RK,HIDC,NN,512, Bf1,RK, xw1,HIDC, Tm,HIDC, dinv2);
  k_gemm_nn<<<dim3(HIDC/64, NN/64),256,0,stream>>>(NN,HIDC,RK, Cm,RK, Tm,HIDC, hbuf,HIDC, dinv2, nullptr, b1f);
  k_bnstats<<<HIDC,256,0,stream>>>(hbuf, yv, dcnt, gmf, btf, scal, shft);
  k_bnapply<<<cdiv(NN*HIDC,T),T,0,stream>>>(hbuf, yv, scal, shft);
  // z2 = D C (Qb^T (D (h2 W))) + b
  k_fill<<<cdiv(2*NN*OUTC,T),T,0,stream>>>(hwA, 0.f, 2*NN*OUTC);
  k_gemm_nn_sk<<<dim3(1, NN/64, 4),256,0,stream>>>(NN,OUTC,HIDC,128, hbuf,HIDC, Wmuf,OUTC, hwA,OUTC);
  k_gemm_nn_sk<<<dim3(1, NN/64, 4),256,0,stream>>>(NN,OUTC,HIDC,128, hbuf,HIDC, Wlvf,OUTC, hwB,OUTC);
  k_fill<<<cdiv(RK*RK,T),T,0,stream>>>(Umu, 0.f, RK*RK);
  k_gemm_tn_sk<<<dim3(RK/16, RK/16, 16),256,0,stream>>>(RK,RK,NN,256, Bf1,RK, hwA,OUTC, Umu,RK, dinv2);
  k_gemm_nn<<<dim3(1, NN/64),256,0,stream>>>(NN,OUTC,RK, Cm,RK, Umu,RK, zout + 2*NN*OUTC,OUTC, dinv2, nullptr, bmuf);
  k_fill<<<cdiv(RK*RK,T),T,0,stream>>>(Umu, 0.f, RK*RK);
  k_gemm_tn_sk<<<dim3(RK/16, RK/16, 16),256,0,stream>>>(RK,RK,NN,256, Bf1,RK, hwB,OUTC, Umu,RK, dinv2);
  k_gemm_nn<<<dim3(1, NN/64),256,0,stream>>>(NN,OUTC,RK, Cm,RK, Umu,RK, zout + 3*NN*OUTC,OUTC, dinv2, nullptr, blvf);
}

// Round 5
// 900.562 us; speedup vs baseline: 1.2640x; 1.0329x over previous
//
#include <hip/hip_runtime.h>
#include <hip/hip_bf16.h>

// GCNEncoder — r21: factorization split out as k_chol64 (blockDim=64, ONE
// wave): lane j owns column j fully in registers (compile-time indices;
// diagonal tracked in cdiag scalar), per-step LDS column broadcast fenced by
// __syncthreads (1-wave barrier ~free). Update order arithmetically identical
// to r16's proven factorization. Inverse stays blocked (r19/r20-proven) in
// k_trinv64 (blockDim=256), consuming L+sdinv via global. r20's single-thread
// diag factor regressed (85->100us: serial f64 LDS chains); this removes the
// cross-wave-barrier cost AND the serial-LDS cost.
// History: r20 930us; r19 943us; r18 982us; r16 1138us.

#define NN    4096
#define NEDG  131072
#define INC   512
#define HIDC  512
#define OUTC  64
#define RK    64
#define NDOM  4
#define EPSBN 1e-5f

static inline int cdiv(int a, int b){ return (a + b - 1) / b; }

// ---------------- input dtype detection (f32 vs bf16 carriers) ----------------
__global__ __launch_bounds__(256) void k_detect(const unsigned short* __restrict__ p,
                                                int* __restrict__ flag){
  int t = threadIdx.x;
  int cnt = 0;
  for (int i = t; i < 4096; i += 256){
    unsigned short v = p[2*i];
    int e = (v >> 7) & 0xFF;
    if (e >= 100 && e <= 140) cnt++;
  }
  __shared__ int sh[256];
  sh[t] = cnt; __syncthreads();
  for (int off = 128; off > 0; off >>= 1){ if (t < off) sh[t] += sh[t+off]; __syncthreads(); }
  if (t == 0) *flag = (sh[0] >= 2048) ? 0 : 1;
}

// ---------------- fused upcast of all 10 inputs ----------------
__device__ __forceinline__ float upc1(const void* s, int f, int off){
  return f ? ((const float*)s)[off]
           : __bfloat162float(((const __hip_bfloat16*)s)[off]);
}
#define SEG_X   2097152
#define SEG_W1  262144
#define SEG_W   131072
#define SEG_WMU 32768
#define SEG_GB  2048
#define SEG_B1  512
#define SEG_BO  64
#define OFF1 (SEG_X)
#define OFF2 (OFF1+SEG_W1)
#define OFF3 (OFF2+SEG_W)
#define OFF4 (OFF3+SEG_WMU)
#define OFF5 (OFF4+SEG_WMU)
#define OFF6 (OFF5+SEG_GB)
#define OFF7 (OFF6+SEG_GB)
#define OFF8 (OFF7+SEG_B1)
#define OFF9 (OFF8+SEG_BO)
#define OFFT (OFF9+SEG_BO)

__global__ __launch_bounds__(256) void k_upcast_all(
    const void* x, const void* W1, const void* w, const void* Wmu, const void* Wlv,
    const void* gm, const void* bt, const void* b1, const void* bmu, const void* blv,
    const int* __restrict__ isf32,
    float* dx, float* dW1, float* dw, float* dWmu, float* dWlv,
    float* dgm, float* dbt, float* db1, float* dbmu, float* dblv){
  int i = blockIdx.x*256 + threadIdx.x;
  if (i >= OFFT) return;
  int f = *isf32;
  if      (i < OFF1) dx  [i]        = upc1(x,   f, i);
  else if (i < OFF2) dW1 [i - OFF1] = upc1(W1,  f, i - OFF1);
  else if (i < OFF3) dw  [i - OFF2] = upc1(w,   f, i - OFF2);
  else if (i < OFF4) dWmu[i - OFF3] = upc1(Wmu, f, i - OFF3);
  else if (i < OFF5) dWlv[i - OFF4] = upc1(Wlv, f, i - OFF4);
  else if (i < OFF6) dgm [i - OFF5] = upc1(gm,  f, i - OFF5);
  else if (i < OFF7) dbt [i - OFF6] = upc1(bt,  f, i - OFF6);
  else if (i < OFF8) db1 [i - OFF7] = upc1(b1,  f, i - OFF7);
  else if (i < OFF9) dbmu[i - OFF8] = upc1(bmu, f, i - OFF8);
  else               dblv[i - OFF9] = upc1(blv, f, i - OFF9);
}

// ---------------- elementwise utils ----------------
__global__ __launch_bounds__(256) void k_fill(float* d, float v, int n){
  int i = blockIdx.x*256 + threadIdx.x;
  if (i < n) d[i] = v;
}
__global__ __launch_bounds__(256) void k_filld(double* d, double v, int n){
  int i = blockIdx.x*256 + threadIdx.x;
  if (i < n) d[i] = v;
}
__global__ __launch_bounds__(256) void k_prep(float* deg, int* cntR, int* cntC, int* dcnt){
  int i = blockIdx.x*256 + threadIdx.x;
  if (i < NN){ deg[i] = 1.0f; cntR[i] = 0; cntC[i] = 0; }
  if (i < NDOM) dcnt[i] = 0;
}
__global__ __launch_bounds__(256) void k_f64to32x2(const double* __restrict__ s0, float* __restrict__ d0,
                                                   const double* __restrict__ s1, float* __restrict__ d1,
                                                   int n){
  int i = blockIdx.x*256 + threadIdx.x;
  if (i < n){ d0[i] = (float)s0[i]; d1[i] = (float)s1[i]; }
}

// ---------------- graph preprocessing ----------------
__global__ __launch_bounds__(256) void k_hist(const int* __restrict__ row, const int* __restrict__ col,
                                              const float* __restrict__ w, float* deg,
                                              int* cntR, int* cntC){
  int e = blockIdx.x*256 + threadIdx.x;
  if (e < NEDG){
    atomicAdd(&deg[col[e]], w[e]);
    atomicAdd(&cntR[row[e]], 1);
    atomicAdd(&cntC[col[e]], 1);
  }
}
__global__ __launch_bounds__(256) void k_dinv(const float* deg, float* dinv, int n){
  int i = blockIdx.x*256 + threadIdx.x;
  if (i < n){ float d = deg[i]; dinv[i] = (d > 0.f) ? 1.f/sqrtf(d) : 0.f; }
}
__global__ __launch_bounds__(256) void k_norm1(const int* __restrict__ row, const int* __restrict__ col,
                                               const float* __restrict__ w, const float* __restrict__ dinv,
                                               float* __restrict__ nrm){
  int e = blockIdx.x*256 + threadIdx.x;
  if (e < NEDG) nrm[e] = dinv[row[e]] * w[e] * dinv[col[e]];
}
__global__ __launch_bounds__(1024) void k_scan4096(const int* __restrict__ cnt,
                                                   int* __restrict__ ptr, int* __restrict__ pos){
  __shared__ int sh[1024];
  int t = threadIdx.x;
  int b = t*4;
  int a0 = cnt[b], a1 = cnt[b+1], a2 = cnt[b+2], a3 = cnt[b+3];
  sh[t] = a0 + a1 + a2 + a3;
  __syncthreads();
  for (int off = 1; off < 1024; off <<= 1){
    int v = (t >= off) ? sh[t-off] : 0;
    __syncthreads();
    sh[t] += v;
    __syncthreads();
  }
  int excl = (t == 0) ? 0 : sh[t-1];
  ptr[b]   = excl;            pos[b]   = excl;
  ptr[b+1] = excl+a0;         pos[b+1] = excl+a0;
  ptr[b+2] = excl+a0+a1;      pos[b+2] = excl+a0+a1;
  ptr[b+3] = excl+a0+a1+a2;   pos[b+3] = excl+a0+a1+a2;
  if (t == 1023) ptr[4096] = sh[1023];
}
__global__ __launch_bounds__(256) void k_scatter(const int* __restrict__ row, const int* __restrict__ col,
                                                 int* posR, int* posC, int* eidR, int* eidC){
  int e = blockIdx.x*256 + threadIdx.x;
  if (e < NEDG){
    int p = atomicAdd(&posR[row[e]], 1); eidR[p] = e;
    int q = atomicAdd(&posC[col[e]], 1); eidC[q] = e;
  }
}
__global__ __launch_bounds__(256) void k_dcnt(const int* __restrict__ y, int* dcnt){
  int i = blockIdx.x*256 + threadIdx.x;
  if (i < NN) atomicAdd(&dcnt[y[i]], 1);
}

// ---------------- threefry2x32 core (KAT-verified round 8) ----------------
__device__ __forceinline__ unsigned rotl32(unsigned x, unsigned d){ return (x << d) | (x >> (32u - d)); }
#define TF_ROUND4(R0,R1,R2,R3) \
  x0 += x1; x1 = rotl32(x1,R0); x1 ^= x0; \
  x0 += x1; x1 = rotl32(x1,R1); x1 ^= x0; \
  x0 += x1; x1 = rotl32(x1,R2); x1 ^= x0; \
  x0 += x1; x1 = rotl32(x1,R3); x1 ^= x0;

__device__ __forceinline__ void tf2x32(unsigned k0, unsigned k1, unsigned c0, unsigned c1,
                                       unsigned* o0, unsigned* o1){
  unsigned ks2 = 0x1BD11BDAu ^ k0 ^ k1;
  unsigned x0 = c0 + k0, x1 = c1 + k1;
  TF_ROUND4(13,15,26,6);   x0 += k1;  x1 += ks2 + 1u;
  TF_ROUND4(17,29,16,24);  x0 += ks2; x1 += k0 + 2u;
  TF_ROUND4(13,15,26,6);   x0 += k0;  x1 += k1 + 3u;
  TF_ROUND4(17,29,16,24);  x0 += k1;  x1 += ks2 + 4u;
  TF_ROUND4(13,15,26,6);   x0 += ks2; x1 += k0 + 5u;
  *o0 = x0; *o1 = x1;
}

// ---------------- omega (verified round 10; direct f64 output) ----------------
__device__ double erfinv64(double x){
  double w = -log1p(-x*x);
  double p;
  if (w < 5.0){
    w -= 2.5;
    p = 2.81022636e-08;  p = p*w + 3.43273939e-07; p = p*w - 3.5233877e-06;
    p = p*w - 4.39150654e-06; p = p*w + 0.00021858087; p = p*w - 0.00125372503;
    p = p*w - 0.00417768164;  p = p*w + 0.246640727;   p = p*w + 1.50140941;
  } else {
    w = sqrt(w) - 3.0;
    p = -0.000200214257; p = p*w + 0.000100950558; p = p*w + 0.00134934322;
    p = p*w - 0.00367342844; p = p*w + 0.00573950773; p = p*w - 0.0076224613;
    p = p*w + 0.00943887047; p = p*w + 1.00167406;    p = p*w + 2.83297682;
  }
  double y = p * x;
  const double c = 1.1283791670955126;   // 2/sqrt(pi)
  #pragma unroll
  for (int it = 0; it < 3; it++){
    double err = erf(y) - x;
    y -= err / (c * exp(-y*y));
  }
  return y;
}

__device__ float bits_to_normal(unsigned b){
  float f = __uint_as_float((b >> 9) | 0x3f800000u) - 1.0f;
  const float lo = -0.99999994f;               // nextafter(-1,0) in f32
  float x = fmaxf(lo, f * 2.0f + lo);
  double r = 1.4142135623730951 * erfinv64((double)x);
  return (float)r;
}

__global__ __launch_bounds__(256) void k_omega(double* __restrict__ om){
  int i = blockIdx.x*256 + threadIdx.x;
  if (i >= 262144) return;
  unsigned o0, o1;
  tf2x32(0u, 42u, 0u, (unsigned)i, &o0, &o1);   // counter = (0, i)
  om[i] = (double)bits_to_normal(o0 ^ o1);      // same f32 value as before, widened
}

// ---------------- GEMM (fp32, tiled 64x64, 4x4/thread) ----------------
__global__ __launch_bounds__(256) void k_gemm_nn(int M, int Nn, int K,
      const float* __restrict__ A, int lda, const float* __restrict__ B, int ldb,
      float* __restrict__ Cc, int ldc, const float* __restrict__ rowscale,
      const float* __restrict__ kscale, const float* __restrict__ bias){
  __shared__ float As[16][65];
  __shared__ float Bs[16][65];
  int bm = blockIdx.y*64, bn = blockIdx.x*64;
  int t = threadIdx.x;
  int tr = t >> 4, tc = t & 15;
  float acc[4][4] = {};
  for (int k0 = 0; k0 < K; k0 += 16){
    #pragma unroll
    for (int q = 0; q < 4; q++){
      int idx = t*4 + q;
      int m = idx >> 4, kk = idx & 15;
      As[kk][m] = A[(size_t)(bm+m)*lda + (k0+kk)];
    }
    #pragma unroll
    for (int q = 0; q < 4; q++){
      int idx = t + q*256;
      int kk = idx >> 6, n = idx & 63;
      float ks = kscale ? kscale[k0+kk] : 1.0f;
      Bs[kk][n] = B[(size_t)(k0+kk)*ldb + (bn+n)] * ks;
    }
    __syncthreads();
    #pragma unroll
    for (int kk = 0; kk < 16; kk++){
      float a0 = As[kk][tr*4+0], a1 = As[kk][tr*4+1], a2 = As[kk][tr*4+2], a3 = As[kk][tr*4+3];
      float b0 = Bs[kk][tc*4+0], b1 = Bs[kk][tc*4+1], b2 = Bs[kk][tc*4+2], b3 = Bs[kk][tc*4+3];
      acc[0][0] += a0*b0; acc[0][1] += a0*b1; acc[0][2] += a0*b2; acc[0][3] += a0*b3;
      acc[1][0] += a1*b0; acc[1][1] += a1*b1; acc[1][2] += a1*b2; acc[1][3] += a1*b3;
      acc[2][0] += a2*b0; acc[2][1] += a2*b1; acc[2][2] += a2*b2; acc[2][3] += a2*b3;
      acc[3][0] += a3*b0; acc[3][1] += a3*b1; acc[3][2] += a3*b2; acc[3][3] += a3*b3;
    }
    __syncthreads();
  }
  #pragma unroll
  for (int i2 = 0; i2 < 4; i2++){
    int m = bm + tr*4 + i2;
    float rs = rowscale ? rowscale[m] : 1.0f;
    #pragma unroll
    for (int j2 = 0; j2 < 4; j2++){
      int n = bn + tc*4 + j2;
      float v = acc[i2][j2] * rs;
      if (bias) v += bias[n];
      Cc[(size_t)m*ldc + n] = v;
    }
  }
}

// split-K NN: C += partial (C pre-zeroed); grid (Nn/64, M/64, K/kchunk)
__global__ __launch_bounds__(256) void k_gemm_nn_sk(int M, int Nn, int K, int kchunk,
      const float* __restrict__ A, int lda, const float* __restrict__ B, int ldb,
      float* __restrict__ Cc, int ldc){
  __shared__ float As[16][65];
  __shared__ float Bs[16][65];
  int bm = blockIdx.y*64, bn = blockIdx.x*64;
  int kb = blockIdx.z*kchunk, ke = kb + kchunk;
  int t = threadIdx.x;
  int tr = t >> 4, tc = t & 15;
  float acc[4][4] = {};
  for (int k0 = kb; k0 < ke; k0 += 16){
    #pragma unroll
    for (int q = 0; q < 4; q++){
      int idx = t*4 + q;
      int m = idx >> 4, kk = idx & 15;
      As[kk][m] = A[(size_t)(bm+m)*lda + (k0+kk)];
    }
    #pragma unroll
    for (int q = 0; q < 4; q++){
      int idx = t + q*256;
      int kk = idx >> 6, n = idx & 63;
      Bs[kk][n] = B[(size_t)(k0+kk)*ldb + (bn+n)];
    }
    __syncthreads();
    #pragma unroll
    for (int kk = 0; kk < 16; kk++){
      float a0 = As[kk][tr*4+0], a1 = As[kk][tr*4+1], a2 = As[kk][tr*4+2], a3 = As[kk][tr*4+3];
      float b0 = Bs[kk][tc*4+0], b1 = Bs[kk][tc*4+1], b2 = Bs[kk][tc*4+2], b3 = Bs[kk][tc*4+3];
      acc[0][0] += a0*b0; acc[0][1] += a0*b1; acc[0][2] += a0*b2; acc[0][3] += a0*b3;
      acc[1][0] += a1*b0; acc[1][1] += a1*b1; acc[1][2] += a1*b2; acc[1][3] += a1*b3;
      acc[2][0] += a2*b0; acc[2][1] += a2*b1; acc[2][2] += a2*b2; acc[2][3] += a2*b3;
      acc[3][0] += a3*b0; acc[3][1] += a3*b1; acc[3][2] += a3*b2; acc[3][3] += a3*b3;
    }
    __syncthreads();
  }
  #pragma unroll
  for (int i2 = 0; i2 < 4; i2++){
    int m = bm + tr*4 + i2;
    #pragma unroll
    for (int j2 = 0; j2 < 4; j2++){
      int n = bn + tc*4 + j2;
      atomicAdd(&Cc[(size_t)m*ldc + n], acc[i2][j2]);
    }
  }
}

// split-K TN: C += partial (C pre-zeroed); grid (Nn/16, M/16, K/kchunk)
__global__ __launch_bounds__(256) void k_gemm_tn_sk(int M, int Nn, int K, int kchunk,
      const float* __restrict__ A, int lda, const float* __restrict__ B, int ldb,
      float* __restrict__ Cc, int ldc, const float* __restrict__ kscale){
  __shared__ float As[32][17];
  __shared__ float Bs[32][17];
  int bm = blockIdx.y*16, bn = blockIdx.x*16;
  int kb = blockIdx.z*kchunk, ke = kb + kchunk;
  int t = threadIdx.x;
  int tm = t >> 4, tn = t & 15;
  float acc = 0.f;
  for (int k0 = kb; k0 < ke; k0 += 32){
    #pragma unroll
    for (int q = 0; q < 2; q++){
      int idx = t + q*256;
      int kk = idx >> 4, m = idx & 15;
      float sv = kscale ? kscale[k0+kk] : 1.0f;
      As[kk][m] = A[(size_t)(k0+kk)*lda + (bm+m)] * sv;
      Bs[kk][m] = B[(size_t)(k0+kk)*ldb + (bn+m)];
    }
    __syncthreads();
    #pragma unroll
    for (int kk = 0; kk < 32; kk++) acc += As[kk][tm] * Bs[kk][tn];
    __syncthreads();
  }
  atomicAdd(&Cc[(size_t)(bm+tm)*ldc + (bn+tn)], acc);
}

// ---------------- f64 randomized-subspace chain ----------------
__global__ __launch_bounds__(64) void k_spmm64(const int* __restrict__ ptr, const int* __restrict__ eid,
                       const int* __restrict__ oidx, const float* __restrict__ coef,
                       const double* __restrict__ X, double* __restrict__ Y){
  int seg = blockIdx.x;
  int t = threadIdx.x;
  double acc = 0.0;
  int p0 = ptr[seg], p1 = ptr[seg+1];
  for (int p = p0; p < p1; ++p){
    int e = eid[p];
    acc += (double)coef[e] * X[(size_t)oidx[e]*RK + t];
  }
  Y[(size_t)seg*RK + t] = acc;
}
// Gram: G += Xslice^T Xslice over 64-row slices (G zeroed before)
__global__ __launch_bounds__(256) void k_gram64(const double* __restrict__ X, double* __restrict__ G){
  __shared__ double Xs[64][65];
  int b = blockIdx.x;
  int t = threadIdx.x;
  #pragma unroll
  for (int q = 0; q < 16; q++){
    int idx = t + q*256;
    Xs[idx >> 6][idx & 63] = X[(size_t)(b*64 + (idx >> 6))*RK + (idx & 63)];
  }
  __syncthreads();
  int i = t >> 2;
  int j0 = (t & 3) * 16;
  double acc[16];
  #pragma unroll
  for (int jj = 0; jj < 16; jj++) acc[jj] = 0.0;
  for (int k = 0; k < 64; k++){
    double a = Xs[k][i];
    #pragma unroll
    for (int jj = 0; jj < 16; jj++) acc[jj] += a * Xs[k][j0+jj];
  }
  #pragma unroll
  for (int jj = 0; jj < 16; jj++) atomicAdd(&G[i*RK + j0 + jj], acc[jj]);
}
// ---- Cholesky factorization, ONE wave (r21). Lane j owns column j in
// registers (compile-time indices only; diagonal tracked in cdiag scalar).
// Per step k: owner lane scales column + writes LDS; __syncthreads (1-wave
// barrier, cheap); readers broadcast-read + FMA. Update order identical to
// r16's proven factorization. L overwrites G in global; sdinv -> sdd.
#define CHOL_CHUNK(I0) \
  for (int k2 = 0; k2 < 16; k2++){ \
    int k = (I0) + k2; \
    int buf = k & 1; \
    if (j == k){ \
      double d = sqrt(fmax(cdiag, 1e-300)); \
      double s = 1.0 / d; \
      myd = d; \
      sdd[k] = s; \
      _Pragma("unroll") \
      for (int i = (I0); i < 64; i++){ c[i] *= s; colk[buf][i] = c[i]; } \
    } \
    __syncthreads(); \
    if (j > k){ \
      double cj = colk[buf][j]; \
      cdiag -= cj * cj; \
      _Pragma("unroll") \
      for (int i = (I0); i < 64; i++){ c[i] -= colk[buf][i] * cj; } \
    } \
    __syncthreads(); \
  }

__global__ __launch_bounds__(64) void k_chol64(double* __restrict__ G, double* __restrict__ sdd){
  __shared__ double colk[2][64];
  int j = threadIdx.x;        // 0..63, owns column j
  double c[64];
  #pragma unroll
  for (int i = 0; i < 64; i++) c[i] = G[i*64 + j];
  double cdiag = 0.0, myd = 0.0;
  #pragma unroll
  for (int i = 0; i < 64; i++) if (i == j) cdiag = c[i];
  CHOL_CHUNK(0)
  CHOL_CHUNK(16)
  CHOL_CHUNK(32)
  CHOL_CHUNK(48)
  // dump L over G: L[i][j] for i>j = c[i] (scaled), diag = myd, upper = 0
  #pragma unroll
  for (int i = 0; i < 64; i++){
    double v = (i > j) ? c[i] : 0.0;
    if (i == j) v = myd;
    G[i*64 + j] = v;
  }
}
// ---- blocked triangular inverse (r19/r20-proven stages), 256 threads.
// Reads L (lower, from k_chol64) + sdinv; writes Rinv = R^{-1} (upper).
__global__ __launch_bounds__(256) void k_trinv64(const double* __restrict__ L,
      const double* __restrict__ sdd, double* __restrict__ Rinv){
  __shared__ double gl[64][65];   // L lower; R[i][a] = gl[a][i]
  __shared__ double Xl[64][65];   // X = R^{-1} (upper); lower stays 0
  __shared__ double sdinv[64];
  __shared__ double Sl[3][16][17];
  int t = threadIdx.x;
  #pragma unroll
  for (int q = 0; q < 16; q++){
    int idx = t + (q << 8);
    gl[idx >> 6][idx & 63] = L[idx];
  }
  if (t < 64) sdinv[t] = sdd[t];
  for (int idx = t; idx < 64*65; idx += 256)
    ((double*)Xl)[idx] = 0.0;
  __syncthreads();
  // diag blocks: 4 independent 16x16 upper-tri inverses (one wave)
  if (t < 64){
    int b = t >> 4, c2 = t & 15;
    int g0 = b << 4;
    int gc = g0 + c2;
    Xl[gc][gc] = sdinv[gc];
    for (int i = c2 - 1; i >= 0; i--){
      int gi = g0 + i;
      double s = 0.0;
      for (int k2 = i + 1; k2 <= c2; k2++)
        s += gl[g0 + k2][gi] * Xl[g0 + k2][gc];   // R[gi][a] = L[a][gi]
      Xl[gi][gc] = -s * sdinv[gi];
    }
  }
  __syncthreads();
  // off-diag blocks by superdiagonal d
  for (int d = 1; d < 4; d++){
    int np = 4 - d;
    int tot = np << 8;
    for (int e = t; e < tot; e += 256){
      int p = e >> 8;
      int i = (e >> 4) & 15, jj = e & 15;
      int gi = (p << 4) + i, gj = ((p + d) << 4) + jj;
      double s = 0.0;
      int a0 = (p + 1) << 4, a1 = (p + d + 1) << 4;
      for (int a = a0; a < a1; a++)
        s += gl[a][gi] * Xl[a][gj];
      Sl[p][i][jj] = s;
    }
    __syncthreads();
    for (int e = t; e < tot; e += 256){
      int p = e >> 8;
      int i = (e >> 4) & 15, jj = e & 15;
      int gi = (p << 4) + i, gj = ((p + d) << 4) + jj;
      double s = 0.0;
      #pragma unroll
      for (int k2 = 0; k2 < 16; k2++)
        s += Xl[gi][(p << 4) + k2] * Sl[p][k2][jj];   // Xl lower = 0
      Xl[gi][gj] = -s;
    }
    __syncthreads();
  }
  #pragma unroll
  for (int q = 0; q < 16; q++){
    int e2 = t + (q << 8);
    Rinv[e2] = Xl[e2 >> 6][e2 & 63];
  }
}
// dst[NNx64] = src[NNx64] * Rinv(upper); 4 rows per 256-thread block
__global__ __launch_bounds__(256) void k_applyR64(const double* __restrict__ src,
      const double* __restrict__ Rinv, double* __restrict__ dst){
  __shared__ double Rs[64][65];
  int t = threadIdx.x;
  #pragma unroll
  for (int q = 0; q < 16; q++){
    int idx = t + q*256;
    Rs[idx >> 6][idx & 63] = Rinv[idx];
  }
  __syncthreads();
  int r = blockIdx.x*4 + (t >> 6);
  int j = t & 63;
  const double* rowp = src + (size_t)r*RK;
  double s = 0.0;
  for (int k = 0; k <= j; k++) s += rowp[k] * Rs[k][j];
  dst[(size_t)r*RK + j] = s;
}
__global__ __launch_bounds__(256) void k_qsum64(const double* __restrict__ Q, double* __restrict__ qs){
  int j = blockIdx.x;  int t = threadIdx.x;
  double a = 0.0;
  for (int n = t; n < NN; n += 256) a += Q[(size_t)n*RK + j];
  __shared__ double sh[256];
  sh[t] = a; __syncthreads();
  for (int off = 128; off > 0; off >>= 1){ if (t < off) sh[t] += sh[t+off]; __syncthreads(); }
  if (t == 0) qs[j] = sh[0];
}
__global__ __launch_bounds__(256) void k_deg2f(const double* __restrict__ C, const double* __restrict__ qs,
                                               float* __restrict__ dinv2){
  int i = blockIdx.x*256 + threadIdx.x;
  if (i >= NN) return;
  double s = 0.0;
  #pragma unroll
  for (int k = 0; k < RK; k++) s += C[(size_t)i*RK + k] * qs[k];
  dinv2[i] = (s > 0.0) ? (float)(1.0/sqrt(s)) : 0.f;
}

// ---------------- SpMM over sorted edge lists (f32, branch 1) ----------------
__global__ void k_spmm(const int* __restrict__ ptr, const int* __restrict__ eid,
                       const int* __restrict__ oidx, const float* __restrict__ coef,
                       const float* __restrict__ X, int ldx,
                       float* __restrict__ Y, int ldy, int F,
                       const float* __restrict__ self_dinv, const float* __restrict__ bias){
  int seg = blockIdx.x;
  int t = threadIdx.x, bd = blockDim.x;
  int f1 = t + bd;
  bool two = (f1 < F);
  float acc0 = 0.f, acc1 = 0.f;
  if (self_dinv){
    float sd = self_dinv[seg]; float s2 = sd*sd;
    acc0 = s2 * X[(size_t)seg*ldx + t];
    if (two) acc1 = s2 * X[(size_t)seg*ldx + f1];
  }
  int p0 = ptr[seg], p1 = ptr[seg+1];
  for (int p = p0; p < p1; ++p){
    int e = eid[p];
    int o = oidx[e];
    float c = coef[e];
    const float* xr = X + (size_t)o*ldx;
    acc0 += c * xr[t];
    if (two) acc1 += c * xr[f1];
  }
  if (bias){ acc0 += bias[t]; if (two) acc1 += bias[f1]; }
  Y[(size_t)seg*ldy + t] = acc0;
  if (two) Y[(size_t)seg*ldy + f1] = acc1;
}

// ---------------- domain-specific BN ----------------
__global__ __launch_bounds__(256) void k_bnstats(const float* __restrict__ H, const int* __restrict__ y,
        const int* __restrict__ dcnt, const float* __restrict__ gamma, const float* __restrict__ beta,
        float* __restrict__ scal, float* __restrict__ shft){
  int j = blockIdx.x;
  int t = threadIdx.x;
  float s0=0,s1=0,s2=0,s3=0,q0=0,q1=0,q2=0,q3=0;
  for (int n = t; n < NN; n += 256){
    float v = H[(size_t)n*HIDC + j];
    int d = y[n];
    float v2 = v*v;
    if      (d == 0){ s0 += v; q0 += v2; }
    else if (d == 1){ s1 += v; q1 += v2; }
    else if (d == 2){ s2 += v; q2 += v2; }
    else            { s3 += v; q3 += v2; }
  }
  __shared__ float sh[256][8];
  sh[t][0]=s0; sh[t][1]=s1; sh[t][2]=s2; sh[t][3]=s3;
  sh[t][4]=q0; sh[t][5]=q1; sh[t][6]=q2; sh[t][7]=q3;
  __syncthreads();
  for (int off = 128; off > 0; off >>= 1){
    if (t < off){
      #pragma unroll
      for (int q = 0; q < 8; q++) sh[t][q] += sh[t+off][q];
    }
    __syncthreads();
  }
  if (t < NDOM){
    float cnt  = fmaxf((float)dcnt[t], 1.0f);
    float mean = sh[0][t] / cnt;
    float var  = fmaxf(sh[0][4+t] / cnt - mean*mean, 0.f);
    float inv  = 1.0f / sqrtf(var + EPSBN);
    float gmm  = gamma[t*HIDC + j];
    scal[t*HIDC + j] = gmm * inv;
    shft[t*HIDC + j] = beta[t*HIDC + j] - mean * gmm * inv;
  }
}
__global__ __launch_bounds__(256) void k_bnapply(float* __restrict__ H, const int* __restrict__ y,
        const float* __restrict__ scal, const float* __restrict__ shft){
  int idx = blockIdx.x*256 + threadIdx.x;
  if (idx >= NN*HIDC) return;
  int n = idx >> 9, j = idx & (HIDC-1);
  int d = y[n];
  float v = H[idx] * scal[d*HIDC + j] + shft[d*HIDC + j];
  H[idx] = v > 0.f ? v : 0.f;
}

// ---------------- launch ----------------
extern "C" void kernel_launch(void* const* d_in, const int* in_sizes, int n_in,
                              void* d_out, int out_size, void* d_ws, size_t ws_size,
                              hipStream_t stream){
  (void)in_sizes; (void)n_in; (void)out_size;
  const void* x_in  = d_in[0];
  const int*  ei    = (const int*)d_in[1];
  const void* w_in  = d_in[2];
  const int*  yv    = (const int*)d_in[3];
  const void* W1i   = d_in[4];
  const void* b1i   = d_in[5];
  const void* Wmui  = d_in[6];
  const void* bmui  = d_in[7];
  const void* Wlvi  = d_in[8];
  const void* blvi  = d_in[9];
  const void* gmi   = d_in[10];
  const void* bti   = d_in[11];
  const int* rowA = ei;
  const int* colA = ei + NEDG;
  float* zout = (float*)d_out;

  // ---- workspace: doubles | floats | ints ----
  double* Dp = (double*)d_ws;
  size_t od = 0;
  double* Qd0 = Dp + od; od += (size_t)NN*RK;
  double* Qd1 = Dp + od; od += (size_t)NN*RK;
  double* Cd  = Dp + od; od += (size_t)NN*RK;
  double* Gd  = Dp + od; od += RK*RK;
  double* Rid = Dp + od; od += RK*RK;
  double* qsd = Dp + od; od += RK;
  double* sdd = Dp + od; od += RK;
  float* Fp = (float*)(Dp + od);
  size_t o = 0;
  float* xf   = Fp + o; o += (size_t)NN*INC;       // reused as h1/h2 buffer
  float* W1f  = Fp + o; o += (size_t)INC*HIDC;
  float* b1f  = Fp + o; o += HIDC;
  float* Wmuf = Fp + o; o += (size_t)HIDC*OUTC;
  float* bmuf = Fp + o; o += OUTC;
  float* Wlvf = Fp + o; o += (size_t)HIDC*OUTC;
  float* blvf = Fp + o; o += OUTC;
  float* gmf  = Fp + o; o += NDOM*HIDC;
  float* btf  = Fp + o; o += NDOM*HIDC;
  float* wf   = Fp + o; o += NEDG;
  float* xw1  = Fp + o; o += (size_t)NN*HIDC;
  float* hwA  = Fp + o; o += (size_t)NN*OUTC;
  float* hwB  = Fp + o; o += (size_t)NN*OUTC;     // contiguous after hwA
  float* Bf1  = Fp + o; o += (size_t)NN*RK;        // Qb (f32)
  float* Cm   = Fp + o; o += (size_t)NN*RK;        // C (f32)
  float* Tm   = Fp + o; o += (size_t)RK*HIDC;
  float* Umu  = Fp + o; o += RK*RK;
  float* deg1 = Fp + o; o += NN;
  float* dinv1= Fp + o; o += NN;
  float* dinv2= Fp + o; o += NN;
  float* norm1= Fp + o; o += NEDG;
  float* scal = Fp + o; o += NDOM*HIDC;
  float* shft = Fp + o; o += NDOM*HIDC;
  int* Ip = (int*)(Fp + o);
  size_t oi = 0;
  int* cntR = Ip + oi; oi += NN;
  int* ptrR = Ip + oi; oi += NN + 1;
  int* posR = Ip + oi; oi += NN;
  int* eidR = Ip + oi; oi += NEDG;
  int* cntC = Ip + oi; oi += NN;
  int* ptrC = Ip + oi; oi += NN + 1;
  int* posC = Ip + oi; oi += NN;
  int* eidC = Ip + oi; oi += NEDG;
  int* dcnt = Ip + oi; oi += NDOM;
  int* dflag= Ip + oi; oi += 1;

  size_t need = od*sizeof(double) + o*sizeof(float) + (oi+16)*sizeof(int);
  if (ws_size < need) return;

  float* hbuf = xf;  // x dead after xw1 GEMM

  const int T = 256;
  k_detect<<<1,T,0,stream>>>((const unsigned short*)x_in, dflag);
  k_upcast_all<<<cdiv(OFFT,T),T,0,stream>>>(
      x_in, W1i, w_in, Wmui, Wlvi, gmi, bti, b1i, bmui, blvi, dflag,
      xf, W1f, wf, Wmuf, Wlvf, gmf, btf, b1f, bmuf, blvf);

  k_prep<<<cdiv(NN,T),T,0,stream>>>(deg1, cntR, cntC, dcnt);
  k_hist <<<cdiv(NEDG,T),T,0,stream>>>(rowA, colA, wf, deg1, cntR, cntC);
  k_dinv <<<cdiv(NN,T),T,0,stream>>>(deg1, dinv1, NN);
  k_norm1<<<cdiv(NEDG,T),T,0,stream>>>(rowA, colA, wf, dinv1, norm1);
  k_scan4096<<<1,1024,0,stream>>>(cntR, ptrR, posR);
  k_scan4096<<<1,1024,0,stream>>>(cntC, ptrC, posC);
  k_scatter<<<cdiv(NEDG,T),T,0,stream>>>(rowA, colA, posR, posC, eidR, eidC);
  k_omega<<<cdiv(NN*RK,T),T,0,stream>>>(Qd0);      // f64 seed directly
  k_dcnt <<<cdiv(NN,T),T,0,stream>>>(yv, dcnt);

  // ---- branch 1 ----
  k_gemm_nn<<<dim3(HIDC/64, NN/64),256,0,stream>>>(NN,HIDC,INC, xf,INC, W1f,HIDC, xw1,HIDC, nullptr,nullptr,nullptr);
  k_spmm<<<NN,256,0,stream>>>(ptrC,eidC,rowA,norm1, xw1,HIDC, hbuf,HIDC, HIDC, dinv1, b1f);
  k_bnstats<<<HIDC,256,0,stream>>>(hbuf, yv, dcnt, gmf, btf, scal, shft);
  k_bnapply<<<cdiv(NN*HIDC,T),T,0,stream>>>(hbuf, yv, scal, shft);
  k_fill<<<cdiv(2*NN*OUTC,T),T,0,stream>>>(hwA, 0.f, 2*NN*OUTC);   // hwA|hwB contiguous
  k_gemm_nn_sk<<<dim3(1, NN/64, 4),256,0,stream>>>(NN,OUTC,HIDC,128, hbuf,HIDC, Wmuf,OUTC, hwA,OUTC);
  k_gemm_nn_sk<<<dim3(1, NN/64, 4),256,0,stream>>>(NN,OUTC,HIDC,128, hbuf,HIDC, Wlvf,OUTC, hwB,OUTC);
  k_spmm<<<NN,64,0,stream>>>(ptrC,eidC,rowA,norm1, hwA,OUTC, zout + 0*NN*OUTC,OUTC, OUTC, dinv1, bmuf);
  k_spmm<<<NN,64,0,stream>>>(ptrC,eidC,rowA,norm1, hwB,OUTC, zout + 1*NN*OUTC,OUTC, OUTC, dinv1, blvf);

  // ---- branch 2: f64 subspace, single final QR1 ----
  auto spmmA64 = [&](const double* s, double* d){   // d = A @ s
    k_spmm64<<<NN,64,0,stream>>>(ptrR,eidR,colA,wf, s, d);
  };
  auto spmmAT64 = [&](const double* s, double* d){  // d = A^T @ s
    k_spmm64<<<NN,64,0,stream>>>(ptrC,eidC,rowA,wf, s, d);
  };

  spmmA64 (Qd0, Qd1);                      // P1 -> Qd1
  spmmAT64(Qd1, Qd0);                      // P2 -> Qd0
  spmmA64 (Qd0, Qd1);                      // P3 -> Qd1
  spmmAT64(Qd1, Qd0);                      // P4 -> Qd0
  spmmA64 (Qd0, Qd1);                      // P5 -> Qd1
  k_filld<<<cdiv(RK*RK,T),T,0,stream>>>(Gd, 0.0, RK*RK);
  k_gram64<<<NN/64,256,0,stream>>>(Qd1, Gd);
  k_chol64<<<1,64,0,stream>>>(Gd, sdd);             // L over Gd, sdinv -> sdd
  k_trinv64<<<1,256,0,stream>>>(Gd, sdd, Rid);      // Rinv
  k_applyR64<<<NN/4,256,0,stream>>>(Qd1, Rid, Qd0); // Qb -> Qd0
  spmmAT64(Qd0, Cd);                       // C = A^T Qb  (A2 = Qb C^T)
  k_qsum64<<<RK,256,0,stream>>>(Qd0, qsd);
  k_deg2f<<<cdiv(NN,T),T,0,stream>>>(Cd, qsd, dinv2);
  k_f64to32x2<<<cdiv(NN*RK,T),T,0,stream>>>(Qd0, Bf1, Cd, Cm, NN*RK);

  // h2 = dsbn_relu( D C (Qb^T (D xw1)) + b1 )
  k_fill<<<cdiv(RK*HIDC,T),T,0,stream>>>(Tm, 0.f, RK*HIDC);
  k_gemm_tn_sk<<<dim3(HIDC/16, RK/16, 8),256,0,stream>>>(RK,HIDC,NN,512, Bf1,RK, xw1,HIDC, Tm,HIDC, dinv2);
  k_gemm_nn<<<dim3(HIDC/64, NN/64),256,0,stream>>>(NN,HIDC,RK, Cm,RK, Tm,HIDC, hbuf,HIDC, dinv2, nullptr, b1f);
  k_bnstats<<<HIDC,256,0,stream>>>(hbuf, yv, dcnt, gmf, btf, scal, shft);
  k_bnapply<<<cdiv(NN*HIDC,T),T,0,stream>>>(hbuf, yv, scal, shft);
  // z2 = D C (Qb^T (D (h2 W))) + b
  k_fill<<<cdiv(2*NN*OUTC,T),T,0,stream>>>(hwA, 0.f, 2*NN*OUTC);
  k_gemm_nn_sk<<<dim3(1, NN/64, 4),256,0,stream>>>(NN,OUTC,HIDC,128, hbuf,HIDC, Wmuf,OUTC, hwA,OUTC);
  k_gemm_nn_sk<<<dim3(1, NN/64, 4),256,0,stream>>>(NN,OUTC,HIDC,128, hbuf,HIDC, Wlvf,OUTC, hwB,OUTC);
  k_fill<<<cdiv(RK*RK,T),T,0,stream>>>(Umu, 0.f, RK*RK);
  k_gemm_tn_sk<<<dim3(RK/16, RK/16, 16),256,0,stream>>>(RK,RK,NN,256, Bf1,RK, hwA,OUTC, Umu,RK, dinv2);
  k_gemm_nn<<<dim3(1, NN/64),256,0,stream>>>(NN,OUTC,RK, Cm,RK, Umu,RK, zout + 2*NN*OUTC,OUTC, dinv2, nullptr, bmuf);
  k_fill<<<cdiv(RK*RK,T),T,0,stream>>>(Umu, 0.f, RK*RK);
  k_gemm_tn_sk<<<dim3(RK/16, RK/16, 16),256,0,stream>>>(RK,RK,NN,256, Bf1,RK, hwB,OUTC, Umu,RK, dinv2);
  k_gemm_nn<<<dim3(1, NN/64),256,0,stream>>>(NN,OUTC,RK, Cm,RK, Umu,RK, zout + 3*NN*OUTC,OUTC, dinv2, nullptr, blvf);
}

// Round 6
// 836.143 us; speedup vs baseline: 1.3614x; 1.0770x over previous
//
#include <hip/hip_runtime.h>
#include <hip/hip_bf16.h>

// GCNEncoder — r22: the 4096x512x512 x@W1 GEMM (84.6us, 25TF = 16% of fp32
// vector peak, LDS-bound SIMT) moves to bf16 MFMA (mfma_f32_16x16x32_bf16).
// Inputs are bf16 carriers -> bf16 re-encode is exact; products exact in f32
// accum; only summation order differs (~1e-6). 64x64 tile, 4 waves, B staged
// transposed in LDS for contiguous b128 fragment reads. Measured layouts:
// A/B frag: non-K idx = lane&15, k=(lane>>4)*8+j; C/D: row=(lane>>4)*4+reg,
// col=lane&15. Single change vs r21 for clean attribution.
// History: r21 900us; r20 930us; r19 943us; r18 982us; r16 1138us.

#define NN    4096
#define NEDG  131072
#define INC   512
#define HIDC  512
#define OUTC  64
#define RK    64
#define NDOM  4
#define EPSBN 1e-5f

typedef unsigned short ushortT;
typedef __attribute__((ext_vector_type(8))) short bf16x8;
typedef __attribute__((ext_vector_type(4))) float f32x4;

static inline int cdiv(int a, int b){ return (a + b - 1) / b; }

// ---------------- input dtype detection (f32 vs bf16 carriers) ----------------
__global__ __launch_bounds__(256) void k_detect(const unsigned short* __restrict__ p,
                                                int* __restrict__ flag){
  int t = threadIdx.x;
  int cnt = 0;
  for (int i = t; i < 4096; i += 256){
    unsigned short v = p[2*i];
    int e = (v >> 7) & 0xFF;
    if (e >= 100 && e <= 140) cnt++;
  }
  __shared__ int sh[256];
  sh[t] = cnt; __syncthreads();
  for (int off = 128; off > 0; off >>= 1){ if (t < off) sh[t] += sh[t+off]; __syncthreads(); }
  if (t == 0) *flag = (sh[0] >= 2048) ? 0 : 1;
}

// ---------------- fused upcast of all 10 inputs (+ bf16 copies of x, W1) ----------------
__device__ __forceinline__ float upc1(const void* s, int f, int off){
  return f ? ((const float*)s)[off]
           : __bfloat162float(((const __hip_bfloat16*)s)[off]);
}
__device__ __forceinline__ ushortT tobf(float v){
  __hip_bfloat16 h = __float2bfloat16(v);
  return *(ushortT*)&h;
}
#define SEG_X   2097152
#define SEG_W1  262144
#define SEG_W   131072
#define SEG_WMU 32768
#define SEG_GB  2048
#define SEG_B1  512
#define SEG_BO  64
#define OFF1 (SEG_X)
#define OFF2 (OFF1+SEG_W1)
#define OFF3 (OFF2+SEG_W)
#define OFF4 (OFF3+SEG_WMU)
#define OFF5 (OFF4+SEG_WMU)
#define OFF6 (OFF5+SEG_GB)
#define OFF7 (OFF6+SEG_GB)
#define OFF8 (OFF7+SEG_B1)
#define OFF9 (OFF8+SEG_BO)
#define OFFT (OFF9+SEG_BO)

__global__ __launch_bounds__(256) void k_upcast_all(
    const void* x, const void* W1, const void* w, const void* Wmu, const void* Wlv,
    const void* gm, const void* bt, const void* b1, const void* bmu, const void* blv,
    const int* __restrict__ isf32,
    float* dx, float* dW1, float* dw, float* dWmu, float* dWlv,
    float* dgm, float* dbt, float* db1, float* dbmu, float* dblv,
    ushortT* xbf, ushortT* W1bf){
  int i = blockIdx.x*256 + threadIdx.x;
  if (i >= OFFT) return;
  int f = *isf32;
  if      (i < OFF1){ float v = upc1(x, f, i); dx[i] = v; xbf[i] = tobf(v); }
  else if (i < OFF2){ float v = upc1(W1, f, i - OFF1); dW1[i - OFF1] = v; W1bf[i - OFF1] = tobf(v); }
  else if (i < OFF3) dw  [i - OFF2] = upc1(w,   f, i - OFF2);
  else if (i < OFF4) dWmu[i - OFF3] = upc1(Wmu, f, i - OFF3);
  else if (i < OFF5) dWlv[i - OFF4] = upc1(Wlv, f, i - OFF4);
  else if (i < OFF6) dgm [i - OFF5] = upc1(gm,  f, i - OFF5);
  else if (i < OFF7) dbt [i - OFF6] = upc1(bt,  f, i - OFF6);
  else if (i < OFF8) db1 [i - OFF7] = upc1(b1,  f, i - OFF7);
  else if (i < OFF9) dbmu[i - OFF8] = upc1(bmu, f, i - OFF8);
  else               dblv[i - OFF9] = upc1(blv, f, i - OFF9);
}

// ---------------- elementwise utils ----------------
__global__ __launch_bounds__(256) void k_fill(float* d, float v, int n){
  int i = blockIdx.x*256 + threadIdx.x;
  if (i < n) d[i] = v;
}
__global__ __launch_bounds__(256) void k_filld(double* d, double v, int n){
  int i = blockIdx.x*256 + threadIdx.x;
  if (i < n) d[i] = v;
}
__global__ __launch_bounds__(256) void k_prep(float* deg, int* cntR, int* cntC, int* dcnt){
  int i = blockIdx.x*256 + threadIdx.x;
  if (i < NN){ deg[i] = 1.0f; cntR[i] = 0; cntC[i] = 0; }
  if (i < NDOM) dcnt[i] = 0;
}
__global__ __launch_bounds__(256) void k_f64to32x2(const double* __restrict__ s0, float* __restrict__ d0,
                                                   const double* __restrict__ s1, float* __restrict__ d1,
                                                   int n){
  int i = blockIdx.x*256 + threadIdx.x;
  if (i < n){ d0[i] = (float)s0[i]; d1[i] = (float)s1[i]; }
}

// ---------------- graph preprocessing ----------------
__global__ __launch_bounds__(256) void k_hist(const int* __restrict__ row, const int* __restrict__ col,
                                              const float* __restrict__ w, float* deg,
                                              int* cntR, int* cntC){
  int e = blockIdx.x*256 + threadIdx.x;
  if (e < NEDG){
    atomicAdd(&deg[col[e]], w[e]);
    atomicAdd(&cntR[row[e]], 1);
    atomicAdd(&cntC[col[e]], 1);
  }
}
__global__ __launch_bounds__(256) void k_dinv(const float* deg, float* dinv, int n){
  int i = blockIdx.x*256 + threadIdx.x;
  if (i < n){ float d = deg[i]; dinv[i] = (d > 0.f) ? 1.f/sqrtf(d) : 0.f; }
}
__global__ __launch_bounds__(256) void k_norm1(const int* __restrict__ row, const int* __restrict__ col,
                                               const float* __restrict__ w, const float* __restrict__ dinv,
                                               float* __restrict__ nrm){
  int e = blockIdx.x*256 + threadIdx.x;
  if (e < NEDG) nrm[e] = dinv[row[e]] * w[e] * dinv[col[e]];
}
__global__ __launch_bounds__(1024) void k_scan4096(const int* __restrict__ cnt,
                                                   int* __restrict__ ptr, int* __restrict__ pos){
  __shared__ int sh[1024];
  int t = threadIdx.x;
  int b = t*4;
  int a0 = cnt[b], a1 = cnt[b+1], a2 = cnt[b+2], a3 = cnt[b+3];
  sh[t] = a0 + a1 + a2 + a3;
  __syncthreads();
  for (int off = 1; off < 1024; off <<= 1){
    int v = (t >= off) ? sh[t-off] : 0;
    __syncthreads();
    sh[t] += v;
    __syncthreads();
  }
  int excl = (t == 0) ? 0 : sh[t-1];
  ptr[b]   = excl;            pos[b]   = excl;
  ptr[b+1] = excl+a0;         pos[b+1] = excl+a0;
  ptr[b+2] = excl+a0+a1;      pos[b+2] = excl+a0+a1;
  ptr[b+3] = excl+a0+a1+a2;   pos[b+3] = excl+a0+a1+a2;
  if (t == 1023) ptr[4096] = sh[1023];
}
__global__ __launch_bounds__(256) void k_scatter(const int* __restrict__ row, const int* __restrict__ col,
                                                 int* posR, int* posC, int* eidR, int* eidC){
  int e = blockIdx.x*256 + threadIdx.x;
  if (e < NEDG){
    int p = atomicAdd(&posR[row[e]], 1); eidR[p] = e;
    int q = atomicAdd(&posC[col[e]], 1); eidC[q] = e;
  }
}
__global__ __launch_bounds__(256) void k_dcnt(const int* __restrict__ y, int* dcnt){
  int i = blockIdx.x*256 + threadIdx.x;
  if (i < NN) atomicAdd(&dcnt[y[i]], 1);
}

// ---------------- threefry2x32 core (KAT-verified round 8) ----------------
__device__ __forceinline__ unsigned rotl32(unsigned x, unsigned d){ return (x << d) | (x >> (32u - d)); }
#define TF_ROUND4(R0,R1,R2,R3) \
  x0 += x1; x1 = rotl32(x1,R0); x1 ^= x0; \
  x0 += x1; x1 = rotl32(x1,R1); x1 ^= x0; \
  x0 += x1; x1 = rotl32(x1,R2); x1 ^= x0; \
  x0 += x1; x1 = rotl32(x1,R3); x1 ^= x0;

__device__ __forceinline__ void tf2x32(unsigned k0, unsigned k1, unsigned c0, unsigned c1,
                                       unsigned* o0, unsigned* o1){
  unsigned ks2 = 0x1BD11BDAu ^ k0 ^ k1;
  unsigned x0 = c0 + k0, x1 = c1 + k1;
  TF_ROUND4(13,15,26,6);   x0 += k1;  x1 += ks2 + 1u;
  TF_ROUND4(17,29,16,24);  x0 += ks2; x1 += k0 + 2u;
  TF_ROUND4(13,15,26,6);   x0 += k0;  x1 += k1 + 3u;
  TF_ROUND4(17,29,16,24);  x0 += k1;  x1 += ks2 + 4u;
  TF_ROUND4(13,15,26,6);   x0 += ks2; x1 += k0 + 5u;
  *o0 = x0; *o1 = x1;
}

// ---------------- omega (verified round 10; direct f64 output) ----------------
__device__ double erfinv64(double x){
  double w = -log1p(-x*x);
  double p;
  if (w < 5.0){
    w -= 2.5;
    p = 2.81022636e-08;  p = p*w + 3.43273939e-07; p = p*w - 3.5233877e-06;
    p = p*w - 4.39150654e-06; p = p*w + 0.00021858087; p = p*w - 0.00125372503;
    p = p*w - 0.00417768164;  p = p*w + 0.246640727;   p = p*w + 1.50140941;
  } else {
    w = sqrt(w) - 3.0;
    p = -0.000200214257; p = p*w + 0.000100950558; p = p*w + 0.00134934322;
    p = p*w - 0.00367342844; p = p*w + 0.00573950773; p = p*w - 0.0076224613;
    p = p*w + 0.00943887047; p = p*w + 1.00167406;    p = p*w + 2.83297682;
  }
  double y = p * x;
  const double c = 1.1283791670955126;   // 2/sqrt(pi)
  #pragma unroll
  for (int it = 0; it < 3; it++){
    double err = erf(y) - x;
    y -= err / (c * exp(-y*y));
  }
  return y;
}

__device__ float bits_to_normal(unsigned b){
  float f = __uint_as_float((b >> 9) | 0x3f800000u) - 1.0f;
  const float lo = -0.99999994f;               // nextafter(-1,0) in f32
  float x = fmaxf(lo, f * 2.0f + lo);
  double r = 1.4142135623730951 * erfinv64((double)x);
  return (float)r;
}

__global__ __launch_bounds__(256) void k_omega(double* __restrict__ om){
  int i = blockIdx.x*256 + threadIdx.x;
  if (i >= 262144) return;
  unsigned o0, o1;
  tf2x32(0u, 42u, 0u, (unsigned)i, &o0, &o1);   // counter = (0, i)
  om[i] = (double)bits_to_normal(o0 ^ o1);      // same f32 value as before, widened
}

// ---------------- bf16 MFMA GEMM: C[4096][512] = A[4096][512] @ B[512][512] ----------------
// 64x64 tile per block, 256 threads = 4 waves; wave w owns rows w*16..+15.
// A/B frags: non-K index = lane&15, k = (lane>>4)*8+j (16x16x32 bf16).
// C/D: row = (lane>>4)*4 + reg, col = lane&15  [measured m89].
__global__ __launch_bounds__(256) void k_gemm_bf16(
    const ushortT* __restrict__ A, const ushortT* __restrict__ B,
    float* __restrict__ Cc){
  __shared__ ushortT As2[64][40];   // [row][k] (+8 pad)
  __shared__ ushortT Bs2[64][40];   // [col][k] transposed (+8 pad)
  int t = threadIdx.x;
  int bm = blockIdx.y * 64, bn = blockIdx.x * 64;
  int w = t >> 6, l = t & 63;
  int lr = l & 15, lk = l >> 4;
  f32x4 acc[4] = {};
  int ar = t >> 2, ac = (t & 3) * 8;      // A stage: 64 rows x 32 k, 16B/thread
  int bc = t & 63, bk = (t >> 6) * 8;     // B stage: 64 cols x 8 k gathered
  for (int k0 = 0; k0 < 512; k0 += 32){
    *(uint4*)&As2[ar][ac] = *(const uint4*)&A[(size_t)(bm + ar) * 512 + k0 + ac];
    ushortT tmp[8];
    #pragma unroll
    for (int j = 0; j < 8; j++)
      tmp[j] = B[(size_t)(k0 + bk + j) * 512 + bn + bc];
    *(uint4*)&Bs2[bc][bk] = *(uint4*)tmp;
    __syncthreads();
    bf16x8 afrag = *(bf16x8*)&As2[w * 16 + lr][lk * 8];
    #pragma unroll
    for (int nt = 0; nt < 4; nt++){
      bf16x8 bfrag = *(bf16x8*)&Bs2[nt * 16 + lr][lk * 8];
      acc[nt] = __builtin_amdgcn_mfma_f32_16x16x32_bf16(afrag, bfrag, acc[nt], 0, 0, 0);
    }
    __syncthreads();
  }
  #pragma unroll
  for (int nt = 0; nt < 4; nt++){
    #pragma unroll
    for (int i = 0; i < 4; i++){
      Cc[(size_t)(bm + w * 16 + lk * 4 + i) * 512 + bn + nt * 16 + lr] = acc[nt][i];
    }
  }
}

// ---------------- GEMM (fp32, tiled 64x64, 4x4/thread) ----------------
__global__ __launch_bounds__(256) void k_gemm_nn(int M, int Nn, int K,
      const float* __restrict__ A, int lda, const float* __restrict__ B, int ldb,
      float* __restrict__ Cc, int ldc, const float* __restrict__ rowscale,
      const float* __restrict__ kscale, const float* __restrict__ bias){
  __shared__ float As[16][65];
  __shared__ float Bs[16][65];
  int bm = blockIdx.y*64, bn = blockIdx.x*64;
  int t = threadIdx.x;
  int tr = t >> 4, tc = t & 15;
  float acc[4][4] = {};
  for (int k0 = 0; k0 < K; k0 += 16){
    #pragma unroll
    for (int q = 0; q < 4; q++){
      int idx = t*4 + q;
      int m = idx >> 4, kk = idx & 15;
      As[kk][m] = A[(size_t)(bm+m)*lda + (k0+kk)];
    }
    #pragma unroll
    for (int q = 0; q < 4; q++){
      int idx = t + q*256;
      int kk = idx >> 6, n = idx & 63;
      float ks = kscale ? kscale[k0+kk] : 1.0f;
      Bs[kk][n] = B[(size_t)(k0+kk)*ldb + (bn+n)] * ks;
    }
    __syncthreads();
    #pragma unroll
    for (int kk = 0; kk < 16; kk++){
      float a0 = As[kk][tr*4+0], a1 = As[kk][tr*4+1], a2 = As[kk][tr*4+2], a3 = As[kk][tr*4+3];
      float b0 = Bs[kk][tc*4+0], b1 = Bs[kk][tc*4+1], b2 = Bs[kk][tc*4+2], b3 = Bs[kk][tc*4+3];
      acc[0][0] += a0*b0; acc[0][1] += a0*b1; acc[0][2] += a0*b2; acc[0][3] += a0*b3;
      acc[1][0] += a1*b0; acc[1][1] += a1*b1; acc[1][2] += a1*b2; acc[1][3] += a1*b3;
      acc[2][0] += a2*b0; acc[2][1] += a2*b1; acc[2][2] += a2*b2; acc[2][3] += a2*b3;
      acc[3][0] += a3*b0; acc[3][1] += a3*b1; acc[3][2] += a3*b2; acc[3][3] += a3*b3;
    }
    __syncthreads();
  }
  #pragma unroll
  for (int i2 = 0; i2 < 4; i2++){
    int m = bm + tr*4 + i2;
    float rs = rowscale ? rowscale[m] : 1.0f;
    #pragma unroll
    for (int j2 = 0; j2 < 4; j2++){
      int n = bn + tc*4 + j2;
      float v = acc[i2][j2] * rs;
      if (bias) v += bias[n];
      Cc[(size_t)m*ldc + n] = v;
    }
  }
}

// split-K NN: C += partial (C pre-zeroed); grid (Nn/64, M/64, K/kchunk)
__global__ __launch_bounds__(256) void k_gemm_nn_sk(int M, int Nn, int K, int kchunk,
      const float* __restrict__ A, int lda, const float* __restrict__ B, int ldb,
      float* __restrict__ Cc, int ldc){
  __shared__ float As[16][65];
  __shared__ float Bs[16][65];
  int bm = blockIdx.y*64, bn = blockIdx.x*64;
  int kb = blockIdx.z*kchunk, ke = kb + kchunk;
  int t = threadIdx.x;
  int tr = t >> 4, tc = t & 15;
  float acc[4][4] = {};
  for (int k0 = kb; k0 < ke; k0 += 16){
    #pragma unroll
    for (int q = 0; q < 4; q++){
      int idx = t*4 + q;
      int m = idx >> 4, kk = idx & 15;
      As[kk][m] = A[(size_t)(bm+m)*lda + (k0+kk)];
    }
    #pragma unroll
    for (int q = 0; q < 4; q++){
      int idx = t + q*256;
      int kk = idx >> 6, n = idx & 63;
      Bs[kk][n] = B[(size_t)(k0+kk)*ldb + (bn+n)];
    }
    __syncthreads();
    #pragma unroll
    for (int kk = 0; kk < 16; kk++){
      float a0 = As[kk][tr*4+0], a1 = As[kk][tr*4+1], a2 = As[kk][tr*4+2], a3 = As[kk][tr*4+3];
      float b0 = Bs[kk][tc*4+0], b1 = Bs[kk][tc*4+1], b2 = Bs[kk][tc*4+2], b3 = Bs[kk][tc*4+3];
      acc[0][0] += a0*b0; acc[0][1] += a0*b1; acc[0][2] += a0*b2; acc[0][3] += a0*b3;
      acc[1][0] += a1*b0; acc[1][1] += a1*b1; acc[1][2] += a1*b2; acc[1][3] += a1*b3;
      acc[2][0] += a2*b0; acc[2][1] += a2*b1; acc[2][2] += a2*b2; acc[2][3] += a2*b3;
      acc[3][0] += a3*b0; acc[3][1] += a3*b1; acc[3][2] += a3*b2; acc[3][3] += a3*b3;
    }
    __syncthreads();
  }
  #pragma unroll
  for (int i2 = 0; i2 < 4; i2++){
    int m = bm + tr*4 + i2;
    #pragma unroll
    for (int j2 = 0; j2 < 4; j2++){
      int n = bn + tc*4 + j2;
      atomicAdd(&Cc[(size_t)m*ldc + n], acc[i2][j2]);
    }
  }
}

// split-K TN: C += partial (C pre-zeroed); grid (Nn/16, M/16, K/kchunk)
__global__ __launch_bounds__(256) void k_gemm_tn_sk(int M, int Nn, int K, int kchunk,
      const float* __restrict__ A, int lda, const float* __restrict__ B, int ldb,
      float* __restrict__ Cc, int ldc, const float* __restrict__ kscale){
  __shared__ float As[32][17];
  __shared__ float Bs[32][17];
  int bm = blockIdx.y*16, bn = blockIdx.x*16;
  int kb = blockIdx.z*kchunk, ke = kb + kchunk;
  int t = threadIdx.x;
  int tm = t >> 4, tn = t & 15;
  float acc = 0.f;
  for (int k0 = kb; k0 < ke; k0 += 32){
    #pragma unroll
    for (int q = 0; q < 2; q++){
      int idx = t + q*256;
      int kk = idx >> 4, m = idx & 15;
      float sv = kscale ? kscale[k0+kk] : 1.0f;
      As[kk][m] = A[(size_t)(k0+kk)*lda + (bm+m)] * sv;
      Bs[kk][m] = B[(size_t)(k0+kk)*ldb + (bn+m)];
    }
    __syncthreads();
    #pragma unroll
    for (int kk = 0; kk < 32; kk++) acc += As[kk][tm] * Bs[kk][tn];
    __syncthreads();
  }
  atomicAdd(&Cc[(size_t)(bm+tm)*ldc + (bn+tn)], acc);
}

// ---------------- f64 randomized-subspace chain ----------------
__global__ __launch_bounds__(64) void k_spmm64(const int* __restrict__ ptr, const int* __restrict__ eid,
                       const int* __restrict__ oidx, const float* __restrict__ coef,
                       const double* __restrict__ X, double* __restrict__ Y){
  int seg = blockIdx.x;
  int t = threadIdx.x;
  double acc = 0.0;
  int p0 = ptr[seg], p1 = ptr[seg+1];
  for (int p = p0; p < p1; ++p){
    int e = eid[p];
    acc += (double)coef[e] * X[(size_t)oidx[e]*RK + t];
  }
  Y[(size_t)seg*RK + t] = acc;
}
// Gram: G += Xslice^T Xslice over 64-row slices (G zeroed before)
__global__ __launch_bounds__(256) void k_gram64(const double* __restrict__ X, double* __restrict__ G){
  __shared__ double Xs[64][65];
  int b = blockIdx.x;
  int t = threadIdx.x;
  #pragma unroll
  for (int q = 0; q < 16; q++){
    int idx = t + q*256;
    Xs[idx >> 6][idx & 63] = X[(size_t)(b*64 + (idx >> 6))*RK + (idx & 63)];
  }
  __syncthreads();
  int i = t >> 2;
  int j0 = (t & 3) * 16;
  double acc[16];
  #pragma unroll
  for (int jj = 0; jj < 16; jj++) acc[jj] = 0.0;
  for (int k = 0; k < 64; k++){
    double a = Xs[k][i];
    #pragma unroll
    for (int jj = 0; jj < 16; jj++) acc[jj] += a * Xs[k][j0+jj];
  }
  #pragma unroll
  for (int jj = 0; jj < 16; jj++) atomicAdd(&G[i*RK + j0 + jj], acc[jj]);
}
// ---- Cholesky factorization, ONE wave (r21-proven). ----
#define CHOL_CHUNK(I0) \
  for (int k2 = 0; k2 < 16; k2++){ \
    int k = (I0) + k2; \
    int buf = k & 1; \
    if (j == k){ \
      double d = sqrt(fmax(cdiag, 1e-300)); \
      double s = 1.0 / d; \
      myd = d; \
      sdd[k] = s; \
      _Pragma("unroll") \
      for (int i = (I0); i < 64; i++){ c[i] *= s; colk[buf][i] = c[i]; } \
    } \
    __syncthreads(); \
    if (j > k){ \
      double cj = colk[buf][j]; \
      cdiag -= cj * cj; \
      _Pragma("unroll") \
      for (int i = (I0); i < 64; i++){ c[i] -= colk[buf][i] * cj; } \
    } \
    __syncthreads(); \
  }

__global__ __launch_bounds__(64) void k_chol64(double* __restrict__ G, double* __restrict__ sdd){
  __shared__ double colk[2][64];
  int j = threadIdx.x;        // 0..63, owns column j
  double c[64];
  #pragma unroll
  for (int i = 0; i < 64; i++) c[i] = G[i*64 + j];
  double cdiag = 0.0, myd = 0.0;
  #pragma unroll
  for (int i = 0; i < 64; i++) if (i == j) cdiag = c[i];
  CHOL_CHUNK(0)
  CHOL_CHUNK(16)
  CHOL_CHUNK(32)
  CHOL_CHUNK(48)
  #pragma unroll
  for (int i = 0; i < 64; i++){
    double v = (i > j) ? c[i] : 0.0;
    if (i == j) v = myd;
    G[i*64 + j] = v;
  }
}
// ---- blocked triangular inverse (r19/r20/r21-proven stages), 256 threads. ----
__global__ __launch_bounds__(256) void k_trinv64(const double* __restrict__ L,
      const double* __restrict__ sdd, double* __restrict__ Rinv){
  __shared__ double gl[64][65];   // L lower; R[i][a] = gl[a][i]
  __shared__ double Xl[64][65];   // X = R^{-1} (upper); lower stays 0
  __shared__ double sdinv[64];
  __shared__ double Sl[3][16][17];
  int t = threadIdx.x;
  #pragma unroll
  for (int q = 0; q < 16; q++){
    int idx = t + (q << 8);
    gl[idx >> 6][idx & 63] = L[idx];
  }
  if (t < 64) sdinv[t] = sdd[t];
  for (int idx = t; idx < 64*65; idx += 256)
    ((double*)Xl)[idx] = 0.0;
  __syncthreads();
  if (t < 64){
    int b = t >> 4, c2 = t & 15;
    int g0 = b << 4;
    int gc = g0 + c2;
    Xl[gc][gc] = sdinv[gc];
    for (int i = c2 - 1; i >= 0; i--){
      int gi = g0 + i;
      double s = 0.0;
      for (int k2 = i + 1; k2 <= c2; k2++)
        s += gl[g0 + k2][gi] * Xl[g0 + k2][gc];
      Xl[gi][gc] = -s * sdinv[gi];
    }
  }
  __syncthreads();
  for (int d = 1; d < 4; d++){
    int np = 4 - d;
    int tot = np << 8;
    for (int e = t; e < tot; e += 256){
      int p = e >> 8;
      int i = (e >> 4) & 15, jj = e & 15;
      int gi = (p << 4) + i, gj = ((p + d) << 4) + jj;
      double s = 0.0;
      int a0 = (p + 1) << 4, a1 = (p + d + 1) << 4;
      for (int a = a0; a < a1; a++)
        s += gl[a][gi] * Xl[a][gj];
      Sl[p][i][jj] = s;
    }
    __syncthreads();
    for (int e = t; e < tot; e += 256){
      int p = e >> 8;
      int i = (e >> 4) & 15, jj = e & 15;
      int gi = (p << 4) + i, gj = ((p + d) << 4) + jj;
      double s = 0.0;
      #pragma unroll
      for (int k2 = 0; k2 < 16; k2++)
        s += Xl[gi][(p << 4) + k2] * Sl[p][k2][jj];
      Xl[gi][gj] = -s;
    }
    __syncthreads();
  }
  #pragma unroll
  for (int q = 0; q < 16; q++){
    int e2 = t + (q << 8);
    Rinv[e2] = Xl[e2 >> 6][e2 & 63];
  }
}
// dst[NNx64] = src[NNx64] * Rinv(upper); 4 rows per 256-thread block
__global__ __launch_bounds__(256) void k_applyR64(const double* __restrict__ src,
      const double* __restrict__ Rinv, double* __restrict__ dst){
  __shared__ double Rs[64][65];
  int t = threadIdx.x;
  #pragma unroll
  for (int q = 0; q < 16; q++){
    int idx = t + q*256;
    Rs[idx >> 6][idx & 63] = Rinv[idx];
  }
  __syncthreads();
  int r = blockIdx.x*4 + (t >> 6);
  int j = t & 63;
  const double* rowp = src + (size_t)r*RK;
  double s = 0.0;
  for (int k = 0; k <= j; k++) s += rowp[k] * Rs[k][j];
  dst[(size_t)r*RK + j] = s;
}
__global__ __launch_bounds__(256) void k_qsum64(const double* __restrict__ Q, double* __restrict__ qs){
  int j = blockIdx.x;  int t = threadIdx.x;
  double a = 0.0;
  for (int n = t; n < NN; n += 256) a += Q[(size_t)n*RK + j];
  __shared__ double sh[256];
  sh[t] = a; __syncthreads();
  for (int off = 128; off > 0; off >>= 1){ if (t < off) sh[t] += sh[t+off]; __syncthreads(); }
  if (t == 0) qs[j] = sh[0];
}
__global__ __launch_bounds__(256) void k_deg2f(const double* __restrict__ C, const double* __restrict__ qs,
                                               float* __restrict__ dinv2){
  int i = blockIdx.x*256 + threadIdx.x;
  if (i >= NN) return;
  double s = 0.0;
  #pragma unroll
  for (int k = 0; k < RK; k++) s += C[(size_t)i*RK + k] * qs[k];
  dinv2[i] = (s > 0.0) ? (float)(1.0/sqrt(s)) : 0.f;
}

// ---------------- SpMM over sorted edge lists (f32, branch 1) ----------------
__global__ void k_spmm(const int* __restrict__ ptr, const int* __restrict__ eid,
                       const int* __restrict__ oidx, const float* __restrict__ coef,
                       const float* __restrict__ X, int ldx,
                       float* __restrict__ Y, int ldy, int F,
                       const float* __restrict__ self_dinv, const float* __restrict__ bias){
  int seg = blockIdx.x;
  int t = threadIdx.x, bd = blockDim.x;
  int f1 = t + bd;
  bool two = (f1 < F);
  float acc0 = 0.f, acc1 = 0.f;
  if (self_dinv){
    float sd = self_dinv[seg]; float s2 = sd*sd;
    acc0 = s2 * X[(size_t)seg*ldx + t];
    if (two) acc1 = s2 * X[(size_t)seg*ldx + f1];
  }
  int p0 = ptr[seg], p1 = ptr[seg+1];
  for (int p = p0; p < p1; ++p){
    int e = eid[p];
    int o = oidx[e];
    float c = coef[e];
    const float* xr = X + (size_t)o*ldx;
    acc0 += c * xr[t];
    if (two) acc1 += c * xr[f1];
  }
  if (bias){ acc0 += bias[t]; if (two) acc1 += bias[f1]; }
  Y[(size_t)seg*ldy + t] = acc0;
  if (two) Y[(size_t)seg*ldy + f1] = acc1;
}

// ---------------- domain-specific BN ----------------
__global__ __launch_bounds__(256) void k_bnstats(const float* __restrict__ H, const int* __restrict__ y,
        const int* __restrict__ dcnt, const float* __restrict__ gamma, const float* __restrict__ beta,
        float* __restrict__ scal, float* __restrict__ shft){
  int j = blockIdx.x;
  int t = threadIdx.x;
  float s0=0,s1=0,s2=0,s3=0,q0=0,q1=0,q2=0,q3=0;
  for (int n = t; n < NN; n += 256){
    float v = H[(size_t)n*HIDC + j];
    int d = y[n];
    float v2 = v*v;
    if      (d == 0){ s0 += v; q0 += v2; }
    else if (d == 1){ s1 += v; q1 += v2; }
    else if (d == 2){ s2 += v; q2 += v2; }
    else            { s3 += v; q3 += v2; }
  }
  __shared__ float sh[256][8];
  sh[t][0]=s0; sh[t][1]=s1; sh[t][2]=s2; sh[t][3]=s3;
  sh[t][4]=q0; sh[t][5]=q1; sh[t][6]=q2; sh[t][7]=q3;
  __syncthreads();
  for (int off = 128; off > 0; off >>= 1){
    if (t < off){
      #pragma unroll
      for (int q = 0; q < 8; q++) sh[t][q] += sh[t+off][q];
    }
    __syncthreads();
  }
  if (t < NDOM){
    float cnt  = fmaxf((float)dcnt[t], 1.0f);
    float mean = sh[0][t] / cnt;
    float var  = fmaxf(sh[0][4+t] / cnt - mean*mean, 0.f);
    float inv  = 1.0f / sqrtf(var + EPSBN);
    float gmm  = gamma[t*HIDC + j];
    scal[t*HIDC + j] = gmm * inv;
    shft[t*HIDC + j] = beta[t*HIDC + j] - mean * gmm * inv;
  }
}
__global__ __launch_bounds__(256) void k_bnapply(float* __restrict__ H, const int* __restrict__ y,
        const float* __restrict__ scal, const float* __restrict__ shft){
  int idx = blockIdx.x*256 + threadIdx.x;
  if (idx >= NN*HIDC) return;
  int n = idx >> 9, j = idx & (HIDC-1);
  int d = y[n];
  float v = H[idx] * scal[d*HIDC + j] + shft[d*HIDC + j];
  H[idx] = v > 0.f ? v : 0.f;
}

// ---------------- launch ----------------
extern "C" void kernel_launch(void* const* d_in, const int* in_sizes, int n_in,
                              void* d_out, int out_size, void* d_ws, size_t ws_size,
                              hipStream_t stream){
  (void)in_sizes; (void)n_in; (void)out_size;
  const void* x_in  = d_in[0];
  const int*  ei    = (const int*)d_in[1];
  const void* w_in  = d_in[2];
  const int*  yv    = (const int*)d_in[3];
  const void* W1i   = d_in[4];
  const void* b1i   = d_in[5];
  const void* Wmui  = d_in[6];
  const void* bmui  = d_in[7];
  const void* Wlvi  = d_in[8];
  const void* blvi  = d_in[9];
  const void* gmi   = d_in[10];
  const void* bti   = d_in[11];
  const int* rowA = ei;
  const int* colA = ei + NEDG;
  float* zout = (float*)d_out;

  // ---- workspace: doubles | floats (+bf16) | ints ----
  double* Dp = (double*)d_ws;
  size_t od = 0;
  double* Qd0 = Dp + od; od += (size_t)NN*RK;
  double* Qd1 = Dp + od; od += (size_t)NN*RK;
  double* Cd  = Dp + od; od += (size_t)NN*RK;
  double* Gd  = Dp + od; od += RK*RK;
  double* Rid = Dp + od; od += RK*RK;
  double* qsd = Dp + od; od += RK;
  double* sdd = Dp + od; od += RK;
  float* Fp = (float*)(Dp + od);
  size_t o = 0;
  float* xf   = Fp + o; o += (size_t)NN*INC;       // reused as h1/h2 buffer
  float* W1f  = Fp + o; o += (size_t)INC*HIDC;
  float* b1f  = Fp + o; o += HIDC;
  float* Wmuf = Fp + o; o += (size_t)HIDC*OUTC;
  float* bmuf = Fp + o; o += OUTC;
  float* Wlvf = Fp + o; o += (size_t)HIDC*OUTC;
  float* blvf = Fp + o; o += OUTC;
  float* gmf  = Fp + o; o += NDOM*HIDC;
  float* btf  = Fp + o; o += NDOM*HIDC;
  float* wf   = Fp + o; o += NEDG;
  float* xw1  = Fp + o; o += (size_t)NN*HIDC;
  float* hwA  = Fp + o; o += (size_t)NN*OUTC;
  float* hwB  = Fp + o; o += (size_t)NN*OUTC;     // contiguous after hwA
  float* Bf1  = Fp + o; o += (size_t)NN*RK;        // Qb (f32)
  float* Cm   = Fp + o; o += (size_t)NN*RK;        // C (f32)
  float* Tm   = Fp + o; o += (size_t)RK*HIDC;
  float* Umu  = Fp + o; o += RK*RK;
  float* deg1 = Fp + o; o += NN;
  float* dinv1= Fp + o; o += NN;
  float* dinv2= Fp + o; o += NN;
  float* norm1= Fp + o; o += NEDG;
  float* scal = Fp + o; o += NDOM*HIDC;
  float* shft = Fp + o; o += NDOM*HIDC;
  ushortT* xbf  = (ushortT*)(Fp + o); o += (size_t)NN*INC/2;    // bf16 x
  ushortT* W1bf = (ushortT*)(Fp + o); o += (size_t)INC*HIDC/2;  // bf16 W1
  int* Ip = (int*)(Fp + o);
  size_t oi = 0;
  int* cntR = Ip + oi; oi += NN;
  int* ptrR = Ip + oi; oi += NN + 1;
  int* posR = Ip + oi; oi += NN;
  int* eidR = Ip + oi; oi += NEDG;
  int* cntC = Ip + oi; oi += NN;
  int* ptrC = Ip + oi; oi += NN + 1;
  int* posC = Ip + oi; oi += NN;
  int* eidC = Ip + oi; oi += NEDG;
  int* dcnt = Ip + oi; oi += NDOM;
  int* dflag= Ip + oi; oi += 1;

  size_t need = od*sizeof(double) + o*sizeof(float) + (oi+16)*sizeof(int);
  if (ws_size < need) return;

  float* hbuf = xf;  // x dead after xw1 GEMM

  const int T = 256;
  k_detect<<<1,T,0,stream>>>((const unsigned short*)x_in, dflag);
  k_upcast_all<<<cdiv(OFFT,T),T,0,stream>>>(
      x_in, W1i, w_in, Wmui, Wlvi, gmi, bti, b1i, bmui, blvi, dflag,
      xf, W1f, wf, Wmuf, Wlvf, gmf, btf, b1f, bmuf, blvf, xbf, W1bf);

  k_prep<<<cdiv(NN,T),T,0,stream>>>(deg1, cntR, cntC, dcnt);
  k_hist <<<cdiv(NEDG,T),T,0,stream>>>(rowA, colA, wf, deg1, cntR, cntC);
  k_dinv <<<cdiv(NN,T),T,0,stream>>>(deg1, dinv1, NN);
  k_norm1<<<cdiv(NEDG,T),T,0,stream>>>(rowA, colA, wf, dinv1, norm1);
  k_scan4096<<<1,1024,0,stream>>>(cntR, ptrR, posR);
  k_scan4096<<<1,1024,0,stream>>>(cntC, ptrC, posC);
  k_scatter<<<cdiv(NEDG,T),T,0,stream>>>(rowA, colA, posR, posC, eidR, eidC);
  k_omega<<<cdiv(NN*RK,T),T,0,stream>>>(Qd0);      // f64 seed directly
  k_dcnt <<<cdiv(NN,T),T,0,stream>>>(yv, dcnt);

  // ---- branch 1 ----
  k_gemm_bf16<<<dim3(HIDC/64, NN/64),256,0,stream>>>(xbf, W1bf, xw1);
  k_spmm<<<NN,256,0,stream>>>(ptrC,eidC,rowA,norm1, xw1,HIDC, hbuf,HIDC, HIDC, dinv1, b1f);
  k_bnstats<<<HIDC,256,0,stream>>>(hbuf, yv, dcnt, gmf, btf, scal, shft);
  k_bnapply<<<cdiv(NN*HIDC,T),T,0,stream>>>(hbuf, yv, scal, shft);
  k_fill<<<cdiv(2*NN*OUTC,T),T,0,stream>>>(hwA, 0.f, 2*NN*OUTC);   // hwA|hwB contiguous
  k_gemm_nn_sk<<<dim3(1, NN/64, 4),256,0,stream>>>(NN,OUTC,HIDC,128, hbuf,HIDC, Wmuf,OUTC, hwA,OUTC);
  k_gemm_nn_sk<<<dim3(1, NN/64, 4),256,0,stream>>>(NN,OUTC,HIDC,128, hbuf,HIDC, Wlvf,OUTC, hwB,OUTC);
  k_spmm<<<NN,64,0,stream>>>(ptrC,eidC,rowA,norm1, hwA,OUTC, zout + 0*NN*OUTC,OUTC, OUTC, dinv1, bmuf);
  k_spmm<<<NN,64,0,stream>>>(ptrC,eidC,rowA,norm1, hwB,OUTC, zout + 1*NN*OUTC,OUTC, OUTC, dinv1, blvf);

  // ---- branch 2: f64 subspace, single final QR1 ----
  auto spmmA64 = [&](const double* s, double* d){   // d = A @ s
    k_spmm64<<<NN,64,0,stream>>>(ptrR,eidR,colA,wf, s, d);
  };
  auto spmmAT64 = [&](const double* s, double* d){  // d = A^T @ s
    k_spmm64<<<NN,64,0,stream>>>(ptrC,eidC,rowA,wf, s, d);
  };

  spmmA64 (Qd0, Qd1);                      // P1 -> Qd1
  spmmAT64(Qd1, Qd0);                      // P2 -> Qd0
  spmmA64 (Qd0, Qd1);                      // P3 -> Qd1
  spmmAT64(Qd1, Qd0);                      // P4 -> Qd0
  spmmA64 (Qd0, Qd1);                      // P5 -> Qd1
  k_filld<<<cdiv(RK*RK,T),T,0,stream>>>(Gd, 0.0, RK*RK);
  k_gram64<<<NN/64,256,0,stream>>>(Qd1, Gd);
  k_chol64<<<1,64,0,stream>>>(Gd, sdd);             // L over Gd, sdinv -> sdd
  k_trinv64<<<1,256,0,stream>>>(Gd, sdd, Rid);      // Rinv
  k_applyR64<<<NN/4,256,0,stream>>>(Qd1, Rid, Qd0); // Qb -> Qd0
  spmmAT64(Qd0, Cd);                       // C = A^T Qb  (A2 = Qb C^T)
  k_qsum64<<<RK,256,0,stream>>>(Qd0, qsd);
  k_deg2f<<<cdiv(NN,T),T,0,stream>>>(Cd, qsd, dinv2);
  k_f64to32x2<<<cdiv(NN*RK,T),T,0,stream>>>(Qd0, Bf1, Cd, Cm, NN*RK);

  // h2 = dsbn_relu( D C (Qb^T (D xw1)) + b1 )
  k_fill<<<cdiv(RK*HIDC,T),T,0,stream>>>(Tm, 0.f, RK*HIDC);
  k_gemm_tn_sk<<<dim3(HIDC/16, RK/16, 8),256,0,stream>>>(RK,HIDC,NN,512, Bf1,RK, xw1,HIDC, Tm,HIDC, dinv2);
  k_gemm_nn<<<dim3(HIDC/64, NN/64),256,0,stream>>>(NN,HIDC,RK, Cm,RK, Tm,HIDC, hbuf,HIDC, dinv2, nullptr, b1f);
  k_bnstats<<<HIDC,256,0,stream>>>(hbuf, yv, dcnt, gmf, btf, scal, shft);
  k_bnapply<<<cdiv(NN*HIDC,T),T,0,stream>>>(hbuf, yv, scal, shft);
  // z2 = D C (Qb^T (D (h2 W))) + b
  k_fill<<<cdiv(2*NN*OUTC,T),T,0,stream>>>(hwA, 0.f, 2*NN*OUTC);
  k_gemm_nn_sk<<<dim3(1, NN/64, 4),256,0,stream>>>(NN,OUTC,HIDC,128, hbuf,HIDC, Wmuf,OUTC, hwA,OUTC);
  k_gemm_nn_sk<<<dim3(1, NN/64, 4),256,0,stream>>>(NN,OUTC,HIDC,128, hbuf,HIDC, Wlvf,OUTC, hwB,OUTC);
  k_fill<<<cdiv(RK*RK,T),T,0,stream>>>(Umu, 0.f, RK*RK);
  k_gemm_tn_sk<<<dim3(RK/16, RK/16, 16),256,0,stream>>>(RK,RK,NN,256, Bf1,RK, hwA,OUTC, Umu,RK, dinv2);
  k_gemm_nn<<<dim3(1, NN/64),256,0,stream>>>(NN,OUTC,RK, Cm,RK, Umu,RK, zout + 2*NN*OUTC,OUTC, dinv2, nullptr, bmuf);
  k_fill<<<cdiv(RK*RK,T),T,0,stream>>>(Umu, 0.f, RK*RK);
  k_gemm_tn_sk<<<dim3(RK/16, RK/16, 16),256,0,stream>>>(RK,RK,NN,256, Bf1,RK, hwB,OUTC, Umu,RK, dinv2);
  k_gemm_nn<<<dim3(1, NN/64),256,0,stream>>>(NN,OUTC,RK, Cm,RK, Umu,RK, zout + 3*NN*OUTC,OUTC, dinv2, nullptr, blvf);
}

// Round 7
// 733.504 us; speedup vs baseline: 1.5519x; 1.1399x over previous
//
#include <hip/hip_runtime.h>
#include <hip/hip_bf16.h>

// GCNEncoder — r23: attack the SpMM family. (a) branch-1 512-wide spmm
// gathers xw1 in bf16 (4MB -> fits per-XCD L2; halves traffic; h1 pre-BN
// rounding ~0.2% rel, BN renormalizes). k_gemm_bf16 emits xw1 in f32+bf16.
// (b) contiguous per-segment edge arrays (src,coef) built once — removes the
// eid->oidx/coef double indirection from ALL spmms (7x f64 subspace + 2x
// 64-wide output + the 512-wide). History: r22 836us (bf16 MFMA x@W1);
// r21 900us; r20 930us; r19 943us; r18 982us; r16 1138us.

#define NN    4096
#define NEDG  131072
#define INC   512
#define HIDC  512
#define OUTC  64
#define RK    64
#define NDOM  4
#define EPSBN 1e-5f

typedef unsigned short ushortT;
typedef __attribute__((ext_vector_type(8))) short bf16x8;
typedef __attribute__((ext_vector_type(4))) float f32x4;

static inline int cdiv(int a, int b){ return (a + b - 1) / b; }

__device__ __forceinline__ float bf2f(unsigned u){ return __uint_as_float(u << 16); }

// ---------------- input dtype detection (f32 vs bf16 carriers) ----------------
__global__ __launch_bounds__(256) void k_detect(const unsigned short* __restrict__ p,
                                                int* __restrict__ flag){
  int t = threadIdx.x;
  int cnt = 0;
  for (int i = t; i < 4096; i += 256){
    unsigned short v = p[2*i];
    int e = (v >> 7) & 0xFF;
    if (e >= 100 && e <= 140) cnt++;
  }
  __shared__ int sh[256];
  sh[t] = cnt; __syncthreads();
  for (int off = 128; off > 0; off >>= 1){ if (t < off) sh[t] += sh[t+off]; __syncthreads(); }
  if (t == 0) *flag = (sh[0] >= 2048) ? 0 : 1;
}

// ---------------- fused upcast of all 10 inputs (+ bf16 copies of x, W1) ----------------
__device__ __forceinline__ float upc1(const void* s, int f, int off){
  return f ? ((const float*)s)[off]
           : __bfloat162float(((const __hip_bfloat16*)s)[off]);
}
__device__ __forceinline__ ushortT tobf(float v){
  __hip_bfloat16 h = __float2bfloat16(v);
  return *(ushortT*)&h;
}
#define SEG_X   2097152
#define SEG_W1  262144
#define SEG_W   131072
#define SEG_WMU 32768
#define SEG_GB  2048
#define SEG_B1  512
#define SEG_BO  64
#define OFF1 (SEG_X)
#define OFF2 (OFF1+SEG_W1)
#define OFF3 (OFF2+SEG_W)
#define OFF4 (OFF3+SEG_WMU)
#define OFF5 (OFF4+SEG_WMU)
#define OFF6 (OFF5+SEG_GB)
#define OFF7 (OFF6+SEG_GB)
#define OFF8 (OFF7+SEG_B1)
#define OFF9 (OFF8+SEG_BO)
#define OFFT (OFF9+SEG_BO)

__global__ __launch_bounds__(256) void k_upcast_all(
    const void* x, const void* W1, const void* w, const void* Wmu, const void* Wlv,
    const void* gm, const void* bt, const void* b1, const void* bmu, const void* blv,
    const int* __restrict__ isf32,
    float* dx, float* dW1, float* dw, float* dWmu, float* dWlv,
    float* dgm, float* dbt, float* db1, float* dbmu, float* dblv,
    ushortT* xbf, ushortT* W1bf){
  int i = blockIdx.x*256 + threadIdx.x;
  if (i >= OFFT) return;
  int f = *isf32;
  if      (i < OFF1){ float v = upc1(x, f, i); dx[i] = v; xbf[i] = tobf(v); }
  else if (i < OFF2){ float v = upc1(W1, f, i - OFF1); dW1[i - OFF1] = v; W1bf[i - OFF1] = tobf(v); }
  else if (i < OFF3) dw  [i - OFF2] = upc1(w,   f, i - OFF2);
  else if (i < OFF4) dWmu[i - OFF3] = upc1(Wmu, f, i - OFF3);
  else if (i < OFF5) dWlv[i - OFF4] = upc1(Wlv, f, i - OFF4);
  else if (i < OFF6) dgm [i - OFF5] = upc1(gm,  f, i - OFF5);
  else if (i < OFF7) dbt [i - OFF6] = upc1(bt,  f, i - OFF6);
  else if (i < OFF8) db1 [i - OFF7] = upc1(b1,  f, i - OFF7);
  else if (i < OFF9) dbmu[i - OFF8] = upc1(bmu, f, i - OFF8);
  else               dblv[i - OFF9] = upc1(blv, f, i - OFF9);
}

// ---------------- elementwise utils ----------------
__global__ __launch_bounds__(256) void k_fill(float* d, float v, int n){
  int i = blockIdx.x*256 + threadIdx.x;
  if (i < n) d[i] = v;
}
__global__ __launch_bounds__(256) void k_filld(double* d, double v, int n){
  int i = blockIdx.x*256 + threadIdx.x;
  if (i < n) d[i] = v;
}
__global__ __launch_bounds__(256) void k_prep(float* deg, int* cntR, int* cntC, int* dcnt){
  int i = blockIdx.x*256 + threadIdx.x;
  if (i < NN){ deg[i] = 1.0f; cntR[i] = 0; cntC[i] = 0; }
  if (i < NDOM) dcnt[i] = 0;
}
__global__ __launch_bounds__(256) void k_f64to32x2(const double* __restrict__ s0, float* __restrict__ d0,
                                                   const double* __restrict__ s1, float* __restrict__ d1,
                                                   int n){
  int i = blockIdx.x*256 + threadIdx.x;
  if (i < n){ d0[i] = (float)s0[i]; d1[i] = (float)s1[i]; }
}

// ---------------- graph preprocessing ----------------
__global__ __launch_bounds__(256) void k_hist(const int* __restrict__ row, const int* __restrict__ col,
                                              const float* __restrict__ w, float* deg,
                                              int* cntR, int* cntC){
  int e = blockIdx.x*256 + threadIdx.x;
  if (e < NEDG){
    atomicAdd(&deg[col[e]], w[e]);
    atomicAdd(&cntR[row[e]], 1);
    atomicAdd(&cntC[col[e]], 1);
  }
}
__global__ __launch_bounds__(256) void k_dinv(const float* deg, float* dinv, int n){
  int i = blockIdx.x*256 + threadIdx.x;
  if (i < n){ float d = deg[i]; dinv[i] = (d > 0.f) ? 1.f/sqrtf(d) : 0.f; }
}
__global__ __launch_bounds__(256) void k_norm1(const int* __restrict__ row, const int* __restrict__ col,
                                               const float* __restrict__ w, const float* __restrict__ dinv,
                                               float* __restrict__ nrm){
  int e = blockIdx.x*256 + threadIdx.x;
  if (e < NEDG) nrm[e] = dinv[row[e]] * w[e] * dinv[col[e]];
}
__global__ __launch_bounds__(1024) void k_scan4096(const int* __restrict__ cnt,
                                                   int* __restrict__ ptr, int* __restrict__ pos){
  __shared__ int sh[1024];
  int t = threadIdx.x;
  int b = t*4;
  int a0 = cnt[b], a1 = cnt[b+1], a2 = cnt[b+2], a3 = cnt[b+3];
  sh[t] = a0 + a1 + a2 + a3;
  __syncthreads();
  for (int off = 1; off < 1024; off <<= 1){
    int v = (t >= off) ? sh[t-off] : 0;
    __syncthreads();
    sh[t] += v;
    __syncthreads();
  }
  int excl = (t == 0) ? 0 : sh[t-1];
  ptr[b]   = excl;            pos[b]   = excl;
  ptr[b+1] = excl+a0;         pos[b+1] = excl+a0;
  ptr[b+2] = excl+a0+a1;      pos[b+2] = excl+a0+a1;
  ptr[b+3] = excl+a0+a1+a2;   pos[b+3] = excl+a0+a1+a2;
  if (t == 1023) ptr[4096] = sh[1023];
}
__global__ __launch_bounds__(256) void k_scatter(const int* __restrict__ row, const int* __restrict__ col,
                                                 int* posR, int* posC, int* eidR, int* eidC){
  int e = blockIdx.x*256 + threadIdx.x;
  if (e < NEDG){
    int p = atomicAdd(&posR[row[e]], 1); eidR[p] = e;
    int q = atomicAdd(&posC[col[e]], 1); eidC[q] = e;
  }
}
// contiguous per-segment edge data (removes eid indirection from all spmms)
__global__ __launch_bounds__(256) void k_edges(const int* __restrict__ rowA, const int* __restrict__ colA,
        const float* __restrict__ wf, const float* __restrict__ nrm,
        const int* __restrict__ eidR, const int* __restrict__ eidC,
        int* __restrict__ csrSrc, float* __restrict__ csrW,
        int* __restrict__ cscSrc, float* __restrict__ cscW, float* __restrict__ cscN){
  int p = blockIdx.x*256 + threadIdx.x;
  if (p < NEDG){
    int eR = eidR[p]; csrSrc[p] = colA[eR]; csrW[p] = wf[eR];
    int eC = eidC[p]; cscSrc[p] = rowA[eC]; cscW[p] = wf[eC]; cscN[p] = nrm[eC];
  }
}
__global__ __launch_bounds__(256) void k_dcnt(const int* __restrict__ y, int* dcnt){
  int i = blockIdx.x*256 + threadIdx.x;
  if (i < NN) atomicAdd(&dcnt[y[i]], 1);
}

// ---------------- threefry2x32 core (KAT-verified round 8) ----------------
__device__ __forceinline__ unsigned rotl32(unsigned x, unsigned d){ return (x << d) | (x >> (32u - d)); }
#define TF_ROUND4(R0,R1,R2,R3) \
  x0 += x1; x1 = rotl32(x1,R0); x1 ^= x0; \
  x0 += x1; x1 = rotl32(x1,R1); x1 ^= x0; \
  x0 += x1; x1 = rotl32(x1,R2); x1 ^= x0; \
  x0 += x1; x1 = rotl32(x1,R3); x1 ^= x0;

__device__ __forceinline__ void tf2x32(unsigned k0, unsigned k1, unsigned c0, unsigned c1,
                                       unsigned* o0, unsigned* o1){
  unsigned ks2 = 0x1BD11BDAu ^ k0 ^ k1;
  unsigned x0 = c0 + k0, x1 = c1 + k1;
  TF_ROUND4(13,15,26,6);   x0 += k1;  x1 += ks2 + 1u;
  TF_ROUND4(17,29,16,24);  x0 += ks2; x1 += k0 + 2u;
  TF_ROUND4(13,15,26,6);   x0 += k0;  x1 += k1 + 3u;
  TF_ROUND4(17,29,16,24);  x0 += k1;  x1 += ks2 + 4u;
  TF_ROUND4(13,15,26,6);   x0 += ks2; x1 += k0 + 5u;
  *o0 = x0; *o1 = x1;
}

// ---------------- omega (verified round 10; direct f64 output) ----------------
__device__ double erfinv64(double x){
  double w = -log1p(-x*x);
  double p;
  if (w < 5.0){
    w -= 2.5;
    p = 2.81022636e-08;  p = p*w + 3.43273939e-07; p = p*w - 3.5233877e-06;
    p = p*w - 4.39150654e-06; p = p*w + 0.00021858087; p = p*w - 0.00125372503;
    p = p*w - 0.00417768164;  p = p*w + 0.246640727;   p = p*w + 1.50140941;
  } else {
    w = sqrt(w) - 3.0;
    p = -0.000200214257; p = p*w + 0.000100950558; p = p*w + 0.00134934322;
    p = p*w - 0.00367342844; p = p*w + 0.00573950773; p = p*w - 0.0076224613;
    p = p*w + 0.00943887047; p = p*w + 1.00167406;    p = p*w + 2.83297682;
  }
  double y = p * x;
  const double c = 1.1283791670955126;   // 2/sqrt(pi)
  #pragma unroll
  for (int it = 0; it < 3; it++){
    double err = erf(y) - x;
    y -= err / (c * exp(-y*y));
  }
  return y;
}

__device__ float bits_to_normal(unsigned b){
  float f = __uint_as_float((b >> 9) | 0x3f800000u) - 1.0f;
  const float lo = -0.99999994f;               // nextafter(-1,0) in f32
  float x = fmaxf(lo, f * 2.0f + lo);
  double r = 1.4142135623730951 * erfinv64((double)x);
  return (float)r;
}

__global__ __launch_bounds__(256) void k_omega(double* __restrict__ om){
  int i = blockIdx.x*256 + threadIdx.x;
  if (i >= 262144) return;
  unsigned o0, o1;
  tf2x32(0u, 42u, 0u, (unsigned)i, &o0, &o1);   // counter = (0, i)
  om[i] = (double)bits_to_normal(o0 ^ o1);      // same f32 value as before, widened
}

// ---------------- bf16 MFMA GEMM (r22-proven) + bf16 C copy ----------------
__global__ __launch_bounds__(256) void k_gemm_bf16(
    const ushortT* __restrict__ A, const ushortT* __restrict__ B,
    float* __restrict__ Cc, ushortT* __restrict__ Cbf){
  __shared__ ushortT As2[64][40];   // [row][k] (+8 pad)
  __shared__ ushortT Bs2[64][40];   // [col][k] transposed (+8 pad)
  int t = threadIdx.x;
  int bm = blockIdx.y * 64, bn = blockIdx.x * 64;
  int w = t >> 6, l = t & 63;
  int lr = l & 15, lk = l >> 4;
  f32x4 acc[4] = {};
  int ar = t >> 2, ac = (t & 3) * 8;      // A stage: 64 rows x 32 k, 16B/thread
  int bc = t & 63, bk = (t >> 6) * 8;     // B stage: 64 cols x 8 k gathered
  for (int k0 = 0; k0 < 512; k0 += 32){
    *(uint4*)&As2[ar][ac] = *(const uint4*)&A[(size_t)(bm + ar) * 512 + k0 + ac];
    ushortT tmp[8];
    #pragma unroll
    for (int j = 0; j < 8; j++)
      tmp[j] = B[(size_t)(k0 + bk + j) * 512 + bn + bc];
    *(uint4*)&Bs2[bc][bk] = *(uint4*)tmp;
    __syncthreads();
    bf16x8 afrag = *(bf16x8*)&As2[w * 16 + lr][lk * 8];
    #pragma unroll
    for (int nt = 0; nt < 4; nt++){
      bf16x8 bfrag = *(bf16x8*)&Bs2[nt * 16 + lr][lk * 8];
      acc[nt] = __builtin_amdgcn_mfma_f32_16x16x32_bf16(afrag, bfrag, acc[nt], 0, 0, 0);
    }
    __syncthreads();
  }
  #pragma unroll
  for (int nt = 0; nt < 4; nt++){
    #pragma unroll
    for (int i = 0; i < 4; i++){
      size_t idx = (size_t)(bm + w * 16 + lk * 4 + i) * 512 + bn + nt * 16 + lr;
      float v = acc[nt][i];
      Cc[idx] = v;
      Cbf[idx] = tobf(v);
    }
  }
}

// ---------------- GEMM (fp32, tiled 64x64, 4x4/thread) ----------------
__global__ __launch_bounds__(256) void k_gemm_nn(int M, int Nn, int K,
      const float* __restrict__ A, int lda, const float* __restrict__ B, int ldb,
      float* __restrict__ Cc, int ldc, const float* __restrict__ rowscale,
      const float* __restrict__ kscale, const float* __restrict__ bias){
  __shared__ float As[16][65];
  __shared__ float Bs[16][65];
  int bm = blockIdx.y*64, bn = blockIdx.x*64;
  int t = threadIdx.x;
  int tr = t >> 4, tc = t & 15;
  float acc[4][4] = {};
  for (int k0 = 0; k0 < K; k0 += 16){
    #pragma unroll
    for (int q = 0; q < 4; q++){
      int idx = t*4 + q;
      int m = idx >> 4, kk = idx & 15;
      As[kk][m] = A[(size_t)(bm+m)*lda + (k0+kk)];
    }
    #pragma unroll
    for (int q = 0; q < 4; q++){
      int idx = t + q*256;
      int kk = idx >> 6, n = idx & 63;
      float ks = kscale ? kscale[k0+kk] : 1.0f;
      Bs[kk][n] = B[(size_t)(k0+kk)*ldb + (bn+n)] * ks;
    }
    __syncthreads();
    #pragma unroll
    for (int kk = 0; kk < 16; kk++){
      float a0 = As[kk][tr*4+0], a1 = As[kk][tr*4+1], a2 = As[kk][tr*4+2], a3 = As[kk][tr*4+3];
      float b0 = Bs[kk][tc*4+0], b1 = Bs[kk][tc*4+1], b2 = Bs[kk][tc*4+2], b3 = Bs[kk][tc*4+3];
      acc[0][0] += a0*b0; acc[0][1] += a0*b1; acc[0][2] += a0*b2; acc[0][3] += a0*b3;
      acc[1][0] += a1*b0; acc[1][1] += a1*b1; acc[1][2] += a1*b2; acc[1][3] += a1*b3;
      acc[2][0] += a2*b0; acc[2][1] += a2*b1; acc[2][2] += a2*b2; acc[2][3] += a2*b3;
      acc[3][0] += a3*b0; acc[3][1] += a3*b1; acc[3][2] += a3*b2; acc[3][3] += a3*b3;
    }
    __syncthreads();
  }
  #pragma unroll
  for (int i2 = 0; i2 < 4; i2++){
    int m = bm + tr*4 + i2;
    float rs = rowscale ? rowscale[m] : 1.0f;
    #pragma unroll
    for (int j2 = 0; j2 < 4; j2++){
      int n = bn + tc*4 + j2;
      float v = acc[i2][j2] * rs;
      if (bias) v += bias[n];
      Cc[(size_t)m*ldc + n] = v;
    }
  }
}

// split-K NN: C += partial (C pre-zeroed); grid (Nn/64, M/64, K/kchunk)
__global__ __launch_bounds__(256) void k_gemm_nn_sk(int M, int Nn, int K, int kchunk,
      const float* __restrict__ A, int lda, const float* __restrict__ B, int ldb,
      float* __restrict__ Cc, int ldc){
  __shared__ float As[16][65];
  __shared__ float Bs[16][65];
  int bm = blockIdx.y*64, bn = blockIdx.x*64;
  int kb = blockIdx.z*kchunk, ke = kb + kchunk;
  int t = threadIdx.x;
  int tr = t >> 4, tc = t & 15;
  float acc[4][4] = {};
  for (int k0 = kb; k0 < ke; k0 += 16){
    #pragma unroll
    for (int q = 0; q < 4; q++){
      int idx = t*4 + q;
      int m = idx >> 4, kk = idx & 15;
      As[kk][m] = A[(size_t)(bm+m)*lda + (k0+kk)];
    }
    #pragma unroll
    for (int q = 0; q < 4; q++){
      int idx = t + q*256;
      int kk = idx >> 6, n = idx & 63;
      Bs[kk][n] = B[(size_t)(k0+kk)*ldb + (bn+n)];
    }
    __syncthreads();
    #pragma unroll
    for (int kk = 0; kk < 16; kk++){
      float a0 = As[kk][tr*4+0], a1 = As[kk][tr*4+1], a2 = As[kk][tr*4+2], a3 = As[kk][tr*4+3];
      float b0 = Bs[kk][tc*4+0], b1 = Bs[kk][tc*4+1], b2 = Bs[kk][tc*4+2], b3 = Bs[kk][tc*4+3];
      acc[0][0] += a0*b0; acc[0][1] += a0*b1; acc[0][2] += a0*b2; acc[0][3] += a0*b3;
      acc[1][0] += a1*b0; acc[1][1] += a1*b1; acc[1][2] += a1*b2; acc[1][3] += a1*b3;
      acc[2][0] += a2*b0; acc[2][1] += a2*b1; acc[2][2] += a2*b2; acc[2][3] += a2*b3;
      acc[3][0] += a3*b0; acc[3][1] += a3*b1; acc[3][2] += a3*b2; acc[3][3] += a3*b3;
    }
    __syncthreads();
  }
  #pragma unroll
  for (int i2 = 0; i2 < 4; i2++){
    int m = bm + tr*4 + i2;
    #pragma unroll
    for (int j2 = 0; j2 < 4; j2++){
      int n = bn + tc*4 + j2;
      atomicAdd(&Cc[(size_t)m*ldc + n], acc[i2][j2]);
    }
  }
}

// split-K TN: C += partial (C pre-zeroed); grid (Nn/16, M/16, K/kchunk)
__global__ __launch_bounds__(256) void k_gemm_tn_sk(int M, int Nn, int K, int kchunk,
      const float* __restrict__ A, int lda, const float* __restrict__ B, int ldb,
      float* __restrict__ Cc, int ldc, const float* __restrict__ kscale){
  __shared__ float As[32][17];
  __shared__ float Bs[32][17];
  int bm = blockIdx.y*16, bn = blockIdx.x*16;
  int kb = blockIdx.z*kchunk, ke = kb + kchunk;
  int t = threadIdx.x;
  int tm = t >> 4, tn = t & 15;
  float acc = 0.f;
  for (int k0 = kb; k0 < ke; k0 += 32){
    #pragma unroll
    for (int q = 0; q < 2; q++){
      int idx = t + q*256;
      int kk = idx >> 4, m = idx & 15;
      float sv = kscale ? kscale[k0+kk] : 1.0f;
      As[kk][m] = A[(size_t)(k0+kk)*lda + (bm+m)] * sv;
      Bs[kk][m] = B[(size_t)(k0+kk)*ldb + (bn+m)];
    }
    __syncthreads();
    #pragma unroll
    for (int kk = 0; kk < 32; kk++) acc += As[kk][tm] * Bs[kk][tn];
    __syncthreads();
  }
  atomicAdd(&Cc[(size_t)(bm+tm)*ldc + (bn+tn)], acc);
}

// ---------------- f64 randomized-subspace chain ----------------
__global__ __launch_bounds__(64) void k_spmm64(const int* __restrict__ ptr,
                       const int* __restrict__ src, const float* __restrict__ cf,
                       const double* __restrict__ X, double* __restrict__ Y){
  int seg = blockIdx.x;
  int t = threadIdx.x;
  double acc = 0.0;
  int p0 = ptr[seg], p1 = ptr[seg+1];
  for (int p = p0; p < p1; ++p){
    acc += (double)cf[p] * X[(size_t)src[p]*RK + t];
  }
  Y[(size_t)seg*RK + t] = acc;
}
// Gram: G += Xslice^T Xslice over 64-row slices (G zeroed before)
__global__ __launch_bounds__(256) void k_gram64(const double* __restrict__ X, double* __restrict__ G){
  __shared__ double Xs[64][65];
  int b = blockIdx.x;
  int t = threadIdx.x;
  #pragma unroll
  for (int q = 0; q < 16; q++){
    int idx = t + q*256;
    Xs[idx >> 6][idx & 63] = X[(size_t)(b*64 + (idx >> 6))*RK + (idx & 63)];
  }
  __syncthreads();
  int i = t >> 2;
  int j0 = (t & 3) * 16;
  double acc[16];
  #pragma unroll
  for (int jj = 0; jj < 16; jj++) acc[jj] = 0.0;
  for (int k = 0; k < 64; k++){
    double a = Xs[k][i];
    #pragma unroll
    for (int jj = 0; jj < 16; jj++) acc[jj] += a * Xs[k][j0+jj];
  }
  #pragma unroll
  for (int jj = 0; jj < 16; jj++) atomicAdd(&G[i*RK + j0 + jj], acc[jj]);
}
// ---- Cholesky factorization, ONE wave (r21-proven). ----
#define CHOL_CHUNK(I0) \
  for (int k2 = 0; k2 < 16; k2++){ \
    int k = (I0) + k2; \
    int buf = k & 1; \
    if (j == k){ \
      double d = sqrt(fmax(cdiag, 1e-300)); \
      double s = 1.0 / d; \
      myd = d; \
      sdd[k] = s; \
      _Pragma("unroll") \
      for (int i = (I0); i < 64; i++){ c[i] *= s; colk[buf][i] = c[i]; } \
    } \
    __syncthreads(); \
    if (j > k){ \
      double cj = colk[buf][j]; \
      cdiag -= cj * cj; \
      _Pragma("unroll") \
      for (int i = (I0); i < 64; i++){ c[i] -= colk[buf][i] * cj; } \
    } \
    __syncthreads(); \
  }

__global__ __launch_bounds__(64) void k_chol64(double* __restrict__ G, double* __restrict__ sdd){
  __shared__ double colk[2][64];
  int j = threadIdx.x;        // 0..63, owns column j
  double c[64];
  #pragma unroll
  for (int i = 0; i < 64; i++) c[i] = G[i*64 + j];
  double cdiag = 0.0, myd = 0.0;
  #pragma unroll
  for (int i = 0; i < 64; i++) if (i == j) cdiag = c[i];
  CHOL_CHUNK(0)
  CHOL_CHUNK(16)
  CHOL_CHUNK(32)
  CHOL_CHUNK(48)
  #pragma unroll
  for (int i = 0; i < 64; i++){
    double v = (i > j) ? c[i] : 0.0;
    if (i == j) v = myd;
    G[i*64 + j] = v;
  }
}
// ---- blocked triangular inverse (r19/r20/r21-proven stages), 256 threads. ----
__global__ __launch_bounds__(256) void k_trinv64(const double* __restrict__ L,
      const double* __restrict__ sdd, double* __restrict__ Rinv){
  __shared__ double gl[64][65];   // L lower; R[i][a] = gl[a][i]
  __shared__ double Xl[64][65];   // X = R^{-1} (upper); lower stays 0
  __shared__ double sdinv[64];
  __shared__ double Sl[3][16][17];
  int t = threadIdx.x;
  #pragma unroll
  for (int q = 0; q < 16; q++){
    int idx = t + (q << 8);
    gl[idx >> 6][idx & 63] = L[idx];
  }
  if (t < 64) sdinv[t] = sdd[t];
  for (int idx = t; idx < 64*65; idx += 256)
    ((double*)Xl)[idx] = 0.0;
  __syncthreads();
  if (t < 64){
    int b = t >> 4, c2 = t & 15;
    int g0 = b << 4;
    int gc = g0 + c2;
    Xl[gc][gc] = sdinv[gc];
    for (int i = c2 - 1; i >= 0; i--){
      int gi = g0 + i;
      double s = 0.0;
      for (int k2 = i + 1; k2 <= c2; k2++)
        s += gl[g0 + k2][gi] * Xl[g0 + k2][gc];
      Xl[gi][gc] = -s * sdinv[gi];
    }
  }
  __syncthreads();
  for (int d = 1; d < 4; d++){
    int np = 4 - d;
    int tot = np << 8;
    for (int e = t; e < tot; e += 256){
      int p = e >> 8;
      int i = (e >> 4) & 15, jj = e & 15;
      int gi = (p << 4) + i, gj = ((p + d) << 4) + jj;
      double s = 0.0;
      int a0 = (p + 1) << 4, a1 = (p + d + 1) << 4;
      for (int a = a0; a < a1; a++)
        s += gl[a][gi] * Xl[a][gj];
      Sl[p][i][jj] = s;
    }
    __syncthreads();
    for (int e = t; e < tot; e += 256){
      int p = e >> 8;
      int i = (e >> 4) & 15, jj = e & 15;
      int gi = (p << 4) + i, gj = ((p + d) << 4) + jj;
      double s = 0.0;
      #pragma unroll
      for (int k2 = 0; k2 < 16; k2++)
        s += Xl[gi][(p << 4) + k2] * Sl[p][k2][jj];
      Xl[gi][gj] = -s;
    }
    __syncthreads();
  }
  #pragma unroll
  for (int q = 0; q < 16; q++){
    int e2 = t + (q << 8);
    Rinv[e2] = Xl[e2 >> 6][e2 & 63];
  }
}
// dst[NNx64] = src[NNx64] * Rinv(upper); 4 rows per 256-thread block
__global__ __launch_bounds__(256) void k_applyR64(const double* __restrict__ src,
      const double* __restrict__ Rinv, double* __restrict__ dst){
  __shared__ double Rs[64][65];
  int t = threadIdx.x;
  #pragma unroll
  for (int q = 0; q < 16; q++){
    int idx = t + q*256;
    Rs[idx >> 6][idx & 63] = Rinv[idx];
  }
  __syncthreads();
  int r = blockIdx.x*4 + (t >> 6);
  int j = t & 63;
  const double* rowp = src + (size_t)r*RK;
  double s = 0.0;
  for (int k = 0; k <= j; k++) s += rowp[k] * Rs[k][j];
  dst[(size_t)r*RK + j] = s;
}
__global__ __launch_bounds__(256) void k_qsum64(const double* __restrict__ Q, double* __restrict__ qs){
  int j = blockIdx.x;  int t = threadIdx.x;
  double a = 0.0;
  for (int n = t; n < NN; n += 256) a += Q[(size_t)n*RK + j];
  __shared__ double sh[256];
  sh[t] = a; __syncthreads();
  for (int off = 128; off > 0; off >>= 1){ if (t < off) sh[t] += sh[t+off]; __syncthreads(); }
  if (t == 0) qs[j] = sh[0];
}
__global__ __launch_bounds__(256) void k_deg2f(const double* __restrict__ C, const double* __restrict__ qs,
                                               float* __restrict__ dinv2){
  int i = blockIdx.x*256 + threadIdx.x;
  if (i >= NN) return;
  double s = 0.0;
  #pragma unroll
  for (int k = 0; k < RK; k++) s += C[(size_t)i*RK + k] * qs[k];
  dinv2[i] = (s > 0.0) ? (float)(1.0/sqrt(s)) : 0.f;
}

// ---------------- SpMMs over contiguous per-segment edge data ----------------
// 512-wide bf16 gather (branch-1 h1): thread t handles cols 2t, 2t+1.
__global__ __launch_bounds__(256) void k_spmm_bf16(const int* __restrict__ ptr,
        const int* __restrict__ src, const float* __restrict__ cf,
        const ushortT* __restrict__ Xb, float* __restrict__ Y,
        const float* __restrict__ self_dinv, const float* __restrict__ bias){
  int seg = blockIdx.x;
  int t = threadIdx.x;
  float acc0, acc1;
  {
    float sd = self_dinv[seg]; float s2 = sd*sd;
    unsigned v = *(const unsigned*)&Xb[(size_t)seg*HIDC + 2*t];
    acc0 = s2 * bf2f(v & 0xffffu);
    acc1 = s2 * bf2f(v >> 16);
  }
  int p0 = ptr[seg], p1 = ptr[seg+1];
  for (int p = p0; p < p1; ++p){
    int o = src[p];
    float c = cf[p];
    unsigned v = *(const unsigned*)&Xb[(size_t)o*HIDC + 2*t];
    acc0 += c * bf2f(v & 0xffffu);
    acc1 += c * bf2f(v >> 16);
  }
  acc0 += bias[2*t];
  acc1 += bias[2*t+1];
  Y[(size_t)seg*HIDC + 2*t]     = acc0;
  Y[(size_t)seg*HIDC + 2*t + 1] = acc1;
}
// f32 spmm (64-wide, output stage)
__global__ void k_spmm(const int* __restrict__ ptr, const int* __restrict__ src,
                       const float* __restrict__ cf,
                       const float* __restrict__ X, int ldx,
                       float* __restrict__ Y, int ldy,
                       const float* __restrict__ self_dinv, const float* __restrict__ bias){
  int seg = blockIdx.x;
  int t = threadIdx.x;
  float acc0 = 0.f;
  {
    float sd = self_dinv[seg];
    acc0 = sd*sd * X[(size_t)seg*ldx + t];
  }
  int p0 = ptr[seg], p1 = ptr[seg+1];
  for (int p = p0; p < p1; ++p){
    acc0 += cf[p] * X[(size_t)src[p]*ldx + t];
  }
  acc0 += bias[t];
  Y[(size_t)seg*ldy + t] = acc0;
}

// ---------------- domain-specific BN ----------------
__global__ __launch_bounds__(256) void k_bnstats(const float* __restrict__ H, const int* __restrict__ y,
        const int* __restrict__ dcnt, const float* __restrict__ gamma, const float* __restrict__ beta,
        float* __restrict__ scal, float* __restrict__ shft){
  int j = blockIdx.x;
  int t = threadIdx.x;
  float s0=0,s1=0,s2=0,s3=0,q0=0,q1=0,q2=0,q3=0;
  for (int n = t; n < NN; n += 256){
    float v = H[(size_t)n*HIDC + j];
    int d = y[n];
    float v2 = v*v;
    if      (d == 0){ s0 += v; q0 += v2; }
    else if (d == 1){ s1 += v; q1 += v2; }
    else if (d == 2){ s2 += v; q2 += v2; }
    else            { s3 += v; q3 += v2; }
  }
  __shared__ float sh[256][8];
  sh[t][0]=s0; sh[t][1]=s1; sh[t][2]=s2; sh[t][3]=s3;
  sh[t][4]=q0; sh[t][5]=q1; sh[t][6]=q2; sh[t][7]=q3;
  __syncthreads();
  for (int off = 128; off > 0; off >>= 1){
    if (t < off){
      #pragma unroll
      for (int q = 0; q < 8; q++) sh[t][q] += sh[t+off][q];
    }
    __syncthreads();
  }
  if (t < NDOM){
    float cnt  = fmaxf((float)dcnt[t], 1.0f);
    float mean = sh[0][t] / cnt;
    float var  = fmaxf(sh[0][4+t] / cnt - mean*mean, 0.f);
    float inv  = 1.0f / sqrtf(var + EPSBN);
    float gmm  = gamma[t*HIDC + j];
    scal[t*HIDC + j] = gmm * inv;
    shft[t*HIDC + j] = beta[t*HIDC + j] - mean * gmm * inv;
  }
}
__global__ __launch_bounds__(256) void k_bnapply(float* __restrict__ H, const int* __restrict__ y,
        const float* __restrict__ scal, const float* __restrict__ shft){
  int idx = blockIdx.x*256 + threadIdx.x;
  if (idx >= NN*HIDC) return;
  int n = idx >> 9, j = idx & (HIDC-1);
  int d = y[n];
  float v = H[idx] * scal[d*HIDC + j] + shft[d*HIDC + j];
  H[idx] = v > 0.f ? v : 0.f;
}

// ---------------- launch ----------------
extern "C" void kernel_launch(void* const* d_in, const int* in_sizes, int n_in,
                              void* d_out, int out_size, void* d_ws, size_t ws_size,
                              hipStream_t stream){
  (void)in_sizes; (void)n_in; (void)out_size;
  const void* x_in  = d_in[0];
  const int*  ei    = (const int*)d_in[1];
  const void* w_in  = d_in[2];
  const int*  yv    = (const int*)d_in[3];
  const void* W1i   = d_in[4];
  const void* b1i   = d_in[5];
  const void* Wmui  = d_in[6];
  const void* bmui  = d_in[7];
  const void* Wlvi  = d_in[8];
  const void* blvi  = d_in[9];
  const void* gmi   = d_in[10];
  const void* bti   = d_in[11];
  const int* rowA = ei;
  const int* colA = ei + NEDG;
  float* zout = (float*)d_out;

  // ---- workspace: doubles | floats (+bf16) | ints ----
  double* Dp = (double*)d_ws;
  size_t od = 0;
  double* Qd0 = Dp + od; od += (size_t)NN*RK;
  double* Qd1 = Dp + od; od += (size_t)NN*RK;
  double* Cd  = Dp + od; od += (size_t)NN*RK;
  double* Gd  = Dp + od; od += RK*RK;
  double* Rid = Dp + od; od += RK*RK;
  double* qsd = Dp + od; od += RK;
  double* sdd = Dp + od; od += RK;
  float* Fp = (float*)(Dp + od);
  size_t o = 0;
  float* xf   = Fp + o; o += (size_t)NN*INC;       // reused as h1/h2 buffer
  float* W1f  = Fp + o; o += (size_t)INC*HIDC;
  float* b1f  = Fp + o; o += HIDC;
  float* Wmuf = Fp + o; o += (size_t)HIDC*OUTC;
  float* bmuf = Fp + o; o += OUTC;
  float* Wlvf = Fp + o; o += (size_t)HIDC*OUTC;
  float* blvf = Fp + o; o += OUTC;
  float* gmf  = Fp + o; o += NDOM*HIDC;
  float* btf  = Fp + o; o += NDOM*HIDC;
  float* wf   = Fp + o; o += NEDG;
  float* xw1  = Fp + o; o += (size_t)NN*HIDC;
  float* hwA  = Fp + o; o += (size_t)NN*OUTC;
  float* hwB  = Fp + o; o += (size_t)NN*OUTC;     // contiguous after hwA
  float* Bf1  = Fp + o; o += (size_t)NN*RK;        // Qb (f32)
  float* Cm   = Fp + o; o += (size_t)NN*RK;        // C (f32)
  float* Tm   = Fp + o; o += (size_t)RK*HIDC;
  float* Umu  = Fp + o; o += RK*RK;
  float* deg1 = Fp + o; o += NN;
  float* dinv1= Fp + o; o += NN;
  float* dinv2= Fp + o; o += NN;
  float* norm1= Fp + o; o += NEDG;
  float* scal = Fp + o; o += NDOM*HIDC;
  float* shft = Fp + o; o += NDOM*HIDC;
  float* csrW = Fp + o; o += NEDG;
  float* cscW = Fp + o; o += NEDG;
  float* cscN = Fp + o; o += NEDG;
  ushortT* xbf   = (ushortT*)(Fp + o); o += (size_t)NN*INC/2;    // bf16 x
  ushortT* W1bf  = (ushortT*)(Fp + o); o += (size_t)INC*HIDC/2;  // bf16 W1
  ushortT* xw1bf = (ushortT*)(Fp + o); o += (size_t)NN*HIDC/2;   // bf16 xw1
  int* Ip = (int*)(Fp + o);
  size_t oi = 0;
  int* cntR = Ip + oi; oi += NN;
  int* ptrR = Ip + oi; oi += NN + 1;
  int* posR = Ip + oi; oi += NN;
  int* eidR = Ip + oi; oi += NEDG;
  int* cntC = Ip + oi; oi += NN;
  int* ptrC = Ip + oi; oi += NN + 1;
  int* posC = Ip + oi; oi += NN;
  int* eidC = Ip + oi; oi += NEDG;
  int* csrSrc = Ip + oi; oi += NEDG;
  int* cscSrc = Ip + oi; oi += NEDG;
  int* dcnt = Ip + oi; oi += NDOM;
  int* dflag= Ip + oi; oi += 1;

  size_t need = od*sizeof(double) + o*sizeof(float) + (oi+16)*sizeof(int);
  if (ws_size < need) return;

  float* hbuf = xf;  // x dead after xw1 GEMM

  const int T = 256;
  k_detect<<<1,T,0,stream>>>((const unsigned short*)x_in, dflag);
  k_upcast_all<<<cdiv(OFFT,T),T,0,stream>>>(
      x_in, W1i, w_in, Wmui, Wlvi, gmi, bti, b1i, bmui, blvi, dflag,
      xf, W1f, wf, Wmuf, Wlvf, gmf, btf, b1f, bmuf, blvf, xbf, W1bf);

  k_prep<<<cdiv(NN,T),T,0,stream>>>(deg1, cntR, cntC, dcnt);
  k_hist <<<cdiv(NEDG,T),T,0,stream>>>(rowA, colA, wf, deg1, cntR, cntC);
  k_dinv <<<cdiv(NN,T),T,0,stream>>>(deg1, dinv1, NN);
  k_norm1<<<cdiv(NEDG,T),T,0,stream>>>(rowA, colA, wf, dinv1, norm1);
  k_scan4096<<<1,1024,0,stream>>>(cntR, ptrR, posR);
  k_scan4096<<<1,1024,0,stream>>>(cntC, ptrC, posC);
  k_scatter<<<cdiv(NEDG,T),T,0,stream>>>(rowA, colA, posR, posC, eidR, eidC);
  k_edges<<<cdiv(NEDG,T),T,0,stream>>>(rowA, colA, wf, norm1, eidR, eidC,
                                       csrSrc, csrW, cscSrc, cscW, cscN);
  k_omega<<<cdiv(NN*RK,T),T,0,stream>>>(Qd0);      // f64 seed directly
  k_dcnt <<<cdiv(NN,T),T,0,stream>>>(yv, dcnt);

  // ---- branch 1 ----
  k_gemm_bf16<<<dim3(HIDC/64, NN/64),256,0,stream>>>(xbf, W1bf, xw1, xw1bf);
  k_spmm_bf16<<<NN,256,0,stream>>>(ptrC, cscSrc, cscN, xw1bf, hbuf, dinv1, b1f);
  k_bnstats<<<HIDC,256,0,stream>>>(hbuf, yv, dcnt, gmf, btf, scal, shft);
  k_bnapply<<<cdiv(NN*HIDC,T),T,0,stream>>>(hbuf, yv, scal, shft);
  k_fill<<<cdiv(2*NN*OUTC,T),T,0,stream>>>(hwA, 0.f, 2*NN*OUTC);   // hwA|hwB contiguous
  k_gemm_nn_sk<<<dim3(1, NN/64, 4),256,0,stream>>>(NN,OUTC,HIDC,128, hbuf,HIDC, Wmuf,OUTC, hwA,OUTC);
  k_gemm_nn_sk<<<dim3(1, NN/64, 4),256,0,stream>>>(NN,OUTC,HIDC,128, hbuf,HIDC, Wlvf,OUTC, hwB,OUTC);
  k_spmm<<<NN,64,0,stream>>>(ptrC, cscSrc, cscN, hwA,OUTC, zout + 0*NN*OUTC,OUTC, dinv1, bmuf);
  k_spmm<<<NN,64,0,stream>>>(ptrC, cscSrc, cscN, hwB,OUTC, zout + 1*NN*OUTC,OUTC, dinv1, blvf);

  // ---- branch 2: f64 subspace, single final QR1 ----
  auto spmmA64 = [&](const double* s, double* d){   // d = A @ s
    k_spmm64<<<NN,64,0,stream>>>(ptrR, csrSrc, csrW, s, d);
  };
  auto spmmAT64 = [&](const double* s, double* d){  // d = A^T @ s
    k_spmm64<<<NN,64,0,stream>>>(ptrC, cscSrc, cscW, s, d);
  };

  spmmA64 (Qd0, Qd1);                      // P1 -> Qd1
  spmmAT64(Qd1, Qd0);                      // P2 -> Qd0
  spmmA64 (Qd0, Qd1);                      // P3 -> Qd1
  spmmAT64(Qd1, Qd0);                      // P4 -> Qd0
  spmmA64 (Qd0, Qd1);                      // P5 -> Qd1
  k_filld<<<cdiv(RK*RK,T),T,0,stream>>>(Gd, 0.0, RK*RK);
  k_gram64<<<NN/64,256,0,stream>>>(Qd1, Gd);
  k_chol64<<<1,64,0,stream>>>(Gd, sdd);             // L over Gd, sdinv -> sdd
  k_trinv64<<<1,256,0,stream>>>(Gd, sdd, Rid);      // Rinv
  k_applyR64<<<NN/4,256,0,stream>>>(Qd1, Rid, Qd0); // Qb -> Qd0
  spmmAT64(Qd0, Cd);                       // C = A^T Qb  (A2 = Qb C^T)
  k_qsum64<<<RK,256,0,stream>>>(Qd0, qsd);
  k_deg2f<<<cdiv(NN,T),T,0,stream>>>(Cd, qsd, dinv2);
  k_f64to32x2<<<cdiv(NN*RK,T),T,0,stream>>>(Qd0, Bf1, Cd, Cm, NN*RK);

  // h2 = dsbn_relu( D C (Qb^T (D xw1)) + b1 )
  k_fill<<<cdiv(RK*HIDC,T),T,0,stream>>>(Tm, 0.f, RK*HIDC);
  k_gemm_tn_sk<<<dim3(HIDC/16, RK/16, 8),256,0,stream>>>(RK,HIDC,NN,512, Bf1,RK, xw1,HIDC, Tm,HIDC, dinv2);
  k_gemm_nn<<<dim3(HIDC/64, NN/64),256,0,stream>>>(NN,HIDC,RK, Cm,RK, Tm,HIDC, hbuf,HIDC, dinv2, nullptr, b1f);
  k_bnstats<<<HIDC,256,0,stream>>>(hbuf, yv, dcnt, gmf, btf, scal, shft);
  k_bnapply<<<cdiv(NN*HIDC,T),T,0,stream>>>(hbuf, yv, scal, shft);
  // z2 = D C (Qb^T (D (h2 W))) + b
  k_fill<<<cdiv(2*NN*OUTC,T),T,0,stream>>>(hwA, 0.f, 2*NN*OUTC);
  k_gemm_nn_sk<<<dim3(1, NN/64, 4),256,0,stream>>>(NN,OUTC,HIDC,128, hbuf,HIDC, Wmuf,OUTC, hwA,OUTC);
  k_gemm_nn_sk<<<dim3(1, NN/64, 4),256,0,stream>>>(NN,OUTC,HIDC,128, hbuf,HIDC, Wlvf,OUTC, hwB,OUTC);
  k_fill<<<cdiv(RK*RK,T),T,0,stream>>>(Umu, 0.f, RK*RK);
  k_gemm_tn_sk<<<dim3(RK/16, RK/16, 16),256,0,stream>>>(RK,RK,NN,256, Bf1,RK, hwA,OUTC, Umu,RK, dinv2);
  k_gemm_nn<<<dim3(1, NN/64),256,0,stream>>>(NN,OUTC,RK, Cm,RK, Umu,RK, zout + 2*NN*OUTC,OUTC, dinv2, nullptr, bmuf);
  k_fill<<<cdiv(RK*RK,T),T,0,stream>>>(Umu, 0.f, RK*RK);
  k_gemm_tn_sk<<<dim3(RK/16, RK/16, 16),256,0,stream>>>(RK,RK,NN,256, Bf1,RK, hwB,OUTC, Umu,RK, dinv2);
  k_gemm_nn<<<dim3(1, NN/64),256,0,stream>>>(NN,OUTC,RK, Cm,RK, Umu,RK, zout + 3*NN*OUTC,OUTC, dinv2, nullptr, blvf);
}

// Round 8
// 695.101 us; speedup vs baseline: 1.6376x; 1.0552x over previous
//
#include <hip/hip_runtime.h>
#include <hip/hip_bf16.h>

// GCNEncoder — r24: (a) k_chol64 v2 — deferred scaling (owner publishes
// UNSCALED column + s^2; readers use f=s^2*colk[j]; each lane scales its own
// column once at the end) + merged owner/reader phase (lane k+1 stages column
// k+1 into the other buffer inside the update phase) -> ONE barrier/iter,
// no serial scale pass. Single wave = lockstep; barriers are LDS fences;
// double-buffer WAR fenced by intervening barrier (r21-proven argument).
// (b) the 4x 4096x64x512 hw GEMMs (atomic split-K f32) -> bf16 MFMA
// (r22-proven pattern), bnapply emits h-bf16 into dead xw1bf, -2 fills.
// History: r23 733us; r22 836us; r21 900us; r20 930us; r18 982us; r16 1138us.

#define NN    4096
#define NEDG  131072
#define INC   512
#define HIDC  512
#define OUTC  64
#define RK    64
#define NDOM  4
#define EPSBN 1e-5f

typedef unsigned short ushortT;
typedef __attribute__((ext_vector_type(8))) short bf16x8;
typedef __attribute__((ext_vector_type(4))) float f32x4;

static inline int cdiv(int a, int b){ return (a + b - 1) / b; }

__device__ __forceinline__ float bf2f(unsigned u){ return __uint_as_float(u << 16); }

// ---------------- input dtype detection (f32 vs bf16 carriers) ----------------
__global__ __launch_bounds__(256) void k_detect(const unsigned short* __restrict__ p,
                                                int* __restrict__ flag){
  int t = threadIdx.x;
  int cnt = 0;
  for (int i = t; i < 4096; i += 256){
    unsigned short v = p[2*i];
    int e = (v >> 7) & 0xFF;
    if (e >= 100 && e <= 140) cnt++;
  }
  __shared__ int sh[256];
  sh[t] = cnt; __syncthreads();
  for (int off = 128; off > 0; off >>= 1){ if (t < off) sh[t] += sh[t+off]; __syncthreads(); }
  if (t == 0) *flag = (sh[0] >= 2048) ? 0 : 1;
}

// ---------------- fused upcast (+ bf16 copies of x, W1, Wmu, Wlv) ----------------
__device__ __forceinline__ float upc1(const void* s, int f, int off){
  return f ? ((const float*)s)[off]
           : __bfloat162float(((const __hip_bfloat16*)s)[off]);
}
__device__ __forceinline__ ushortT tobf(float v){
  __hip_bfloat16 h = __float2bfloat16(v);
  return *(ushortT*)&h;
}
#define SEG_X   2097152
#define SEG_W1  262144
#define SEG_W   131072
#define SEG_WMU 32768
#define SEG_GB  2048
#define SEG_B1  512
#define SEG_BO  64
#define OFF1 (SEG_X)
#define OFF2 (OFF1+SEG_W1)
#define OFF3 (OFF2+SEG_W)
#define OFF4 (OFF3+SEG_WMU)
#define OFF5 (OFF4+SEG_WMU)
#define OFF6 (OFF5+SEG_GB)
#define OFF7 (OFF6+SEG_GB)
#define OFF8 (OFF7+SEG_B1)
#define OFF9 (OFF8+SEG_BO)
#define OFFT (OFF9+SEG_BO)

__global__ __launch_bounds__(256) void k_upcast_all(
    const void* x, const void* W1, const void* w, const void* Wmu, const void* Wlv,
    const void* gm, const void* bt, const void* b1, const void* bmu, const void* blv,
    const int* __restrict__ isf32,
    float* dx, float* dW1, float* dw, float* dWmu, float* dWlv,
    float* dgm, float* dbt, float* db1, float* dbmu, float* dblv,
    ushortT* xbf, ushortT* W1bf, ushortT* Wmubf, ushortT* Wlvbf){
  int i = blockIdx.x*256 + threadIdx.x;
  if (i >= OFFT) return;
  int f = *isf32;
  if      (i < OFF1){ float v = upc1(x, f, i); dx[i] = v; xbf[i] = tobf(v); }
  else if (i < OFF2){ float v = upc1(W1, f, i - OFF1); dW1[i - OFF1] = v; W1bf[i - OFF1] = tobf(v); }
  else if (i < OFF3) dw  [i - OFF2] = upc1(w,   f, i - OFF2);
  else if (i < OFF4){ float v = upc1(Wmu, f, i - OFF3); dWmu[i - OFF3] = v; Wmubf[i - OFF3] = tobf(v); }
  else if (i < OFF5){ float v = upc1(Wlv, f, i - OFF4); dWlv[i - OFF4] = v; Wlvbf[i - OFF4] = tobf(v); }
  else if (i < OFF6) dgm [i - OFF5] = upc1(gm,  f, i - OFF5);
  else if (i < OFF7) dbt [i - OFF6] = upc1(bt,  f, i - OFF6);
  else if (i < OFF8) db1 [i - OFF7] = upc1(b1,  f, i - OFF7);
  else if (i < OFF9) dbmu[i - OFF8] = upc1(bmu, f, i - OFF8);
  else               dblv[i - OFF9] = upc1(blv, f, i - OFF9);
}

// ---------------- elementwise utils ----------------
__global__ __launch_bounds__(256) void k_fill(float* d, float v, int n){
  int i = blockIdx.x*256 + threadIdx.x;
  if (i < n) d[i] = v;
}
__global__ __launch_bounds__(256) void k_filld(double* d, double v, int n){
  int i = blockIdx.x*256 + threadIdx.x;
  if (i < n) d[i] = v;
}
__global__ __launch_bounds__(256) void k_prep(float* deg, int* cntR, int* cntC, int* dcnt){
  int i = blockIdx.x*256 + threadIdx.x;
  if (i < NN){ deg[i] = 1.0f; cntR[i] = 0; cntC[i] = 0; }
  if (i < NDOM) dcnt[i] = 0;
}
__global__ __launch_bounds__(256) void k_f64to32x2(const double* __restrict__ s0, float* __restrict__ d0,
                                                   const double* __restrict__ s1, float* __restrict__ d1,
                                                   int n){
  int i = blockIdx.x*256 + threadIdx.x;
  if (i < n){ d0[i] = (float)s0[i]; d1[i] = (float)s1[i]; }
}

// ---------------- graph preprocessing ----------------
__global__ __launch_bounds__(256) void k_hist(const int* __restrict__ row, const int* __restrict__ col,
                                              const float* __restrict__ w, float* deg,
                                              int* cntR, int* cntC){
  int e = blockIdx.x*256 + threadIdx.x;
  if (e < NEDG){
    atomicAdd(&deg[col[e]], w[e]);
    atomicAdd(&cntR[row[e]], 1);
    atomicAdd(&cntC[col[e]], 1);
  }
}
__global__ __launch_bounds__(256) void k_dinv(const float* deg, float* dinv, int n){
  int i = blockIdx.x*256 + threadIdx.x;
  if (i < n){ float d = deg[i]; dinv[i] = (d > 0.f) ? 1.f/sqrtf(d) : 0.f; }
}
__global__ __launch_bounds__(256) void k_norm1(const int* __restrict__ row, const int* __restrict__ col,
                                               const float* __restrict__ w, const float* __restrict__ dinv,
                                               float* __restrict__ nrm){
  int e = blockIdx.x*256 + threadIdx.x;
  if (e < NEDG) nrm[e] = dinv[row[e]] * w[e] * dinv[col[e]];
}
__global__ __launch_bounds__(1024) void k_scan4096(const int* __restrict__ cnt,
                                                   int* __restrict__ ptr, int* __restrict__ pos){
  __shared__ int sh[1024];
  int t = threadIdx.x;
  int b = t*4;
  int a0 = cnt[b], a1 = cnt[b+1], a2 = cnt[b+2], a3 = cnt[b+3];
  sh[t] = a0 + a1 + a2 + a3;
  __syncthreads();
  for (int off = 1; off < 1024; off <<= 1){
    int v = (t >= off) ? sh[t-off] : 0;
    __syncthreads();
    sh[t] += v;
    __syncthreads();
  }
  int excl = (t == 0) ? 0 : sh[t-1];
  ptr[b]   = excl;            pos[b]   = excl;
  ptr[b+1] = excl+a0;         pos[b+1] = excl+a0;
  ptr[b+2] = excl+a0+a1;      pos[b+2] = excl+a0+a1;
  ptr[b+3] = excl+a0+a1+a2;   pos[b+3] = excl+a0+a1+a2;
  if (t == 1023) ptr[4096] = sh[1023];
}
__global__ __launch_bounds__(256) void k_scatter(const int* __restrict__ row, const int* __restrict__ col,
                                                 int* posR, int* posC, int* eidR, int* eidC){
  int e = blockIdx.x*256 + threadIdx.x;
  if (e < NEDG){
    int p = atomicAdd(&posR[row[e]], 1); eidR[p] = e;
    int q = atomicAdd(&posC[col[e]], 1); eidC[q] = e;
  }
}
// contiguous per-segment edge data (removes eid indirection from all spmms)
__global__ __launch_bounds__(256) void k_edges(const int* __restrict__ rowA, const int* __restrict__ colA,
        const float* __restrict__ wf, const float* __restrict__ nrm,
        const int* __restrict__ eidR, const int* __restrict__ eidC,
        int* __restrict__ csrSrc, float* __restrict__ csrW,
        int* __restrict__ cscSrc, float* __restrict__ cscW, float* __restrict__ cscN){
  int p = blockIdx.x*256 + threadIdx.x;
  if (p < NEDG){
    int eR = eidR[p]; csrSrc[p] = colA[eR]; csrW[p] = wf[eR];
    int eC = eidC[p]; cscSrc[p] = rowA[eC]; cscW[p] = wf[eC]; cscN[p] = nrm[eC];
  }
}
__global__ __launch_bounds__(256) void k_dcnt(const int* __restrict__ y, int* dcnt){
  int i = blockIdx.x*256 + threadIdx.x;
  if (i < NN) atomicAdd(&dcnt[y[i]], 1);
}

// ---------------- threefry2x32 core (KAT-verified round 8) ----------------
__device__ __forceinline__ unsigned rotl32(unsigned x, unsigned d){ return (x << d) | (x >> (32u - d)); }
#define TF_ROUND4(R0,R1,R2,R3) \
  x0 += x1; x1 = rotl32(x1,R0); x1 ^= x0; \
  x0 += x1; x1 = rotl32(x1,R1); x1 ^= x0; \
  x0 += x1; x1 = rotl32(x1,R2); x1 ^= x0; \
  x0 += x1; x1 = rotl32(x1,R3); x1 ^= x0;

__device__ __forceinline__ void tf2x32(unsigned k0, unsigned k1, unsigned c0, unsigned c1,
                                       unsigned* o0, unsigned* o1){
  unsigned ks2 = 0x1BD11BDAu ^ k0 ^ k1;
  unsigned x0 = c0 + k0, x1 = c1 + k1;
  TF_ROUND4(13,15,26,6);   x0 += k1;  x1 += ks2 + 1u;
  TF_ROUND4(17,29,16,24);  x0 += ks2; x1 += k0 + 2u;
  TF_ROUND4(13,15,26,6);   x0 += k0;  x1 += k1 + 3u;
  TF_ROUND4(17,29,16,24);  x0 += k1;  x1 += ks2 + 4u;
  TF_ROUND4(13,15,26,6);   x0 += ks2; x1 += k0 + 5u;
  *o0 = x0; *o1 = x1;
}

// ---------------- omega (verified round 10; direct f64 output) ----------------
__device__ double erfinv64(double x){
  double w = -log1p(-x*x);
  double p;
  if (w < 5.0){
    w -= 2.5;
    p = 2.81022636e-08;  p = p*w + 3.43273939e-07; p = p*w - 3.5233877e-06;
    p = p*w - 4.39150654e-06; p = p*w + 0.00021858087; p = p*w - 0.00125372503;
    p = p*w - 0.00417768164;  p = p*w + 0.246640727;   p = p*w + 1.50140941;
  } else {
    w = sqrt(w) - 3.0;
    p = -0.000200214257; p = p*w + 0.000100950558; p = p*w + 0.00134934322;
    p = p*w - 0.00367342844; p = p*w + 0.00573950773; p = p*w - 0.0076224613;
    p = p*w + 0.00943887047; p = p*w + 1.00167406;    p = p*w + 2.83297682;
  }
  double y = p * x;
  const double c = 1.1283791670955126;   // 2/sqrt(pi)
  #pragma unroll
  for (int it = 0; it < 3; it++){
    double err = erf(y) - x;
    y -= err / (c * exp(-y*y));
  }
  return y;
}

__device__ float bits_to_normal(unsigned b){
  float f = __uint_as_float((b >> 9) | 0x3f800000u) - 1.0f;
  const float lo = -0.99999994f;               // nextafter(-1,0) in f32
  float x = fmaxf(lo, f * 2.0f + lo);
  double r = 1.4142135623730951 * erfinv64((double)x);
  return (float)r;
}

__global__ __launch_bounds__(256) void k_omega(double* __restrict__ om){
  int i = blockIdx.x*256 + threadIdx.x;
  if (i >= 262144) return;
  unsigned o0, o1;
  tf2x32(0u, 42u, 0u, (unsigned)i, &o0, &o1);   // counter = (0, i)
  om[i] = (double)bits_to_normal(o0 ^ o1);      // same f32 value as before, widened
}

// ---------------- bf16 MFMA GEMM (r22-proven) + bf16 C copy ----------------
__global__ __launch_bounds__(256) void k_gemm_bf16(
    const ushortT* __restrict__ A, const ushortT* __restrict__ B,
    float* __restrict__ Cc, ushortT* __restrict__ Cbf){
  __shared__ ushortT As2[64][40];   // [row][k] (+8 pad)
  __shared__ ushortT Bs2[64][40];   // [col][k] transposed (+8 pad)
  int t = threadIdx.x;
  int bm = blockIdx.y * 64, bn = blockIdx.x * 64;
  int w = t >> 6, l = t & 63;
  int lr = l & 15, lk = l >> 4;
  f32x4 acc[4] = {};
  int ar = t >> 2, ac = (t & 3) * 8;      // A stage: 64 rows x 32 k, 16B/thread
  int bc = t & 63, bk = (t >> 6) * 8;     // B stage: 64 cols x 8 k gathered
  for (int k0 = 0; k0 < 512; k0 += 32){
    *(uint4*)&As2[ar][ac] = *(const uint4*)&A[(size_t)(bm + ar) * 512 + k0 + ac];
    ushortT tmp[8];
    #pragma unroll
    for (int j = 0; j < 8; j++)
      tmp[j] = B[(size_t)(k0 + bk + j) * 512 + bn + bc];
    *(uint4*)&Bs2[bc][bk] = *(uint4*)tmp;
    __syncthreads();
    bf16x8 afrag = *(bf16x8*)&As2[w * 16 + lr][lk * 8];
    #pragma unroll
    for (int nt = 0; nt < 4; nt++){
      bf16x8 bfrag = *(bf16x8*)&Bs2[nt * 16 + lr][lk * 8];
      acc[nt] = __builtin_amdgcn_mfma_f32_16x16x32_bf16(afrag, bfrag, acc[nt], 0, 0, 0);
    }
    __syncthreads();
  }
  #pragma unroll
  for (int nt = 0; nt < 4; nt++){
    #pragma unroll
    for (int i = 0; i < 4; i++){
      size_t idx = (size_t)(bm + w * 16 + lk * 4 + i) * 512 + bn + nt * 16 + lr;
      float v = acc[nt][i];
      Cc[idx] = v;
      Cbf[idx] = tobf(v);
    }
  }
}

// hw GEMM: C[4096][64] = Hbf[4096][512] @ Wbf[512][64], f32 out, no bias.
// Same MFMA pattern, grid = NN/64 blocks.
__global__ __launch_bounds__(256) void k_gemm_hw(
    const ushortT* __restrict__ A, const ushortT* __restrict__ B,
    float* __restrict__ Cc){
  __shared__ ushortT As2[64][40];
  __shared__ ushortT Bs2[64][40];
  int t = threadIdx.x;
  int bm = blockIdx.x * 64;
  int w = t >> 6, l = t & 63;
  int lr = l & 15, lk = l >> 4;
  f32x4 acc[4] = {};
  int ar = t >> 2, ac = (t & 3) * 8;
  int bc = t & 63, bk = (t >> 6) * 8;
  for (int k0 = 0; k0 < 512; k0 += 32){
    *(uint4*)&As2[ar][ac] = *(const uint4*)&A[(size_t)(bm + ar) * 512 + k0 + ac];
    ushortT tmp[8];
    #pragma unroll
    for (int j = 0; j < 8; j++)
      tmp[j] = B[(size_t)(k0 + bk + j) * 64 + bc];
    *(uint4*)&Bs2[bc][bk] = *(uint4*)tmp;
    __syncthreads();
    bf16x8 afrag = *(bf16x8*)&As2[w * 16 + lr][lk * 8];
    #pragma unroll
    for (int nt = 0; nt < 4; nt++){
      bf16x8 bfrag = *(bf16x8*)&Bs2[nt * 16 + lr][lk * 8];
      acc[nt] = __builtin_amdgcn_mfma_f32_16x16x32_bf16(afrag, bfrag, acc[nt], 0, 0, 0);
    }
    __syncthreads();
  }
  #pragma unroll
  for (int nt = 0; nt < 4; nt++){
    #pragma unroll
    for (int i = 0; i < 4; i++){
      Cc[(size_t)(bm + w * 16 + lk * 4 + i) * 64 + nt * 16 + lr] = acc[nt][i];
    }
  }
}

// ---------------- GEMM (fp32, tiled 64x64, 4x4/thread) ----------------
__global__ __launch_bounds__(256) void k_gemm_nn(int M, int Nn, int K,
      const float* __restrict__ A, int lda, const float* __restrict__ B, int ldb,
      float* __restrict__ Cc, int ldc, const float* __restrict__ rowscale,
      const float* __restrict__ kscale, const float* __restrict__ bias){
  __shared__ float As[16][65];
  __shared__ float Bs[16][65];
  int bm = blockIdx.y*64, bn = blockIdx.x*64;
  int t = threadIdx.x;
  int tr = t >> 4, tc = t & 15;
  float acc[4][4] = {};
  for (int k0 = 0; k0 < K; k0 += 16){
    #pragma unroll
    for (int q = 0; q < 4; q++){
      int idx = t*4 + q;
      int m = idx >> 4, kk = idx & 15;
      As[kk][m] = A[(size_t)(bm+m)*lda + (k0+kk)];
    }
    #pragma unroll
    for (int q = 0; q < 4; q++){
      int idx = t + q*256;
      int kk = idx >> 6, n = idx & 63;
      float ks = kscale ? kscale[k0+kk] : 1.0f;
      Bs[kk][n] = B[(size_t)(k0+kk)*ldb + (bn+n)] * ks;
    }
    __syncthreads();
    #pragma unroll
    for (int kk = 0; kk < 16; kk++){
      float a0 = As[kk][tr*4+0], a1 = As[kk][tr*4+1], a2 = As[kk][tr*4+2], a3 = As[kk][tr*4+3];
      float b0 = Bs[kk][tc*4+0], b1 = Bs[kk][tc*4+1], b2 = Bs[kk][tc*4+2], b3 = Bs[kk][tc*4+3];
      acc[0][0] += a0*b0; acc[0][1] += a0*b1; acc[0][2] += a0*b2; acc[0][3] += a0*b3;
      acc[1][0] += a1*b0; acc[1][1] += a1*b1; acc[1][2] += a1*b2; acc[1][3] += a1*b3;
      acc[2][0] += a2*b0; acc[2][1] += a2*b1; acc[2][2] += a2*b2; acc[2][3] += a2*b3;
      acc[3][0] += a3*b0; acc[3][1] += a3*b1; acc[3][2] += a3*b2; acc[3][3] += a3*b3;
    }
    __syncthreads();
  }
  #pragma unroll
  for (int i2 = 0; i2 < 4; i2++){
    int m = bm + tr*4 + i2;
    float rs = rowscale ? rowscale[m] : 1.0f;
    #pragma unroll
    for (int j2 = 0; j2 < 4; j2++){
      int n = bn + tc*4 + j2;
      float v = acc[i2][j2] * rs;
      if (bias) v += bias[n];
      Cc[(size_t)m*ldc + n] = v;
    }
  }
}

// split-K TN: C += partial (C pre-zeroed); grid (Nn/16, M/16, K/kchunk)
__global__ __launch_bounds__(256) void k_gemm_tn_sk(int M, int Nn, int K, int kchunk,
      const float* __restrict__ A, int lda, const float* __restrict__ B, int ldb,
      float* __restrict__ Cc, int ldc, const float* __restrict__ kscale){
  __shared__ float As[32][17];
  __shared__ float Bs[32][17];
  int bm = blockIdx.y*16, bn = blockIdx.x*16;
  int kb = blockIdx.z*kchunk, ke = kb + kchunk;
  int t = threadIdx.x;
  int tm = t >> 4, tn = t & 15;
  float acc = 0.f;
  for (int k0 = kb; k0 < ke; k0 += 32){
    #pragma unroll
    for (int q = 0; q < 2; q++){
      int idx = t + q*256;
      int kk = idx >> 4, m = idx & 15;
      float sv = kscale ? kscale[k0+kk] : 1.0f;
      As[kk][m] = A[(size_t)(k0+kk)*lda + (bm+m)] * sv;
      Bs[kk][m] = B[(size_t)(k0+kk)*ldb + (bn+m)];
    }
    __syncthreads();
    #pragma unroll
    for (int kk = 0; kk < 32; kk++) acc += As[kk][tm] * Bs[kk][tn];
    __syncthreads();
  }
  atomicAdd(&Cc[(size_t)(bm+tm)*ldc + (bn+tn)], acc);
}

// ---------------- f64 randomized-subspace chain ----------------
__global__ __launch_bounds__(64) void k_spmm64(const int* __restrict__ ptr,
                       const int* __restrict__ src, const float* __restrict__ cf,
                       const double* __restrict__ X, double* __restrict__ Y){
  int seg = blockIdx.x;
  int t = threadIdx.x;
  double acc = 0.0;
  int p0 = ptr[seg], p1 = ptr[seg+1];
  for (int p = p0; p < p1; ++p){
    acc += (double)cf[p] * X[(size_t)src[p]*RK + t];
  }
  Y[(size_t)seg*RK + t] = acc;
}
// Gram: G += Xslice^T Xslice over 64-row slices (G zeroed before)
__global__ __launch_bounds__(256) void k_gram64(const double* __restrict__ X, double* __restrict__ G){
  __shared__ double Xs[64][65];
  int b = blockIdx.x;
  int t = threadIdx.x;
  #pragma unroll
  for (int q = 0; q < 16; q++){
    int idx = t + q*256;
    Xs[idx >> 6][idx & 63] = X[(size_t)(b*64 + (idx >> 6))*RK + (idx & 63)];
  }
  __syncthreads();
  int i = t >> 2;
  int j0 = (t & 3) * 16;
  double acc[16];
  #pragma unroll
  for (int jj = 0; jj < 16; jj++) acc[jj] = 0.0;
  for (int k = 0; k < 64; k++){
    double a = Xs[k][i];
    #pragma unroll
    for (int jj = 0; jj < 16; jj++) acc[jj] += a * Xs[k][j0+jj];
  }
  #pragma unroll
  for (int jj = 0; jj < 16; jj++) atomicAdd(&G[i*RK + j0 + jj], acc[jj]);
}
// ---- Cholesky factorization v2 (r24): ONE wave, ONE barrier/iter,
// deferred scaling. Owner publishes UNSCALED column + s^2; readers use
// f = s2*colk[j]; lane k+1 stages column k+1 inside the update phase
// (other colk buffer). Each lane scales its own column once at the end.
// Update math: c[i] -= Cu[i] * (s2*Cu[j]); cdiag -= s2*Cu[j]^2.
// Final: L[i][j] = c[i]*s_j (i>j), L[j][j] = cdiag_j*s_j = sqrt(cdiag_j).
#define CHOL2_CHUNK(I0) \
  for (int k2 = 0; k2 < 16; k2++){ \
    int k = (I0) + k2; \
    int buf = k & 1; \
    double s2 = s2b[buf]; \
    double cj = colk[buf][j]; \
    double f = s2 * cj; \
    if (j > k){ \
      cdiag -= f * cj; \
      _Pragma("unroll") \
      for (int i = (I0); i < 64; i++) c[i] -= colk[buf][i] * f; \
    } \
    if (j == k + 1){ \
      double s = rsqrt(fmax(cdiag, 1e-300)); \
      mys = s; \
      sdd[j] = s; \
      s2b[buf ^ 1] = s * s; \
      _Pragma("unroll") \
      for (int i = (I0); i < 64; i++) if (i > j) colk[buf ^ 1][i] = c[i]; \
    } \
    __syncthreads(); \
  }

__global__ __launch_bounds__(64) void k_chol64(double* __restrict__ G, double* __restrict__ sdd){
  __shared__ double colk[2][64];
  __shared__ double s2b[2];
  int j = threadIdx.x;        // 0..63, owns column j
  double c[64];
  #pragma unroll
  for (int i = 0; i < 64; i++) c[i] = G[i*64 + j];
  double cdiag = 0.0, mys = 0.0;
  #pragma unroll
  for (int i = 0; i < 64; i++) if (i == j) cdiag = c[i];
  if (j == 0){
    double s = rsqrt(fmax(cdiag, 1e-300));
    mys = s;
    sdd[0] = s;
    s2b[0] = s * s;
    #pragma unroll
    for (int i = 1; i < 64; i++) colk[0][i] = c[i];
  }
  __syncthreads();
  CHOL2_CHUNK(0)
  CHOL2_CHUNK(16)
  CHOL2_CHUNK(32)
  CHOL2_CHUNK(48)
  // final scale (all lanes in parallel) + store L
  #pragma unroll
  for (int i = 0; i < 64; i++){
    double v = (i > j) ? c[i] * mys : 0.0;
    if (i == j) v = cdiag * mys;      // = sqrt(cdiag_j)
    G[i*64 + j] = v;
  }
}
// ---- blocked triangular inverse (r19/r20/r21-proven stages), 256 threads. ----
__global__ __launch_bounds__(256) void k_trinv64(const double* __restrict__ L,
      const double* __restrict__ sdd, double* __restrict__ Rinv){
  __shared__ double gl[64][65];   // L lower; R[i][a] = gl[a][i]
  __shared__ double Xl[64][65];   // X = R^{-1} (upper); lower stays 0
  __shared__ double sdinv[64];
  __shared__ double Sl[3][16][17];
  int t = threadIdx.x;
  #pragma unroll
  for (int q = 0; q < 16; q++){
    int idx = t + (q << 8);
    gl[idx >> 6][idx & 63] = L[idx];
  }
  if (t < 64) sdinv[t] = sdd[t];
  for (int idx = t; idx < 64*65; idx += 256)
    ((double*)Xl)[idx] = 0.0;
  __syncthreads();
  if (t < 64){
    int b = t >> 4, c2 = t & 15;
    int g0 = b << 4;
    int gc = g0 + c2;
    Xl[gc][gc] = sdinv[gc];
    for (int i = c2 - 1; i >= 0; i--){
      int gi = g0 + i;
      double s = 0.0;
      for (int k2 = i + 1; k2 <= c2; k2++)
        s += gl[g0 + k2][gi] * Xl[g0 + k2][gc];
      Xl[gi][gc] = -s * sdinv[gi];
    }
  }
  __syncthreads();
  for (int d = 1; d < 4; d++){
    int np = 4 - d;
    int tot = np << 8;
    for (int e = t; e < tot; e += 256){
      int p = e >> 8;
      int i = (e >> 4) & 15, jj = e & 15;
      int gi = (p << 4) + i, gj = ((p + d) << 4) + jj;
      double s = 0.0;
      int a0 = (p + 1) << 4, a1 = (p + d + 1) << 4;
      for (int a = a0; a < a1; a++)
        s += gl[a][gi] * Xl[a][gj];
      Sl[p][i][jj] = s;
    }
    __syncthreads();
    for (int e = t; e < tot; e += 256){
      int p = e >> 8;
      int i = (e >> 4) & 15, jj = e & 15;
      int gi = (p << 4) + i, gj = ((p + d) << 4) + jj;
      double s = 0.0;
      #pragma unroll
      for (int k2 = 0; k2 < 16; k2++)
        s += Xl[gi][(p << 4) + k2] * Sl[p][k2][jj];
      Xl[gi][gj] = -s;
    }
    __syncthreads();
  }
  #pragma unroll
  for (int q = 0; q < 16; q++){
    int e2 = t + (q << 8);
    Rinv[e2] = Xl[e2 >> 6][e2 & 63];
  }
}
// dst[NNx64] = src[NNx64] * Rinv(upper); 4 rows per 256-thread block
__global__ __launch_bounds__(256) void k_applyR64(const double* __restrict__ src,
      const double* __restrict__ Rinv, double* __restrict__ dst){
  __shared__ double Rs[64][65];
  int t = threadIdx.x;
  #pragma unroll
  for (int q = 0; q < 16; q++){
    int idx = t + q*256;
    Rs[idx >> 6][idx & 63] = Rinv[idx];
  }
  __syncthreads();
  int r = blockIdx.x*4 + (t >> 6);
  int j = t & 63;
  const double* rowp = src + (size_t)r*RK;
  double s = 0.0;
  for (int k = 0; k <= j; k++) s += rowp[k] * Rs[k][j];
  dst[(size_t)r*RK + j] = s;
}
__global__ __launch_bounds__(256) void k_qsum64(const double* __restrict__ Q, double* __restrict__ qs){
  int j = blockIdx.x;  int t = threadIdx.x;
  double a = 0.0;
  for (int n = t; n < NN; n += 256) a += Q[(size_t)n*RK + j];
  __shared__ double sh[256];
  sh[t] = a; __syncthreads();
  for (int off = 128; off > 0; off >>= 1){ if (t < off) sh[t] += sh[t+off]; __syncthreads(); }
  if (t == 0) qs[j] = sh[0];
}
__global__ __launch_bounds__(256) void k_deg2f(const double* __restrict__ C, const double* __restrict__ qs,
                                               float* __restrict__ dinv2){
  int i = blockIdx.x*256 + threadIdx.x;
  if (i >= NN) return;
  double s = 0.0;
  #pragma unroll
  for (int k = 0; k < RK; k++) s += C[(size_t)i*RK + k] * qs[k];
  dinv2[i] = (s > 0.0) ? (float)(1.0/sqrt(s)) : 0.f;
}

// ---------------- SpMMs over contiguous per-segment edge data ----------------
// 512-wide bf16 gather (branch-1 h1): thread t handles cols 2t, 2t+1.
__global__ __launch_bounds__(256) void k_spmm_bf16(const int* __restrict__ ptr,
        const int* __restrict__ src, const float* __restrict__ cf,
        const ushortT* __restrict__ Xb, float* __restrict__ Y,
        const float* __restrict__ self_dinv, const float* __restrict__ bias){
  int seg = blockIdx.x;
  int t = threadIdx.x;
  float acc0, acc1;
  {
    float sd = self_dinv[seg]; float s2 = sd*sd;
    unsigned v = *(const unsigned*)&Xb[(size_t)seg*HIDC + 2*t];
    acc0 = s2 * bf2f(v & 0xffffu);
    acc1 = s2 * bf2f(v >> 16);
  }
  int p0 = ptr[seg], p1 = ptr[seg+1];
  for (int p = p0; p < p1; ++p){
    int o = src[p];
    float c = cf[p];
    unsigned v = *(const unsigned*)&Xb[(size_t)o*HIDC + 2*t];
    acc0 += c * bf2f(v & 0xffffu);
    acc1 += c * bf2f(v >> 16);
  }
  acc0 += bias[2*t];
  acc1 += bias[2*t+1];
  Y[(size_t)seg*HIDC + 2*t]     = acc0;
  Y[(size_t)seg*HIDC + 2*t + 1] = acc1;
}
// f32 spmm (64-wide, output stage)
__global__ void k_spmm(const int* __restrict__ ptr, const int* __restrict__ src,
                       const float* __restrict__ cf,
                       const float* __restrict__ X, int ldx,
                       float* __restrict__ Y, int ldy,
                       const float* __restrict__ self_dinv, const float* __restrict__ bias){
  int seg = blockIdx.x;
  int t = threadIdx.x;
  float acc0 = 0.f;
  {
    float sd = self_dinv[seg];
    acc0 = sd*sd * X[(size_t)seg*ldx + t];
  }
  int p0 = ptr[seg], p1 = ptr[seg+1];
  for (int p = p0; p < p1; ++p){
    acc0 += cf[p] * X[(size_t)src[p]*ldx + t];
  }
  acc0 += bias[t];
  Y[(size_t)seg*ldy + t] = acc0;
}

// ---------------- domain-specific BN ----------------
__global__ __launch_bounds__(256) void k_bnstats(const float* __restrict__ H, const int* __restrict__ y,
        const int* __restrict__ dcnt, const float* __restrict__ gamma, const float* __restrict__ beta,
        float* __restrict__ scal, float* __restrict__ shft){
  int j = blockIdx.x;
  int t = threadIdx.x;
  float s0=0,s1=0,s2=0,s3=0,q0=0,q1=0,q2=0,q3=0;
  for (int n = t; n < NN; n += 256){
    float v = H[(size_t)n*HIDC + j];
    int d = y[n];
    float v2 = v*v;
    if      (d == 0){ s0 += v; q0 += v2; }
    else if (d == 1){ s1 += v; q1 += v2; }
    else if (d == 2){ s2 += v; q2 += v2; }
    else            { s3 += v; q3 += v2; }
  }
  __shared__ float sh[256][8];
  sh[t][0]=s0; sh[t][1]=s1; sh[t][2]=s2; sh[t][3]=s3;
  sh[t][4]=q0; sh[t][5]=q1; sh[t][6]=q2; sh[t][7]=q3;
  __syncthreads();
  for (int off = 128; off > 0; off >>= 1){
    if (t < off){
      #pragma unroll
      for (int q = 0; q < 8; q++) sh[t][q] += sh[t+off][q];
    }
    __syncthreads();
  }
  if (t < NDOM){
    float cnt  = fmaxf((float)dcnt[t], 1.0f);
    float mean = sh[0][t] / cnt;
    float var  = fmaxf(sh[0][4+t] / cnt - mean*mean, 0.f);
    float inv  = 1.0f / sqrtf(var + EPSBN);
    float gmm  = gamma[t*HIDC + j];
    scal[t*HIDC + j] = gmm * inv;
    shft[t*HIDC + j] = beta[t*HIDC + j] - mean * gmm * inv;
  }
}
// BN apply + ReLU; also emits bf16 copy of H for the MFMA hw GEMMs.
__global__ __launch_bounds__(256) void k_bnapply(float* __restrict__ H, const int* __restrict__ y,
        const float* __restrict__ scal, const float* __restrict__ shft,
        ushortT* __restrict__ Hbf){
  int idx = blockIdx.x*256 + threadIdx.x;
  if (idx >= NN*HIDC) return;
  int n = idx >> 9, j = idx & (HIDC-1);
  int d = y[n];
  float v = H[idx] * scal[d*HIDC + j] + shft[d*HIDC + j];
  v = v > 0.f ? v : 0.f;
  H[idx] = v;
  Hbf[idx] = tobf(v);
}

// ---------------- launch ----------------
extern "C" void kernel_launch(void* const* d_in, const int* in_sizes, int n_in,
                              void* d_out, int out_size, void* d_ws, size_t ws_size,
                              hipStream_t stream){
  (void)in_sizes; (void)n_in; (void)out_size;
  const void* x_in  = d_in[0];
  const int*  ei    = (const int*)d_in[1];
  const void* w_in  = d_in[2];
  const int*  yv    = (const int*)d_in[3];
  const void* W1i   = d_in[4];
  const void* b1i   = d_in[5];
  const void* Wmui  = d_in[6];
  const void* bmui  = d_in[7];
  const void* Wlvi  = d_in[8];
  const void* blvi  = d_in[9];
  const void* gmi   = d_in[10];
  const void* bti   = d_in[11];
  const int* rowA = ei;
  const int* colA = ei + NEDG;
  float* zout = (float*)d_out;

  // ---- workspace: doubles | floats (+bf16) | ints ----
  double* Dp = (double*)d_ws;
  size_t od = 0;
  double* Qd0 = Dp + od; od += (size_t)NN*RK;
  double* Qd1 = Dp + od; od += (size_t)NN*RK;
  double* Cd  = Dp + od; od += (size_t)NN*RK;
  double* Gd  = Dp + od; od += RK*RK;
  double* Rid = Dp + od; od += RK*RK;
  double* qsd = Dp + od; od += RK;
  double* sdd = Dp + od; od += RK;
  float* Fp = (float*)(Dp + od);
  size_t o = 0;
  float* xf   = Fp + o; o += (size_t)NN*INC;       // reused as h1/h2 buffer
  float* W1f  = Fp + o; o += (size_t)INC*HIDC;
  float* b1f  = Fp + o; o += HIDC;
  float* Wmuf = Fp + o; o += (size_t)HIDC*OUTC;
  float* bmuf = Fp + o; o += OUTC;
  float* Wlvf = Fp + o; o += (size_t)HIDC*OUTC;
  float* blvf = Fp + o; o += OUTC;
  float* gmf  = Fp + o; o += NDOM*HIDC;
  float* btf  = Fp + o; o += NDOM*HIDC;
  float* wf   = Fp + o; o += NEDG;
  float* xw1  = Fp + o; o += (size_t)NN*HIDC;
  float* hwA  = Fp + o; o += (size_t)NN*OUTC;
  float* hwB  = Fp + o; o += (size_t)NN*OUTC;     // contiguous after hwA
  float* Bf1  = Fp + o; o += (size_t)NN*RK;        // Qb (f32)
  float* Cm   = Fp + o; o += (size_t)NN*RK;        // C (f32)
  float* Tm   = Fp + o; o += (size_t)RK*HIDC;
  float* Umu  = Fp + o; o += RK*RK;
  float* deg1 = Fp + o; o += NN;
  float* dinv1= Fp + o; o += NN;
  float* dinv2= Fp + o; o += NN;
  float* norm1= Fp + o; o += NEDG;
  float* scal = Fp + o; o += NDOM*HIDC;
  float* shft = Fp + o; o += NDOM*HIDC;
  float* csrW = Fp + o; o += NEDG;
  float* cscW = Fp + o; o += NEDG;
  float* cscN = Fp + o; o += NEDG;
  ushortT* xbf   = (ushortT*)(Fp + o); o += (size_t)NN*INC/2;    // bf16 x
  ushortT* W1bf  = (ushortT*)(Fp + o); o += (size_t)INC*HIDC/2;  // bf16 W1
  ushortT* xw1bf = (ushortT*)(Fp + o); o += (size_t)NN*HIDC/2;   // bf16 xw1 / h
  ushortT* Wmubf = (ushortT*)(Fp + o); o += (size_t)HIDC*OUTC/2;
  ushortT* Wlvbf = (ushortT*)(Fp + o); o += (size_t)HIDC*OUTC/2;
  int* Ip = (int*)(Fp + o);
  size_t oi = 0;
  int* cntR = Ip + oi; oi += NN;
  int* ptrR = Ip + oi; oi += NN + 1;
  int* posR = Ip + oi; oi += NN;
  int* eidR = Ip + oi; oi += NEDG;
  int* cntC = Ip + oi; oi += NN;
  int* ptrC = Ip + oi; oi += NN + 1;
  int* posC = Ip + oi; oi += NN;
  int* eidC = Ip + oi; oi += NEDG;
  int* csrSrc = Ip + oi; oi += NEDG;
  int* cscSrc = Ip + oi; oi += NEDG;
  int* dcnt = Ip + oi; oi += NDOM;
  int* dflag= Ip + oi; oi += 1;

  size_t need = od*sizeof(double) + o*sizeof(float) + (oi+16)*sizeof(int);
  if (ws_size < need) return;

  float* hbuf = xf;  // x dead after xw1 GEMM

  const int T = 256;
  k_detect<<<1,T,0,stream>>>((const unsigned short*)x_in, dflag);
  k_upcast_all<<<cdiv(OFFT,T),T,0,stream>>>(
      x_in, W1i, w_in, Wmui, Wlvi, gmi, bti, b1i, bmui, blvi, dflag,
      xf, W1f, wf, Wmuf, Wlvf, gmf, btf, b1f, bmuf, blvf,
      xbf, W1bf, Wmubf, Wlvbf);

  k_prep<<<cdiv(NN,T),T,0,stream>>>(deg1, cntR, cntC, dcnt);
  k_hist <<<cdiv(NEDG,T),T,0,stream>>>(rowA, colA, wf, deg1, cntR, cntC);
  k_dinv <<<cdiv(NN,T),T,0,stream>>>(deg1, dinv1, NN);
  k_norm1<<<cdiv(NEDG,T),T,0,stream>>>(rowA, colA, wf, dinv1, norm1);
  k_scan4096<<<1,1024,0,stream>>>(cntR, ptrR, posR);
  k_scan4096<<<1,1024,0,stream>>>(cntC, ptrC, posC);
  k_scatter<<<cdiv(NEDG,T),T,0,stream>>>(rowA, colA, posR, posC, eidR, eidC);
  k_edges<<<cdiv(NEDG,T),T,0,stream>>>(rowA, colA, wf, norm1, eidR, eidC,
                                       csrSrc, csrW, cscSrc, cscW, cscN);
  k_omega<<<cdiv(NN*RK,T),T,0,stream>>>(Qd0);      // f64 seed directly
  k_dcnt <<<cdiv(NN,T),T,0,stream>>>(yv, dcnt);

  // ---- branch 1 ----
  k_gemm_bf16<<<dim3(HIDC/64, NN/64),256,0,stream>>>(xbf, W1bf, xw1, xw1bf);
  k_spmm_bf16<<<NN,256,0,stream>>>(ptrC, cscSrc, cscN, xw1bf, hbuf, dinv1, b1f);
  k_bnstats<<<HIDC,256,0,stream>>>(hbuf, yv, dcnt, gmf, btf, scal, shft);
  k_bnapply<<<cdiv(NN*HIDC,T),T,0,stream>>>(hbuf, yv, scal, shft, xw1bf);
  k_gemm_hw<<<NN/64,256,0,stream>>>(xw1bf, Wmubf, hwA);
  k_gemm_hw<<<NN/64,256,0,stream>>>(xw1bf, Wlvbf, hwB);
  k_spmm<<<NN,64,0,stream>>>(ptrC, cscSrc, cscN, hwA,OUTC, zout + 0*NN*OUTC,OUTC, dinv1, bmuf);
  k_spmm<<<NN,64,0,stream>>>(ptrC, cscSrc, cscN, hwB,OUTC, zout + 1*NN*OUTC,OUTC, dinv1, blvf);

  // ---- branch 2: f64 subspace, single final QR1 ----
  auto spmmA64 = [&](const double* s, double* d){   // d = A @ s
    k_spmm64<<<NN,64,0,stream>>>(ptrR, csrSrc, csrW, s, d);
  };
  auto spmmAT64 = [&](const double* s, double* d){  // d = A^T @ s
    k_spmm64<<<NN,64,0,stream>>>(ptrC, cscSrc, cscW, s, d);
  };

  spmmA64 (Qd0, Qd1);                      // P1 -> Qd1
  spmmAT64(Qd1, Qd0);                      // P2 -> Qd0
  spmmA64 (Qd0, Qd1);                      // P3 -> Qd1
  spmmAT64(Qd1, Qd0);                      // P4 -> Qd0
  spmmA64 (Qd0, Qd1);                      // P5 -> Qd1
  k_filld<<<cdiv(RK*RK,T),T,0,stream>>>(Gd, 0.0, RK*RK);
  k_gram64<<<NN/64,256,0,stream>>>(Qd1, Gd);
  k_chol64<<<1,64,0,stream>>>(Gd, sdd);             // L over Gd, sdinv -> sdd
  k_trinv64<<<1,256,0,stream>>>(Gd, sdd, Rid);      // Rinv
  k_applyR64<<<NN/4,256,0,stream>>>(Qd1, Rid, Qd0); // Qb -> Qd0
  spmmAT64(Qd0, Cd);                       // C = A^T Qb  (A2 = Qb C^T)
  k_qsum64<<<RK,256,0,stream>>>(Qd0, qsd);
  k_deg2f<<<cdiv(NN,T),T,0,stream>>>(Cd, qsd, dinv2);
  k_f64to32x2<<<cdiv(NN*RK,T),T,0,stream>>>(Qd0, Bf1, Cd, Cm, NN*RK);

  // h2 = dsbn_relu( D C (Qb^T (D xw1)) + b1 )
  k_fill<<<cdiv(RK*HIDC,T),T,0,stream>>>(Tm, 0.f, RK*HIDC);
  k_gemm_tn_sk<<<dim3(HIDC/16, RK/16, 8),256,0,stream>>>(RK,HIDC,NN,512, Bf1,RK, xw1,HIDC, Tm,HIDC, dinv2);
  k_gemm_nn<<<dim3(HIDC/64, NN/64),256,0,stream>>>(NN,HIDC,RK, Cm,RK, Tm,HIDC, hbuf,HIDC, dinv2, nullptr, b1f);
  k_bnstats<<<HIDC,256,0,stream>>>(hbuf, yv, dcnt, gmf, btf, scal, shft);
  k_bnapply<<<cdiv(NN*HIDC,T),T,0,stream>>>(hbuf, yv, scal, shft, xw1bf);
  // z2 = D C (Qb^T (D (h2 W))) + b
  k_gemm_hw<<<NN/64,256,0,stream>>>(xw1bf, Wmubf, hwA);
  k_gemm_hw<<<NN/64,256,0,stream>>>(xw1bf, Wlvbf, hwB);
  k_fill<<<cdiv(RK*RK,T),T,0,stream>>>(Umu, 0.f, RK*RK);
  k_gemm_tn_sk<<<dim3(RK/16, RK/16, 16),256,0,stream>>>(RK,RK,NN,256, Bf1,RK, hwA,OUTC, Umu,RK, dinv2);
  k_gemm_nn<<<dim3(1, NN/64),256,0,stream>>>(NN,OUTC,RK, Cm,RK, Umu,RK, zout + 2*NN*OUTC,OUTC, dinv2, nullptr, bmuf);
  k_fill<<<cdiv(RK*RK,T),T,0,stream>>>(Umu, 0.f, RK*RK);
  k_gemm_tn_sk<<<dim3(RK/16, RK/16, 16),256,0,stream>>>(RK,RK,NN,256, Bf1,RK, hwB,OUTC, Umu,RK, dinv2);
  k_gemm_nn<<<dim3(1, NN/64),256,0,stream>>>(NN,OUTC,RK, Cm,RK, Umu,RK, zout + 3*NN*OUTC,OUTC, dinv2, nullptr, blvf);
}

// Round 10
// 650.414 us; speedup vs baseline: 1.7501x; 1.0687x over previous
//
#include <hip/hip_runtime.h>
#include <hip/hip_bf16.h>

// GCNEncoder — r25 (resubmit; previous attempt hit an infra failure —
// "MI355X container failed twice" — kernel never ran, so no evidence against
// it; resubmitting byte-identical for clean attribution):
// (a) REVERT k_chol64 to r21/r23-proven v1 (52us; r24's v2 merged-phase
// variant regressed to 89.8us — single-wave issue slots are consumed even by
// exec-masked lanes, and v2 lengthened the serial rsqrt/stage chain).
// (b) subspace power chain P1-P4 in f32 storage with f64 accumulation
// (halves the 67MB/step edge-gather; reference runs svd_lowrank fully in
// f32, so f32 intermediates match reference behavior); P5 reads f32 writes
// f64; Gram/chol/trinv/applyR stay f64 (kappa(G) unchanged).
// History: r24 695us; r23 733us; r22 836us; r21 900us; r18 982us; r16 1138us.

#define NN    4096
#define NEDG  131072
#define INC   512
#define HIDC  512
#define OUTC  64
#define RK    64
#define NDOM  4
#define EPSBN 1e-5f

typedef unsigned short ushortT;
typedef __attribute__((ext_vector_type(8))) short bf16x8;
typedef __attribute__((ext_vector_type(4))) float f32x4;

static inline int cdiv(int a, int b){ return (a + b - 1) / b; }

__device__ __forceinline__ float bf2f(unsigned u){ return __uint_as_float(u << 16); }

// ---------------- input dtype detection (f32 vs bf16 carriers) ----------------
__global__ __launch_bounds__(256) void k_detect(const unsigned short* __restrict__ p,
                                                int* __restrict__ flag){
  int t = threadIdx.x;
  int cnt = 0;
  for (int i = t; i < 4096; i += 256){
    unsigned short v = p[2*i];
    int e = (v >> 7) & 0xFF;
    if (e >= 100 && e <= 140) cnt++;
  }
  __shared__ int sh[256];
  sh[t] = cnt; __syncthreads();
  for (int off = 128; off > 0; off >>= 1){ if (t < off) sh[t] += sh[t+off]; __syncthreads(); }
  if (t == 0) *flag = (sh[0] >= 2048) ? 0 : 1;
}

// ---------------- fused upcast (+ bf16 copies of x, W1, Wmu, Wlv) ----------------
__device__ __forceinline__ float upc1(const void* s, int f, int off){
  return f ? ((const float*)s)[off]
           : __bfloat162float(((const __hip_bfloat16*)s)[off]);
}
__device__ __forceinline__ ushortT tobf(float v){
  __hip_bfloat16 h = __float2bfloat16(v);
  return *(ushortT*)&h;
}
#define SEG_X   2097152
#define SEG_W1  262144
#define SEG_W   131072
#define SEG_WMU 32768
#define SEG_GB  2048
#define SEG_B1  512
#define SEG_BO  64
#define OFF1 (SEG_X)
#define OFF2 (OFF1+SEG_W1)
#define OFF3 (OFF2+SEG_W)
#define OFF4 (OFF3+SEG_WMU)
#define OFF5 (OFF4+SEG_WMU)
#define OFF6 (OFF5+SEG_GB)
#define OFF7 (OFF6+SEG_GB)
#define OFF8 (OFF7+SEG_B1)
#define OFF9 (OFF8+SEG_BO)
#define OFFT (OFF9+SEG_BO)

__global__ __launch_bounds__(256) void k_upcast_all(
    const void* x, const void* W1, const void* w, const void* Wmu, const void* Wlv,
    const void* gm, const void* bt, const void* b1, const void* bmu, const void* blv,
    const int* __restrict__ isf32,
    float* dx, float* dW1, float* dw, float* dWmu, float* dWlv,
    float* dgm, float* dbt, float* db1, float* dbmu, float* dblv,
    ushortT* xbf, ushortT* W1bf, ushortT* Wmubf, ushortT* Wlvbf){
  int i = blockIdx.x*256 + threadIdx.x;
  if (i >= OFFT) return;
  int f = *isf32;
  if      (i < OFF1){ float v = upc1(x, f, i); dx[i] = v; xbf[i] = tobf(v); }
  else if (i < OFF2){ float v = upc1(W1, f, i - OFF1); dW1[i - OFF1] = v; W1bf[i - OFF1] = tobf(v); }
  else if (i < OFF3) dw  [i - OFF2] = upc1(w,   f, i - OFF2);
  else if (i < OFF4){ float v = upc1(Wmu, f, i - OFF3); dWmu[i - OFF3] = v; Wmubf[i - OFF3] = tobf(v); }
  else if (i < OFF5){ float v = upc1(Wlv, f, i - OFF4); dWlv[i - OFF4] = v; Wlvbf[i - OFF4] = tobf(v); }
  else if (i < OFF6) dgm [i - OFF5] = upc1(gm,  f, i - OFF5);
  else if (i < OFF7) dbt [i - OFF6] = upc1(bt,  f, i - OFF6);
  else if (i < OFF8) db1 [i - OFF7] = upc1(b1,  f, i - OFF7);
  else if (i < OFF9) dbmu[i - OFF8] = upc1(bmu, f, i - OFF8);
  else               dblv[i - OFF9] = upc1(blv, f, i - OFF9);
}

// ---------------- elementwise utils ----------------
__global__ __launch_bounds__(256) void k_fill(float* d, float v, int n){
  int i = blockIdx.x*256 + threadIdx.x;
  if (i < n) d[i] = v;
}
__global__ __launch_bounds__(256) void k_filld(double* d, double v, int n){
  int i = blockIdx.x*256 + threadIdx.x;
  if (i < n) d[i] = v;
}
__global__ __launch_bounds__(256) void k_prep(float* deg, int* cntR, int* cntC, int* dcnt){
  int i = blockIdx.x*256 + threadIdx.x;
  if (i < NN){ deg[i] = 1.0f; cntR[i] = 0; cntC[i] = 0; }
  if (i < NDOM) dcnt[i] = 0;
}
__global__ __launch_bounds__(256) void k_f64to32x2(const double* __restrict__ s0, float* __restrict__ d0,
                                                   const double* __restrict__ s1, float* __restrict__ d1,
                                                   int n){
  int i = blockIdx.x*256 + threadIdx.x;
  if (i < n){ d0[i] = (float)s0[i]; d1[i] = (float)s1[i]; }
}

// ---------------- graph preprocessing ----------------
__global__ __launch_bounds__(256) void k_hist(const int* __restrict__ row, const int* __restrict__ col,
                                              const float* __restrict__ w, float* deg,
                                              int* cntR, int* cntC){
  int e = blockIdx.x*256 + threadIdx.x;
  if (e < NEDG){
    atomicAdd(&deg[col[e]], w[e]);
    atomicAdd(&cntR[row[e]], 1);
    atomicAdd(&cntC[col[e]], 1);
  }
}
__global__ __launch_bounds__(256) void k_dinv(const float* deg, float* dinv, int n){
  int i = blockIdx.x*256 + threadIdx.x;
  if (i < n){ float d = deg[i]; dinv[i] = (d > 0.f) ? 1.f/sqrtf(d) : 0.f; }
}
__global__ __launch_bounds__(256) void k_norm1(const int* __restrict__ row, const int* __restrict__ col,
                                               const float* __restrict__ w, const float* __restrict__ dinv,
                                               float* __restrict__ nrm){
  int e = blockIdx.x*256 + threadIdx.x;
  if (e < NEDG) nrm[e] = dinv[row[e]] * w[e] * dinv[col[e]];
}
__global__ __launch_bounds__(1024) void k_scan4096(const int* __restrict__ cnt,
                                                   int* __restrict__ ptr, int* __restrict__ pos){
  __shared__ int sh[1024];
  int t = threadIdx.x;
  int b = t*4;
  int a0 = cnt[b], a1 = cnt[b+1], a2 = cnt[b+2], a3 = cnt[b+3];
  sh[t] = a0 + a1 + a2 + a3;
  __syncthreads();
  for (int off = 1; off < 1024; off <<= 1){
    int v = (t >= off) ? sh[t-off] : 0;
    __syncthreads();
    sh[t] += v;
    __syncthreads();
  }
  int excl = (t == 0) ? 0 : sh[t-1];
  ptr[b]   = excl;            pos[b]   = excl;
  ptr[b+1] = excl+a0;         pos[b+1] = excl+a0;
  ptr[b+2] = excl+a0+a1;      pos[b+2] = excl+a0+a1;
  ptr[b+3] = excl+a0+a1+a2;   pos[b+3] = excl+a0+a1+a2;
  if (t == 1023) ptr[4096] = sh[1023];
}
__global__ __launch_bounds__(256) void k_scatter(const int* __restrict__ row, const int* __restrict__ col,
                                                 int* posR, int* posC, int* eidR, int* eidC){
  int e = blockIdx.x*256 + threadIdx.x;
  if (e < NEDG){
    int p = atomicAdd(&posR[row[e]], 1); eidR[p] = e;
    int q = atomicAdd(&posC[col[e]], 1); eidC[q] = e;
  }
}
// contiguous per-segment edge data (removes eid indirection from all spmms)
__global__ __launch_bounds__(256) void k_edges(const int* __restrict__ rowA, const int* __restrict__ colA,
        const float* __restrict__ wf, const float* __restrict__ nrm,
        const int* __restrict__ eidR, const int* __restrict__ eidC,
        int* __restrict__ csrSrc, float* __restrict__ csrW,
        int* __restrict__ cscSrc, float* __restrict__ cscW, float* __restrict__ cscN){
  int p = blockIdx.x*256 + threadIdx.x;
  if (p < NEDG){
    int eR = eidR[p]; csrSrc[p] = colA[eR]; csrW[p] = wf[eR];
    int eC = eidC[p]; cscSrc[p] = rowA[eC]; cscW[p] = wf[eC]; cscN[p] = nrm[eC];
  }
}
__global__ __launch_bounds__(256) void k_dcnt(const int* __restrict__ y, int* dcnt){
  int i = blockIdx.x*256 + threadIdx.x;
  if (i < NN) atomicAdd(&dcnt[y[i]], 1);
}

// ---------------- threefry2x32 core (KAT-verified round 8) ----------------
__device__ __forceinline__ unsigned rotl32(unsigned x, unsigned d){ return (x << d) | (x >> (32u - d)); }
#define TF_ROUND4(R0,R1,R2,R3) \
  x0 += x1; x1 = rotl32(x1,R0); x1 ^= x0; \
  x0 += x1; x1 = rotl32(x1,R1); x1 ^= x0; \
  x0 += x1; x1 = rotl32(x1,R2); x1 ^= x0; \
  x0 += x1; x1 = rotl32(x1,R3); x1 ^= x0;

__device__ __forceinline__ void tf2x32(unsigned k0, unsigned k1, unsigned c0, unsigned c1,
                                       unsigned* o0, unsigned* o1){
  unsigned ks2 = 0x1BD11BDAu ^ k0 ^ k1;
  unsigned x0 = c0 + k0, x1 = c1 + k1;
  TF_ROUND4(13,15,26,6);   x0 += k1;  x1 += ks2 + 1u;
  TF_ROUND4(17,29,16,24);  x0 += ks2; x1 += k0 + 2u;
  TF_ROUND4(13,15,26,6);   x0 += k0;  x1 += k1 + 3u;
  TF_ROUND4(17,29,16,24);  x0 += k1;  x1 += ks2 + 4u;
  TF_ROUND4(13,15,26,6);   x0 += ks2; x1 += k0 + 5u;
  *o0 = x0; *o1 = x1;
}

// ---------------- omega (verified round 10; f32 output for f32 chain) ----------------
__device__ double erfinv64(double x){
  double w = -log1p(-x*x);
  double p;
  if (w < 5.0){
    w -= 2.5;
    p = 2.81022636e-08;  p = p*w + 3.43273939e-07; p = p*w - 3.5233877e-06;
    p = p*w - 4.39150654e-06; p = p*w + 0.00021858087; p = p*w - 0.00125372503;
    p = p*w - 0.00417768164;  p = p*w + 0.246640727;   p = p*w + 1.50140941;
  } else {
    w = sqrt(w) - 3.0;
    p = -0.000200214257; p = p*w + 0.000100950558; p = p*w + 0.00134934322;
    p = p*w - 0.00367342844; p = p*w + 0.00573950773; p = p*w - 0.0076224613;
    p = p*w + 0.00943887047; p = p*w + 1.00167406;    p = p*w + 2.83297682;
  }
  double y = p * x;
  const double c = 1.1283791670955126;   // 2/sqrt(pi)
  #pragma unroll
  for (int it = 0; it < 3; it++){
    double err = erf(y) - x;
    y -= err / (c * exp(-y*y));
  }
  return y;
}

__device__ float bits_to_normal(unsigned b){
  float f = __uint_as_float((b >> 9) | 0x3f800000u) - 1.0f;
  const float lo = -0.99999994f;               // nextafter(-1,0) in f32
  float x = fmaxf(lo, f * 2.0f + lo);
  double r = 1.4142135623730951 * erfinv64((double)x);
  return (float)r;
}

__global__ __launch_bounds__(256) void k_omega(float* __restrict__ om){
  int i = blockIdx.x*256 + threadIdx.x;
  if (i >= 262144) return;
  unsigned o0, o1;
  tf2x32(0u, 42u, 0u, (unsigned)i, &o0, &o1);   // counter = (0, i)
  om[i] = bits_to_normal(o0 ^ o1);
}

// ---------------- bf16 MFMA GEMM (r22-proven) + bf16 C copy ----------------
__global__ __launch_bounds__(256) void k_gemm_bf16(
    const ushortT* __restrict__ A, const ushortT* __restrict__ B,
    float* __restrict__ Cc, ushortT* __restrict__ Cbf){
  __shared__ ushortT As2[64][40];   // [row][k] (+8 pad)
  __shared__ ushortT Bs2[64][40];   // [col][k] transposed (+8 pad)
  int t = threadIdx.x;
  int bm = blockIdx.y * 64, bn = blockIdx.x * 64;
  int w = t >> 6, l = t & 63;
  int lr = l & 15, lk = l >> 4;
  f32x4 acc[4] = {};
  int ar = t >> 2, ac = (t & 3) * 8;      // A stage: 64 rows x 32 k, 16B/thread
  int bc = t & 63, bk = (t >> 6) * 8;     // B stage: 64 cols x 8 k gathered
  for (int k0 = 0; k0 < 512; k0 += 32){
    *(uint4*)&As2[ar][ac] = *(const uint4*)&A[(size_t)(bm + ar) * 512 + k0 + ac];
    ushortT tmp[8];
    #pragma unroll
    for (int j = 0; j < 8; j++)
      tmp[j] = B[(size_t)(k0 + bk + j) * 512 + bn + bc];
    *(uint4*)&Bs2[bc][bk] = *(uint4*)tmp;
    __syncthreads();
    bf16x8 afrag = *(bf16x8*)&As2[w * 16 + lr][lk * 8];
    #pragma unroll
    for (int nt = 0; nt < 4; nt++){
      bf16x8 bfrag = *(bf16x8*)&Bs2[nt * 16 + lr][lk * 8];
      acc[nt] = __builtin_amdgcn_mfma_f32_16x16x32_bf16(afrag, bfrag, acc[nt], 0, 0, 0);
    }
    __syncthreads();
  }
  #pragma unroll
  for (int nt = 0; nt < 4; nt++){
    #pragma unroll
    for (int i = 0; i < 4; i++){
      size_t idx = (size_t)(bm + w * 16 + lk * 4 + i) * 512 + bn + nt * 16 + lr;
      float v = acc[nt][i];
      Cc[idx] = v;
      Cbf[idx] = tobf(v);
    }
  }
}

// hw GEMM: C[4096][64] = Hbf[4096][512] @ Wbf[512][64], f32 out, no bias.
__global__ __launch_bounds__(256) void k_gemm_hw(
    const ushortT* __restrict__ A, const ushortT* __restrict__ B,
    float* __restrict__ Cc){
  __shared__ ushortT As2[64][40];
  __shared__ ushortT Bs2[64][40];
  int t = threadIdx.x;
  int bm = blockIdx.x * 64;
  int w = t >> 6, l = t & 63;
  int lr = l & 15, lk = l >> 4;
  f32x4 acc[4] = {};
  int ar = t >> 2, ac = (t & 3) * 8;
  int bc = t & 63, bk = (t >> 6) * 8;
  for (int k0 = 0; k0 < 512; k0 += 32){
    *(uint4*)&As2[ar][ac] = *(const uint4*)&A[(size_t)(bm + ar) * 512 + k0 + ac];
    ushortT tmp[8];
    #pragma unroll
    for (int j = 0; j < 8; j++)
      tmp[j] = B[(size_t)(k0 + bk + j) * 64 + bc];
    *(uint4*)&Bs2[bc][bk] = *(uint4*)tmp;
    __syncthreads();
    bf16x8 afrag = *(bf16x8*)&As2[w * 16 + lr][lk * 8];
    #pragma unroll
    for (int nt = 0; nt < 4; nt++){
      bf16x8 bfrag = *(bf16x8*)&Bs2[nt * 16 + lr][lk * 8];
      acc[nt] = __builtin_amdgcn_mfma_f32_16x16x32_bf16(afrag, bfrag, acc[nt], 0, 0, 0);
    }
    __syncthreads();
  }
  #pragma unroll
  for (int nt = 0; nt < 4; nt++){
    #pragma unroll
    for (int i = 0; i < 4; i++){
      Cc[(size_t)(bm + w * 16 + lk * 4 + i) * 64 + nt * 16 + lr] = acc[nt][i];
    }
  }
}

// ---------------- GEMM (fp32, tiled 64x64, 4x4/thread) ----------------
__global__ __launch_bounds__(256) void k_gemm_nn(int M, int Nn, int K,
      const float* __restrict__ A, int lda, const float* __restrict__ B, int ldb,
      float* __restrict__ Cc, int ldc, const float* __restrict__ rowscale,
      const float* __restrict__ kscale, const float* __restrict__ bias){
  __shared__ float As[16][65];
  __shared__ float Bs[16][65];
  int bm = blockIdx.y*64, bn = blockIdx.x*64;
  int t = threadIdx.x;
  int tr = t >> 4, tc = t & 15;
  float acc[4][4] = {};
  for (int k0 = 0; k0 < K; k0 += 16){
    #pragma unroll
    for (int q = 0; q < 4; q++){
      int idx = t*4 + q;
      int m = idx >> 4, kk = idx & 15;
      As[kk][m] = A[(size_t)(bm+m)*lda + (k0+kk)];
    }
    #pragma unroll
    for (int q = 0; q < 4; q++){
      int idx = t + q*256;
      int kk = idx >> 6, n = idx & 63;
      float ks = kscale ? kscale[k0+kk] : 1.0f;
      Bs[kk][n] = B[(size_t)(k0+kk)*ldb + (bn+n)] * ks;
    }
    __syncthreads();
    #pragma unroll
    for (int kk = 0; kk < 16; kk++){
      float a0 = As[kk][tr*4+0], a1 = As[kk][tr*4+1], a2 = As[kk][tr*4+2], a3 = As[kk][tr*4+3];
      float b0 = Bs[kk][tc*4+0], b1 = Bs[kk][tc*4+1], b2 = Bs[kk][tc*4+2], b3 = Bs[kk][tc*4+3];
      acc[0][0] += a0*b0; acc[0][1] += a0*b1; acc[0][2] += a0*b2; acc[0][3] += a0*b3;
      acc[1][0] += a1*b0; acc[1][1] += a1*b1; acc[1][2] += a1*b2; acc[1][3] += a1*b3;
      acc[2][0] += a2*b0; acc[2][1] += a2*b1; acc[2][2] += a2*b2; acc[2][3] += a2*b3;
      acc[3][0] += a3*b0; acc[3][1] += a3*b1; acc[3][2] += a3*b2; acc[3][3] += a3*b3;
    }
    __syncthreads();
  }
  #pragma unroll
  for (int i2 = 0; i2 < 4; i2++){
    int m = bm + tr*4 + i2;
    float rs = rowscale ? rowscale[m] : 1.0f;
    #pragma unroll
    for (int j2 = 0; j2 < 4; j2++){
      int n = bn + tc*4 + j2;
      float v = acc[i2][j2] * rs;
      if (bias) v += bias[n];
      Cc[(size_t)m*ldc + n] = v;
    }
  }
}

// split-K TN: C += partial (C pre-zeroed); grid (Nn/16, M/16, K/kchunk)
__global__ __launch_bounds__(256) void k_gemm_tn_sk(int M, int Nn, int K, int kchunk,
      const float* __restrict__ A, int lda, const float* __restrict__ B, int ldb,
      float* __restrict__ Cc, int ldc, const float* __restrict__ kscale){
  __shared__ float As[32][17];
  __shared__ float Bs[32][17];
  int bm = blockIdx.y*16, bn = blockIdx.x*16;
  int kb = blockIdx.z*kchunk, ke = kb + kchunk;
  int t = threadIdx.x;
  int tm = t >> 4, tn = t & 15;
  float acc = 0.f;
  for (int k0 = kb; k0 < ke; k0 += 32){
    #pragma unroll
    for (int q = 0; q < 2; q++){
      int idx = t + q*256;
      int kk = idx >> 4, m = idx & 15;
      float sv = kscale ? kscale[k0+kk] : 1.0f;
      As[kk][m] = A[(size_t)(k0+kk)*lda + (bm+m)] * sv;
      Bs[kk][m] = B[(size_t)(k0+kk)*ldb + (bn+m)];
    }
    __syncthreads();
    #pragma unroll
    for (int kk = 0; kk < 32; kk++) acc += As[kk][tm] * Bs[kk][tn];
    __syncthreads();
  }
  atomicAdd(&Cc[(size_t)(bm+tm)*ldc + (bn+tn)], acc);
}

// ---------------- subspace chain SpMMs ----------------
// f32 storage, f64 accumulation (P1-P4)
__global__ __launch_bounds__(64) void k_spmm32(const int* __restrict__ ptr,
                       const int* __restrict__ src, const float* __restrict__ cf,
                       const float* __restrict__ X, float* __restrict__ Y){
  int seg = blockIdx.x;
  int t = threadIdx.x;
  double acc = 0.0;
  int p0 = ptr[seg], p1 = ptr[seg+1];
  for (int p = p0; p < p1; ++p){
    acc += (double)cf[p] * (double)X[(size_t)src[p]*RK + t];
  }
  Y[(size_t)seg*RK + t] = (float)acc;
}
// f32 in, f64 out (P5)
__global__ __launch_bounds__(64) void k_spmm32to64(const int* __restrict__ ptr,
                       const int* __restrict__ src, const float* __restrict__ cf,
                       const float* __restrict__ X, double* __restrict__ Y){
  int seg = blockIdx.x;
  int t = threadIdx.x;
  double acc = 0.0;
  int p0 = ptr[seg], p1 = ptr[seg+1];
  for (int p = p0; p < p1; ++p){
    acc += (double)cf[p] * (double)X[(size_t)src[p]*RK + t];
  }
  Y[(size_t)seg*RK + t] = acc;
}
// f64 spmm (final C = A^T Qb)
__global__ __launch_bounds__(64) void k_spmm64(const int* __restrict__ ptr,
                       const int* __restrict__ src, const float* __restrict__ cf,
                       const double* __restrict__ X, double* __restrict__ Y){
  int seg = blockIdx.x;
  int t = threadIdx.x;
  double acc = 0.0;
  int p0 = ptr[seg], p1 = ptr[seg+1];
  for (int p = p0; p < p1; ++p){
    acc += (double)cf[p] * X[(size_t)src[p]*RK + t];
  }
  Y[(size_t)seg*RK + t] = acc;
}
// Gram: G += Xslice^T Xslice over 64-row slices (G zeroed before)
__global__ __launch_bounds__(256) void k_gram64(const double* __restrict__ X, double* __restrict__ G){
  __shared__ double Xs[64][65];
  int b = blockIdx.x;
  int t = threadIdx.x;
  #pragma unroll
  for (int q = 0; q < 16; q++){
    int idx = t + q*256;
    Xs[idx >> 6][idx & 63] = X[(size_t)(b*64 + (idx >> 6))*RK + (idx & 63)];
  }
  __syncthreads();
  int i = t >> 2;
  int j0 = (t & 3) * 16;
  double acc[16];
  #pragma unroll
  for (int jj = 0; jj < 16; jj++) acc[jj] = 0.0;
  for (int k = 0; k < 64; k++){
    double a = Xs[k][i];
    #pragma unroll
    for (int jj = 0; jj < 16; jj++) acc[jj] += a * Xs[k][j0+jj];
  }
  #pragma unroll
  for (int jj = 0; jj < 16; jj++) atomicAdd(&G[i*RK + j0 + jj], acc[jj]);
}
// ---- Cholesky factorization, ONE wave (r21/r23-PROVEN v1, 52us). ----
#define CHOL_CHUNK(I0) \
  for (int k2 = 0; k2 < 16; k2++){ \
    int k = (I0) + k2; \
    int buf = k & 1; \
    if (j == k){ \
      double d = sqrt(fmax(cdiag, 1e-300)); \
      double s = 1.0 / d; \
      myd = d; \
      sdd[k] = s; \
      _Pragma("unroll") \
      for (int i = (I0); i < 64; i++){ c[i] *= s; colk[buf][i] = c[i]; } \
    } \
    __syncthreads(); \
    if (j > k){ \
      double cj = colk[buf][j]; \
      cdiag -= cj * cj; \
      _Pragma("unroll") \
      for (int i = (I0); i < 64; i++){ c[i] -= colk[buf][i] * cj; } \
    } \
    __syncthreads(); \
  }

__global__ __launch_bounds__(64) void k_chol64(double* __restrict__ G, double* __restrict__ sdd){
  __shared__ double colk[2][64];
  int j = threadIdx.x;        // 0..63, owns column j
  double c[64];
  #pragma unroll
  for (int i = 0; i < 64; i++) c[i] = G[i*64 + j];
  double cdiag = 0.0, myd = 0.0;
  #pragma unroll
  for (int i = 0; i < 64; i++) if (i == j) cdiag = c[i];
  CHOL_CHUNK(0)
  CHOL_CHUNK(16)
  CHOL_CHUNK(32)
  CHOL_CHUNK(48)
  #pragma unroll
  for (int i = 0; i < 64; i++){
    double v = (i > j) ? c[i] : 0.0;
    if (i == j) v = myd;
    G[i*64 + j] = v;
  }
}
// ---- blocked triangular inverse (r19..r24-proven stages), 256 threads. ----
__global__ __launch_bounds__(256) void k_trinv64(const double* __restrict__ L,
      const double* __restrict__ sdd, double* __restrict__ Rinv){
  __shared__ double gl[64][65];   // L lower; R[i][a] = gl[a][i]
  __shared__ double Xl[64][65];   // X = R^{-1} (upper); lower stays 0
  __shared__ double sdinv[64];
  __shared__ double Sl[3][16][17];
  int t = threadIdx.x;
  #pragma unroll
  for (int q = 0; q < 16; q++){
    int idx = t + (q << 8);
    gl[idx >> 6][idx & 63] = L[idx];
  }
  if (t < 64) sdinv[t] = sdd[t];
  for (int idx = t; idx < 64*65; idx += 256)
    ((double*)Xl)[idx] = 0.0;
  __syncthreads();
  if (t < 64){
    int b = t >> 4, c2 = t & 15;
    int g0 = b << 4;
    int gc = g0 + c2;
    Xl[gc][gc] = sdinv[gc];
    for (int i = c2 - 1; i >= 0; i--){
      int gi = g0 + i;
      double s = 0.0;
      for (int k2 = i + 1; k2 <= c2; k2++)
        s += gl[g0 + k2][gi] * Xl[g0 + k2][gc];
      Xl[gi][gc] = -s * sdinv[gi];
    }
  }
  __syncthreads();
  for (int d = 1; d < 4; d++){
    int np = 4 - d;
    int tot = np << 8;
    for (int e = t; e < tot; e += 256){
      int p = e >> 8;
      int i = (e >> 4) & 15, jj = e & 15;
      int gi = (p << 4) + i, gj = ((p + d) << 4) + jj;
      double s = 0.0;
      int a0 = (p + 1) << 4, a1 = (p + d + 1) << 4;
      for (int a = a0; a < a1; a++)
        s += gl[a][gi] * Xl[a][gj];
      Sl[p][i][jj] = s;
    }
    __syncthreads();
    for (int e = t; e < tot; e += 256){
      int p = e >> 8;
      int i = (e >> 4) & 15, jj = e & 15;
      int gi = (p << 4) + i, gj = ((p + d) << 4) + jj;
      double s = 0.0;
      #pragma unroll
      for (int k2 = 0; k2 < 16; k2++)
        s += Xl[gi][(p << 4) + k2] * Sl[p][k2][jj];
      Xl[gi][gj] = -s;
    }
    __syncthreads();
  }
  #pragma unroll
  for (int q = 0; q < 16; q++){
    int e2 = t + (q << 8);
    Rinv[e2] = Xl[e2 >> 6][e2 & 63];
  }
}
// dst[NNx64] = src[NNx64] * Rinv(upper); 4 rows per 256-thread block
__global__ __launch_bounds__(256) void k_applyR64(const double* __restrict__ src,
      const double* __restrict__ Rinv, double* __restrict__ dst){
  __shared__ double Rs[64][65];
  int t = threadIdx.x;
  #pragma unroll
  for (int q = 0; q < 16; q++){
    int idx = t + q*256;
    Rs[idx >> 6][idx & 63] = Rinv[idx];
  }
  __syncthreads();
  int r = blockIdx.x*4 + (t >> 6);
  int j = t & 63;
  const double* rowp = src + (size_t)r*RK;
  double s = 0.0;
  for (int k = 0; k <= j; k++) s += rowp[k] * Rs[k][j];
  dst[(size_t)r*RK + j] = s;
}
__global__ __launch_bounds__(256) void k_qsum64(const double* __restrict__ Q, double* __restrict__ qs){
  int j = blockIdx.x;  int t = threadIdx.x;
  double a = 0.0;
  for (int n = t; n < NN; n += 256) a += Q[(size_t)n*RK + j];
  __shared__ double sh[256];
  sh[t] = a; __syncthreads();
  for (int off = 128; off > 0; off >>= 1){ if (t < off) sh[t] += sh[t+off]; __syncthreads(); }
  if (t == 0) qs[j] = sh[0];
}
__global__ __launch_bounds__(256) void k_deg2f(const double* __restrict__ C, const double* __restrict__ qs,
                                               float* __restrict__ dinv2){
  int i = blockIdx.x*256 + threadIdx.x;
  if (i >= NN) return;
  double s = 0.0;
  #pragma unroll
  for (int k = 0; k < RK; k++) s += C[(size_t)i*RK + k] * qs[k];
  dinv2[i] = (s > 0.0) ? (float)(1.0/sqrt(s)) : 0.f;
}

// ---------------- SpMMs over contiguous per-segment edge data ----------------
// 512-wide bf16 gather (branch-1 h1): thread t handles cols 2t, 2t+1.
__global__ __launch_bounds__(256) void k_spmm_bf16(const int* __restrict__ ptr,
        const int* __restrict__ src, const float* __restrict__ cf,
        const ushortT* __restrict__ Xb, float* __restrict__ Y,
        const float* __restrict__ self_dinv, const float* __restrict__ bias){
  int seg = blockIdx.x;
  int t = threadIdx.x;
  float acc0, acc1;
  {
    float sd = self_dinv[seg]; float s2 = sd*sd;
    unsigned v = *(const unsigned*)&Xb[(size_t)seg*HIDC + 2*t];
    acc0 = s2 * bf2f(v & 0xffffu);
    acc1 = s2 * bf2f(v >> 16);
  }
  int p0 = ptr[seg], p1 = ptr[seg+1];
  for (int p = p0; p < p1; ++p){
    int o = src[p];
    float c = cf[p];
    unsigned v = *(const unsigned*)&Xb[(size_t)o*HIDC + 2*t];
    acc0 += c * bf2f(v & 0xffffu);
    acc1 += c * bf2f(v >> 16);
  }
  acc0 += bias[2*t];
  acc1 += bias[2*t+1];
  Y[(size_t)seg*HIDC + 2*t]     = acc0;
  Y[(size_t)seg*HIDC + 2*t + 1] = acc1;
}
// f32 spmm (64-wide, output stage)
__global__ void k_spmm(const int* __restrict__ ptr, const int* __restrict__ src,
                       const float* __restrict__ cf,
                       const float* __restrict__ X, int ldx,
                       float* __restrict__ Y, int ldy,
                       const float* __restrict__ self_dinv, const float* __restrict__ bias){
  int seg = blockIdx.x;
  int t = threadIdx.x;
  float acc0 = 0.f;
  {
    float sd = self_dinv[seg];
    acc0 = sd*sd * X[(size_t)seg*ldx + t];
  }
  int p0 = ptr[seg], p1 = ptr[seg+1];
  for (int p = p0; p < p1; ++p){
    acc0 += cf[p] * X[(size_t)src[p]*ldx + t];
  }
  acc0 += bias[t];
  Y[(size_t)seg*ldy + t] = acc0;
}

// ---------------- domain-specific BN ----------------
__global__ __launch_bounds__(256) void k_bnstats(const float* __restrict__ H, const int* __restrict__ y,
        const int* __restrict__ dcnt, const float* __restrict__ gamma, const float* __restrict__ beta,
        float* __restrict__ scal, float* __restrict__ shft){
  int j = blockIdx.x;
  int t = threadIdx.x;
  float s0=0,s1=0,s2=0,s3=0,q0=0,q1=0,q2=0,q3=0;
  for (int n = t; n < NN; n += 256){
    float v = H[(size_t)n*HIDC + j];
    int d = y[n];
    float v2 = v*v;
    if      (d == 0){ s0 += v; q0 += v2; }
    else if (d == 1){ s1 += v; q1 += v2; }
    else if (d == 2){ s2 += v; q2 += v2; }
    else            { s3 += v; q3 += v2; }
  }
  __shared__ float sh[256][8];
  sh[t][0]=s0; sh[t][1]=s1; sh[t][2]=s2; sh[t][3]=s3;
  sh[t][4]=q0; sh[t][5]=q1; sh[t][6]=q2; sh[t][7]=q3;
  __syncthreads();
  for (int off = 128; off > 0; off >>= 1){
    if (t < off){
      #pragma unroll
      for (int q = 0; q < 8; q++) sh[t][q] += sh[t+off][q];
    }
    __syncthreads();
  }
  if (t < NDOM){
    float cnt  = fmaxf((float)dcnt[t], 1.0f);
    float mean = sh[0][t] / cnt;
    float var  = fmaxf(sh[0][4+t] / cnt - mean*mean, 0.f);
    float inv  = 1.0f / sqrtf(var + EPSBN);
    float gmm  = gamma[t*HIDC + j];
    scal[t*HIDC + j] = gmm * inv;
    shft[t*HIDC + j] = beta[t*HIDC + j] - mean * gmm * inv;
  }
}
// BN apply + ReLU; also emits bf16 copy of H for the MFMA hw GEMMs.
__global__ __launch_bounds__(256) void k_bnapply(float* __restrict__ H, const int* __restrict__ y,
        const float* __restrict__ scal, const float* __restrict__ shft,
        ushortT* __restrict__ Hbf){
  int idx = blockIdx.x*256 + threadIdx.x;
  if (idx >= NN*HIDC) return;
  int n = idx >> 9, j = idx & (HIDC-1);
  int d = y[n];
  float v = H[idx] * scal[d*HIDC + j] + shft[d*HIDC + j];
  v = v > 0.f ? v : 0.f;
  H[idx] = v;
  Hbf[idx] = tobf(v);
}

// ---------------- launch ----------------
extern "C" void kernel_launch(void* const* d_in, const int* in_sizes, int n_in,
                              void* d_out, int out_size, void* d_ws, size_t ws_size,
                              hipStream_t stream){
  (void)in_sizes; (void)n_in; (void)out_size;
  const void* x_in  = d_in[0];
  const int*  ei    = (const int*)d_in[1];
  const void* w_in  = d_in[2];
  const int*  yv    = (const int*)d_in[3];
  const void* W1i   = d_in[4];
  const void* b1i   = d_in[5];
  const void* Wmui  = d_in[6];
  const void* bmui  = d_in[7];
  const void* Wlvi  = d_in[8];
  const void* blvi  = d_in[9];
  const void* gmi   = d_in[10];
  const void* bti   = d_in[11];
  const int* rowA = ei;
  const int* colA = ei + NEDG;
  float* zout = (float*)d_out;

  // ---- workspace: doubles | floats (+bf16) | ints ----
  double* Dp = (double*)d_ws;
  size_t od = 0;
  double* Qd0 = Dp + od; od += (size_t)NN*RK;
  double* Qd1 = Dp + od; od += (size_t)NN*RK;
  double* Cd  = Dp + od; od += (size_t)NN*RK;
  double* Gd  = Dp + od; od += RK*RK;
  double* Rid = Dp + od; od += RK*RK;
  double* qsd = Dp + od; od += RK;
  double* sdd = Dp + od; od += RK;
  float* Fp = (float*)(Dp + od);
  size_t o = 0;
  float* xf   = Fp + o; o += (size_t)NN*INC;       // reused as h1/h2 buffer
  float* W1f  = Fp + o; o += (size_t)INC*HIDC;
  float* b1f  = Fp + o; o += HIDC;
  float* Wmuf = Fp + o; o += (size_t)HIDC*OUTC;
  float* bmuf = Fp + o; o += OUTC;
  float* Wlvf = Fp + o; o += (size_t)HIDC*OUTC;
  float* blvf = Fp + o; o += OUTC;
  float* gmf  = Fp + o; o += NDOM*HIDC;
  float* btf  = Fp + o; o += NDOM*HIDC;
  float* wf   = Fp + o; o += NEDG;
  float* xw1  = Fp + o; o += (size_t)NN*HIDC;
  float* hwA  = Fp + o; o += (size_t)NN*OUTC;
  float* hwB  = Fp + o; o += (size_t)NN*OUTC;     // contiguous after hwA
  float* Bf1  = Fp + o; o += (size_t)NN*RK;        // Qb (f32)
  float* Cm   = Fp + o; o += (size_t)NN*RK;        // C (f32)
  float* Qf0  = Fp + o; o += (size_t)NN*RK;        // f32 subspace ping
  float* Qf1  = Fp + o; o += (size_t)NN*RK;        // f32 subspace pong
  float* Tm   = Fp + o; o += (size_t)RK*HIDC;
  float* Umu  = Fp + o; o += RK*RK;
  float* deg1 = Fp + o; o += NN;
  float* dinv1= Fp + o; o += NN;
  float* dinv2= Fp + o; o += NN;
  float* norm1= Fp + o; o += NEDG;
  float* scal = Fp + o; o += NDOM*HIDC;
  float* shft = Fp + o; o += NDOM*HIDC;
  float* csrW = Fp + o; o += NEDG;
  float* cscW = Fp + o; o += NEDG;
  float* cscN = Fp + o; o += NEDG;
  ushortT* xbf   = (ushortT*)(Fp + o); o += (size_t)NN*INC/2;    // bf16 x
  ushortT* W1bf  = (ushortT*)(Fp + o); o += (size_t)INC*HIDC/2;  // bf16 W1
  ushortT* xw1bf = (ushortT*)(Fp + o); o += (size_t)NN*HIDC/2;   // bf16 xw1 / h
  ushortT* Wmubf = (ushortT*)(Fp + o); o += (size_t)HIDC*OUTC/2;
  ushortT* Wlvbf = (ushortT*)(Fp + o); o += (size_t)HIDC*OUTC/2;
  int* Ip = (int*)(Fp + o);
  size_t oi = 0;
  int* cntR = Ip + oi; oi += NN;
  int* ptrR = Ip + oi; oi += NN + 1;
  int* posR = Ip + oi; oi += NN;
  int* eidR = Ip + oi; oi += NEDG;
  int* cntC = Ip + oi; oi += NN;
  int* ptrC = Ip + oi; oi += NN + 1;
  int* posC = Ip + oi; oi += NN;
  int* eidC = Ip + oi; oi += NEDG;
  int* csrSrc = Ip + oi; oi += NEDG;
  int* cscSrc = Ip + oi; oi += NEDG;
  int* dcnt = Ip + oi; oi += NDOM;
  int* dflag= Ip + oi; oi += 1;

  size_t need = od*sizeof(double) + o*sizeof(float) + (oi+16)*sizeof(int);
  if (ws_size < need) return;

  float* hbuf = xf;  // x dead after xw1 GEMM

  const int T = 256;
  k_detect<<<1,T,0,stream>>>((const unsigned short*)x_in, dflag);
  k_upcast_all<<<cdiv(OFFT,T),T,0,stream>>>(
      x_in, W1i, w_in, Wmui, Wlvi, gmi, bti, b1i, bmui, blvi, dflag,
      xf, W1f, wf, Wmuf, Wlvf, gmf, btf, b1f, bmuf, blvf,
      xbf, W1bf, Wmubf, Wlvbf);

  k_prep<<<cdiv(NN,T),T,0,stream>>>(deg1, cntR, cntC, dcnt);
  k_hist <<<cdiv(NEDG,T),T,0,stream>>>(rowA, colA, wf, deg1, cntR, cntC);
  k_dinv <<<cdiv(NN,T),T,0,stream>>>(deg1, dinv1, NN);
  k_norm1<<<cdiv(NEDG,T),T,0,stream>>>(rowA, colA, wf, dinv1, norm1);
  k_scan4096<<<1,1024,0,stream>>>(cntR, ptrR, posR);
  k_scan4096<<<1,1024,0,stream>>>(cntC, ptrC, posC);
  k_scatter<<<cdiv(NEDG,T),T,0,stream>>>(rowA, colA, posR, posC, eidR, eidC);
  k_edges<<<cdiv(NEDG,T),T,0,stream>>>(rowA, colA, wf, norm1, eidR, eidC,
                                       csrSrc, csrW, cscSrc, cscW, cscN);
  k_omega<<<cdiv(NN*RK,T),T,0,stream>>>(Qf0);      // f32 seed
  k_dcnt <<<cdiv(NN,T),T,0,stream>>>(yv, dcnt);

  // ---- branch 1 ----
  k_gemm_bf16<<<dim3(HIDC/64, NN/64),256,0,stream>>>(xbf, W1bf, xw1, xw1bf);
  k_spmm_bf16<<<NN,256,0,stream>>>(ptrC, cscSrc, cscN, xw1bf, hbuf, dinv1, b1f);
  k_bnstats<<<HIDC,256,0,stream>>>(hbuf, yv, dcnt, gmf, btf, scal, shft);
  k_bnapply<<<cdiv(NN*HIDC,T),T,0,stream>>>(hbuf, yv, scal, shft, xw1bf);
  k_gemm_hw<<<NN/64,256,0,stream>>>(xw1bf, Wmubf, hwA);
  k_gemm_hw<<<NN/64,256,0,stream>>>(xw1bf, Wlvbf, hwB);
  k_spmm<<<NN,64,0,stream>>>(ptrC, cscSrc, cscN, hwA,OUTC, zout + 0*NN*OUTC,OUTC, dinv1, bmuf);
  k_spmm<<<NN,64,0,stream>>>(ptrC, cscSrc, cscN, hwB,OUTC, zout + 1*NN*OUTC,OUTC, dinv1, blvf);

  // ---- branch 2: subspace chain (P1-P4 f32 storage / f64 accum; P5 -> f64) ----
  k_spmm32<<<NN,64,0,stream>>>(ptrR, csrSrc, csrW, Qf0, Qf1);       // P1 = A    @ om
  k_spmm32<<<NN,64,0,stream>>>(ptrC, cscSrc, cscW, Qf1, Qf0);       // P2 = A^T  @ P1
  k_spmm32<<<NN,64,0,stream>>>(ptrR, csrSrc, csrW, Qf0, Qf1);       // P3 = A    @ P2
  k_spmm32<<<NN,64,0,stream>>>(ptrC, cscSrc, cscW, Qf1, Qf0);       // P4 = A^T  @ P3
  k_spmm32to64<<<NN,64,0,stream>>>(ptrR, csrSrc, csrW, Qf0, Qd1);   // P5 = A    @ P4 (f64)
  k_filld<<<cdiv(RK*RK,T),T,0,stream>>>(Gd, 0.0, RK*RK);
  k_gram64<<<NN/64,256,0,stream>>>(Qd1, Gd);
  k_chol64<<<1,64,0,stream>>>(Gd, sdd);             // L over Gd, sdinv -> sdd
  k_trinv64<<<1,256,0,stream>>>(Gd, sdd, Rid);      // Rinv
  k_applyR64<<<NN/4,256,0,stream>>>(Qd1, Rid, Qd0); // Qb -> Qd0
  k_spmm64<<<NN,64,0,stream>>>(ptrC, cscSrc, cscW, Qd0, Cd);  // C = A^T Qb
  k_qsum64<<<RK,256,0,stream>>>(Qd0, qsd);
  k_deg2f<<<cdiv(NN,T),T,0,stream>>>(Cd, qsd, dinv2);
  k_f64to32x2<<<cdiv(NN*RK,T),T,0,stream>>>(Qd0, Bf1, Cd, Cm, NN*RK);

  // h2 = dsbn_relu( D C (Qb^T (D xw1)) + b1 )
  k_fill<<<cdiv(RK*HIDC,T),T,0,stream>>>(Tm, 0.f, RK*HIDC);
  k_gemm_tn_sk<<<dim3(HIDC/16, RK/16, 8),256,0,stream>>>(RK,HIDC,NN,512, Bf1,RK, xw1,HIDC, Tm,HIDC, dinv2);
  k_gemm_nn<<<dim3(HIDC/64, NN/64),256,0,stream>>>(NN,HIDC,RK, Cm,RK, Tm,HIDC, hbuf,HIDC, dinv2, nullptr, b1f);
  k_bnstats<<<HIDC,256,0,stream>>>(hbuf, yv, dcnt, gmf, btf, scal, shft);
  k_bnapply<<<cdiv(NN*HIDC,T),T,0,stream>>>(hbuf, yv, scal, shft, xw1bf);
  // z2 = D C (Qb^T (D (h2 W))) + b
  k_gemm_hw<<<NN/64,256,0,stream>>>(xw1bf, Wmubf, hwA);
  k_gemm_hw<<<NN/64,256,0,stream>>>(xw1bf, Wlvbf, hwB);
  k_fill<<<cdiv(RK*RK,T),T,0,stream>>>(Umu, 0.f, RK*RK);
  k_gemm_tn_sk<<<dim3(RK/16, RK/16, 16),256,0,stream>>>(RK,RK,NN,256, Bf1,RK, hwA,OUTC, Umu,RK, dinv2);
  k_gemm_nn<<<dim3(1, NN/64),256,0,stream>>>(NN,OUTC,RK, Cm,RK, Umu,RK, zout + 2*NN*OUTC,OUTC, dinv2, nullptr, bmuf);
  k_fill<<<cdiv(RK*RK,T),T,0,stream>>>(Umu, 0.f, RK*RK);
  k_gemm_tn_sk<<<dim3(RK/16, RK/16, 16),256,0,stream>>>(RK,RK,NN,256, Bf1,RK, hwB,OUTC, Umu,RK, dinv2);
  k_gemm_nn<<<dim3(1, NN/64),256,0,stream>>>(NN,OUTC,RK, Cm,RK, Umu,RK, zout + 3*NN*OUTC,OUTC, dinv2, nullptr, blvf);
}

// Round 11
// 578.125 us; speedup vs baseline: 1.9689x; 1.1250x over previous
//
#include <hip/hip_runtime.h>
#include <hip/hip_bf16.h>

// GCNEncoder — r26: (a) FUSE chol (1-block, 52us latency island) with the
// 512-wide h1 spmm: grid NN+1, block0 = chol v1 body (barriers uniform over
// 256 thr, work masked t<64), blocks 1..NN = spmm_bf16 body -> spmm hides
// under chol (max instead of sum). (b) launch merges (no numerics change):
// gemm_hw pair -> gemm_hw2, output spmm pair -> spmm2, Umu/Ulv fill+tn_sk+
// gemm_nn triples -> z-dim pairs, deg2f folded into f64->f32 convert (k_fin).
// absmax must stay EXACTLY 0.0078125 (zero arithmetic changes).
// History: r25 650us; r24 695us; r23 733us; r22 836us; r21 900us; r16 1138us.

#define NN    4096
#define NEDG  131072
#define INC   512
#define HIDC  512
#define OUTC  64
#define RK    64
#define NDOM  4
#define EPSBN 1e-5f

typedef unsigned short ushortT;
typedef __attribute__((ext_vector_type(8))) short bf16x8;
typedef __attribute__((ext_vector_type(4))) float f32x4;

static inline int cdiv(int a, int b){ return (a + b - 1) / b; }

__device__ __forceinline__ float bf2f(unsigned u){ return __uint_as_float(u << 16); }

// ---------------- input dtype detection (f32 vs bf16 carriers) ----------------
__global__ __launch_bounds__(256) void k_detect(const unsigned short* __restrict__ p,
                                                int* __restrict__ flag){
  int t = threadIdx.x;
  int cnt = 0;
  for (int i = t; i < 4096; i += 256){
    unsigned short v = p[2*i];
    int e = (v >> 7) & 0xFF;
    if (e >= 100 && e <= 140) cnt++;
  }
  __shared__ int sh[256];
  sh[t] = cnt; __syncthreads();
  for (int off = 128; off > 0; off >>= 1){ if (t < off) sh[t] += sh[t+off]; __syncthreads(); }
  if (t == 0) *flag = (sh[0] >= 2048) ? 0 : 1;
}

// ---------------- fused upcast (+ bf16 copies of x, W1, Wmu, Wlv) ----------------
__device__ __forceinline__ float upc1(const void* s, int f, int off){
  return f ? ((const float*)s)[off]
           : __bfloat162float(((const __hip_bfloat16*)s)[off]);
}
__device__ __forceinline__ ushortT tobf(float v){
  __hip_bfloat16 h = __float2bfloat16(v);
  return *(ushortT*)&h;
}
#define SEG_X   2097152
#define SEG_W1  262144
#define SEG_W   131072
#define SEG_WMU 32768
#define SEG_GB  2048
#define SEG_B1  512
#define SEG_BO  64
#define OFF1 (SEG_X)
#define OFF2 (OFF1+SEG_W1)
#define OFF3 (OFF2+SEG_W)
#define OFF4 (OFF3+SEG_WMU)
#define OFF5 (OFF4+SEG_WMU)
#define OFF6 (OFF5+SEG_GB)
#define OFF7 (OFF6+SEG_GB)
#define OFF8 (OFF7+SEG_B1)
#define OFF9 (OFF8+SEG_BO)
#define OFFT (OFF9+SEG_BO)

__global__ __launch_bounds__(256) void k_upcast_all(
    const void* x, const void* W1, const void* w, const void* Wmu, const void* Wlv,
    const void* gm, const void* bt, const void* b1, const void* bmu, const void* blv,
    const int* __restrict__ isf32,
    float* dx, float* dW1, float* dw, float* dWmu, float* dWlv,
    float* dgm, float* dbt, float* db1, float* dbmu, float* dblv,
    ushortT* xbf, ushortT* W1bf, ushortT* Wmubf, ushortT* Wlvbf){
  int i = blockIdx.x*256 + threadIdx.x;
  if (i >= OFFT) return;
  int f = *isf32;
  if      (i < OFF1){ float v = upc1(x, f, i); dx[i] = v; xbf[i] = tobf(v); }
  else if (i < OFF2){ float v = upc1(W1, f, i - OFF1); dW1[i - OFF1] = v; W1bf[i - OFF1] = tobf(v); }
  else if (i < OFF3) dw  [i - OFF2] = upc1(w,   f, i - OFF2);
  else if (i < OFF4){ float v = upc1(Wmu, f, i - OFF3); dWmu[i - OFF3] = v; Wmubf[i - OFF3] = tobf(v); }
  else if (i < OFF5){ float v = upc1(Wlv, f, i - OFF4); dWlv[i - OFF4] = v; Wlvbf[i - OFF4] = tobf(v); }
  else if (i < OFF6) dgm [i - OFF5] = upc1(gm,  f, i - OFF5);
  else if (i < OFF7) dbt [i - OFF6] = upc1(bt,  f, i - OFF6);
  else if (i < OFF8) db1 [i - OFF7] = upc1(b1,  f, i - OFF7);
  else if (i < OFF9) dbmu[i - OFF8] = upc1(bmu, f, i - OFF8);
  else               dblv[i - OFF9] = upc1(blv, f, i - OFF9);
}

// ---------------- elementwise utils ----------------
__global__ __launch_bounds__(256) void k_fill(float* d, float v, int n){
  int i = blockIdx.x*256 + threadIdx.x;
  if (i < n) d[i] = v;
}
__global__ __launch_bounds__(256) void k_filld(double* d, double v, int n){
  int i = blockIdx.x*256 + threadIdx.x;
  if (i < n) d[i] = v;
}
__global__ __launch_bounds__(256) void k_prep(float* deg, int* cntR, int* cntC, int* dcnt){
  int i = blockIdx.x*256 + threadIdx.x;
  if (i < NN){ deg[i] = 1.0f; cntR[i] = 0; cntC[i] = 0; }
  if (i < NDOM) dcnt[i] = 0;
}
// f64->f32 converts (Qb->Bf1, Cd->Cm) + deg2f fused (reads qsd; thread i<NN)
__global__ __launch_bounds__(256) void k_fin(const double* __restrict__ Qd,
        float* __restrict__ Bf1, const double* __restrict__ Cd, float* __restrict__ Cm,
        const double* __restrict__ qs, float* __restrict__ dinv2){
  int i = blockIdx.x*256 + threadIdx.x;
  if (i < NN*RK){ Bf1[i] = (float)Qd[i]; Cm[i] = (float)Cd[i]; }
  if (i < NN){
    double s = 0.0;
    #pragma unroll
    for (int k = 0; k < RK; k++) s += Cd[(size_t)i*RK + k] * qs[k];
    dinv2[i] = (s > 0.0) ? (float)(1.0/sqrt(s)) : 0.f;
  }
}

// ---------------- graph preprocessing ----------------
__global__ __launch_bounds__(256) void k_hist(const int* __restrict__ row, const int* __restrict__ col,
                                              const float* __restrict__ w, float* deg,
                                              int* cntR, int* cntC){
  int e = blockIdx.x*256 + threadIdx.x;
  if (e < NEDG){
    atomicAdd(&deg[col[e]], w[e]);
    atomicAdd(&cntR[row[e]], 1);
    atomicAdd(&cntC[col[e]], 1);
  }
}
__global__ __launch_bounds__(256) void k_dinv(const float* deg, float* dinv, int n){
  int i = blockIdx.x*256 + threadIdx.x;
  if (i < n){ float d = deg[i]; dinv[i] = (d > 0.f) ? 1.f/sqrtf(d) : 0.f; }
}
__global__ __launch_bounds__(256) void k_norm1(const int* __restrict__ row, const int* __restrict__ col,
                                               const float* __restrict__ w, const float* __restrict__ dinv,
                                               float* __restrict__ nrm){
  int e = blockIdx.x*256 + threadIdx.x;
  if (e < NEDG) nrm[e] = dinv[row[e]] * w[e] * dinv[col[e]];
}
__global__ __launch_bounds__(1024) void k_scan4096(const int* __restrict__ cnt,
                                                   int* __restrict__ ptr, int* __restrict__ pos){
  __shared__ int sh[1024];
  int t = threadIdx.x;
  int b = t*4;
  int a0 = cnt[b], a1 = cnt[b+1], a2 = cnt[b+2], a3 = cnt[b+3];
  sh[t] = a0 + a1 + a2 + a3;
  __syncthreads();
  for (int off = 1; off < 1024; off <<= 1){
    int v = (t >= off) ? sh[t-off] : 0;
    __syncthreads();
    sh[t] += v;
    __syncthreads();
  }
  int excl = (t == 0) ? 0 : sh[t-1];
  ptr[b]   = excl;            pos[b]   = excl;
  ptr[b+1] = excl+a0;         pos[b+1] = excl+a0;
  ptr[b+2] = excl+a0+a1;      pos[b+2] = excl+a0+a1;
  ptr[b+3] = excl+a0+a1+a2;   pos[b+3] = excl+a0+a1+a2;
  if (t == 1023) ptr[4096] = sh[1023];
}
__global__ __launch_bounds__(256) void k_scatter(const int* __restrict__ row, const int* __restrict__ col,
                                                 int* posR, int* posC, int* eidR, int* eidC){
  int e = blockIdx.x*256 + threadIdx.x;
  if (e < NEDG){
    int p = atomicAdd(&posR[row[e]], 1); eidR[p] = e;
    int q = atomicAdd(&posC[col[e]], 1); eidC[q] = e;
  }
}
__global__ __launch_bounds__(256) void k_edges(const int* __restrict__ rowA, const int* __restrict__ colA,
        const float* __restrict__ wf, const float* __restrict__ nrm,
        const int* __restrict__ eidR, const int* __restrict__ eidC,
        int* __restrict__ csrSrc, float* __restrict__ csrW,
        int* __restrict__ cscSrc, float* __restrict__ cscW, float* __restrict__ cscN){
  int p = blockIdx.x*256 + threadIdx.x;
  if (p < NEDG){
    int eR = eidR[p]; csrSrc[p] = colA[eR]; csrW[p] = wf[eR];
    int eC = eidC[p]; cscSrc[p] = rowA[eC]; cscW[p] = wf[eC]; cscN[p] = nrm[eC];
  }
}
__global__ __launch_bounds__(256) void k_dcnt(const int* __restrict__ y, int* dcnt){
  int i = blockIdx.x*256 + threadIdx.x;
  if (i < NN) atomicAdd(&dcnt[y[i]], 1);
}

// ---------------- threefry2x32 core (KAT-verified round 8) ----------------
__device__ __forceinline__ unsigned rotl32(unsigned x, unsigned d){ return (x << d) | (x >> (32u - d)); }
#define TF_ROUND4(R0,R1,R2,R3) \
  x0 += x1; x1 = rotl32(x1,R0); x1 ^= x0; \
  x0 += x1; x1 = rotl32(x1,R1); x1 ^= x0; \
  x0 += x1; x1 = rotl32(x1,R2); x1 ^= x0; \
  x0 += x1; x1 = rotl32(x1,R3); x1 ^= x0;

__device__ __forceinline__ void tf2x32(unsigned k0, unsigned k1, unsigned c0, unsigned c1,
                                       unsigned* o0, unsigned* o1){
  unsigned ks2 = 0x1BD11BDAu ^ k0 ^ k1;
  unsigned x0 = c0 + k0, x1 = c1 + k1;
  TF_ROUND4(13,15,26,6);   x0 += k1;  x1 += ks2 + 1u;
  TF_ROUND4(17,29,16,24);  x0 += ks2; x1 += k0 + 2u;
  TF_ROUND4(13,15,26,6);   x0 += k0;  x1 += k1 + 3u;
  TF_ROUND4(17,29,16,24);  x0 += k1;  x1 += ks2 + 4u;
  TF_ROUND4(13,15,26,6);   x0 += ks2; x1 += k0 + 5u;
  *o0 = x0; *o1 = x1;
}

// ---------------- omega (verified round 10; f32 output for f32 chain) ----------------
__device__ double erfinv64(double x){
  double w = -log1p(-x*x);
  double p;
  if (w < 5.0){
    w -= 2.5;
    p = 2.81022636e-08;  p = p*w + 3.43273939e-07; p = p*w - 3.5233877e-06;
    p = p*w - 4.39150654e-06; p = p*w + 0.00021858087; p = p*w - 0.00125372503;
    p = p*w - 0.00417768164;  p = p*w + 0.246640727;   p = p*w + 1.50140941;
  } else {
    w = sqrt(w) - 3.0;
    p = -0.000200214257; p = p*w + 0.000100950558; p = p*w + 0.00134934322;
    p = p*w - 0.00367342844; p = p*w + 0.00573950773; p = p*w - 0.0076224613;
    p = p*w + 0.00943887047; p = p*w + 1.00167406;    p = p*w + 2.83297682;
  }
  double y = p * x;
  const double c = 1.1283791670955126;   // 2/sqrt(pi)
  #pragma unroll
  for (int it = 0; it < 3; it++){
    double err = erf(y) - x;
    y -= err / (c * exp(-y*y));
  }
  return y;
}

__device__ float bits_to_normal(unsigned b){
  float f = __uint_as_float((b >> 9) | 0x3f800000u) - 1.0f;
  const float lo = -0.99999994f;               // nextafter(-1,0) in f32
  float x = fmaxf(lo, f * 2.0f + lo);
  double r = 1.4142135623730951 * erfinv64((double)x);
  return (float)r;
}

__global__ __launch_bounds__(256) void k_omega(float* __restrict__ om){
  int i = blockIdx.x*256 + threadIdx.x;
  if (i >= 262144) return;
  unsigned o0, o1;
  tf2x32(0u, 42u, 0u, (unsigned)i, &o0, &o1);   // counter = (0, i)
  om[i] = bits_to_normal(o0 ^ o1);
}

// ---------------- bf16 MFMA GEMM (r22-proven) + bf16 C copy ----------------
__global__ __launch_bounds__(256) void k_gemm_bf16(
    const ushortT* __restrict__ A, const ushortT* __restrict__ B,
    float* __restrict__ Cc, ushortT* __restrict__ Cbf){
  __shared__ ushortT As2[64][40];   // [row][k] (+8 pad)
  __shared__ ushortT Bs2[64][40];   // [col][k] transposed (+8 pad)
  int t = threadIdx.x;
  int bm = blockIdx.y * 64, bn = blockIdx.x * 64;
  int w = t >> 6, l = t & 63;
  int lr = l & 15, lk = l >> 4;
  f32x4 acc[4] = {};
  int ar = t >> 2, ac = (t & 3) * 8;      // A stage: 64 rows x 32 k, 16B/thread
  int bc = t & 63, bk = (t >> 6) * 8;     // B stage: 64 cols x 8 k gathered
  for (int k0 = 0; k0 < 512; k0 += 32){
    *(uint4*)&As2[ar][ac] = *(const uint4*)&A[(size_t)(bm + ar) * 512 + k0 + ac];
    ushortT tmp[8];
    #pragma unroll
    for (int j = 0; j < 8; j++)
      tmp[j] = B[(size_t)(k0 + bk + j) * 512 + bn + bc];
    *(uint4*)&Bs2[bc][bk] = *(uint4*)tmp;
    __syncthreads();
    bf16x8 afrag = *(bf16x8*)&As2[w * 16 + lr][lk * 8];
    #pragma unroll
    for (int nt = 0; nt < 4; nt++){
      bf16x8 bfrag = *(bf16x8*)&Bs2[nt * 16 + lr][lk * 8];
      acc[nt] = __builtin_amdgcn_mfma_f32_16x16x32_bf16(afrag, bfrag, acc[nt], 0, 0, 0);
    }
    __syncthreads();
  }
  #pragma unroll
  for (int nt = 0; nt < 4; nt++){
    #pragma unroll
    for (int i = 0; i < 4; i++){
      size_t idx = (size_t)(bm + w * 16 + lk * 4 + i) * 512 + bn + nt * 16 + lr;
      float v = acc[nt][i];
      Cc[idx] = v;
      Cbf[idx] = tobf(v);
    }
  }
}

// paired hw GEMMs: blocks [0,NN/64) -> Hbf@Wmubf -> hwA; rest -> Hbf@Wlvbf -> hwB
__global__ __launch_bounds__(256) void k_gemm_hw2(
    const ushortT* __restrict__ A, const ushortT* __restrict__ Bm,
    const ushortT* __restrict__ Bl, float* __restrict__ Ca, float* __restrict__ Cb){
  __shared__ ushortT As2[64][40];
  __shared__ ushortT Bs2[64][40];
  int t = threadIdx.x;
  int nb = NN/64;
  int second = blockIdx.x >= nb;
  int bm = (blockIdx.x - (second ? nb : 0)) * 64;
  const ushortT* B = second ? Bl : Bm;
  float* Cc = second ? Cb : Ca;
  int w = t >> 6, l = t & 63;
  int lr = l & 15, lk = l >> 4;
  f32x4 acc[4] = {};
  int ar = t >> 2, ac = (t & 3) * 8;
  int bc = t & 63, bk = (t >> 6) * 8;
  for (int k0 = 0; k0 < 512; k0 += 32){
    *(uint4*)&As2[ar][ac] = *(const uint4*)&A[(size_t)(bm + ar) * 512 + k0 + ac];
    ushortT tmp[8];
    #pragma unroll
    for (int j = 0; j < 8; j++)
      tmp[j] = B[(size_t)(k0 + bk + j) * 64 + bc];
    *(uint4*)&Bs2[bc][bk] = *(uint4*)tmp;
    __syncthreads();
    bf16x8 afrag = *(bf16x8*)&As2[w * 16 + lr][lk * 8];
    #pragma unroll
    for (int nt = 0; nt < 4; nt++){
      bf16x8 bfrag = *(bf16x8*)&Bs2[nt * 16 + lr][lk * 8];
      acc[nt] = __builtin_amdgcn_mfma_f32_16x16x32_bf16(afrag, bfrag, acc[nt], 0, 0, 0);
    }
    __syncthreads();
  }
  #pragma unroll
  for (int nt = 0; nt < 4; nt++){
    #pragma unroll
    for (int i = 0; i < 4; i++){
      Cc[(size_t)(bm + w * 16 + lk * 4 + i) * 64 + nt * 16 + lr] = acc[nt][i];
    }
  }
}

// ---------------- GEMM (fp32, tiled 64x64, 4x4/thread) — used for h2 ----------------
__global__ __launch_bounds__(256) void k_gemm_nn(int M, int Nn, int K,
      const float* __restrict__ A, int lda, const float* __restrict__ B, int ldb,
      float* __restrict__ Cc, int ldc, const float* __restrict__ rowscale,
      const float* __restrict__ kscale, const float* __restrict__ bias){
  __shared__ float As[16][65];
  __shared__ float Bs[16][65];
  int bm = blockIdx.y*64, bn = blockIdx.x*64;
  int t = threadIdx.x;
  int tr = t >> 4, tc = t & 15;
  float acc[4][4] = {};
  for (int k0 = 0; k0 < K; k0 += 16){
    #pragma unroll
    for (int q = 0; q < 4; q++){
      int idx = t*4 + q;
      int m = idx >> 4, kk = idx & 15;
      As[kk][m] = A[(size_t)(bm+m)*lda + (k0+kk)];
    }
    #pragma unroll
    for (int q = 0; q < 4; q++){
      int idx = t + q*256;
      int kk = idx >> 6, n = idx & 63;
      float ks = kscale ? kscale[k0+kk] : 1.0f;
      Bs[kk][n] = B[(size_t)(k0+kk)*ldb + (bn+n)] * ks;
    }
    __syncthreads();
    #pragma unroll
    for (int kk = 0; kk < 16; kk++){
      float a0 = As[kk][tr*4+0], a1 = As[kk][tr*4+1], a2 = As[kk][tr*4+2], a3 = As[kk][tr*4+3];
      float b0 = Bs[kk][tc*4+0], b1 = Bs[kk][tc*4+1], b2 = Bs[kk][tc*4+2], b3 = Bs[kk][tc*4+3];
      acc[0][0] += a0*b0; acc[0][1] += a0*b1; acc[0][2] += a0*b2; acc[0][3] += a0*b3;
      acc[1][0] += a1*b0; acc[1][1] += a1*b1; acc[1][2] += a1*b2; acc[1][3] += a1*b3;
      acc[2][0] += a2*b0; acc[2][1] += a2*b1; acc[2][2] += a2*b2; acc[2][3] += a2*b3;
      acc[3][0] += a3*b0; acc[3][1] += a3*b1; acc[3][2] += a3*b2; acc[3][3] += a3*b3;
    }
    __syncthreads();
  }
  #pragma unroll
  for (int i2 = 0; i2 < 4; i2++){
    int m = bm + tr*4 + i2;
    float rs = rowscale ? rowscale[m] : 1.0f;
    #pragma unroll
    for (int j2 = 0; j2 < 4; j2++){
      int n = bn + tc*4 + j2;
      float v = acc[i2][j2] * rs;
      if (bias) v += bias[n];
      Cc[(size_t)m*ldc + n] = v;
    }
  }
}

// paired zout2/zout3 GEMMs: z picks Umu/Ulv + bias; out = zout + (2+z)*NN*OUTC
__global__ __launch_bounds__(256) void k_gemm_nn2(
      const float* __restrict__ A,           // Cm [NN][RK]
      const float* __restrict__ Um,          // Umu|Ulv [2][RK][RK]
      const float* __restrict__ rowscale,    // dinv2
      const float* __restrict__ bmu, const float* __restrict__ blv,
      float* __restrict__ zout){
  __shared__ float As[16][65];
  __shared__ float Bs[16][65];
  int z = blockIdx.z;
  const float* B = Um + (size_t)z*RK*RK;
  const float* bias = z ? blv : bmu;
  float* Cc = zout + (size_t)(2+z)*NN*OUTC;
  int bm = blockIdx.y*64;
  int t = threadIdx.x;
  int tr = t >> 4, tc = t & 15;
  float acc[4][4] = {};
  for (int k0 = 0; k0 < RK; k0 += 16){
    #pragma unroll
    for (int q = 0; q < 4; q++){
      int idx = t*4 + q;
      int m = idx >> 4, kk = idx & 15;
      As[kk][m] = A[(size_t)(bm+m)*RK + (k0+kk)];
    }
    #pragma unroll
    for (int q = 0; q < 4; q++){
      int idx = t + q*256;
      int kk = idx >> 6, n = idx & 63;
      Bs[kk][n] = B[(size_t)(k0+kk)*RK + n];
    }
    __syncthreads();
    #pragma unroll
    for (int kk = 0; kk < 16; kk++){
      float a0 = As[kk][tr*4+0], a1 = As[kk][tr*4+1], a2 = As[kk][tr*4+2], a3 = As[kk][tr*4+3];
      float b0 = Bs[kk][tc*4+0], b1 = Bs[kk][tc*4+1], b2 = Bs[kk][tc*4+2], b3 = Bs[kk][tc*4+3];
      acc[0][0] += a0*b0; acc[0][1] += a0*b1; acc[0][2] += a0*b2; acc[0][3] += a0*b3;
      acc[1][0] += a1*b0; acc[1][1] += a1*b1; acc[1][2] += a1*b2; acc[1][3] += a1*b3;
      acc[2][0] += a2*b0; acc[2][1] += a2*b1; acc[2][2] += a2*b2; acc[2][3] += a2*b3;
      acc[3][0] += a3*b0; acc[3][1] += a3*b1; acc[3][2] += a3*b2; acc[3][3] += a3*b3;
    }
    __syncthreads();
  }
  #pragma unroll
  for (int i2 = 0; i2 < 4; i2++){
    int m = bm + tr*4 + i2;
    float rs = rowscale[m];
    #pragma unroll
    for (int j2 = 0; j2 < 4; j2++){
      int n = tc*4 + j2;
      Cc[(size_t)m*OUTC + n] = acc[i2][j2] * rs + bias[n];
    }
  }
}

// split-K TN: C += partial (C pre-zeroed); grid (Nn/16, M/16, K/kchunk) — Tm
__global__ __launch_bounds__(256) void k_gemm_tn_sk(int M, int Nn, int K, int kchunk,
      const float* __restrict__ A, int lda, const float* __restrict__ B, int ldb,
      float* __restrict__ Cc, int ldc, const float* __restrict__ kscale){
  __shared__ float As[32][17];
  __shared__ float Bs[32][17];
  int bm = blockIdx.y*16, bn = blockIdx.x*16;
  int kb = blockIdx.z*kchunk, ke = kb + kchunk;
  int t = threadIdx.x;
  int tm = t >> 4, tn = t & 15;
  float acc = 0.f;
  for (int k0 = kb; k0 < ke; k0 += 32){
    #pragma unroll
    for (int q = 0; q < 2; q++){
      int idx = t + q*256;
      int kk = idx >> 4, m = idx & 15;
      float sv = kscale ? kscale[k0+kk] : 1.0f;
      As[kk][m] = A[(size_t)(k0+kk)*lda + (bm+m)] * sv;
      Bs[kk][m] = B[(size_t)(k0+kk)*ldb + (bn+m)];
    }
    __syncthreads();
    #pragma unroll
    for (int kk = 0; kk < 32; kk++) acc += As[kk][tm] * Bs[kk][tn];
    __syncthreads();
  }
  atomicAdd(&Cc[(size_t)(bm+tm)*ldc + (bn+tn)], acc);
}

// paired Umu/Ulv split-K TN: grid (RK/16, RK/16, 32); z<16 -> hwA->Umu, else hwB->Ulv
__global__ __launch_bounds__(256) void k_gemm_tn_sk2(
      const float* __restrict__ A,           // Bf1 [NN][RK]
      const float* __restrict__ Ba, const float* __restrict__ Bb,  // hwA,hwB [NN][OUTC]
      float* __restrict__ Um,                // Umu|Ulv [2][RK][RK]
      const float* __restrict__ kscale){     // dinv2
  __shared__ float As[32][17];
  __shared__ float Bs[32][17];
  int z = blockIdx.z;
  int second = z >= 16;
  int kb = (second ? z - 16 : z) * 256, ke = kb + 256;
  const float* B = second ? Bb : Ba;
  float* Cc = Um + (second ? RK*RK : 0);
  int bm = blockIdx.y*16, bn = blockIdx.x*16;
  int t = threadIdx.x;
  int tm = t >> 4, tn = t & 15;
  float acc = 0.f;
  for (int k0 = kb; k0 < ke; k0 += 32){
    #pragma unroll
    for (int q = 0; q < 2; q++){
      int idx = t + q*256;
      int kk = idx >> 4, m = idx & 15;
      As[kk][m] = A[(size_t)(k0+kk)*RK + (bm+m)] * kscale[k0+kk];
      Bs[kk][m] = B[(size_t)(k0+kk)*OUTC + (bn+m)];
    }
    __syncthreads();
    #pragma unroll
    for (int kk = 0; kk < 32; kk++) acc += As[kk][tm] * Bs[kk][tn];
    __syncthreads();
  }
  atomicAdd(&Cc[(size_t)(bm+tm)*RK + (bn+tn)], acc);
}

// ---------------- subspace chain SpMMs ----------------
__global__ __launch_bounds__(64) void k_spmm32(const int* __restrict__ ptr,
                       const int* __restrict__ src, const float* __restrict__ cf,
                       const float* __restrict__ X, float* __restrict__ Y){
  int seg = blockIdx.x;
  int t = threadIdx.x;
  double acc = 0.0;
  int p0 = ptr[seg], p1 = ptr[seg+1];
  for (int p = p0; p < p1; ++p){
    acc += (double)cf[p] * (double)X[(size_t)src[p]*RK + t];
  }
  Y[(size_t)seg*RK + t] = (float)acc;
}
__global__ __launch_bounds__(64) void k_spmm32to64(const int* __restrict__ ptr,
                       const int* __restrict__ src, const float* __restrict__ cf,
                       const float* __restrict__ X, double* __restrict__ Y){
  int seg = blockIdx.x;
  int t = threadIdx.x;
  double acc = 0.0;
  int p0 = ptr[seg], p1 = ptr[seg+1];
  for (int p = p0; p < p1; ++p){
    acc += (double)cf[p] * (double)X[(size_t)src[p]*RK + t];
  }
  Y[(size_t)seg*RK + t] = acc;
}
__global__ __launch_bounds__(64) void k_spmm64(const int* __restrict__ ptr,
                       const int* __restrict__ src, const float* __restrict__ cf,
                       const double* __restrict__ X, double* __restrict__ Y){
  int seg = blockIdx.x;
  int t = threadIdx.x;
  double acc = 0.0;
  int p0 = ptr[seg], p1 = ptr[seg+1];
  for (int p = p0; p < p1; ++p){
    acc += (double)cf[p] * X[(size_t)src[p]*RK + t];
  }
  Y[(size_t)seg*RK + t] = acc;
}
// Gram: G += Xslice^T Xslice over 64-row slices (G zeroed before)
__global__ __launch_bounds__(256) void k_gram64(const double* __restrict__ X, double* __restrict__ G){
  __shared__ double Xs[64][65];
  int b = blockIdx.x;
  int t = threadIdx.x;
  #pragma unroll
  for (int q = 0; q < 16; q++){
    int idx = t + q*256;
    Xs[idx >> 6][idx & 63] = X[(size_t)(b*64 + (idx >> 6))*RK + (idx & 63)];
  }
  __syncthreads();
  int i = t >> 2;
  int j0 = (t & 3) * 16;
  double acc[16];
  #pragma unroll
  for (int jj = 0; jj < 16; jj++) acc[jj] = 0.0;
  for (int k = 0; k < 64; k++){
    double a = Xs[k][i];
    #pragma unroll
    for (int jj = 0; jj < 16; jj++) acc[jj] += a * Xs[k][j0+jj];
  }
  #pragma unroll
  for (int jj = 0; jj < 16; jj++) atomicAdd(&G[i*RK + j0 + jj], acc[jj]);
}

// ---- FUSED: block0 = Cholesky v1 (r21/r23-proven math; barriers uniform over
// 256 thr, all work masked t<64); blocks 1..NN = 512-wide bf16 h1 spmm. ----
#define CHOLF_CHUNK(I0) \
  for (int k2 = 0; k2 < 16; k2++){ \
    int k = (I0) + k2; \
    int buf = k & 1; \
    if (t < 64 && j == k){ \
      double d = sqrt(fmax(cdiag, 1e-300)); \
      double s = 1.0 / d; \
      myd = d; \
      sdd[k] = s; \
      _Pragma("unroll") \
      for (int i = (I0); i < 64; i++){ c[i] *= s; colk[buf][i] = c[i]; } \
    } \
    __syncthreads(); \
    if (t < 64 && j > k && j < 64){ \
      double cj = colk[buf][j]; \
      cdiag -= cj * cj; \
      _Pragma("unroll") \
      for (int i = (I0); i < 64; i++){ c[i] -= colk[buf][i] * cj; } \
    } \
    __syncthreads(); \
  }

__global__ __launch_bounds__(256) void k_chol_spmm(
    double* __restrict__ G, double* __restrict__ sdd,
    const int* __restrict__ ptr, const int* __restrict__ src, const float* __restrict__ cf,
    const ushortT* __restrict__ Xb, float* __restrict__ Y,
    const float* __restrict__ self_dinv, const float* __restrict__ bias){
  __shared__ double colk[2][64];
  int t = threadIdx.x;
  if (blockIdx.x == 0){
    int j = t;                    // lanes >= 64 inert (guarded)
    double c[64];
    double cdiag = 0.0, myd = 0.0;
    if (t < 64){
      #pragma unroll
      for (int i = 0; i < 64; i++) c[i] = G[i*64 + j];
      #pragma unroll
      for (int i = 0; i < 64; i++) if (i == j) cdiag = c[i];
    }
    CHOLF_CHUNK(0)
    CHOLF_CHUNK(16)
    CHOLF_CHUNK(32)
    CHOLF_CHUNK(48)
    if (t < 64){
      #pragma unroll
      for (int i = 0; i < 64; i++){
        double v = (i > j) ? c[i] : 0.0;
        if (i == j) v = myd;
        G[i*64 + j] = v;
      }
    }
  } else {
    int seg = blockIdx.x - 1;
    float acc0, acc1;
    {
      float sd = self_dinv[seg]; float s2 = sd*sd;
      unsigned v = *(const unsigned*)&Xb[(size_t)seg*HIDC + 2*t];
      acc0 = s2 * bf2f(v & 0xffffu);
      acc1 = s2 * bf2f(v >> 16);
    }
    int p0 = ptr[seg], p1 = ptr[seg+1];
    for (int p = p0; p < p1; ++p){
      int o = src[p];
      float cc = cf[p];
      unsigned v = *(const unsigned*)&Xb[(size_t)o*HIDC + 2*t];
      acc0 += cc * bf2f(v & 0xffffu);
      acc1 += cc * bf2f(v >> 16);
    }
    acc0 += bias[2*t];
    acc1 += bias[2*t+1];
    Y[(size_t)seg*HIDC + 2*t]     = acc0;
    Y[(size_t)seg*HIDC + 2*t + 1] = acc1;
  }
}

// ---- blocked triangular inverse (r19..r25-proven stages), 256 threads. ----
__global__ __launch_bounds__(256) void k_trinv64(const double* __restrict__ L,
      const double* __restrict__ sdd, double* __restrict__ Rinv){
  __shared__ double gl[64][65];   // L lower; R[i][a] = gl[a][i]
  __shared__ double Xl[64][65];   // X = R^{-1} (upper); lower stays 0
  __shared__ double sdinv[64];
  __shared__ double Sl[3][16][17];
  int t = threadIdx.x;
  #pragma unroll
  for (int q = 0; q < 16; q++){
    int idx = t + (q << 8);
    gl[idx >> 6][idx & 63] = L[idx];
  }
  if (t < 64) sdinv[t] = sdd[t];
  for (int idx = t; idx < 64*65; idx += 256)
    ((double*)Xl)[idx] = 0.0;
  __syncthreads();
  if (t < 64){
    int b = t >> 4, c2 = t & 15;
    int g0 = b << 4;
    int gc = g0 + c2;
    Xl[gc][gc] = sdinv[gc];
    for (int i = c2 - 1; i >= 0; i--){
      int gi = g0 + i;
      double s = 0.0;
      for (int k2 = i + 1; k2 <= c2; k2++)
        s += gl[g0 + k2][gi] * Xl[g0 + k2][gc];
      Xl[gi][gc] = -s * sdinv[gi];
    }
  }
  __syncthreads();
  for (int d = 1; d < 4; d++){
    int np = 4 - d;
    int tot = np << 8;
    for (int e = t; e < tot; e += 256){
      int p = e >> 8;
      int i = (e >> 4) & 15, jj = e & 15;
      int gi = (p << 4) + i, gj = ((p + d) << 4) + jj;
      double s = 0.0;
      int a0 = (p + 1) << 4, a1 = (p + d + 1) << 4;
      for (int a = a0; a < a1; a++)
        s += gl[a][gi] * Xl[a][gj];
      Sl[p][i][jj] = s;
    }
    __syncthreads();
    for (int e = t; e < tot; e += 256){
      int p = e >> 8;
      int i = (e >> 4) & 15, jj = e & 15;
      int gi = (p << 4) + i, gj = ((p + d) << 4) + jj;
      double s = 0.0;
      #pragma unroll
      for (int k2 = 0; k2 < 16; k2++)
        s += Xl[gi][(p << 4) + k2] * Sl[p][k2][jj];
      Xl[gi][gj] = -s;
    }
    __syncthreads();
  }
  #pragma unroll
  for (int q = 0; q < 16; q++){
    int e2 = t + (q << 8);
    Rinv[e2] = Xl[e2 >> 6][e2 & 63];
  }
}
// dst[NNx64] = src[NNx64] * Rinv(upper); 4 rows per 256-thread block
__global__ __launch_bounds__(256) void k_applyR64(const double* __restrict__ src,
      const double* __restrict__ Rinv, double* __restrict__ dst){
  __shared__ double Rs[64][65];
  int t = threadIdx.x;
  #pragma unroll
  for (int q = 0; q < 16; q++){
    int idx = t + q*256;
    Rs[idx >> 6][idx & 63] = Rinv[idx];
  }
  __syncthreads();
  int r = blockIdx.x*4 + (t >> 6);
  int j = t & 63;
  const double* rowp = src + (size_t)r*RK;
  double s = 0.0;
  for (int k = 0; k <= j; k++) s += rowp[k] * Rs[k][j];
  dst[(size_t)r*RK + j] = s;
}
__global__ __launch_bounds__(256) void k_qsum64(const double* __restrict__ Q, double* __restrict__ qs){
  int j = blockIdx.x;  int t = threadIdx.x;
  double a = 0.0;
  for (int n = t; n < NN; n += 256) a += Q[(size_t)n*RK + j];
  __shared__ double sh[256];
  sh[t] = a; __syncthreads();
  for (int off = 128; off > 0; off >>= 1){ if (t < off) sh[t] += sh[t+off]; __syncthreads(); }
  if (t == 0) qs[j] = sh[0];
}

// paired branch-1 output SpMMs: blocks [0,NN) -> hwA/bmuf -> zout0; [NN,2NN) -> hwB/blvf -> zout1
__global__ void k_spmm2(const int* __restrict__ ptr, const int* __restrict__ src,
                        const float* __restrict__ cf,
                        const float* __restrict__ Xa, const float* __restrict__ Xb2,
                        float* __restrict__ zout,
                        const float* __restrict__ self_dinv,
                        const float* __restrict__ bmu, const float* __restrict__ blv){
  int b = blockIdx.x;
  int second = b >= NN;
  int seg = second ? b - NN : b;
  const float* X = second ? Xb2 : Xa;
  const float* bias = second ? blv : bmu;
  float* Y = zout + (second ? (size_t)NN*OUTC : 0);
  int t = threadIdx.x;
  float acc0;
  {
    float sd = self_dinv[seg];
    acc0 = sd*sd * X[(size_t)seg*OUTC + t];
  }
  int p0 = ptr[seg], p1 = ptr[seg+1];
  for (int p = p0; p < p1; ++p){
    acc0 += cf[p] * X[(size_t)src[p]*OUTC + t];
  }
  acc0 += bias[t];
  Y[(size_t)seg*OUTC + t] = acc0;
}

// ---------------- domain-specific BN ----------------
__global__ __launch_bounds__(256) void k_bnstats(const float* __restrict__ H, const int* __restrict__ y,
        const int* __restrict__ dcnt, const float* __restrict__ gamma, const float* __restrict__ beta,
        float* __restrict__ scal, float* __restrict__ shft){
  int j = blockIdx.x;
  int t = threadIdx.x;
  float s0=0,s1=0,s2=0,s3=0,q0=0,q1=0,q2=0,q3=0;
  for (int n = t; n < NN; n += 256){
    float v = H[(size_t)n*HIDC + j];
    int d = y[n];
    float v2 = v*v;
    if      (d == 0){ s0 += v; q0 += v2; }
    else if (d == 1){ s1 += v; q1 += v2; }
    else if (d == 2){ s2 += v; q2 += v2; }
    else            { s3 += v; q3 += v2; }
  }
  __shared__ float sh[256][8];
  sh[t][0]=s0; sh[t][1]=s1; sh[t][2]=s2; sh[t][3]=s3;
  sh[t][4]=q0; sh[t][5]=q1; sh[t][6]=q2; sh[t][7]=q3;
  __syncthreads();
  for (int off = 128; off > 0; off >>= 1){
    if (t < off){
      #pragma unroll
      for (int q = 0; q < 8; q++) sh[t][q] += sh[t+off][q];
    }
    __syncthreads();
  }
  if (t < NDOM){
    float cnt  = fmaxf((float)dcnt[t], 1.0f);
    float mean = sh[0][t] / cnt;
    float var  = fmaxf(sh[0][4+t] / cnt - mean*mean, 0.f);
    float inv  = 1.0f / sqrtf(var + EPSBN);
    float gmm  = gamma[t*HIDC + j];
    scal[t*HIDC + j] = gmm * inv;
    shft[t*HIDC + j] = beta[t*HIDC + j] - mean * gmm * inv;
  }
}
// BN apply + ReLU; also emits bf16 copy of H for the MFMA hw GEMMs.
__global__ __launch_bounds__(256) void k_bnapply(float* __restrict__ H, const int* __restrict__ y,
        const float* __restrict__ scal, const float* __restrict__ shft,
        ushortT* __restrict__ Hbf){
  int idx = blockIdx.x*256 + threadIdx.x;
  if (idx >= NN*HIDC) return;
  int n = idx >> 9, j = idx & (HIDC-1);
  int d = y[n];
  float v = H[idx] * scal[d*HIDC + j] + shft[d*HIDC + j];
  v = v > 0.f ? v : 0.f;
  H[idx] = v;
  Hbf[idx] = tobf(v);
}

// ---------------- launch ----------------
extern "C" void kernel_launch(void* const* d_in, const int* in_sizes, int n_in,
                              void* d_out, int out_size, void* d_ws, size_t ws_size,
                              hipStream_t stream){
  (void)in_sizes; (void)n_in; (void)out_size;
  const void* x_in  = d_in[0];
  const int*  ei    = (const int*)d_in[1];
  const void* w_in  = d_in[2];
  const int*  yv    = (const int*)d_in[3];
  const void* W1i   = d_in[4];
  const void* b1i   = d_in[5];
  const void* Wmui  = d_in[6];
  const void* bmui  = d_in[7];
  const void* Wlvi  = d_in[8];
  const void* blvi  = d_in[9];
  const void* gmi   = d_in[10];
  const void* bti   = d_in[11];
  const int* rowA = ei;
  const int* colA = ei + NEDG;
  float* zout = (float*)d_out;

  // ---- workspace: doubles | floats (+bf16) | ints ----
  double* Dp = (double*)d_ws;
  size_t od = 0;
  double* Qd0 = Dp + od; od += (size_t)NN*RK;
  double* Qd1 = Dp + od; od += (size_t)NN*RK;
  double* Cd  = Dp + od; od += (size_t)NN*RK;
  double* Gd  = Dp + od; od += RK*RK;
  double* Rid = Dp + od; od += RK*RK;
  double* qsd = Dp + od; od += RK;
  double* sdd = Dp + od; od += RK;
  float* Fp = (float*)(Dp + od);
  size_t o = 0;
  float* xf   = Fp + o; o += (size_t)NN*INC;       // reused as h1/h2 buffer
  float* W1f  = Fp + o; o += (size_t)INC*HIDC;
  float* b1f  = Fp + o; o += HIDC;
  float* Wmuf = Fp + o; o += (size_t)HIDC*OUTC;
  float* bmuf = Fp + o; o += OUTC;
  float* Wlvf = Fp + o; o += (size_t)HIDC*OUTC;
  float* blvf = Fp + o; o += OUTC;
  float* gmf  = Fp + o; o += NDOM*HIDC;
  float* btf  = Fp + o; o += NDOM*HIDC;
  float* wf   = Fp + o; o += NEDG;
  float* xw1  = Fp + o; o += (size_t)NN*HIDC;
  float* hwA  = Fp + o; o += (size_t)NN*OUTC;
  float* hwB  = Fp + o; o += (size_t)NN*OUTC;     // contiguous after hwA
  float* Bf1  = Fp + o; o += (size_t)NN*RK;        // Qb (f32)
  float* Cm   = Fp + o; o += (size_t)NN*RK;        // C (f32)
  float* Qf0  = Fp + o; o += (size_t)NN*RK;        // f32 subspace ping
  float* Qf1  = Fp + o; o += (size_t)NN*RK;        // f32 subspace pong
  float* Tm   = Fp + o; o += (size_t)RK*HIDC;
  float* Umu  = Fp + o; o += 2*RK*RK;              // Umu | Ulv contiguous
  float* deg1 = Fp + o; o += NN;
  float* dinv1= Fp + o; o += NN;
  float* dinv2= Fp + o; o += NN;
  float* norm1= Fp + o; o += NEDG;
  float* scal = Fp + o; o += NDOM*HIDC;
  float* shft = Fp + o; o += NDOM*HIDC;
  float* csrW = Fp + o; o += NEDG;
  float* cscW = Fp + o; o += NEDG;
  float* cscN = Fp + o; o += NEDG;
  ushortT* xbf   = (ushortT*)(Fp + o); o += (size_t)NN*INC/2;    // bf16 x
  ushortT* W1bf  = (ushortT*)(Fp + o); o += (size_t)INC*HIDC/2;  // bf16 W1
  ushortT* xw1bf = (ushortT*)(Fp + o); o += (size_t)NN*HIDC/2;   // bf16 xw1
  ushortT* hbf   = (ushortT*)(Fp + o); o += (size_t)NN*HIDC/2;   // bf16 h1/h2
  ushortT* Wmubf = (ushortT*)(Fp + o); o += (size_t)HIDC*OUTC/2;
  ushortT* Wlvbf = (ushortT*)(Fp + o); o += (size_t)HIDC*OUTC/2;
  int* Ip = (int*)(Fp + o);
  size_t oi = 0;
  int* cntR = Ip + oi; oi += NN;
  int* ptrR = Ip + oi; oi += NN + 1;
  int* posR = Ip + oi; oi += NN;
  int* eidR = Ip + oi; oi += NEDG;
  int* cntC = Ip + oi; oi += NN;
  int* ptrC = Ip + oi; oi += NN + 1;
  int* posC = Ip + oi; oi += NN;
  int* eidC = Ip + oi; oi += NEDG;
  int* csrSrc = Ip + oi; oi += NEDG;
  int* cscSrc = Ip + oi; oi += NEDG;
  int* dcnt = Ip + oi; oi += NDOM;
  int* dflag= Ip + oi; oi += 1;

  size_t need = od*sizeof(double) + o*sizeof(float) + (oi+16)*sizeof(int);
  if (ws_size < need) return;

  float* hbuf = xf;  // x dead after xw1 GEMM

  const int T = 256;
  k_detect<<<1,T,0,stream>>>((const unsigned short*)x_in, dflag);
  k_upcast_all<<<cdiv(OFFT,T),T,0,stream>>>(
      x_in, W1i, w_in, Wmui, Wlvi, gmi, bti, b1i, bmui, blvi, dflag,
      xf, W1f, wf, Wmuf, Wlvf, gmf, btf, b1f, bmuf, blvf,
      xbf, W1bf, Wmubf, Wlvbf);

  k_prep<<<cdiv(NN,T),T,0,stream>>>(deg1, cntR, cntC, dcnt);
  k_hist <<<cdiv(NEDG,T),T,0,stream>>>(rowA, colA, wf, deg1, cntR, cntC);
  k_dinv <<<cdiv(NN,T),T,0,stream>>>(deg1, dinv1, NN);
  k_norm1<<<cdiv(NEDG,T),T,0,stream>>>(rowA, colA, wf, dinv1, norm1);
  k_scan4096<<<1,1024,0,stream>>>(cntR, ptrR, posR);
  k_scan4096<<<1,1024,0,stream>>>(cntC, ptrC, posC);
  k_scatter<<<cdiv(NEDG,T),T,0,stream>>>(rowA, colA, posR, posC, eidR, eidC);
  k_edges<<<cdiv(NEDG,T),T,0,stream>>>(rowA, colA, wf, norm1, eidR, eidC,
                                       csrSrc, csrW, cscSrc, cscW, cscN);
  k_omega<<<cdiv(NN*RK,T),T,0,stream>>>(Qf0);      // f32 seed
  k_dcnt <<<cdiv(NN,T),T,0,stream>>>(yv, dcnt);

  // ---- branch-1 head (early, independent of branch 2) ----
  k_gemm_bf16<<<dim3(HIDC/64, NN/64),256,0,stream>>>(xbf, W1bf, xw1, xw1bf);

  // ---- branch-2 subspace chain up to Gram ----
  k_spmm32<<<NN,64,0,stream>>>(ptrR, csrSrc, csrW, Qf0, Qf1);       // P1
  k_spmm32<<<NN,64,0,stream>>>(ptrC, cscSrc, cscW, Qf1, Qf0);       // P2
  k_spmm32<<<NN,64,0,stream>>>(ptrR, csrSrc, csrW, Qf0, Qf1);       // P3
  k_spmm32<<<NN,64,0,stream>>>(ptrC, cscSrc, cscW, Qf1, Qf0);       // P4
  k_spmm32to64<<<NN,64,0,stream>>>(ptrR, csrSrc, csrW, Qf0, Qd1);   // P5 (f64)
  k_filld<<<cdiv(RK*RK,T),T,0,stream>>>(Gd, 0.0, RK*RK);
  k_gram64<<<NN/64,256,0,stream>>>(Qd1, Gd);

  // ---- FUSED: chol (block0) + h1 spmm (blocks 1..NN) ----
  k_chol_spmm<<<NN+1,256,0,stream>>>(Gd, sdd, ptrC, cscSrc, cscN, xw1bf, hbuf,
                                     dinv1, b1f);

  k_trinv64<<<1,256,0,stream>>>(Gd, sdd, Rid);      // Rinv
  k_applyR64<<<NN/4,256,0,stream>>>(Qd1, Rid, Qd0); // Qb -> Qd0
  k_spmm64<<<NN,64,0,stream>>>(ptrC, cscSrc, cscW, Qd0, Cd);  // C = A^T Qb
  k_qsum64<<<RK,256,0,stream>>>(Qd0, qsd);
  k_fin<<<cdiv(NN*RK,T),T,0,stream>>>(Qd0, Bf1, Cd, Cm, qsd, dinv2);

  // ---- branch-1 tail ----
  k_bnstats<<<HIDC,256,0,stream>>>(hbuf, yv, dcnt, gmf, btf, scal, shft);
  k_bnapply<<<cdiv(NN*HIDC,T),T,0,stream>>>(hbuf, yv, scal, shft, hbf);
  k_gemm_hw2<<<2*(NN/64),256,0,stream>>>(hbf, Wmubf, Wlvbf, hwA, hwB);
  k_spmm2<<<2*NN,64,0,stream>>>(ptrC, cscSrc, cscN, hwA, hwB, zout, dinv1, bmuf, blvf);

  // ---- branch-2 tail ----
  k_fill<<<cdiv(RK*HIDC,T),T,0,stream>>>(Tm, 0.f, RK*HIDC);
  k_gemm_tn_sk<<<dim3(HIDC/16, RK/16, 8),256,0,stream>>>(RK,HIDC,NN,512, Bf1,RK, xw1,HIDC, Tm,HIDC, dinv2);
  k_gemm_nn<<<dim3(HIDC/64, NN/64),256,0,stream>>>(NN,HIDC,RK, Cm,RK, Tm,HIDC, hbuf,HIDC, dinv2, nullptr, b1f);
  k_bnstats<<<HIDC,256,0,stream>>>(hbuf, yv, dcnt, gmf, btf, scal, shft);
  k_bnapply<<<cdiv(NN*HIDC,T),T,0,stream>>>(hbuf, yv, scal, shft, hbf);
  k_gemm_hw2<<<2*(NN/64),256,0,stream>>>(hbf, Wmubf, Wlvbf, hwA, hwB);
  k_fill<<<cdiv(2*RK*RK,T),T,0,stream>>>(Umu, 0.f, 2*RK*RK);
  k_gemm_tn_sk2<<<dim3(RK/16, RK/16, 32),256,0,stream>>>(Bf1, hwA, hwB, Umu, dinv2);
  k_gemm_nn2<<<dim3(1, NN/64, 2),256,0,stream>>>(Cm, Umu, dinv2, bmuf, blvf, zout);
}

// Round 12
// 556.312 us; speedup vs baseline: 2.0461x; 1.0392x over previous
//
#include <hip/hip_runtime.h>
#include <hip/hip_bf16.h>

// GCNEncoder — r27: (a) coalesced BN stats: 128-block row-chunk partials
// (float2 reads, named per-domain regs) + f32 atomics into bnsum[8][512];
// finalize moved inline into bnapply (same formula). Old column-strided
// bnstats had ~16x cacheline overfetch. (b) island fusions (r26-validated
// mechanism): [trinv|bnpart], [applyR|bnapply], [spmm64C|gemm_hw2],
// [qsum|spmm2]. (c) Gd-zero folded into omega; Tm/Umu/bnsum-rezero into fin.
// History: r26 578us; r25 650us; r24 695us; r23 733us; r22 836us; r16 1138us.

#define NN    4096
#define NEDG  131072
#define INC   512
#define HIDC  512
#define OUTC  64
#define RK    64
#define NDOM  4
#define EPSBN 1e-5f

typedef unsigned short ushortT;
typedef __attribute__((ext_vector_type(8))) short bf16x8;
typedef __attribute__((ext_vector_type(4))) float f32x4;

static inline int cdiv(int a, int b){ return (a + b - 1) / b; }

__device__ __forceinline__ float bf2f(unsigned u){ return __uint_as_float(u << 16); }

// ---------------- input dtype detection ----------------
__global__ __launch_bounds__(256) void k_detect(const unsigned short* __restrict__ p,
                                                int* __restrict__ flag){
  int t = threadIdx.x;
  int cnt = 0;
  for (int i = t; i < 4096; i += 256){
    unsigned short v = p[2*i];
    int e = (v >> 7) & 0xFF;
    if (e >= 100 && e <= 140) cnt++;
  }
  __shared__ int sh[256];
  sh[t] = cnt; __syncthreads();
  for (int off = 128; off > 0; off >>= 1){ if (t < off) sh[t] += sh[t+off]; __syncthreads(); }
  if (t == 0) *flag = (sh[0] >= 2048) ? 0 : 1;
}

// ---------------- fused upcast ----------------
__device__ __forceinline__ float upc1(const void* s, int f, int off){
  return f ? ((const float*)s)[off]
           : __bfloat162float(((const __hip_bfloat16*)s)[off]);
}
__device__ __forceinline__ ushortT tobf(float v){
  __hip_bfloat16 h = __float2bfloat16(v);
  return *(ushortT*)&h;
}
#define SEG_X   2097152
#define SEG_W1  262144
#define SEG_W   131072
#define SEG_WMU 32768
#define SEG_GB  2048
#define SEG_B1  512
#define SEG_BO  64
#define OFF1 (SEG_X)
#define OFF2 (OFF1+SEG_W1)
#define OFF3 (OFF2+SEG_W)
#define OFF4 (OFF3+SEG_WMU)
#define OFF5 (OFF4+SEG_WMU)
#define OFF6 (OFF5+SEG_GB)
#define OFF7 (OFF6+SEG_GB)
#define OFF8 (OFF7+SEG_B1)
#define OFF9 (OFF8+SEG_BO)
#define OFFT (OFF9+SEG_BO)

__global__ __launch_bounds__(256) void k_upcast_all(
    const void* x, const void* W1, const void* w, const void* Wmu, const void* Wlv,
    const void* gm, const void* bt, const void* b1, const void* bmu, const void* blv,
    const int* __restrict__ isf32,
    float* dx, float* dW1, float* dw, float* dWmu, float* dWlv,
    float* dgm, float* dbt, float* db1, float* dbmu, float* dblv,
    ushortT* xbf, ushortT* W1bf, ushortT* Wmubf, ushortT* Wlvbf){
  int i = blockIdx.x*256 + threadIdx.x;
  if (i >= OFFT) return;
  int f = *isf32;
  if      (i < OFF1){ float v = upc1(x, f, i); dx[i] = v; xbf[i] = tobf(v); }
  else if (i < OFF2){ float v = upc1(W1, f, i - OFF1); dW1[i - OFF1] = v; W1bf[i - OFF1] = tobf(v); }
  else if (i < OFF3) dw  [i - OFF2] = upc1(w,   f, i - OFF2);
  else if (i < OFF4){ float v = upc1(Wmu, f, i - OFF3); dWmu[i - OFF3] = v; Wmubf[i - OFF3] = tobf(v); }
  else if (i < OFF5){ float v = upc1(Wlv, f, i - OFF4); dWlv[i - OFF4] = v; Wlvbf[i - OFF4] = tobf(v); }
  else if (i < OFF6) dgm [i - OFF5] = upc1(gm,  f, i - OFF5);
  else if (i < OFF7) dbt [i - OFF6] = upc1(bt,  f, i - OFF6);
  else if (i < OFF8) db1 [i - OFF7] = upc1(b1,  f, i - OFF7);
  else if (i < OFF9) dbmu[i - OFF8] = upc1(bmu, f, i - OFF8);
  else               dblv[i - OFF9] = upc1(blv, f, i - OFF9);
}

// ---------------- small utils ----------------
__global__ __launch_bounds__(256) void k_prep(float* deg, int* cntR, int* cntC, int* dcnt,
                                              float* bnsum){
  int i = blockIdx.x*256 + threadIdx.x;
  if (i < NN){ deg[i] = 1.0f; cntR[i] = 0; cntC[i] = 0; }
  if (i < NDOM) dcnt[i] = 0;
  if (i < 8*HIDC) bnsum[i] = 0.f;
}
// f64->f32 converts + deg2f + zero Tm/Umu/bnsum (for h2 pass)
__global__ __launch_bounds__(256) void k_fin(const double* __restrict__ Qd,
        float* __restrict__ Bf1, const double* __restrict__ Cd, float* __restrict__ Cm,
        const double* __restrict__ qs, float* __restrict__ dinv2,
        float* __restrict__ Tm, float* __restrict__ Um, float* __restrict__ bnsum){
  int i = blockIdx.x*256 + threadIdx.x;
  if (i < NN*RK){ Bf1[i] = (float)Qd[i]; Cm[i] = (float)Cd[i]; }
  if (i < NN){
    double s = 0.0;
    #pragma unroll
    for (int k = 0; k < RK; k++) s += Cd[(size_t)i*RK + k] * qs[k];
    dinv2[i] = (s > 0.0) ? (float)(1.0/sqrt(s)) : 0.f;
  }
  if (i < RK*HIDC) Tm[i] = 0.f;
  if (i < 2*RK*RK) Um[i] = 0.f;
  if (i < 8*HIDC)  bnsum[i] = 0.f;
}

// ---------------- graph preprocessing ----------------
__global__ __launch_bounds__(256) void k_hist(const int* __restrict__ row, const int* __restrict__ col,
                                              const float* __restrict__ w, float* deg,
                                              int* cntR, int* cntC){
  int e = blockIdx.x*256 + threadIdx.x;
  if (e < NEDG){
    atomicAdd(&deg[col[e]], w[e]);
    atomicAdd(&cntR[row[e]], 1);
    atomicAdd(&cntC[col[e]], 1);
  }
}
__global__ __launch_bounds__(256) void k_dinv(const float* deg, float* dinv, int n){
  int i = blockIdx.x*256 + threadIdx.x;
  if (i < n){ float d = deg[i]; dinv[i] = (d > 0.f) ? 1.f/sqrtf(d) : 0.f; }
}
__global__ __launch_bounds__(256) void k_norm1(const int* __restrict__ row, const int* __restrict__ col,
                                               const float* __restrict__ w, const float* __restrict__ dinv,
                                               float* __restrict__ nrm){
  int e = blockIdx.x*256 + threadIdx.x;
  if (e < NEDG) nrm[e] = dinv[row[e]] * w[e] * dinv[col[e]];
}
__global__ __launch_bounds__(1024) void k_scan4096(const int* __restrict__ cnt,
                                                   int* __restrict__ ptr, int* __restrict__ pos){
  __shared__ int sh[1024];
  int t = threadIdx.x;
  int b = t*4;
  int a0 = cnt[b], a1 = cnt[b+1], a2 = cnt[b+2], a3 = cnt[b+3];
  sh[t] = a0 + a1 + a2 + a3;
  __syncthreads();
  for (int off = 1; off < 1024; off <<= 1){
    int v = (t >= off) ? sh[t-off] : 0;
    __syncthreads();
    sh[t] += v;
    __syncthreads();
  }
  int excl = (t == 0) ? 0 : sh[t-1];
  ptr[b]   = excl;            pos[b]   = excl;
  ptr[b+1] = excl+a0;         pos[b+1] = excl+a0;
  ptr[b+2] = excl+a0+a1;      pos[b+2] = excl+a0+a1;
  ptr[b+3] = excl+a0+a1+a2;   pos[b+3] = excl+a0+a1+a2;
  if (t == 1023) ptr[4096] = sh[1023];
}
__global__ __launch_bounds__(256) void k_scatter(const int* __restrict__ row, const int* __restrict__ col,
                                                 int* posR, int* posC, int* eidR, int* eidC){
  int e = blockIdx.x*256 + threadIdx.x;
  if (e < NEDG){
    int p = atomicAdd(&posR[row[e]], 1); eidR[p] = e;
    int q = atomicAdd(&posC[col[e]], 1); eidC[q] = e;
  }
}
__global__ __launch_bounds__(256) void k_edges(const int* __restrict__ rowA, const int* __restrict__ colA,
        const float* __restrict__ wf, const float* __restrict__ nrm,
        const int* __restrict__ eidR, const int* __restrict__ eidC,
        int* __restrict__ csrSrc, float* __restrict__ csrW,
        int* __restrict__ cscSrc, float* __restrict__ cscW, float* __restrict__ cscN){
  int p = blockIdx.x*256 + threadIdx.x;
  if (p < NEDG){
    int eR = eidR[p]; csrSrc[p] = colA[eR]; csrW[p] = wf[eR];
    int eC = eidC[p]; cscSrc[p] = rowA[eC]; cscW[p] = wf[eC]; cscN[p] = nrm[eC];
  }
}
__global__ __launch_bounds__(256) void k_dcnt(const int* __restrict__ y, int* dcnt){
  int i = blockIdx.x*256 + threadIdx.x;
  if (i < NN) atomicAdd(&dcnt[y[i]], 1);
}

// ---------------- threefry2x32 (KAT-verified) ----------------
__device__ __forceinline__ unsigned rotl32(unsigned x, unsigned d){ return (x << d) | (x >> (32u - d)); }
#define TF_ROUND4(R0,R1,R2,R3) \
  x0 += x1; x1 = rotl32(x1,R0); x1 ^= x0; \
  x0 += x1; x1 = rotl32(x1,R1); x1 ^= x0; \
  x0 += x1; x1 = rotl32(x1,R2); x1 ^= x0; \
  x0 += x1; x1 = rotl32(x1,R3); x1 ^= x0;

__device__ __forceinline__ void tf2x32(unsigned k0, unsigned k1, unsigned c0, unsigned c1,
                                       unsigned* o0, unsigned* o1){
  unsigned ks2 = 0x1BD11BDAu ^ k0 ^ k1;
  unsigned x0 = c0 + k0, x1 = c1 + k1;
  TF_ROUND4(13,15,26,6);   x0 += k1;  x1 += ks2 + 1u;
  TF_ROUND4(17,29,16,24);  x0 += ks2; x1 += k0 + 2u;
  TF_ROUND4(13,15,26,6);   x0 += k0;  x1 += k1 + 3u;
  TF_ROUND4(17,29,16,24);  x0 += k1;  x1 += ks2 + 4u;
  TF_ROUND4(13,15,26,6);   x0 += ks2; x1 += k0 + 5u;
  *o0 = x0; *o1 = x1;
}

// ---------------- omega (verified; f32 out; + Gd zero fold) ----------------
__device__ double erfinv64(double x){
  double w = -log1p(-x*x);
  double p;
  if (w < 5.0){
    w -= 2.5;
    p = 2.81022636e-08;  p = p*w + 3.43273939e-07; p = p*w - 3.5233877e-06;
    p = p*w - 4.39150654e-06; p = p*w + 0.00021858087; p = p*w - 0.00125372503;
    p = p*w - 0.00417768164;  p = p*w + 0.246640727;   p = p*w + 1.50140941;
  } else {
    w = sqrt(w) - 3.0;
    p = -0.000200214257; p = p*w + 0.000100950558; p = p*w + 0.00134934322;
    p = p*w - 0.00367342844; p = p*w + 0.00573950773; p = p*w - 0.0076224613;
    p = p*w + 0.00943887047; p = p*w + 1.00167406;    p = p*w + 2.83297682;
  }
  double y = p * x;
  const double c = 1.1283791670955126;   // 2/sqrt(pi)
  #pragma unroll
  for (int it = 0; it < 3; it++){
    double err = erf(y) - x;
    y -= err / (c * exp(-y*y));
  }
  return y;
}

__device__ float bits_to_normal(unsigned b){
  float f = __uint_as_float((b >> 9) | 0x3f800000u) - 1.0f;
  const float lo = -0.99999994f;
  float x = fmaxf(lo, f * 2.0f + lo);
  double r = 1.4142135623730951 * erfinv64((double)x);
  return (float)r;
}

__global__ __launch_bounds__(256) void k_omega(float* __restrict__ om, double* __restrict__ Gd){
  int i = blockIdx.x*256 + threadIdx.x;
  if (i < RK*RK) Gd[i] = 0.0;
  if (i >= 262144) return;
  unsigned o0, o1;
  tf2x32(0u, 42u, 0u, (unsigned)i, &o0, &o1);
  om[i] = bits_to_normal(o0 ^ o1);
}

// ---------------- bf16 MFMA GEMM (r22-proven) + bf16 C copy ----------------
__global__ __launch_bounds__(256) void k_gemm_bf16(
    const ushortT* __restrict__ A, const ushortT* __restrict__ B,
    float* __restrict__ Cc, ushortT* __restrict__ Cbf){
  __shared__ ushortT As2[64][40];
  __shared__ ushortT Bs2[64][40];
  int t = threadIdx.x;
  int bm = blockIdx.y * 64, bn = blockIdx.x * 64;
  int w = t >> 6, l = t & 63;
  int lr = l & 15, lk = l >> 4;
  f32x4 acc[4] = {};
  int ar = t >> 2, ac = (t & 3) * 8;
  int bc = t & 63, bk = (t >> 6) * 8;
  for (int k0 = 0; k0 < 512; k0 += 32){
    *(uint4*)&As2[ar][ac] = *(const uint4*)&A[(size_t)(bm + ar) * 512 + k0 + ac];
    ushortT tmp[8];
    #pragma unroll
    for (int j = 0; j < 8; j++)
      tmp[j] = B[(size_t)(k0 + bk + j) * 512 + bn + bc];
    *(uint4*)&Bs2[bc][bk] = *(uint4*)tmp;
    __syncthreads();
    bf16x8 afrag = *(bf16x8*)&As2[w * 16 + lr][lk * 8];
    #pragma unroll
    for (int nt = 0; nt < 4; nt++){
      bf16x8 bfrag = *(bf16x8*)&Bs2[nt * 16 + lr][lk * 8];
      acc[nt] = __builtin_amdgcn_mfma_f32_16x16x32_bf16(afrag, bfrag, acc[nt], 0, 0, 0);
    }
    __syncthreads();
  }
  #pragma unroll
  for (int nt = 0; nt < 4; nt++){
    #pragma unroll
    for (int i = 0; i < 4; i++){
      size_t idx = (size_t)(bm + w * 16 + lk * 4 + i) * 512 + bn + nt * 16 + lr;
      float v = acc[nt][i];
      Cc[idx] = v;
      Cbf[idx] = tobf(v);
    }
  }
}

// device body: paired hw GEMM (bx in [0,128): bx<64 -> Wm->Ca, else Wl->Cb)
__device__ __forceinline__ void d_hw2(int bx, int t,
    const ushortT* __restrict__ A, const ushortT* __restrict__ Bm,
    const ushortT* __restrict__ Bl, float* __restrict__ Ca, float* __restrict__ Cb){
  __shared__ ushortT As2[64][40];
  __shared__ ushortT Bs2[64][40];
  int nb = NN/64;
  int second = bx >= nb;
  int bm = (bx - (second ? nb : 0)) * 64;
  const ushortT* B = second ? Bl : Bm;
  float* Cc = second ? Cb : Ca;
  int w = t >> 6, l = t & 63;
  int lr = l & 15, lk = l >> 4;
  f32x4 acc[4] = {};
  int ar = t >> 2, ac = (t & 3) * 8;
  int bc = t & 63, bk = (t >> 6) * 8;
  for (int k0 = 0; k0 < 512; k0 += 32){
    *(uint4*)&As2[ar][ac] = *(const uint4*)&A[(size_t)(bm + ar) * 512 + k0 + ac];
    ushortT tmp[8];
    #pragma unroll
    for (int j = 0; j < 8; j++)
      tmp[j] = B[(size_t)(k0 + bk + j) * 64 + bc];
    *(uint4*)&Bs2[bc][bk] = *(uint4*)tmp;
    __syncthreads();
    bf16x8 afrag = *(bf16x8*)&As2[w * 16 + lr][lk * 8];
    #pragma unroll
    for (int nt = 0; nt < 4; nt++){
      bf16x8 bfrag = *(bf16x8*)&Bs2[nt * 16 + lr][lk * 8];
      acc[nt] = __builtin_amdgcn_mfma_f32_16x16x32_bf16(afrag, bfrag, acc[nt], 0, 0, 0);
    }
    __syncthreads();
  }
  #pragma unroll
  for (int nt = 0; nt < 4; nt++){
    #pragma unroll
    for (int i = 0; i < 4; i++){
      Cc[(size_t)(bm + w * 16 + lk * 4 + i) * 64 + nt * 16 + lr] = acc[nt][i];
    }
  }
}
__global__ __launch_bounds__(256) void k_gemm_hw2(
    const ushortT* __restrict__ A, const ushortT* __restrict__ Bm,
    const ushortT* __restrict__ Bl, float* __restrict__ Ca, float* __restrict__ Cb){
  d_hw2(blockIdx.x, threadIdx.x, A, Bm, Bl, Ca, Cb);
}

// ---------------- GEMM (fp32, h2 dense) ----------------
__global__ __launch_bounds__(256) void k_gemm_nn(int M, int Nn, int K,
      const float* __restrict__ A, int lda, const float* __restrict__ B, int ldb,
      float* __restrict__ Cc, int ldc, const float* __restrict__ rowscale,
      const float* __restrict__ kscale, const float* __restrict__ bias){
  __shared__ float As[16][65];
  __shared__ float Bs[16][65];
  int bm = blockIdx.y*64, bn = blockIdx.x*64;
  int t = threadIdx.x;
  int tr = t >> 4, tc = t & 15;
  float acc[4][4] = {};
  for (int k0 = 0; k0 < K; k0 += 16){
    #pragma unroll
    for (int q = 0; q < 4; q++){
      int idx = t*4 + q;
      int m = idx >> 4, kk = idx & 15;
      As[kk][m] = A[(size_t)(bm+m)*lda + (k0+kk)];
    }
    #pragma unroll
    for (int q = 0; q < 4; q++){
      int idx = t + q*256;
      int kk = idx >> 6, n = idx & 63;
      float ks = kscale ? kscale[k0+kk] : 1.0f;
      Bs[kk][n] = B[(size_t)(k0+kk)*ldb + (bn+n)] * ks;
    }
    __syncthreads();
    #pragma unroll
    for (int kk = 0; kk < 16; kk++){
      float a0 = As[kk][tr*4+0], a1 = As[kk][tr*4+1], a2 = As[kk][tr*4+2], a3 = As[kk][tr*4+3];
      float b0 = Bs[kk][tc*4+0], b1 = Bs[kk][tc*4+1], b2 = Bs[kk][tc*4+2], b3 = Bs[kk][tc*4+3];
      acc[0][0] += a0*b0; acc[0][1] += a0*b1; acc[0][2] += a0*b2; acc[0][3] += a0*b3;
      acc[1][0] += a1*b0; acc[1][1] += a1*b1; acc[1][2] += a1*b2; acc[1][3] += a1*b3;
      acc[2][0] += a2*b0; acc[2][1] += a2*b1; acc[2][2] += a2*b2; acc[2][3] += a2*b3;
      acc[3][0] += a3*b0; acc[3][1] += a3*b1; acc[3][2] += a3*b2; acc[3][3] += a3*b3;
    }
    __syncthreads();
  }
  #pragma unroll
  for (int i2 = 0; i2 < 4; i2++){
    int m = bm + tr*4 + i2;
    float rs = rowscale ? rowscale[m] : 1.0f;
    #pragma unroll
    for (int j2 = 0; j2 < 4; j2++){
      int n = bn + tc*4 + j2;
      float v = acc[i2][j2] * rs;
      if (bias) v += bias[n];
      Cc[(size_t)m*ldc + n] = v;
    }
  }
}

// paired zout2/zout3 GEMMs
__global__ __launch_bounds__(256) void k_gemm_nn2(
      const float* __restrict__ A, const float* __restrict__ Um,
      const float* __restrict__ rowscale,
      const float* __restrict__ bmu, const float* __restrict__ blv,
      float* __restrict__ zout){
  __shared__ float As[16][65];
  __shared__ float Bs[16][65];
  int z = blockIdx.z;
  const float* B = Um + (size_t)z*RK*RK;
  const float* bias = z ? blv : bmu;
  float* Cc = zout + (size_t)(2+z)*NN*OUTC;
  int bm = blockIdx.y*64;
  int t = threadIdx.x;
  int tr = t >> 4, tc = t & 15;
  float acc[4][4] = {};
  for (int k0 = 0; k0 < RK; k0 += 16){
    #pragma unroll
    for (int q = 0; q < 4; q++){
      int idx = t*4 + q;
      int m = idx >> 4, kk = idx & 15;
      As[kk][m] = A[(size_t)(bm+m)*RK + (k0+kk)];
    }
    #pragma unroll
    for (int q = 0; q < 4; q++){
      int idx = t + q*256;
      int kk = idx >> 6, n = idx & 63;
      Bs[kk][n] = B[(size_t)(k0+kk)*RK + n];
    }
    __syncthreads();
    #pragma unroll
    for (int kk = 0; kk < 16; kk++){
      float a0 = As[kk][tr*4+0], a1 = As[kk][tr*4+1], a2 = As[kk][tr*4+2], a3 = As[kk][tr*4+3];
      float b0 = Bs[kk][tc*4+0], b1 = Bs[kk][tc*4+1], b2 = Bs[kk][tc*4+2], b3 = Bs[kk][tc*4+3];
      acc[0][0] += a0*b0; acc[0][1] += a0*b1; acc[0][2] += a0*b2; acc[0][3] += a0*b3;
      acc[1][0] += a1*b0; acc[1][1] += a1*b1; acc[1][2] += a1*b2; acc[1][3] += a1*b3;
      acc[2][0] += a2*b0; acc[2][1] += a2*b1; acc[2][2] += a2*b2; acc[2][3] += a2*b3;
      acc[3][0] += a3*b0; acc[3][1] += a3*b1; acc[3][2] += a3*b2; acc[3][3] += a3*b3;
    }
    __syncthreads();
  }
  #pragma unroll
  for (int i2 = 0; i2 < 4; i2++){
    int m = bm + tr*4 + i2;
    float rs = rowscale[m];
    #pragma unroll
    for (int j2 = 0; j2 < 4; j2++){
      int n = tc*4 + j2;
      Cc[(size_t)m*OUTC + n] = acc[i2][j2] * rs + bias[n];
    }
  }
}

// split-K TN (Tm)
__global__ __launch_bounds__(256) void k_gemm_tn_sk(int M, int Nn, int K, int kchunk,
      const float* __restrict__ A, int lda, const float* __restrict__ B, int ldb,
      float* __restrict__ Cc, int ldc, const float* __restrict__ kscale){
  __shared__ float As[32][17];
  __shared__ float Bs[32][17];
  int bm = blockIdx.y*16, bn = blockIdx.x*16;
  int kb = blockIdx.z*kchunk, ke = kb + kchunk;
  int t = threadIdx.x;
  int tm = t >> 4, tn = t & 15;
  float acc = 0.f;
  for (int k0 = kb; k0 < ke; k0 += 32){
    #pragma unroll
    for (int q = 0; q < 2; q++){
      int idx = t + q*256;
      int kk = idx >> 4, m = idx & 15;
      float sv = kscale ? kscale[k0+kk] : 1.0f;
      As[kk][m] = A[(size_t)(k0+kk)*lda + (bm+m)] * sv;
      Bs[kk][m] = B[(size_t)(k0+kk)*ldb + (bn+m)];
    }
    __syncthreads();
    #pragma unroll
    for (int kk = 0; kk < 32; kk++) acc += As[kk][tm] * Bs[kk][tn];
    __syncthreads();
  }
  atomicAdd(&Cc[(size_t)(bm+tm)*ldc + (bn+tn)], acc);
}

// paired Umu/Ulv split-K TN
__global__ __launch_bounds__(256) void k_gemm_tn_sk2(
      const float* __restrict__ A,
      const float* __restrict__ Ba, const float* __restrict__ Bb,
      float* __restrict__ Um, const float* __restrict__ kscale){
  __shared__ float As[32][17];
  __shared__ float Bs[32][17];
  int z = blockIdx.z;
  int second = z >= 16;
  int kb = (second ? z - 16 : z) * 256, ke = kb + 256;
  const float* B = second ? Bb : Ba;
  float* Cc = Um + (second ? RK*RK : 0);
  int bm = blockIdx.y*16, bn = blockIdx.x*16;
  int t = threadIdx.x;
  int tm = t >> 4, tn = t & 15;
  float acc = 0.f;
  for (int k0 = kb; k0 < ke; k0 += 32){
    #pragma unroll
    for (int q = 0; q < 2; q++){
      int idx = t + q*256;
      int kk = idx >> 4, m = idx & 15;
      As[kk][m] = A[(size_t)(k0+kk)*RK + (bm+m)] * kscale[k0+kk];
      Bs[kk][m] = B[(size_t)(k0+kk)*OUTC + (bn+m)];
    }
    __syncthreads();
    #pragma unroll
    for (int kk = 0; kk < 32; kk++) acc += As[kk][tm] * Bs[kk][tn];
    __syncthreads();
  }
  atomicAdd(&Cc[(size_t)(bm+tm)*RK + (bn+tn)], acc);
}

// ---------------- subspace chain SpMMs ----------------
__global__ __launch_bounds__(64) void k_spmm32(const int* __restrict__ ptr,
                       const int* __restrict__ src, const float* __restrict__ cf,
                       const float* __restrict__ X, float* __restrict__ Y){
  int seg = blockIdx.x;
  int t = threadIdx.x;
  double acc = 0.0;
  int p0 = ptr[seg], p1 = ptr[seg+1];
  for (int p = p0; p < p1; ++p){
    acc += (double)cf[p] * (double)X[(size_t)src[p]*RK + t];
  }
  Y[(size_t)seg*RK + t] = (float)acc;
}
__global__ __launch_bounds__(64) void k_spmm32to64(const int* __restrict__ ptr,
                       const int* __restrict__ src, const float* __restrict__ cf,
                       const float* __restrict__ X, double* __restrict__ Y){
  int seg = blockIdx.x;
  int t = threadIdx.x;
  double acc = 0.0;
  int p0 = ptr[seg], p1 = ptr[seg+1];
  for (int p = p0; p < p1; ++p){
    acc += (double)cf[p] * (double)X[(size_t)src[p]*RK + t];
  }
  Y[(size_t)seg*RK + t] = acc;
}
// Gram: G += Xslice^T Xslice
__global__ __launch_bounds__(256) void k_gram64(const double* __restrict__ X, double* __restrict__ G){
  __shared__ double Xs[64][65];
  int b = blockIdx.x;
  int t = threadIdx.x;
  #pragma unroll
  for (int q = 0; q < 16; q++){
    int idx = t + q*256;
    Xs[idx >> 6][idx & 63] = X[(size_t)(b*64 + (idx >> 6))*RK + (idx & 63)];
  }
  __syncthreads();
  int i = t >> 2;
  int j0 = (t & 3) * 16;
  double acc[16];
  #pragma unroll
  for (int jj = 0; jj < 16; jj++) acc[jj] = 0.0;
  for (int k = 0; k < 64; k++){
    double a = Xs[k][i];
    #pragma unroll
    for (int jj = 0; jj < 16; jj++) acc[jj] += a * Xs[k][j0+jj];
  }
  #pragma unroll
  for (int jj = 0; jj < 16; jj++) atomicAdd(&G[i*RK + j0 + jj], acc[jj]);
}

// ---- FUSED: block0 = Cholesky v1 (r26-proven); blocks 1..NN = h1 spmm ----
#define CHOLF_CHUNK(I0) \
  for (int k2 = 0; k2 < 16; k2++){ \
    int k = (I0) + k2; \
    int buf = k & 1; \
    if (t < 64 && j == k){ \
      double d = sqrt(fmax(cdiag, 1e-300)); \
      double s = 1.0 / d; \
      myd = d; \
      sdd[k] = s; \
      _Pragma("unroll") \
      for (int i = (I0); i < 64; i++){ c[i] *= s; colk[buf][i] = c[i]; } \
    } \
    __syncthreads(); \
    if (t < 64 && j > k && j < 64){ \
      double cj = colk[buf][j]; \
      cdiag -= cj * cj; \
      _Pragma("unroll") \
      for (int i = (I0); i < 64; i++){ c[i] -= colk[buf][i] * cj; } \
    } \
    __syncthreads(); \
  }

__global__ __launch_bounds__(256) void k_chol_spmm(
    double* __restrict__ G, double* __restrict__ sdd,
    const int* __restrict__ ptr, const int* __restrict__ src, const float* __restrict__ cf,
    const ushortT* __restrict__ Xb, float* __restrict__ Y,
    const float* __restrict__ self_dinv, const float* __restrict__ bias){
  __shared__ double colk[2][64];
  int t = threadIdx.x;
  if (blockIdx.x == 0){
    int j = t;
    double c[64];
    double cdiag = 0.0, myd = 0.0;
    if (t < 64){
      #pragma unroll
      for (int i = 0; i < 64; i++) c[i] = G[i*64 + j];
      #pragma unroll
      for (int i = 0; i < 64; i++) if (i == j) cdiag = c[i];
    }
    CHOLF_CHUNK(0)
    CHOLF_CHUNK(16)
    CHOLF_CHUNK(32)
    CHOLF_CHUNK(48)
    if (t < 64){
      #pragma unroll
      for (int i = 0; i < 64; i++){
        double v = (i > j) ? c[i] : 0.0;
        if (i == j) v = myd;
        G[i*64 + j] = v;
      }
    }
  } else {
    int seg = blockIdx.x - 1;
    float acc0, acc1;
    {
      float sd = self_dinv[seg]; float s2 = sd*sd;
      unsigned v = *(const unsigned*)&Xb[(size_t)seg*HIDC + 2*t];
      acc0 = s2 * bf2f(v & 0xffffu);
      acc1 = s2 * bf2f(v >> 16);
    }
    int p0 = ptr[seg], p1 = ptr[seg+1];
    for (int p = p0; p < p1; ++p){
      int o = src[p];
      float cc = cf[p];
      unsigned v = *(const unsigned*)&Xb[(size_t)o*HIDC + 2*t];
      acc0 += cc * bf2f(v & 0xffffu);
      acc1 += cc * bf2f(v >> 16);
    }
    acc0 += bias[2*t];
    acc1 += bias[2*t+1];
    Y[(size_t)seg*HIDC + 2*t]     = acc0;
    Y[(size_t)seg*HIDC + 2*t + 1] = acc1;
  }
}

// ---- BN partials: block handles 32 rows x 512 cols, coalesced float2 ----
__device__ __forceinline__ void d_bnpart(int b, int t,
    const float* __restrict__ H, const int* __restrict__ y, float* __restrict__ bnsum){
  int j0 = 2*t;
  float s00=0,s01=0,s10=0,s11=0,s20=0,s21=0,s30=0,s31=0;
  float q00=0,q01=0,q10=0,q11=0,q20=0,q21=0,q30=0,q31=0;
  int r0 = b*32;
  for (int r = r0; r < r0+32; r++){
    int d = y[r];
    float2 v = *(const float2*)&H[(size_t)r*HIDC + j0];
    float ax = v.x, ay = v.y;
    float bx = ax*ax, by = ay*ay;
    if      (d == 0){ s00+=ax; s01+=ay; q00+=bx; q01+=by; }
    else if (d == 1){ s10+=ax; s11+=ay; q10+=bx; q11+=by; }
    else if (d == 2){ s20+=ax; s21+=ay; q20+=bx; q21+=by; }
    else            { s30+=ax; s31+=ay; q30+=bx; q31+=by; }
  }
  atomicAdd(&bnsum[0*HIDC+j0], s00); atomicAdd(&bnsum[0*HIDC+j0+1], s01);
  atomicAdd(&bnsum[1*HIDC+j0], s10); atomicAdd(&bnsum[1*HIDC+j0+1], s11);
  atomicAdd(&bnsum[2*HIDC+j0], s20); atomicAdd(&bnsum[2*HIDC+j0+1], s21);
  atomicAdd(&bnsum[3*HIDC+j0], s30); atomicAdd(&bnsum[3*HIDC+j0+1], s31);
  atomicAdd(&bnsum[4*HIDC+j0], q00); atomicAdd(&bnsum[4*HIDC+j0+1], q01);
  atomicAdd(&bnsum[5*HIDC+j0], q10); atomicAdd(&bnsum[5*HIDC+j0+1], q11);
  atomicAdd(&bnsum[6*HIDC+j0], q20); atomicAdd(&bnsum[6*HIDC+j0+1], q21);
  atomicAdd(&bnsum[7*HIDC+j0], q30); atomicAdd(&bnsum[7*HIDC+j0+1], q31);
}
__global__ __launch_bounds__(256) void k_bnpart(const float* __restrict__ H,
        const int* __restrict__ y, float* __restrict__ bnsum){
  d_bnpart(blockIdx.x, threadIdx.x, H, y, bnsum);
}

// ---- BN apply with inline finalize (same formula as old bnstats) ----
__device__ __forceinline__ void d_bnapply(int idx,
    float* __restrict__ H, const int* __restrict__ y,
    const float* __restrict__ bnsum, const int* __restrict__ dcnt,
    const float* __restrict__ gamma, const float* __restrict__ beta,
    ushortT* __restrict__ Hbf){
  int n = idx >> 9, j = idx & (HIDC-1);
  int d = y[n];
  float cnt  = fmaxf((float)dcnt[d], 1.0f);
  float mean = bnsum[d*HIDC + j] / cnt;
  float var  = fmaxf(bnsum[(4+d)*HIDC + j] / cnt - mean*mean, 0.f);
  float inv  = 1.0f / sqrtf(var + EPSBN);
  float gmm  = gamma[d*HIDC + j];
  float scal = gmm * inv;
  float shft = beta[d*HIDC + j] - mean * gmm * inv;
  float v = H[idx] * scal + shft;
  v = v > 0.f ? v : 0.f;
  H[idx] = v;
  Hbf[idx] = tobf(v);
}
__global__ __launch_bounds__(256) void k_bnapply(float* __restrict__ H, const int* __restrict__ y,
        const float* __restrict__ bnsum, const int* __restrict__ dcnt,
        const float* __restrict__ gamma, const float* __restrict__ beta,
        ushortT* __restrict__ Hbf){
  int idx = blockIdx.x*256 + threadIdx.x;
  if (idx < NN*HIDC) d_bnapply(idx, H, y, bnsum, dcnt, gamma, beta, Hbf);
}

// ---- FUSED: block0 = trinv (r19..-proven); blocks 1..128 = bnpart(h1) ----
__global__ __launch_bounds__(256) void k_trinv_bn(const double* __restrict__ L,
      const double* __restrict__ sdd, double* __restrict__ Rinv,
      const float* __restrict__ H, const int* __restrict__ y, float* __restrict__ bnsum){
  int t = threadIdx.x;
  if (blockIdx.x > 0){
    d_bnpart(blockIdx.x - 1, t, H, y, bnsum);
    return;
  }
  __shared__ double gl[64][65];
  __shared__ double Xl[64][65];
  __shared__ double sdinv[64];
  __shared__ double Sl[3][16][17];
  #pragma unroll
  for (int q = 0; q < 16; q++){
    int idx = t + (q << 8);
    gl[idx >> 6][idx & 63] = L[idx];
  }
  if (t < 64) sdinv[t] = sdd[t];
  for (int idx = t; idx < 64*65; idx += 256)
    ((double*)Xl)[idx] = 0.0;
  __syncthreads();
  if (t < 64){
    int b = t >> 4, c2 = t & 15;
    int g0 = b << 4;
    int gc = g0 + c2;
    Xl[gc][gc] = sdinv[gc];
    for (int i = c2 - 1; i >= 0; i--){
      int gi = g0 + i;
      double s = 0.0;
      for (int k2 = i + 1; k2 <= c2; k2++)
        s += gl[g0 + k2][gi] * Xl[g0 + k2][gc];
      Xl[gi][gc] = -s * sdinv[gi];
    }
  }
  __syncthreads();
  for (int d = 1; d < 4; d++){
    int np = 4 - d;
    int tot = np << 8;
    for (int e = t; e < tot; e += 256){
      int p = e >> 8;
      int i = (e >> 4) & 15, jj = e & 15;
      int gi = (p << 4) + i, gj = ((p + d) << 4) + jj;
      double s = 0.0;
      int a0 = (p + 1) << 4, a1 = (p + d + 1) << 4;
      for (int a = a0; a < a1; a++)
        s += gl[a][gi] * Xl[a][gj];
      Sl[p][i][jj] = s;
    }
    __syncthreads();
    for (int e = t; e < tot; e += 256){
      int p = e >> 8;
      int i = (e >> 4) & 15, jj = e & 15;
      int gi = (p << 4) + i, gj = ((p + d) << 4) + jj;
      double s = 0.0;
      #pragma unroll
      for (int k2 = 0; k2 < 16; k2++)
        s += Xl[gi][(p << 4) + k2] * Sl[p][k2][jj];
      Xl[gi][gj] = -s;
    }
    __syncthreads();
  }
  #pragma unroll
  for (int q = 0; q < 16; q++){
    int e2 = t + (q << 8);
    Rinv[e2] = Xl[e2 >> 6][e2 & 63];
  }
}

// ---- FUSED: blocks [0,1024) = applyR; rest = bnapply(h1) ----
__global__ __launch_bounds__(256) void k_applyR_bn(const double* __restrict__ srcQ,
      const double* __restrict__ Rinv, double* __restrict__ dst,
      float* __restrict__ H, const int* __restrict__ y,
      const float* __restrict__ bnsum, const int* __restrict__ dcnt,
      const float* __restrict__ gamma, const float* __restrict__ beta,
      ushortT* __restrict__ Hbf){
  int t = threadIdx.x;
  if (blockIdx.x >= NN/4){
    int idx = (blockIdx.x - NN/4)*256 + t;
    if (idx < NN*HIDC) d_bnapply(idx, H, y, bnsum, dcnt, gamma, beta, Hbf);
    return;
  }
  __shared__ double Rs[64][65];
  #pragma unroll
  for (int q = 0; q < 16; q++){
    int idx = t + q*256;
    Rs[idx >> 6][idx & 63] = Rinv[idx];
  }
  __syncthreads();
  int r = blockIdx.x*4 + (t >> 6);
  int j = t & 63;
  const double* rowp = srcQ + (size_t)r*RK;
  double s = 0.0;
  for (int k = 0; k <= j; k++) s += rowp[k] * Rs[k][j];
  dst[(size_t)r*RK + j] = s;
}

// ---- FUSED: blocks [0,1024) = spmm64 C (4 segs/block); rest = gemm_hw2(h1) ----
__global__ __launch_bounds__(256) void k_spmmC_hw2(
    const int* __restrict__ ptr, const int* __restrict__ src, const float* __restrict__ cf,
    const double* __restrict__ X, double* __restrict__ Y,
    const ushortT* __restrict__ A, const ushortT* __restrict__ Bm,
    const ushortT* __restrict__ Bl, float* __restrict__ Ca, float* __restrict__ Cb){
  int t = threadIdx.x;
  if (blockIdx.x >= NN/4){
    d_hw2(blockIdx.x - NN/4, t, A, Bm, Bl, Ca, Cb);
    return;
  }
  int seg = blockIdx.x*4 + (t >> 6);
  int lane = t & 63;
  double acc = 0.0;
  int p0 = ptr[seg], p1 = ptr[seg+1];
  for (int p = p0; p < p1; ++p){
    acc += (double)cf[p] * X[(size_t)src[p]*RK + lane];
  }
  Y[(size_t)seg*RK + lane] = acc;
}

// ---- FUSED: blocks [0,64) = qsum; rest = paired output spmm2 (4 segs/block) ----
__global__ __launch_bounds__(256) void k_qsum_spmm2(
    const double* __restrict__ Q, double* __restrict__ qs,
    const int* __restrict__ ptr, const int* __restrict__ src, const float* __restrict__ cf,
    const float* __restrict__ Xa, const float* __restrict__ Xb2,
    float* __restrict__ zout, const float* __restrict__ self_dinv,
    const float* __restrict__ bmu, const float* __restrict__ blv){
  int t = threadIdx.x;
  if (blockIdx.x < 64){
    int j = blockIdx.x;
    double a = 0.0;
    for (int n = t; n < NN; n += 256) a += Q[(size_t)n*RK + j];
    __shared__ double sh[256];
    sh[t] = a; __syncthreads();
    for (int off = 128; off > 0; off >>= 1){ if (t < off) sh[t] += sh[t+off]; __syncthreads(); }
    if (t == 0) qs[j] = sh[0];
    return;
  }
  int bb = blockIdx.x - 64;        // 0 .. 2*NN/4-1
  int second = bb >= NN/4;
  int seg = (second ? bb - NN/4 : bb)*4 + (t >> 6);
  int lane = t & 63;
  const float* X = second ? Xb2 : Xa;
  const float* bias = second ? blv : bmu;
  float* Y = zout + (second ? (size_t)NN*OUTC : 0);
  float acc0;
  {
    float sd = self_dinv[seg];
    acc0 = sd*sd * X[(size_t)seg*OUTC + lane];
  }
  int p0 = ptr[seg], p1 = ptr[seg+1];
  for (int p = p0; p < p1; ++p){
    acc0 += cf[p] * X[(size_t)src[p]*OUTC + lane];
  }
  acc0 += bias[lane];
  Y[(size_t)seg*OUTC + lane] = acc0;
}

// ---------------- launch ----------------
extern "C" void kernel_launch(void* const* d_in, const int* in_sizes, int n_in,
                              void* d_out, int out_size, void* d_ws, size_t ws_size,
                              hipStream_t stream){
  (void)in_sizes; (void)n_in; (void)out_size;
  const void* x_in  = d_in[0];
  const int*  ei    = (const int*)d_in[1];
  const void* w_in  = d_in[2];
  const int*  yv    = (const int*)d_in[3];
  const void* W1i   = d_in[4];
  const void* b1i   = d_in[5];
  const void* Wmui  = d_in[6];
  const void* bmui  = d_in[7];
  const void* Wlvi  = d_in[8];
  const void* blvi  = d_in[9];
  const void* gmi   = d_in[10];
  const void* bti   = d_in[11];
  const int* rowA = ei;
  const int* colA = ei + NEDG;
  float* zout = (float*)d_out;

  // ---- workspace ----
  double* Dp = (double*)d_ws;
  size_t od = 0;
  double* Qd0 = Dp + od; od += (size_t)NN*RK;
  double* Qd1 = Dp + od; od += (size_t)NN*RK;
  double* Cd  = Dp + od; od += (size_t)NN*RK;
  double* Gd  = Dp + od; od += RK*RK;
  double* Rid = Dp + od; od += RK*RK;
  double* qsd = Dp + od; od += RK;
  double* sdd = Dp + od; od += RK;
  float* Fp = (float*)(Dp + od);
  size_t o = 0;
  float* xf   = Fp + o; o += (size_t)NN*INC;       // reused as h1/h2 buffer
  float* W1f  = Fp + o; o += (size_t)INC*HIDC;
  float* b1f  = Fp + o; o += HIDC;
  float* Wmuf = Fp + o; o += (size_t)HIDC*OUTC;
  float* bmuf = Fp + o; o += OUTC;
  float* Wlvf = Fp + o; o += (size_t)HIDC*OUTC;
  float* blvf = Fp + o; o += OUTC;
  float* gmf  = Fp + o; o += NDOM*HIDC;
  float* btf  = Fp + o; o += NDOM*HIDC;
  float* wf   = Fp + o; o += NEDG;
  float* xw1  = Fp + o; o += (size_t)NN*HIDC;
  float* hwA  = Fp + o; o += (size_t)NN*OUTC;
  float* hwB  = Fp + o; o += (size_t)NN*OUTC;
  float* Bf1  = Fp + o; o += (size_t)NN*RK;
  float* Cm   = Fp + o; o += (size_t)NN*RK;
  float* Qf0  = Fp + o; o += (size_t)NN*RK;
  float* Qf1  = Fp + o; o += (size_t)NN*RK;
  float* Tm   = Fp + o; o += (size_t)RK*HIDC;
  float* Umu  = Fp + o; o += 2*RK*RK;
  float* deg1 = Fp + o; o += NN;
  float* dinv1= Fp + o; o += NN;
  float* dinv2= Fp + o; o += NN;
  float* norm1= Fp + o; o += NEDG;
  float* bnsum= Fp + o; o += 8*HIDC;
  float* csrW = Fp + o; o += NEDG;
  float* cscW = Fp + o; o += NEDG;
  float* cscN = Fp + o; o += NEDG;
  ushortT* xbf   = (ushortT*)(Fp + o); o += (size_t)NN*INC/2;
  ushortT* W1bf  = (ushortT*)(Fp + o); o += (size_t)INC*HIDC/2;
  ushortT* xw1bf = (ushortT*)(Fp + o); o += (size_t)NN*HIDC/2;
  ushortT* hbf   = (ushortT*)(Fp + o); o += (size_t)NN*HIDC/2;
  ushortT* Wmubf = (ushortT*)(Fp + o); o += (size_t)HIDC*OUTC/2;
  ushortT* Wlvbf = (ushortT*)(Fp + o); o += (size_t)HIDC*OUTC/2;
  int* Ip = (int*)(Fp + o);
  size_t oi = 0;
  int* cntR = Ip + oi; oi += NN;
  int* ptrR = Ip + oi; oi += NN + 1;
  int* posR = Ip + oi; oi += NN;
  int* eidR = Ip + oi; oi += NEDG;
  int* cntC = Ip + oi; oi += NN;
  int* ptrC = Ip + oi; oi += NN + 1;
  int* posC = Ip + oi; oi += NN;
  int* eidC = Ip + oi; oi += NEDG;
  int* csrSrc = Ip + oi; oi += NEDG;
  int* cscSrc = Ip + oi; oi += NEDG;
  int* dcnt = Ip + oi; oi += NDOM;
  int* dflag= Ip + oi; oi += 1;

  size_t need = od*sizeof(double) + o*sizeof(float) + (oi+16)*sizeof(int);
  if (ws_size < need) return;

  float* hbuf = xf;  // x dead after xw1 GEMM

  const int T = 256;
  k_detect<<<1,T,0,stream>>>((const unsigned short*)x_in, dflag);
  k_upcast_all<<<cdiv(OFFT,T),T,0,stream>>>(
      x_in, W1i, w_in, Wmui, Wlvi, gmi, bti, b1i, bmui, blvi, dflag,
      xf, W1f, wf, Wmuf, Wlvf, gmf, btf, b1f, bmuf, blvf,
      xbf, W1bf, Wmubf, Wlvbf);

  k_prep<<<cdiv(NN,T),T,0,stream>>>(deg1, cntR, cntC, dcnt, bnsum);
  k_hist <<<cdiv(NEDG,T),T,0,stream>>>(rowA, colA, wf, deg1, cntR, cntC);
  k_dinv <<<cdiv(NN,T),T,0,stream>>>(deg1, dinv1, NN);
  k_norm1<<<cdiv(NEDG,T),T,0,stream>>>(rowA, colA, wf, dinv1, norm1);
  k_scan4096<<<1,1024,0,stream>>>(cntR, ptrR, posR);
  k_scan4096<<<1,1024,0,stream>>>(cntC, ptrC, posC);
  k_scatter<<<cdiv(NEDG,T),T,0,stream>>>(rowA, colA, posR, posC, eidR, eidC);
  k_edges<<<cdiv(NEDG,T),T,0,stream>>>(rowA, colA, wf, norm1, eidR, eidC,
                                       csrSrc, csrW, cscSrc, cscW, cscN);
  k_omega<<<cdiv(NN*RK,T),T,0,stream>>>(Qf0, Gd);  // f32 seed + Gd zero
  k_dcnt <<<cdiv(NN,T),T,0,stream>>>(yv, dcnt);

  // ---- branch-1 head ----
  k_gemm_bf16<<<dim3(HIDC/64, NN/64),256,0,stream>>>(xbf, W1bf, xw1, xw1bf);

  // ---- branch-2 subspace chain up to Gram ----
  k_spmm32<<<NN,64,0,stream>>>(ptrR, csrSrc, csrW, Qf0, Qf1);       // P1
  k_spmm32<<<NN,64,0,stream>>>(ptrC, cscSrc, cscW, Qf1, Qf0);       // P2
  k_spmm32<<<NN,64,0,stream>>>(ptrR, csrSrc, csrW, Qf0, Qf1);       // P3
  k_spmm32<<<NN,64,0,stream>>>(ptrC, cscSrc, cscW, Qf1, Qf0);       // P4
  k_spmm32to64<<<NN,64,0,stream>>>(ptrR, csrSrc, csrW, Qf0, Qd1);   // P5 (f64)
  k_gram64<<<NN/64,256,0,stream>>>(Qd1, Gd);

  // ---- FUSED: chol | h1 spmm ----
  k_chol_spmm<<<NN+1,256,0,stream>>>(Gd, sdd, ptrC, cscSrc, cscN, xw1bf, hbuf,
                                     dinv1, b1f);
  // ---- FUSED: trinv | bnpart(h1) ----
  k_trinv_bn<<<1+NN/32,256,0,stream>>>(Gd, sdd, Rid, hbuf, yv, bnsum);
  // ---- FUSED: applyR | bnapply(h1) ----
  k_applyR_bn<<<NN/4 + cdiv(NN*HIDC,T),256,0,stream>>>(Qd1, Rid, Qd0,
      hbuf, yv, bnsum, dcnt, gmf, btf, hbf);
  // ---- FUSED: spmm64 C | gemm_hw2(h1) ----
  k_spmmC_hw2<<<NN/4 + 2*(NN/64),256,0,stream>>>(ptrC, cscSrc, cscW, Qd0, Cd,
      hbf, Wmubf, Wlvbf, hwA, hwB);
  // ---- FUSED: qsum | output spmm2(h1) ----
  k_qsum_spmm2<<<64 + 2*(NN/4),256,0,stream>>>(Qd0, qsd, ptrC, cscSrc, cscN,
      hwA, hwB, zout, dinv1, bmuf, blvf);
  // converts + deg2f + zero Tm/Umu/bnsum
  k_fin<<<cdiv(NN*RK,T),T,0,stream>>>(Qd0, Bf1, Cd, Cm, qsd, dinv2, Tm, Umu, bnsum);

  // ---- branch-2 tail ----
  k_gemm_tn_sk<<<dim3(HIDC/16, RK/16, 8),256,0,stream>>>(RK,HIDC,NN,512, Bf1,RK, xw1,HIDC, Tm,HIDC, dinv2);
  k_gemm_nn<<<dim3(HIDC/64, NN/64),256,0,stream>>>(NN,HIDC,RK, Cm,RK, Tm,HIDC, hbuf,HIDC, dinv2, nullptr, b1f);
  k_bnpart<<<NN/32,256,0,stream>>>(hbuf, yv, bnsum);
  k_bnapply<<<cdiv(NN*HIDC,T),T,0,stream>>>(hbuf, yv, bnsum, dcnt, gmf, btf, hbf);
  k_gemm_hw2<<<2*(NN/64),256,0,stream>>>(hbf, Wmubf, Wlvbf, hwA, hwB);
  k_gemm_tn_sk2<<<dim3(RK/16, RK/16, 32),256,0,stream>>>(Bf1, hwA, hwB, Umu, dinv2);
  k_gemm_nn2<<<dim3(1, NN/64, 2),256,0,stream>>>(Cm, Umu, dinv2, bmuf, blvf, zout);
}